// Round 4
// baseline (3653.131 us; speedup 1.0000x reference)
//
#include <hip/hip_runtime.h>
#include <stdint.h>

// ---------------------------------------------------------------------------
// Net_57604101374728: GCN(x3)+BN -> maxpool | 6x belief-prop -> diffpool ->
// dense GCN(x3)+BN -> maxpool -> FC. Full fp32 port of the JAX reference.
//
// R4: R3 (XCD-resident, thread-per-element, bit-exact) + chunked-prefetch
// gather loops (MLP 8/4 instead of 1) in k_bp_step / k_gcn_agg / k_T, and
// order-preserving unroll in k_colsum_part. Edge accumulation order is
// unchanged (ascending edge id) -> FP bit-identical to R1/R3 (absmax 0.0).
// ---------------------------------------------------------------------------

constexpr int NN    = 65536;    // total nodes
constexpr int NEDGE = 524288;   // edges
constexpr int NBG   = 64;       // graphs

__constant__ int cQS[6]   = {2,4,8,16,32,64};

// ---------------- threefry2x32 (20 rounds) ----------------
__device__ __forceinline__ void tf2x32(uint32_t k0, uint32_t k1, uint32_t x0, uint32_t x1,
                                       uint32_t& o0, uint32_t& o1){
  uint32_t ks[3] = {k0, k1, k0 ^ k1 ^ 0x1BD11BDAu};
  x0 += ks[0]; x1 += ks[1];
  const int RA[4] = {13,15,26,6}, RB[4] = {17,29,16,24};
  #pragma unroll
  for (int i=0;i<5;i++){
    const int* r = (i&1)? RB : RA;
    #pragma unroll
    for (int j=0;j<4;j++){
      x0 += x1;
      x1 = (x1 << r[j]) | (x1 >> (32 - r[j]));
      x1 ^= x0;
    }
    x0 += ks[(i+1)%3];
    x1 += ks[(i+2)%3] + (uint32_t)(i+1);
  }
  o0 = x0; o1 = x1;
}

// ---------------- XLA ErfInv32 (Giles), contraction off ----------------
__device__ __forceinline__ float erfinv32(float xx){
  #pragma clang fp contract(off)
  float w = -log1pf(-xx*xx);
  float p;
  if (w < 5.0f){
    w = w - 2.5f;
    p = 2.81022636e-08f;
    p = 3.43273939e-07f  + p*w;
    p = -3.5233877e-06f  + p*w;
    p = -4.39150654e-06f + p*w;
    p = 0.00021858087f   + p*w;
    p = -0.00125372503f  + p*w;
    p = -0.00417768164f  + p*w;
    p = 0.246640727f     + p*w;
    p = 1.50140941f      + p*w;
  } else {
    w = sqrtf(w) - 3.0f;
    p = -0.000200214257f;
    p = 0.000100950558f  + p*w;
    p = 0.00134934322f   + p*w;
    p = -0.00367342844f  + p*w;
    p = 0.00573950773f   + p*w;
    p = -0.0076224613f   + p*w;
    p = 0.00943887047f   + p*w;
    p = 1.00167406f      + p*w;
    p = 2.83297682f      + p*w;
  }
  return p*xx;
}

// ---------------- CSR construction ----------------
__global__ __launch_bounds__(256) void k_count(const int* __restrict__ src, const int* __restrict__ dst,
                                               int* __restrict__ degi, int* __restrict__ dego){
  int e = blockIdx.x*256 + threadIdx.x;
  if (e >= NEDGE) return;
  atomicAdd(&degi[dst[e]], 1);
  atomicAdd(&dego[src[e]], 1);
}

__global__ __launch_bounds__(256) void k_scan1(const int* __restrict__ deg, int* __restrict__ rp,
                                               int* __restrict__ bsum){
  __shared__ int lds[256];
  int b = blockIdx.x, t = threadIdx.x;
  lds[t] = deg[b*256 + t];
  __syncthreads();
  for (int s=1;s<256;s<<=1){
    int add = (t>=s)? lds[t-s] : 0;
    __syncthreads();
    lds[t] += add;
    __syncthreads();
  }
  rp[b*256 + t + 1] = lds[t];
  if (t==0 && b==0) rp[0] = 0;
  if (t==255) bsum[b] = lds[255];
}

__global__ __launch_bounds__(256) void k_scan2(int* __restrict__ bsum){
  __shared__ int lds[256];
  int t = threadIdx.x;
  lds[t] = bsum[t];
  __syncthreads();
  for (int s=1;s<256;s<<=1){
    int add = (t>=s)? lds[t-s] : 0;
    __syncthreads();
    lds[t] += add;
    __syncthreads();
  }
  bsum[t] = (t==0)? 0 : lds[t-1];
}

__global__ __launch_bounds__(256) void k_scan3(int* __restrict__ rp, const int* __restrict__ bsum){
  int b = blockIdx.x, t = threadIdx.x;
  rp[b*256 + t + 1] += bsum[b];
}

__global__ __launch_bounds__(256) void k_fill(const int* __restrict__ key, const int* __restrict__ rp,
                                              int* __restrict__ cnt, int* __restrict__ colbuf){
  int e = blockIdx.x*256 + threadIdx.x;
  if (e >= NEDGE) return;
  int d = key[e];
  int p = atomicAdd(&cnt[d], 1);
  colbuf[rp[d] + p] = e;             // store edge id (sorted next for determinism)
}

__global__ __launch_bounds__(256) void k_sortrow(const int* __restrict__ rp, int* __restrict__ colbuf,
                                                 const int* __restrict__ other){
  int v = blockIdx.x*256 + threadIdx.x;
  if (v >= NN) return;
  int s0 = rp[v], s1 = rp[v+1];
  for (int i=s0+1;i<s1;i++){         // insertion sort by edge id ascending
    int key = colbuf[i]; int j = i-1;
    while (j>=s0 && colbuf[j]>key){ colbuf[j+1]=colbuf[j]; j--; }
    colbuf[j+1] = key;
  }
  for (int i=s0;i<s1;i++) colbuf[i] = other[colbuf[i]];
}

__global__ __launch_bounds__(256) void k_dinv(const int* __restrict__ degi, float* __restrict__ dinv){
  int v = blockIdx.x*256 + threadIdx.x;
  if (v >= NN) return;
  dinv[v] = 1.0f / sqrtf((float)(degi[v] + 1));   // +1 for self loop
}

// ---------------- stage-1 GCN ----------------
template<int CIN>
__global__ __launch_bounds__(256) void k_mm30(const float* __restrict__ x, const float* __restrict__ w,
                                              float* __restrict__ h, int nrow){
  __shared__ float ws[CIN*30];
  int t = threadIdx.x;
  for (int i=t;i<CIN*30;i+=256) ws[i] = w[i];
  __syncthreads();
  int id = blockIdx.x*256 + t;
  if (id >= nrow*30) return;
  int v = id/30, j = id - v*30;
  const float* xr = x + v*CIN;
  float acc = 0.f;
  #pragma unroll
  for (int k=0;k<CIN;k++) acc += xr[k]*ws[k*30+j];
  h[id] = acc;
}

// thread-per-element + XCD-resident mapping + chunk-4 prefetch (MLP).
__global__ __launch_bounds__(256) void k_gcn_agg(const float* __restrict__ h, const int* __restrict__ rp,
    const int* __restrict__ col, const float* __restrict__ dinv, const float* __restrict__ bias,
    float* __restrict__ y){
  int b = blockIdx.x;
  int xcd = b & 7, i = b >> 3;       // 960 per xcd
  int gs = i/120, j = i - gs*120;
  int graph = gs*8 + xcd;
  int id = graph*30720 + j*256 + threadIdx.x;
  int v = id/30, jc = id - v*30;
  float dv = dinv[v];
  float acc = 0.f;
  int a = rp[v], e = rp[v+1];
  for (; a+4<=e; a+=4){
    int s0=col[a], s1=col[a+1], s2=col[a+2], s3=col[a+3];
    float d0=dinv[s0], d1=dinv[s1], d2=dinv[s2], d3=dinv[s3];
    float h0=h[s0*30+jc], h1=h[s1*30+jc], h2=h[s2*30+jc], h3=h[s3*30+jc];
    acc += h0*(d0*dv);
    acc += h1*(d1*dv);
    acc += h2*(d2*dv);
    acc += h3*(d3*dv);
  }
  for (; a<e; ++a){
    int s = col[a];
    acc += h[s*30 + jc] * (dinv[s]*dv);
  }
  acc += h[id]*(dv*dv);      // self loop appended last (matches JAX concat order)
  y[id] = acc + bias[jc];
}

// ---------------- BatchNorm (two-pass, biased var) ----------------
__global__ __launch_bounds__(256) void k_bn_part(const float* __restrict__ x, int nrow,
    const float* __restrict__ mean, int pass, float* __restrict__ part){
  __shared__ float lds[256*31];
  int b = blockIdx.x, t = threadIdx.x;
  int rows = nrow >> 8;              // rows per block (nrow divisible by 256)
  float acc[30];
  #pragma unroll
  for (int f=0;f<30;f++) acc[f] = 0.f;
  for (int r=t; r<rows; r+=256){
    const float* xr = x + (b*rows + r)*30;
    if (pass == 0){
      #pragma unroll
      for (int f=0;f<30;f++) acc[f] += xr[f];
    } else {
      #pragma unroll
      for (int f=0;f<30;f++){ float d = xr[f]-mean[f]; acc[f] += d*d; }
    }
  }
  #pragma unroll
  for (int f=0;f<30;f++) lds[t*31+f] = acc[f];
  __syncthreads();
  for (int s=128;s>0;s>>=1){
    if (t<s){
      #pragma unroll
      for (int f=0;f<30;f++) lds[t*31+f] += lds[(t+s)*31+f];
    }
    __syncthreads();
  }
  if (t<30) part[b*30+t] = lds[t];
}

__global__ void k_bn_red(const float* __restrict__ part, float n, float* __restrict__ out){
  int f = threadIdx.x;
  if (f >= 30) return;
  float s = 0.f;
  for (int b=0;b<256;b++) s += part[b*30+f];
  out[f] = s / n;
}

__global__ __launch_bounds__(256) void k_bn_apply(const float* __restrict__ x, const float* __restrict__ mean,
    const float* __restrict__ var, const float* __restrict__ g, const float* __restrict__ be,
    float* __restrict__ out, int nrow){
  int id = blockIdx.x*256 + threadIdx.x;
  if (id >= nrow*30) return;
  int f = id % 30;
  out[id] = g[f]*(x[id]-mean[f]) * (1.0f/sqrtf(var[f]+1e-5f)) + be[f];
}

// ---------------- belief propagation (thread-per-element, XCD-resident) ----
// Flat block map: 504 blocks/graph (runs: 8,16,32,64,128,256 blocks), 8
// graphs/XCD, 32256 blocks total. Decode run from within-graph block id.
__device__ __forceinline__ void bp_decode(int b, int& graph, int& run, int& jj){
  int xcd = b & 7, i = b >> 3;
  int gs = i/504, j = i - gs*504;
  if      (j <   8){ run=0; jj=j;     }
  else if (j <  24){ run=1; jj=j-8;   }
  else if (j <  56){ run=2; jj=j-24;  }
  else if (j < 120){ run=3; jj=j-56;  }
  else if (j < 248){ run=4; jj=j-120; }
  else             { run=5; jj=j-248; }
  graph = gs*8 + xcd;
}

template<int Q, int CO, int L2Q>
__device__ __forceinline__ void bp_first_elem(int graph, int jj, float* __restrict__ psi,
                                              uint32_t k0, uint32_t k1){
  int elem = jj*256 + threadIdx.x;          // [0, 1024*Q)
  int rg = elem >> L2Q, c = elem & (Q-1);
  int row = graph*1024 + rg;
  uint32_t b0, b1;
  tf2x32(k0, k1, 0u, (uint32_t)(row*Q + c), b0, b1);   // counter = (0, idx)
  uint32_t bits = b0 ^ b1;
  float f = __uint_as_float((bits>>9) | 0x3F800000u) - 1.0f;     // [0,1)
  const float lo = __uint_as_float(0xBF7FFFFFu);                 // nextafter(-1,0)
  float u = fmaxf(lo, f*2.0f + lo);
  float v = __uint_as_float(0x3FB504F3u) * erfinv32(u);          // sqrt(2)*erfinv
  // softmax over q-lane group (same shuffle sequence as R1)
  float m = v;
  #pragma unroll
  for (int off=Q>>1; off; off>>=1) m = fmaxf(m, __shfl_xor(m, off, Q));
  float e = expf(v - m);
  float ss = e;
  #pragma unroll
  for (int off=Q>>1; off; off>>=1) ss += __shfl_xor(ss, off, Q);
  psi[row*126 + CO + c] = e / ss;
}

__global__ __launch_bounds__(256) void k_bp_first(float* __restrict__ psi){
  int graph, run, jj;
  bp_decode(blockIdx.x, graph, run, jj);
  uint32_t k0, k1;
  tf2x32(0u, 42u, 0u, (uint32_t)run, k0, k1);          // fold_in(key(42), run)
  switch(run){
    case 0: bp_first_elem< 2, 0,1>(graph, jj, psi, k0, k1); break;
    case 1: bp_first_elem< 4, 2,2>(graph, jj, psi, k0, k1); break;
    case 2: bp_first_elem< 8, 6,3>(graph, jj, psi, k0, k1); break;
    case 3: bp_first_elem<16,14,4>(graph, jj, psi, k0, k1); break;
    case 4: bp_first_elem<32,30,5>(graph, jj, psi, k0, k1); break;
    default:bp_first_elem<64,62,6>(graph, jj, psi, k0, k1); break;
  }
}

// chunk-8/4 prefetch edge loop; accumulation order ascending edge id (== R1)
template<int Q, int CO, int L2Q>
__device__ __forceinline__ void bp_step_elem(int graph, int run, int jj,
    const float* __restrict__ cur, float* __restrict__ nxt,
    const int* __restrict__ rp, const int* __restrict__ col,
    const float* __restrict__ field, float eb){
  int elem = jj*256 + threadIdx.x;
  int rg = elem >> L2Q, c = elem & (Q-1);
  int row = graph*1024 + rg;
  const float* base = cur + CO + c;
  float acc = 0.f;
  int a = rp[row], b2 = rp[row+1];
  for (; a+8<=b2; a+=8){
    int s0=col[a],s1=col[a+1],s2=col[a+2],s3=col[a+3];
    int s4=col[a+4],s5=col[a+5],s6=col[a+6],s7=col[a+7];
    float v0=base[s0*126],v1=base[s1*126],v2=base[s2*126],v3=base[s3*126];
    float v4=base[s4*126],v5=base[s5*126],v6=base[s6*126],v7=base[s7*126];
    acc += log1pf(eb*v0); acc += log1pf(eb*v1);
    acc += log1pf(eb*v2); acc += log1pf(eb*v3);
    acc += log1pf(eb*v4); acc += log1pf(eb*v5);
    acc += log1pf(eb*v6); acc += log1pf(eb*v7);
  }
  for (; a+4<=b2; a+=4){
    int s0=col[a],s1=col[a+1],s2=col[a+2],s3=col[a+3];
    float v0=base[s0*126],v1=base[s1*126],v2=base[s2*126],v3=base[s3*126];
    acc += log1pf(eb*v0); acc += log1pf(eb*v1);
    acc += log1pf(eb*v2); acc += log1pf(eb*v3);
  }
  for (; a<b2; ++a){
    int s = col[a];
    acc += log1pf(eb * base[s*126]);
  }
  float v = acc - field[run*64 + c];
  float m = v;
  #pragma unroll
  for (int off=Q>>1; off; off>>=1) m = fmaxf(m, __shfl_xor(m, off, Q));
  float e = expf(v - m);
  float ss = e;
  #pragma unroll
  for (int off=Q>>1; off; off>>=1) ss += __shfl_xor(ss, off, Q);
  nxt[row*126 + CO + c] = e / ss;
}

__global__ __launch_bounds__(256) void k_bp_step(const float* __restrict__ cur,
    float* __restrict__ nxt, const int* __restrict__ rp, const int* __restrict__ col,
    const float* __restrict__ field, const float* __restrict__ betas){
  int graph, run, jj;
  bp_decode(blockIdx.x, graph, run, jj);
  float eb = expm1f(betas[run]);
  switch(run){
    case 0: bp_step_elem< 2, 0,1>(graph, run, jj, cur, nxt, rp, col, field, eb); break;
    case 1: bp_step_elem< 4, 2,2>(graph, run, jj, cur, nxt, rp, col, field, eb); break;
    case 2: bp_step_elem< 8, 6,3>(graph, run, jj, cur, nxt, rp, col, field, eb); break;
    case 3: bp_step_elem<16,14,4>(graph, run, jj, cur, nxt, rp, col, field, eb); break;
    case 4: bp_step_elem<32,30,5>(graph, run, jj, cur, nxt, rp, col, field, eb); break;
    default:bp_step_elem<64,62,6>(graph, run, jj, cur, nxt, rp, col, field, eb); break;
  }
}

// column sums, sequential row order within 256-row chunks (order == R1);
// XCD-resident. Loads are independent; unroll keeps add order, adds MLP.
__global__ __launch_bounds__(64) void k_colsum_part(const float* __restrict__ cur, float* __restrict__ part){
  int b = blockIdx.x;
  int xcd = b & 7, i = b >> 3;       // i in [0,192)
  int gs = i/24, rem = i - gs*24;
  int run = rem >> 2, cg = rem & 3;
  int graph = gs*8 + xcd;
  int chunk = graph*4 + cg;          // global 256-row chunk id (== R1 "b")
  int q = cQS[run];
  int co = (run==0)?0:(run==1)?2:(run==2)?6:(run==3)?14:(run==4)?30:62;
  int c = threadIdx.x;
  if (c >= q) return;
  float s = 0.f;
  const float* p = cur + (size_t)chunk*256*126 + co + c;
  #pragma unroll 8
  for (int r=0;r<256;r++) s += p[r*126];
  part[(run*256 + chunk)*64 + c] = s;
}

__global__ void k_field(const float* __restrict__ part, const float* __restrict__ betas,
                        float* __restrict__ field){
  int id = threadIdx.x;              // 384 threads: 6 runs x 64 cols
  int run = id >> 6, c = id & 63;
  if (c >= cQS[run]) return;
  float s = 0.f;
  for (int b=0;b<256;b++) s += part[(run*256 + b)*64 + c];
  float beta = betas[run];
  field[id] = s * (3.8f*beta/65536.0f);
}

// ---------------- diff-pool ----------------
__global__ __launch_bounds__(256) void k_s1(const float* __restrict__ cat, const float* __restrict__ pw,
                                            const float* __restrict__ pb, float* __restrict__ s1){
  __shared__ float wl[12600];
  __shared__ float rowb[2][126];
  __shared__ float red[8];
  int t = threadIdx.x;
  for (int i=t;i<12600;i+=256) wl[i] = pw[i];
  int half = t>>7, tl = t&127, wid = t>>6;
  __syncthreads();
  for (int it=0; it<16; ++it){
    int v = blockIdx.x*32 + it*2 + half;
    if (tl < 126) rowb[half][tl] = cat[v*126 + tl];
    __syncthreads();
    float acc = -3.402823466e38f;
    if (tl < 100){
      acc = pb[tl];
      for (int j=0;j<126;j++) acc += rowb[half][j]*wl[j*100+tl];
    }
    float m = acc;
    for (int off=32; off; off>>=1) m = fmaxf(m, __shfl_xor(m, off, 64));
    if ((t&63)==0) red[wid] = m;
    __syncthreads();
    m = fmaxf(red[half*2], red[half*2+1]);
    float e = (tl<100)? expf(acc - m) : 0.f;
    float ss = e;
    for (int off=32; off; off>>=1) ss += __shfl_xor(ss, off, 64);
    if ((t&63)==0) red[4+wid] = ss;
    __syncthreads();
    float stot = red[4+half*2] + red[4+half*2+1];
    if (tl<100) s1[v*100+tl] = e/stot;
    __syncthreads();
  }
}

// thread-per-element + XCD mapping + chunk-4 prefetch.
__global__ __launch_bounds__(256) void k_T(const float* __restrict__ s1, const int* __restrict__ rp,
                                           const int* __restrict__ col, float* __restrict__ T){
  int b = blockIdx.x;
  int xcd = b & 7, i = b >> 3;       // 3200 per xcd
  int gs = i/400, j = i - gs*400;
  int graph = gs*8 + xcd;
  int id = graph*102400 + j*256 + threadIdx.x;
  int v = id/100, l = id - v*100;
  float acc = 0.f;
  int a = rp[v], e = rp[v+1];
  for (; a+4<=e; a+=4){
    int s0=col[a], s1_=col[a+1], s2=col[a+2], s3=col[a+3];
    float v0=s1[s0*100+l], v1=s1[s1_*100+l], v2=s1[s2*100+l], v3=s1[s3*100+l];
    acc += v0; acc += v1; acc += v2; acc += v3;
  }
  for (; a<e; ++a) acc += s1[col[a]*100 + l];
  T[id] = acc;
}

__global__ __launch_bounds__(128) void k_p1adj(const float* __restrict__ s1, const float* __restrict__ T,
                                               float* __restrict__ padj){
  int b  = blockIdx.x/25;
  int k0 = (blockIdx.x%25)*4;
  int l  = threadIdx.x;
  const float* s1b = s1 + b*1024*100;
  const float* Tb  = T  + b*1024*100;
  float a0=0.f,a1=0.f,a2=0.f,a3=0.f;
  for (int n=0;n<1024;n++){
    float tv = (l<100)? Tb[n*100+l] : 0.f;
    const float* sr = s1b + n*100 + k0;
    a0 += sr[0]*tv; a1 += sr[1]*tv; a2 += sr[2]*tv; a3 += sr[3]*tv;
  }
  if (l<100){
    float* o = padj + b*10000 + k0*100 + l;
    o[0]=a0; o[100]=a1; o[200]=a2; o[300]=a3;
  }
}

__global__ __launch_bounds__(128) void k_p1x(const float* __restrict__ s1, const float* __restrict__ x13,
                                             float* __restrict__ px){
  int b  = blockIdx.x/25;
  int k0 = (blockIdx.x%25)*4;
  int t = threadIdx.x;
  int j = t>>5, d = t&31;
  float acc = 0.f;
  for (int n=0;n<1024;n++){
    float xv = (d<30)? x13[(b*1024+n)*30 + d] : 0.f;
    acc += s1[(b*1024+n)*100 + k0 + j]*xv;
  }
  if (d<30) px[(b*100 + k0 + j)*30 + d] = acc;
}

// ---------------- stage-2 dense GCN ----------------
__global__ __launch_bounds__(256) void k_dinv2(const float* __restrict__ padj, float* __restrict__ dv){
  int id = blockIdx.x*256 + threadIdx.x;
  if (id >= NBG*100) return;
  const float* r = padj + id*100;
  int k = id % 100;
  float s = 0.f;
  for (int l=0;l<100;l++){
    float v = r[l];
    if (l==k) v += 1.0f;     // A = adj + I
    s += v;
  }
  dv[id] = 1.0f/sqrtf(s);
}

__global__ __launch_bounds__(256) void k_Ank(const float* __restrict__ padj, const float* __restrict__ dv,
                                             float* __restrict__ An){
  int id = blockIdx.x*256 + threadIdx.x;
  if (id >= NBG*10000) return;
  int b = id/10000;
  int rem = id - b*10000;
  int k = rem/100, l = rem - k*100;
  float a = padj[id] + ((k==l)? 1.0f : 0.0f);
  An[id] = (dv[b*100+k]*a)*dv[b*100+l];
}

__global__ __launch_bounds__(256) void k_y2(const float* __restrict__ An, const float* __restrict__ h,
    const float* __restrict__ bias, float* __restrict__ y){
  int id = blockIdx.x*256 + threadIdx.x;
  if (id >= NBG*100*30) return;
  int d = id % 30;
  int bk = id / 30;
  int b = bk / 100;
  const float* Ar = An + bk*100;
  const float* hb = h + b*100*30;
  float acc = 0.f;
  for (int l=0;l<100;l++) acc += Ar[l]*hb[l*30+d];
  y[id] = acc + bias[d];
}

// ---------------- pools + FC ----------------
__global__ __launch_bounds__(64) void k_pool(const float* __restrict__ A, const float* __restrict__ Bv,
    const float* __restrict__ Cv, int rows, float* __restrict__ conv, int coff){
  int id = blockIdx.x*64 + threadIdx.x;
  if (id >= NBG*90) return;
  int b = id/90, j = id - b*90;
  const float* X = (j<30)? A : ((j<60)? Bv : Cv);
  int f = j % 30;
  const float* p = X + (b*rows)*30 + f;
  float m = -3.402823466e38f;
  for (int i=0;i<rows;i++) m = fmaxf(m, p[i*30]);
  conv[b*180 + coff + j] = m;
}

__global__ __launch_bounds__(64) void k_fc(const float* __restrict__ conv,
    const float* __restrict__ w1, const float* __restrict__ b1,
    const float* __restrict__ w2, const float* __restrict__ b2, float* __restrict__ out){
  __shared__ float row[180];
  __shared__ float hid[50];
  int b = blockIdx.x, t = threadIdx.x;
  for (int i=t;i<180;i+=64) row[i] = conv[b*180+i];
  __syncthreads();
  if (t < 50){
    float a = b1[t];
    for (int i=0;i<180;i++) a += row[i]*w1[i*50+t];
    hid[t] = fmaxf(a, 0.f);
  }
  __syncthreads();
  if (t < 6){
    float a = b2[t];
    for (int i=0;i<50;i++) a += hid[i]*w2[i*6+t];
    out[b*6+t] = a;
  }
  if (b==0 && t==63) out[NBG*6] = 0.0f;   // second tuple output: zeros((1,))
}

// ---------------------------------------------------------------------------
extern "C" void kernel_launch(void* const* d_in, const int* in_sizes, int n_in,
                              void* d_out, int out_size, void* d_ws, size_t ws_size,
                              hipStream_t stream)
{
  (void)in_sizes; (void)n_in; (void)out_size; (void)ws_size;
  const float* x   = (const float*)d_in[0];
  const int*   src = (const int*)d_in[1];
  const int*   dst = src + NEDGE;
  const float* w11=(const float*)d_in[3],  *b11=(const float*)d_in[4],  *g11=(const float*)d_in[5],  *be11=(const float*)d_in[6];
  const float* w12=(const float*)d_in[7],  *b12=(const float*)d_in[8],  *g12=(const float*)d_in[9],  *be12=(const float*)d_in[10];
  const float* w13=(const float*)d_in[11], *b13=(const float*)d_in[12], *g13=(const float*)d_in[13], *be13=(const float*)d_in[14];
  const float* w21=(const float*)d_in[15], *b21=(const float*)d_in[16], *g21=(const float*)d_in[17], *be21=(const float*)d_in[18];
  const float* w22=(const float*)d_in[19], *b22=(const float*)d_in[20], *g22=(const float*)d_in[21], *be22=(const float*)d_in[22];
  const float* w23=(const float*)d_in[23], *b23=(const float*)d_in[24], *g23=(const float*)d_in[25], *be23=(const float*)d_in[26];
  const float* betas=(const float*)d_in[27];
  const float* poolw=(const float*)d_in[28], *poolb=(const float*)d_in[29];
  const float* fc1w=(const float*)d_in[30], *fc1b=(const float*)d_in[31];
  const float* fc2w=(const float*)d_in[32], *fc2b=(const float*)d_in[33];
  float* out = (float*)d_out;

  uint8_t* basep = (uint8_t*)d_ws;
  size_t off = 0;
  auto take = [&](size_t bytes)->void*{
    void* p = basep + off;
    off = (off + bytes + 255) & ~(size_t)255;
    return p;
  };
  int* degi    = (int*)take((size_t)NN*4);
  int* dego    = (int*)take((size_t)NN*4);
  int* cntA    = (int*)take((size_t)NN*4);
  int* cntB    = (int*)take((size_t)NN*4);
  int* rp_in   = (int*)take((size_t)(NN+1)*4);
  int* rp_out  = (int*)take((size_t)(NN+1)*4);
  int* bsum    = (int*)take(256*4);
  int* col_in  = (int*)take((size_t)NEDGE*4);
  int* col_out = (int*)take((size_t)NEDGE*4);
  float* dinv  = (float*)take((size_t)NN*4);
  float* hbuf  = (float*)take((size_t)NN*30*4);
  float* tmpY  = (float*)take((size_t)NN*30*4);
  float* X1    = (float*)take((size_t)NN*30*4);
  float* X2    = (float*)take((size_t)NN*30*4);
  float* X3    = (float*)take((size_t)NN*30*4);
  float* bufA  = (float*)take((size_t)NN*126*4);
  float* bufB  = (float*)take((size_t)NN*126*4);
  float* partCS= (float*)take((size_t)6*256*64*4);
  float* fieldv= (float*)take(384*4);
  float* partBN= (float*)take(256*30*4);
  float* meanv = (float*)take(128);
  float* varv  = (float*)take(128);
  float* px    = (float*)take(192000*4);
  float* padj  = (float*)take(640000*4);
  float* An    = (float*)take(640000*4);
  float* dinv2 = (float*)take(6400*4);
  float* h2    = (float*)take(192000*4);
  float* y2    = (float*)take(192000*4);
  float* X21   = (float*)take(192000*4);
  float* X22   = (float*)take(192000*4);
  float* X23   = (float*)take(192000*4);
  float* conv  = (float*)take(64*180*4);

  // ---- CSR setup ----
  hipMemsetAsync(degi, 0, (size_t)NN*4, stream);
  hipMemsetAsync(dego, 0, (size_t)NN*4, stream);
  hipMemsetAsync(cntA, 0, (size_t)NN*4, stream);
  hipMemsetAsync(cntB, 0, (size_t)NN*4, stream);
  k_count<<<2048,256,0,stream>>>(src,dst,degi,dego);
  k_scan1<<<256,256,0,stream>>>(degi, rp_in, bsum);
  k_scan2<<<1,256,0,stream>>>(bsum);
  k_scan3<<<256,256,0,stream>>>(rp_in, bsum);
  k_scan1<<<256,256,0,stream>>>(dego, rp_out, bsum);
  k_scan2<<<1,256,0,stream>>>(bsum);
  k_scan3<<<256,256,0,stream>>>(rp_out, bsum);
  k_fill<<<2048,256,0,stream>>>(dst, rp_in, cntA, col_in);
  k_fill<<<2048,256,0,stream>>>(src, rp_out, cntB, col_out);
  k_sortrow<<<256,256,0,stream>>>(rp_in,  col_in,  src);
  k_sortrow<<<256,256,0,stream>>>(rp_out, col_out, dst);
  k_dinv<<<256,256,0,stream>>>(degi, dinv);

  auto run_bn = [&](const float* yin, float* xout, const float* g, const float* be, int nrow){
    k_bn_part<<<256,256,0,stream>>>(yin, nrow, meanv, 0, partBN);
    k_bn_red<<<1,32,0,stream>>>(partBN, (float)nrow, meanv);
    k_bn_part<<<256,256,0,stream>>>(yin, nrow, meanv, 1, partBN);
    k_bn_red<<<1,32,0,stream>>>(partBN, (float)nrow, varv);
    k_bn_apply<<<(nrow*30)/256,256,0,stream>>>(yin, meanv, varv, g, be, xout, nrow);
  };

  // ---- stage 1: sparse GCN + BN x3 ----
  k_mm30<3><<<7680,256,0,stream>>>(x, w11, hbuf, NN);
  k_gcn_agg<<<7680,256,0,stream>>>(hbuf, rp_in, col_in, dinv, b11, tmpY);
  run_bn(tmpY, X1, g11, be11, NN);
  k_mm30<30><<<7680,256,0,stream>>>(X1, w12, hbuf, NN);
  k_gcn_agg<<<7680,256,0,stream>>>(hbuf, rp_in, col_in, dinv, b12, tmpY);
  run_bn(tmpY, X2, g12, be12, NN);
  k_mm30<30><<<7680,256,0,stream>>>(X2, w13, hbuf, NN);
  k_gcn_agg<<<7680,256,0,stream>>>(hbuf, rp_in, col_in, dinv, b13, tmpY);
  run_bn(tmpY, X3, g13, be13, NN);
  k_pool<<<90,64,0,stream>>>(X1, X2, X3, 1024, conv, 0);

  // ---- belief propagation ([NN][126] layout, ping-pong A/B) ----
  k_bp_first<<<32256,256,0,stream>>>(bufA);
  float* cur = bufA; float* nxt = bufB;
  for (int it=0; it<10; ++it){
    k_colsum_part<<<1536,64,0,stream>>>(cur, partCS);
    k_field<<<1,384,0,stream>>>(partCS, betas, fieldv);
    k_bp_step<<<32256,256,0,stream>>>(cur, nxt, rp_in, col_in, fieldv, betas);
    float* tp = cur; cur = nxt; nxt = tp;
  }
  // final concatenated psi [NN][126] now in bufA (10 swaps -> back to bufA)

  // ---- diff-pool ----
  k_s1<<<2048,256,0,stream>>>(bufA, poolw, poolb, bufB);      // s1 [n,100] -> bufB
  k_T<<<25600,256,0,stream>>>(bufB, rp_out, col_out, bufA);   // T = A*s1   -> bufA
  k_p1adj<<<1600,128,0,stream>>>(bufB, bufA, padj);
  k_p1x<<<1600,128,0,stream>>>(bufB, X3, px);
  k_dinv2<<<25,256,0,stream>>>(padj, dinv2);
  k_Ank<<<2500,256,0,stream>>>(padj, dinv2, An);

  // ---- stage 2: dense GCN + BN x3 ----
  auto gcn2 = [&](const float* xin, const float* w, const float* bb, const float* g,
                  const float* be, float* xout){
    k_mm30<30><<<750,256,0,stream>>>(xin, w, h2, NBG*100);
    k_y2<<<750,256,0,stream>>>(An, h2, bb, y2);
    run_bn(y2, xout, g, be, NBG*100);
  };
  gcn2(px,  w21, b21, g21, be21, X21);
  gcn2(X21, w22, b22, g22, be22, X22);
  gcn2(X22, w23, b23, g23, be23, X23);
  k_pool<<<90,64,0,stream>>>(X21, X22, X23, 100, conv, 90);

  // ---- FC head ----
  k_fc<<<64,64,0,stream>>>(conv, fc1w, fc1b, fc2w, fc2b, out);
}

// Round 5
// 1969.380 us; speedup vs baseline: 1.8550x; 1.8550x over previous
//
#include <hip/hip_runtime.h>
#include <stdint.h>

// ---------------------------------------------------------------------------
// Net_57604101374728: GCN(x3)+BN -> maxpool | 6x belief-prop -> diffpool ->
// dense GCN(x3)+BN -> maxpool -> FC. Full fp32 port of the JAX reference.
//
// R5: R3/R4 structure + log1p hoisting: each bp step writes BOTH psi and
// L = log1pf(eb*psi); the next step's edge loop gathers precomputed L and
// just adds (66M -> 16.5M transcendentals per step). Accumulation order and
// all FP bit patterns unchanged vs R1/R3/R4 (absmax 0.0).
// ---------------------------------------------------------------------------

constexpr int NN    = 65536;    // total nodes
constexpr int NEDGE = 524288;   // edges
constexpr int NBG   = 64;       // graphs

__constant__ int cQS[6]   = {2,4,8,16,32,64};

// ---------------- threefry2x32 (20 rounds) ----------------
__device__ __forceinline__ void tf2x32(uint32_t k0, uint32_t k1, uint32_t x0, uint32_t x1,
                                       uint32_t& o0, uint32_t& o1){
  uint32_t ks[3] = {k0, k1, k0 ^ k1 ^ 0x1BD11BDAu};
  x0 += ks[0]; x1 += ks[1];
  const int RA[4] = {13,15,26,6}, RB[4] = {17,29,16,24};
  #pragma unroll
  for (int i=0;i<5;i++){
    const int* r = (i&1)? RB : RA;
    #pragma unroll
    for (int j=0;j<4;j++){
      x0 += x1;
      x1 = (x1 << r[j]) | (x1 >> (32 - r[j]));
      x1 ^= x0;
    }
    x0 += ks[(i+1)%3];
    x1 += ks[(i+2)%3] + (uint32_t)(i+1);
  }
  o0 = x0; o1 = x1;
}

// ---------------- XLA ErfInv32 (Giles), contraction off ----------------
__device__ __forceinline__ float erfinv32(float xx){
  #pragma clang fp contract(off)
  float w = -log1pf(-xx*xx);
  float p;
  if (w < 5.0f){
    w = w - 2.5f;
    p = 2.81022636e-08f;
    p = 3.43273939e-07f  + p*w;
    p = -3.5233877e-06f  + p*w;
    p = -4.39150654e-06f + p*w;
    p = 0.00021858087f   + p*w;
    p = -0.00125372503f  + p*w;
    p = -0.00417768164f  + p*w;
    p = 0.246640727f     + p*w;
    p = 1.50140941f      + p*w;
  } else {
    w = sqrtf(w) - 3.0f;
    p = -0.000200214257f;
    p = 0.000100950558f  + p*w;
    p = 0.00134934322f   + p*w;
    p = -0.00367342844f  + p*w;
    p = 0.00573950773f   + p*w;
    p = -0.0076224613f   + p*w;
    p = 0.00943887047f   + p*w;
    p = 1.00167406f      + p*w;
    p = 2.83297682f      + p*w;
  }
  return p*xx;
}

// ---------------- CSR construction ----------------
__global__ __launch_bounds__(256) void k_count(const int* __restrict__ src, const int* __restrict__ dst,
                                               int* __restrict__ degi, int* __restrict__ dego){
  int e = blockIdx.x*256 + threadIdx.x;
  if (e >= NEDGE) return;
  atomicAdd(&degi[dst[e]], 1);
  atomicAdd(&dego[src[e]], 1);
}

__global__ __launch_bounds__(256) void k_scan1(const int* __restrict__ deg, int* __restrict__ rp,
                                               int* __restrict__ bsum){
  __shared__ int lds[256];
  int b = blockIdx.x, t = threadIdx.x;
  lds[t] = deg[b*256 + t];
  __syncthreads();
  for (int s=1;s<256;s<<=1){
    int add = (t>=s)? lds[t-s] : 0;
    __syncthreads();
    lds[t] += add;
    __syncthreads();
  }
  rp[b*256 + t + 1] = lds[t];
  if (t==0 && b==0) rp[0] = 0;
  if (t==255) bsum[b] = lds[255];
}

__global__ __launch_bounds__(256) void k_scan2(int* __restrict__ bsum){
  __shared__ int lds[256];
  int t = threadIdx.x;
  lds[t] = bsum[t];
  __syncthreads();
  for (int s=1;s<256;s<<=1){
    int add = (t>=s)? lds[t-s] : 0;
    __syncthreads();
    lds[t] += add;
    __syncthreads();
  }
  bsum[t] = (t==0)? 0 : lds[t-1];
}

__global__ __launch_bounds__(256) void k_scan3(int* __restrict__ rp, const int* __restrict__ bsum){
  int b = blockIdx.x, t = threadIdx.x;
  rp[b*256 + t + 1] += bsum[b];
}

__global__ __launch_bounds__(256) void k_fill(const int* __restrict__ key, const int* __restrict__ rp,
                                              int* __restrict__ cnt, int* __restrict__ colbuf){
  int e = blockIdx.x*256 + threadIdx.x;
  if (e >= NEDGE) return;
  int d = key[e];
  int p = atomicAdd(&cnt[d], 1);
  colbuf[rp[d] + p] = e;             // store edge id (sorted next for determinism)
}

__global__ __launch_bounds__(256) void k_sortrow(const int* __restrict__ rp, int* __restrict__ colbuf,
                                                 const int* __restrict__ other){
  int v = blockIdx.x*256 + threadIdx.x;
  if (v >= NN) return;
  int s0 = rp[v], s1 = rp[v+1];
  for (int i=s0+1;i<s1;i++){         // insertion sort by edge id ascending
    int key = colbuf[i]; int j = i-1;
    while (j>=s0 && colbuf[j]>key){ colbuf[j+1]=colbuf[j]; j--; }
    colbuf[j+1] = key;
  }
  for (int i=s0;i<s1;i++) colbuf[i] = other[colbuf[i]];
}

__global__ __launch_bounds__(256) void k_dinv(const int* __restrict__ degi, float* __restrict__ dinv){
  int v = blockIdx.x*256 + threadIdx.x;
  if (v >= NN) return;
  dinv[v] = 1.0f / sqrtf((float)(degi[v] + 1));   // +1 for self loop
}

// ---------------- stage-1 GCN ----------------
template<int CIN>
__global__ __launch_bounds__(256) void k_mm30(const float* __restrict__ x, const float* __restrict__ w,
                                              float* __restrict__ h, int nrow){
  __shared__ float ws[CIN*30];
  int t = threadIdx.x;
  for (int i=t;i<CIN*30;i+=256) ws[i] = w[i];
  __syncthreads();
  int id = blockIdx.x*256 + t;
  if (id >= nrow*30) return;
  int v = id/30, j = id - v*30;
  const float* xr = x + v*CIN;
  float acc = 0.f;
  #pragma unroll
  for (int k=0;k<CIN;k++) acc += xr[k]*ws[k*30+j];
  h[id] = acc;
}

// thread-per-element + XCD-resident mapping + chunk-4 prefetch (MLP).
__global__ __launch_bounds__(256) void k_gcn_agg(const float* __restrict__ h, const int* __restrict__ rp,
    const int* __restrict__ col, const float* __restrict__ dinv, const float* __restrict__ bias,
    float* __restrict__ y){
  int b = blockIdx.x;
  int xcd = b & 7, i = b >> 3;       // 960 per xcd
  int gs = i/120, j = i - gs*120;
  int graph = gs*8 + xcd;
  int id = graph*30720 + j*256 + threadIdx.x;
  int v = id/30, jc = id - v*30;
  float dv = dinv[v];
  float acc = 0.f;
  int a = rp[v], e = rp[v+1];
  for (; a+4<=e; a+=4){
    int s0=col[a], s1=col[a+1], s2=col[a+2], s3=col[a+3];
    float d0=dinv[s0], d1=dinv[s1], d2=dinv[s2], d3=dinv[s3];
    float h0=h[s0*30+jc], h1=h[s1*30+jc], h2=h[s2*30+jc], h3=h[s3*30+jc];
    acc += h0*(d0*dv);
    acc += h1*(d1*dv);
    acc += h2*(d2*dv);
    acc += h3*(d3*dv);
  }
  for (; a<e; ++a){
    int s = col[a];
    acc += h[s*30 + jc] * (dinv[s]*dv);
  }
  acc += h[id]*(dv*dv);      // self loop appended last (matches JAX concat order)
  y[id] = acc + bias[jc];
}

// ---------------- BatchNorm (two-pass, biased var) ----------------
__global__ __launch_bounds__(256) void k_bn_part(const float* __restrict__ x, int nrow,
    const float* __restrict__ mean, int pass, float* __restrict__ part){
  __shared__ float lds[256*31];
  int b = blockIdx.x, t = threadIdx.x;
  int rows = nrow >> 8;              // rows per block (nrow divisible by 256)
  float acc[30];
  #pragma unroll
  for (int f=0;f<30;f++) acc[f] = 0.f;
  for (int r=t; r<rows; r+=256){
    const float* xr = x + (b*rows + r)*30;
    if (pass == 0){
      #pragma unroll
      for (int f=0;f<30;f++) acc[f] += xr[f];
    } else {
      #pragma unroll
      for (int f=0;f<30;f++){ float d = xr[f]-mean[f]; acc[f] += d*d; }
    }
  }
  #pragma unroll
  for (int f=0;f<30;f++) lds[t*31+f] = acc[f];
  __syncthreads();
  for (int s=128;s>0;s>>=1){
    if (t<s){
      #pragma unroll
      for (int f=0;f<30;f++) lds[t*31+f] += lds[(t+s)*31+f];
    }
    __syncthreads();
  }
  if (t<30) part[b*30+t] = lds[t];
}

__global__ void k_bn_red(const float* __restrict__ part, float n, float* __restrict__ out){
  int f = threadIdx.x;
  if (f >= 30) return;
  float s = 0.f;
  for (int b=0;b<256;b++) s += part[b*30+f];
  out[f] = s / n;
}

__global__ __launch_bounds__(256) void k_bn_apply(const float* __restrict__ x, const float* __restrict__ mean,
    const float* __restrict__ var, const float* __restrict__ g, const float* __restrict__ be,
    float* __restrict__ out, int nrow){
  int id = blockIdx.x*256 + threadIdx.x;
  if (id >= nrow*30) return;
  int f = id % 30;
  out[id] = g[f]*(x[id]-mean[f]) * (1.0f/sqrtf(var[f]+1e-5f)) + be[f];
}

// ---------------- belief propagation (thread-per-element, XCD-resident) ----
// Flat block map: 504 blocks/graph (runs: 8,16,32,64,128,256 blocks), 8
// graphs/XCD, 32256 blocks total. Decode run from within-graph block id.
__device__ __forceinline__ void bp_decode(int b, int& graph, int& run, int& jj){
  int xcd = b & 7, i = b >> 3;
  int gs = i/504, j = i - gs*504;
  if      (j <   8){ run=0; jj=j;     }
  else if (j <  24){ run=1; jj=j-8;   }
  else if (j <  56){ run=2; jj=j-24;  }
  else if (j < 120){ run=3; jj=j-56;  }
  else if (j < 248){ run=4; jj=j-120; }
  else             { run=5; jj=j-248; }
  graph = gs*8 + xcd;
}

template<int Q, int CO, int L2Q>
__device__ __forceinline__ void bp_first_elem(int graph, int jj, float* __restrict__ psi,
                                              float* __restrict__ lg, float eb,
                                              uint32_t k0, uint32_t k1){
  int elem = jj*256 + threadIdx.x;          // [0, 1024*Q)
  int rg = elem >> L2Q, c = elem & (Q-1);
  int row = graph*1024 + rg;
  uint32_t b0, b1;
  tf2x32(k0, k1, 0u, (uint32_t)(row*Q + c), b0, b1);   // counter = (0, idx)
  uint32_t bits = b0 ^ b1;
  float f = __uint_as_float((bits>>9) | 0x3F800000u) - 1.0f;     // [0,1)
  const float lo = __uint_as_float(0xBF7FFFFFu);                 // nextafter(-1,0)
  float u = fmaxf(lo, f*2.0f + lo);
  float v = __uint_as_float(0x3FB504F3u) * erfinv32(u);          // sqrt(2)*erfinv
  // softmax over q-lane group (same shuffle sequence as R1)
  float m = v;
  #pragma unroll
  for (int off=Q>>1; off; off>>=1) m = fmaxf(m, __shfl_xor(m, off, Q));
  float e = expf(v - m);
  float ss = e;
  #pragma unroll
  for (int off=Q>>1; off; off>>=1) ss += __shfl_xor(ss, off, Q);
  float pn = e / ss;
  psi[row*126 + CO + c] = pn;
  lg [row*126 + CO + c] = log1pf(eb*pn);
}

__global__ __launch_bounds__(256) void k_bp_first(float* __restrict__ psi, float* __restrict__ lg,
                                                  const float* __restrict__ betas){
  int graph, run, jj;
  bp_decode(blockIdx.x, graph, run, jj);
  uint32_t k0, k1;
  tf2x32(0u, 42u, 0u, (uint32_t)run, k0, k1);          // fold_in(key(42), run)
  float eb = expm1f(betas[run]);
  switch(run){
    case 0: bp_first_elem< 2, 0,1>(graph, jj, psi, lg, eb, k0, k1); break;
    case 1: bp_first_elem< 4, 2,2>(graph, jj, psi, lg, eb, k0, k1); break;
    case 2: bp_first_elem< 8, 6,3>(graph, jj, psi, lg, eb, k0, k1); break;
    case 3: bp_first_elem<16,14,4>(graph, jj, psi, lg, eb, k0, k1); break;
    case 4: bp_first_elem<32,30,5>(graph, jj, psi, lg, eb, k0, k1); break;
    default:bp_first_elem<64,62,6>(graph, jj, psi, lg, eb, k0, k1); break;
  }
}

// edge loop gathers PRECOMPUTED L = log1p(eb*psi) and just sums (order ==
// ascending edge id, bit-identical); epilogue writes psi_new and L_new.
template<int Q, int CO, int L2Q>
__device__ __forceinline__ void bp_step_elem(int graph, int run, int jj,
    const float* __restrict__ lcur, float* __restrict__ nxt, float* __restrict__ lnxt,
    const int* __restrict__ rp, const int* __restrict__ col,
    const float* __restrict__ field, float eb){
  int elem = jj*256 + threadIdx.x;
  int rg = elem >> L2Q, c = elem & (Q-1);
  int row = graph*1024 + rg;
  const float* base = lcur + CO + c;
  float acc = 0.f;
  int a = rp[row], b2 = rp[row+1];
  for (; a+8<=b2; a+=8){
    int s0=col[a],s1=col[a+1],s2=col[a+2],s3=col[a+3];
    int s4=col[a+4],s5=col[a+5],s6=col[a+6],s7=col[a+7];
    float v0=base[s0*126],v1=base[s1*126],v2=base[s2*126],v3=base[s3*126];
    float v4=base[s4*126],v5=base[s5*126],v6=base[s6*126],v7=base[s7*126];
    acc += v0; acc += v1; acc += v2; acc += v3;
    acc += v4; acc += v5; acc += v6; acc += v7;
  }
  for (; a+4<=b2; a+=4){
    int s0=col[a],s1=col[a+1],s2=col[a+2],s3=col[a+3];
    float v0=base[s0*126],v1=base[s1*126],v2=base[s2*126],v3=base[s3*126];
    acc += v0; acc += v1; acc += v2; acc += v3;
  }
  for (; a<b2; ++a){
    acc += base[col[a]*126];
  }
  float v = acc - field[run*64 + c];
  float m = v;
  #pragma unroll
  for (int off=Q>>1; off; off>>=1) m = fmaxf(m, __shfl_xor(m, off, Q));
  float e = expf(v - m);
  float ss = e;
  #pragma unroll
  for (int off=Q>>1; off; off>>=1) ss += __shfl_xor(ss, off, Q);
  float pn = e / ss;
  nxt [row*126 + CO + c] = pn;
  lnxt[row*126 + CO + c] = log1pf(eb*pn);
}

__global__ __launch_bounds__(256) void k_bp_step(
    float* __restrict__ nxt, const float* __restrict__ lcur, float* __restrict__ lnxt,
    const int* __restrict__ rp, const int* __restrict__ col,
    const float* __restrict__ field, const float* __restrict__ betas){
  int graph, run, jj;
  bp_decode(blockIdx.x, graph, run, jj);
  float eb = expm1f(betas[run]);
  switch(run){
    case 0: bp_step_elem< 2, 0,1>(graph, run, jj, lcur, nxt, lnxt, rp, col, field, eb); break;
    case 1: bp_step_elem< 4, 2,2>(graph, run, jj, lcur, nxt, lnxt, rp, col, field, eb); break;
    case 2: bp_step_elem< 8, 6,3>(graph, run, jj, lcur, nxt, lnxt, rp, col, field, eb); break;
    case 3: bp_step_elem<16,14,4>(graph, run, jj, lcur, nxt, lnxt, rp, col, field, eb); break;
    case 4: bp_step_elem<32,30,5>(graph, run, jj, lcur, nxt, lnxt, rp, col, field, eb); break;
    default:bp_step_elem<64,62,6>(graph, run, jj, lcur, nxt, lnxt, rp, col, field, eb); break;
  }
}

// column sums, sequential row order within 256-row chunks (order == R1);
// XCD-resident. Loads are independent; unroll keeps add order, adds MLP.
__global__ __launch_bounds__(64) void k_colsum_part(const float* __restrict__ cur, float* __restrict__ part){
  int b = blockIdx.x;
  int xcd = b & 7, i = b >> 3;       // i in [0,192)
  int gs = i/24, rem = i - gs*24;
  int run = rem >> 2, cg = rem & 3;
  int graph = gs*8 + xcd;
  int chunk = graph*4 + cg;          // global 256-row chunk id (== R1 "b")
  int q = cQS[run];
  int co = (run==0)?0:(run==1)?2:(run==2)?6:(run==3)?14:(run==4)?30:62;
  int c = threadIdx.x;
  if (c >= q) return;
  float s = 0.f;
  const float* p = cur + (size_t)chunk*256*126 + co + c;
  #pragma unroll 8
  for (int r=0;r<256;r++) s += p[r*126];
  part[(run*256 + chunk)*64 + c] = s;
}

__global__ void k_field(const float* __restrict__ part, const float* __restrict__ betas,
                        float* __restrict__ field){
  int id = threadIdx.x;              // 384 threads: 6 runs x 64 cols
  int run = id >> 6, c = id & 63;
  if (c >= cQS[run]) return;
  float s = 0.f;
  for (int b=0;b<256;b++) s += part[(run*256 + b)*64 + c];
  float beta = betas[run];
  field[id] = s * (3.8f*beta/65536.0f);
}

// ---------------- diff-pool ----------------
__global__ __launch_bounds__(256) void k_s1(const float* __restrict__ cat, const float* __restrict__ pw,
                                            const float* __restrict__ pb, float* __restrict__ s1){
  __shared__ float wl[12600];
  __shared__ float rowb[2][126];
  __shared__ float red[8];
  int t = threadIdx.x;
  for (int i=t;i<12600;i+=256) wl[i] = pw[i];
  int half = t>>7, tl = t&127, wid = t>>6;
  __syncthreads();
  for (int it=0; it<16; ++it){
    int v = blockIdx.x*32 + it*2 + half;
    if (tl < 126) rowb[half][tl] = cat[v*126 + tl];
    __syncthreads();
    float acc = -3.402823466e38f;
    if (tl < 100){
      acc = pb[tl];
      for (int j=0;j<126;j++) acc += rowb[half][j]*wl[j*100+tl];
    }
    float m = acc;
    for (int off=32; off; off>>=1) m = fmaxf(m, __shfl_xor(m, off, 64));
    if ((t&63)==0) red[wid] = m;
    __syncthreads();
    m = fmaxf(red[half*2], red[half*2+1]);
    float e = (tl<100)? expf(acc - m) : 0.f;
    float ss = e;
    for (int off=32; off; off>>=1) ss += __shfl_xor(ss, off, 64);
    if ((t&63)==0) red[4+wid] = ss;
    __syncthreads();
    float stot = red[4+half*2] + red[4+half*2+1];
    if (tl<100) s1[v*100+tl] = e/stot;
    __syncthreads();
  }
}

// thread-per-element + XCD mapping + chunk-4 prefetch.
__global__ __launch_bounds__(256) void k_T(const float* __restrict__ s1, const int* __restrict__ rp,
                                           const int* __restrict__ col, float* __restrict__ T){
  int b = blockIdx.x;
  int xcd = b & 7, i = b >> 3;       // 3200 per xcd
  int gs = i/400, j = i - gs*400;
  int graph = gs*8 + xcd;
  int id = graph*102400 + j*256 + threadIdx.x;
  int v = id/100, l = id - v*100;
  float acc = 0.f;
  int a = rp[v], e = rp[v+1];
  for (; a+4<=e; a+=4){
    int s0=col[a], s1_=col[a+1], s2=col[a+2], s3=col[a+3];
    float v0=s1[s0*100+l], v1=s1[s1_*100+l], v2=s1[s2*100+l], v3=s1[s3*100+l];
    acc += v0; acc += v1; acc += v2; acc += v3;
  }
  for (; a<e; ++a) acc += s1[col[a]*100 + l];
  T[id] = acc;
}

__global__ __launch_bounds__(128) void k_p1adj(const float* __restrict__ s1, const float* __restrict__ T,
                                               float* __restrict__ padj){
  int b  = blockIdx.x/25;
  int k0 = (blockIdx.x%25)*4;
  int l  = threadIdx.x;
  const float* s1b = s1 + b*1024*100;
  const float* Tb  = T  + b*1024*100;
  float a0=0.f,a1=0.f,a2=0.f,a3=0.f;
  for (int n=0;n<1024;n++){
    float tv = (l<100)? Tb[n*100+l] : 0.f;
    const float* sr = s1b + n*100 + k0;
    a0 += sr[0]*tv; a1 += sr[1]*tv; a2 += sr[2]*tv; a3 += sr[3]*tv;
  }
  if (l<100){
    float* o = padj + b*10000 + k0*100 + l;
    o[0]=a0; o[100]=a1; o[200]=a2; o[300]=a3;
  }
}

__global__ __launch_bounds__(128) void k_p1x(const float* __restrict__ s1, const float* __restrict__ x13,
                                             float* __restrict__ px){
  int b  = blockIdx.x/25;
  int k0 = (blockIdx.x%25)*4;
  int t = threadIdx.x;
  int j = t>>5, d = t&31;
  float acc = 0.f;
  for (int n=0;n<1024;n++){
    float xv = (d<30)? x13[(b*1024+n)*30 + d] : 0.f;
    acc += s1[(b*1024+n)*100 + k0 + j]*xv;
  }
  if (d<30) px[(b*100 + k0 + j)*30 + d] = acc;
}

// ---------------- stage-2 dense GCN ----------------
__global__ __launch_bounds__(256) void k_dinv2(const float* __restrict__ padj, float* __restrict__ dv){
  int id = blockIdx.x*256 + threadIdx.x;
  if (id >= NBG*100) return;
  const float* r = padj + id*100;
  int k = id % 100;
  float s = 0.f;
  for (int l=0;l<100;l++){
    float v = r[l];
    if (l==k) v += 1.0f;     // A = adj + I
    s += v;
  }
  dv[id] = 1.0f/sqrtf(s);
}

__global__ __launch_bounds__(256) void k_Ank(const float* __restrict__ padj, const float* __restrict__ dv,
                                             float* __restrict__ An){
  int id = blockIdx.x*256 + threadIdx.x;
  if (id >= NBG*10000) return;
  int b = id/10000;
  int rem = id - b*10000;
  int k = rem/100, l = rem - k*100;
  float a = padj[id] + ((k==l)? 1.0f : 0.0f);
  An[id] = (dv[b*100+k]*a)*dv[b*100+l];
}

__global__ __launch_bounds__(256) void k_y2(const float* __restrict__ An, const float* __restrict__ h,
    const float* __restrict__ bias, float* __restrict__ y){
  int id = blockIdx.x*256 + threadIdx.x;
  if (id >= NBG*100*30) return;
  int d = id % 30;
  int bk = id / 30;
  int b = bk / 100;
  const float* Ar = An + bk*100;
  const float* hb = h + b*100*30;
  float acc = 0.f;
  for (int l=0;l<100;l++) acc += Ar[l]*hb[l*30+d];
  y[id] = acc + bias[d];
}

// ---------------- pools + FC ----------------
__global__ __launch_bounds__(64) void k_pool(const float* __restrict__ A, const float* __restrict__ Bv,
    const float* __restrict__ Cv, int rows, float* __restrict__ conv, int coff){
  int id = blockIdx.x*64 + threadIdx.x;
  if (id >= NBG*90) return;
  int b = id/90, j = id - b*90;
  const float* X = (j<30)? A : ((j<60)? Bv : Cv);
  int f = j % 30;
  const float* p = X + (b*rows)*30 + f;
  float m = -3.402823466e38f;
  for (int i=0;i<rows;i++) m = fmaxf(m, p[i*30]);
  conv[b*180 + coff + j] = m;
}

__global__ __launch_bounds__(64) void k_fc(const float* __restrict__ conv,
    const float* __restrict__ w1, const float* __restrict__ b1,
    const float* __restrict__ w2, const float* __restrict__ b2, float* __restrict__ out){
  __shared__ float row[180];
  __shared__ float hid[50];
  int b = blockIdx.x, t = threadIdx.x;
  for (int i=t;i<180;i+=64) row[i] = conv[b*180+i];
  __syncthreads();
  if (t < 50){
    float a = b1[t];
    for (int i=0;i<180;i++) a += row[i]*w1[i*50+t];
    hid[t] = fmaxf(a, 0.f);
  }
  __syncthreads();
  if (t < 6){
    float a = b2[t];
    for (int i=0;i<50;i++) a += hid[i]*w2[i*6+t];
    out[b*6+t] = a;
  }
  if (b==0 && t==63) out[NBG*6] = 0.0f;   // second tuple output: zeros((1,))
}

// ---------------------------------------------------------------------------
extern "C" void kernel_launch(void* const* d_in, const int* in_sizes, int n_in,
                              void* d_out, int out_size, void* d_ws, size_t ws_size,
                              hipStream_t stream)
{
  (void)in_sizes; (void)n_in; (void)out_size; (void)ws_size;
  const float* x   = (const float*)d_in[0];
  const int*   src = (const int*)d_in[1];
  const int*   dst = src + NEDGE;
  const float* w11=(const float*)d_in[3],  *b11=(const float*)d_in[4],  *g11=(const float*)d_in[5],  *be11=(const float*)d_in[6];
  const float* w12=(const float*)d_in[7],  *b12=(const float*)d_in[8],  *g12=(const float*)d_in[9],  *be12=(const float*)d_in[10];
  const float* w13=(const float*)d_in[11], *b13=(const float*)d_in[12], *g13=(const float*)d_in[13], *be13=(const float*)d_in[14];
  const float* w21=(const float*)d_in[15], *b21=(const float*)d_in[16], *g21=(const float*)d_in[17], *be21=(const float*)d_in[18];
  const float* w22=(const float*)d_in[19], *b22=(const float*)d_in[20], *g22=(const float*)d_in[21], *be22=(const float*)d_in[22];
  const float* w23=(const float*)d_in[23], *b23=(const float*)d_in[24], *g23=(const float*)d_in[25], *be23=(const float*)d_in[26];
  const float* betas=(const float*)d_in[27];
  const float* poolw=(const float*)d_in[28], *poolb=(const float*)d_in[29];
  const float* fc1w=(const float*)d_in[30], *fc1b=(const float*)d_in[31];
  const float* fc2w=(const float*)d_in[32], *fc2b=(const float*)d_in[33];
  float* out = (float*)d_out;

  uint8_t* basep = (uint8_t*)d_ws;
  size_t off = 0;
  auto take = [&](size_t bytes)->void*{
    void* p = basep + off;
    off = (off + bytes + 255) & ~(size_t)255;
    return p;
  };
  int* degi    = (int*)take((size_t)NN*4);
  int* dego    = (int*)take((size_t)NN*4);
  int* cntA    = (int*)take((size_t)NN*4);
  int* cntB    = (int*)take((size_t)NN*4);
  int* rp_in   = (int*)take((size_t)(NN+1)*4);
  int* rp_out  = (int*)take((size_t)(NN+1)*4);
  int* bsum    = (int*)take(256*4);
  int* col_in  = (int*)take((size_t)NEDGE*4);
  int* col_out = (int*)take((size_t)NEDGE*4);
  float* dinv  = (float*)take((size_t)NN*4);
  float* hbuf  = (float*)take((size_t)NN*30*4);
  float* tmpY  = (float*)take((size_t)NN*30*4);
  float* X1    = (float*)take((size_t)NN*30*4);
  float* X2    = (float*)take((size_t)NN*30*4);
  float* X3    = (float*)take((size_t)NN*30*4);
  float* bufA  = (float*)take((size_t)NN*126*4);
  float* bufB  = (float*)take((size_t)NN*126*4);
  float* logA  = (float*)take((size_t)NN*126*4);
  float* logB  = (float*)take((size_t)NN*126*4);
  float* partCS= (float*)take((size_t)6*256*64*4);
  float* fieldv= (float*)take(384*4);
  float* partBN= (float*)take(256*30*4);
  float* meanv = (float*)take(128);
  float* varv  = (float*)take(128);
  float* px    = (float*)take(192000*4);
  float* padj  = (float*)take(640000*4);
  float* An    = (float*)take(640000*4);
  float* dinv2 = (float*)take(6400*4);
  float* h2    = (float*)take(192000*4);
  float* y2    = (float*)take(192000*4);
  float* X21   = (float*)take(192000*4);
  float* X22   = (float*)take(192000*4);
  float* X23   = (float*)take(192000*4);
  float* conv  = (float*)take(64*180*4);

  // ---- CSR setup ----
  hipMemsetAsync(degi, 0, (size_t)NN*4, stream);
  hipMemsetAsync(dego, 0, (size_t)NN*4, stream);
  hipMemsetAsync(cntA, 0, (size_t)NN*4, stream);
  hipMemsetAsync(cntB, 0, (size_t)NN*4, stream);
  k_count<<<2048,256,0,stream>>>(src,dst,degi,dego);
  k_scan1<<<256,256,0,stream>>>(degi, rp_in, bsum);
  k_scan2<<<1,256,0,stream>>>(bsum);
  k_scan3<<<256,256,0,stream>>>(rp_in, bsum);
  k_scan1<<<256,256,0,stream>>>(dego, rp_out, bsum);
  k_scan2<<<1,256,0,stream>>>(bsum);
  k_scan3<<<256,256,0,stream>>>(rp_out, bsum);
  k_fill<<<2048,256,0,stream>>>(dst, rp_in, cntA, col_in);
  k_fill<<<2048,256,0,stream>>>(src, rp_out, cntB, col_out);
  k_sortrow<<<256,256,0,stream>>>(rp_in,  col_in,  src);
  k_sortrow<<<256,256,0,stream>>>(rp_out, col_out, dst);
  k_dinv<<<256,256,0,stream>>>(degi, dinv);

  auto run_bn = [&](const float* yin, float* xout, const float* g, const float* be, int nrow){
    k_bn_part<<<256,256,0,stream>>>(yin, nrow, meanv, 0, partBN);
    k_bn_red<<<1,32,0,stream>>>(partBN, (float)nrow, meanv);
    k_bn_part<<<256,256,0,stream>>>(yin, nrow, meanv, 1, partBN);
    k_bn_red<<<1,32,0,stream>>>(partBN, (float)nrow, varv);
    k_bn_apply<<<(nrow*30)/256,256,0,stream>>>(yin, meanv, varv, g, be, xout, nrow);
  };

  // ---- stage 1: sparse GCN + BN x3 ----
  k_mm30<3><<<7680,256,0,stream>>>(x, w11, hbuf, NN);
  k_gcn_agg<<<7680,256,0,stream>>>(hbuf, rp_in, col_in, dinv, b11, tmpY);
  run_bn(tmpY, X1, g11, be11, NN);
  k_mm30<30><<<7680,256,0,stream>>>(X1, w12, hbuf, NN);
  k_gcn_agg<<<7680,256,0,stream>>>(hbuf, rp_in, col_in, dinv, b12, tmpY);
  run_bn(tmpY, X2, g12, be12, NN);
  k_mm30<30><<<7680,256,0,stream>>>(X2, w13, hbuf, NN);
  k_gcn_agg<<<7680,256,0,stream>>>(hbuf, rp_in, col_in, dinv, b13, tmpY);
  run_bn(tmpY, X3, g13, be13, NN);
  k_pool<<<90,64,0,stream>>>(X1, X2, X3, 1024, conv, 0);

  // ---- belief propagation ([NN][126] psi + L ping-pong) ----
  k_bp_first<<<32256,256,0,stream>>>(bufA, logA, betas);
  float* cur = bufA;  float* nxt = bufB;
  float* lcur = logA; float* lnxt = logB;
  for (int it=0; it<10; ++it){
    k_colsum_part<<<1536,64,0,stream>>>(cur, partCS);
    k_field<<<1,384,0,stream>>>(partCS, betas, fieldv);
    k_bp_step<<<32256,256,0,stream>>>(nxt, lcur, lnxt, rp_in, col_in, fieldv, betas);
    float* tp = cur;  cur = nxt;   nxt = tp;
    float* tl = lcur; lcur = lnxt; lnxt = tl;
  }
  // final concatenated psi [NN][126] now in bufA (10 swaps -> back to bufA)

  // ---- diff-pool ----
  k_s1<<<2048,256,0,stream>>>(bufA, poolw, poolb, bufB);      // s1 [n,100] -> bufB
  k_T<<<25600,256,0,stream>>>(bufB, rp_out, col_out, bufA);   // T = A*s1   -> bufA
  k_p1adj<<<1600,128,0,stream>>>(bufB, bufA, padj);
  k_p1x<<<1600,128,0,stream>>>(bufB, X3, px);
  k_dinv2<<<25,256,0,stream>>>(padj, dinv2);
  k_Ank<<<2500,256,0,stream>>>(padj, dinv2, An);

  // ---- stage 2: dense GCN + BN x3 ----
  auto gcn2 = [&](const float* xin, const float* w, const float* bb, const float* g,
                  const float* be, float* xout){
    k_mm30<30><<<750,256,0,stream>>>(xin, w, h2, NBG*100);
    k_y2<<<750,256,0,stream>>>(An, h2, bb, y2);
    run_bn(y2, xout, g, be, NBG*100);
  };
  gcn2(px,  w21, b21, g21, be21, X21);
  gcn2(X21, w22, b22, g22, be22, X22);
  gcn2(X22, w23, b23, g23, be23, X23);
  k_pool<<<90,64,0,stream>>>(X21, X22, X23, 100, conv, 90);

  // ---- FC head ----
  k_fc<<<64,64,0,stream>>>(conv, fc1w, fc1b, fc2w, fc2b, out);
}

// Round 6
// 1833.037 us; speedup vs baseline: 1.9929x; 1.0744x over previous
//
#include <hip/hip_runtime.h>
#include <stdint.h>
#include <float.h>

// ---------------------------------------------------------------------------
// Net_57604101374728: GCN(x3)+BN -> maxpool | 6x belief-prop -> diffpool ->
// dense GCN(x3)+BN -> maxpool -> FC. Full fp32 port of the JAX reference.
//
// R6: R5 + parallel max-pool (k_pool2: 192 blocks x 256 thr, LDS tree reduce;
// was 90x64 serial-per-thread at 0.95% occupancy / 180us), skip dead L-write
// on final bp iter, order-preserving unroll in k_p1adj/k_p1x. All FP orders
// unchanged (max is order-independent) -> absmax stays 0.0.
// ---------------------------------------------------------------------------

constexpr int NN    = 65536;    // total nodes
constexpr int NEDGE = 524288;   // edges
constexpr int NBG   = 64;       // graphs

__constant__ int cQS[6]   = {2,4,8,16,32,64};

// ---------------- threefry2x32 (20 rounds) ----------------
__device__ __forceinline__ void tf2x32(uint32_t k0, uint32_t k1, uint32_t x0, uint32_t x1,
                                       uint32_t& o0, uint32_t& o1){
  uint32_t ks[3] = {k0, k1, k0 ^ k1 ^ 0x1BD11BDAu};
  x0 += ks[0]; x1 += ks[1];
  const int RA[4] = {13,15,26,6}, RB[4] = {17,29,16,24};
  #pragma unroll
  for (int i=0;i<5;i++){
    const int* r = (i&1)? RB : RA;
    #pragma unroll
    for (int j=0;j<4;j++){
      x0 += x1;
      x1 = (x1 << r[j]) | (x1 >> (32 - r[j]));
      x1 ^= x0;
    }
    x0 += ks[(i+1)%3];
    x1 += ks[(i+2)%3] + (uint32_t)(i+1);
  }
  o0 = x0; o1 = x1;
}

// ---------------- XLA ErfInv32 (Giles), contraction off ----------------
__device__ __forceinline__ float erfinv32(float xx){
  #pragma clang fp contract(off)
  float w = -log1pf(-xx*xx);
  float p;
  if (w < 5.0f){
    w = w - 2.5f;
    p = 2.81022636e-08f;
    p = 3.43273939e-07f  + p*w;
    p = -3.5233877e-06f  + p*w;
    p = -4.39150654e-06f + p*w;
    p = 0.00021858087f   + p*w;
    p = -0.00125372503f  + p*w;
    p = -0.00417768164f  + p*w;
    p = 0.246640727f     + p*w;
    p = 1.50140941f      + p*w;
  } else {
    w = sqrtf(w) - 3.0f;
    p = -0.000200214257f;
    p = 0.000100950558f  + p*w;
    p = 0.00134934322f   + p*w;
    p = -0.00367342844f  + p*w;
    p = 0.00573950773f   + p*w;
    p = -0.0076224613f   + p*w;
    p = 0.00943887047f   + p*w;
    p = 1.00167406f      + p*w;
    p = 2.83297682f      + p*w;
  }
  return p*xx;
}

// ---------------- CSR construction ----------------
__global__ __launch_bounds__(256) void k_count(const int* __restrict__ src, const int* __restrict__ dst,
                                               int* __restrict__ degi, int* __restrict__ dego){
  int e = blockIdx.x*256 + threadIdx.x;
  if (e >= NEDGE) return;
  atomicAdd(&degi[dst[e]], 1);
  atomicAdd(&dego[src[e]], 1);
}

__global__ __launch_bounds__(256) void k_scan1(const int* __restrict__ deg, int* __restrict__ rp,
                                               int* __restrict__ bsum){
  __shared__ int lds[256];
  int b = blockIdx.x, t = threadIdx.x;
  lds[t] = deg[b*256 + t];
  __syncthreads();
  for (int s=1;s<256;s<<=1){
    int add = (t>=s)? lds[t-s] : 0;
    __syncthreads();
    lds[t] += add;
    __syncthreads();
  }
  rp[b*256 + t + 1] = lds[t];
  if (t==0 && b==0) rp[0] = 0;
  if (t==255) bsum[b] = lds[255];
}

__global__ __launch_bounds__(256) void k_scan2(int* __restrict__ bsum){
  __shared__ int lds[256];
  int t = threadIdx.x;
  lds[t] = bsum[t];
  __syncthreads();
  for (int s=1;s<256;s<<=1){
    int add = (t>=s)? lds[t-s] : 0;
    __syncthreads();
    lds[t] += add;
    __syncthreads();
  }
  bsum[t] = (t==0)? 0 : lds[t-1];
}

__global__ __launch_bounds__(256) void k_scan3(int* __restrict__ rp, const int* __restrict__ bsum){
  int b = blockIdx.x, t = threadIdx.x;
  rp[b*256 + t + 1] += bsum[b];
}

__global__ __launch_bounds__(256) void k_fill(const int* __restrict__ key, const int* __restrict__ rp,
                                              int* __restrict__ cnt, int* __restrict__ colbuf){
  int e = blockIdx.x*256 + threadIdx.x;
  if (e >= NEDGE) return;
  int d = key[e];
  int p = atomicAdd(&cnt[d], 1);
  colbuf[rp[d] + p] = e;             // store edge id (sorted next for determinism)
}

__global__ __launch_bounds__(256) void k_sortrow(const int* __restrict__ rp, int* __restrict__ colbuf,
                                                 const int* __restrict__ other){
  int v = blockIdx.x*256 + threadIdx.x;
  if (v >= NN) return;
  int s0 = rp[v], s1 = rp[v+1];
  for (int i=s0+1;i<s1;i++){         // insertion sort by edge id ascending
    int key = colbuf[i]; int j = i-1;
    while (j>=s0 && colbuf[j]>key){ colbuf[j+1]=colbuf[j]; j--; }
    colbuf[j+1] = key;
  }
  for (int i=s0;i<s1;i++) colbuf[i] = other[colbuf[i]];
}

__global__ __launch_bounds__(256) void k_dinv(const int* __restrict__ degi, float* __restrict__ dinv){
  int v = blockIdx.x*256 + threadIdx.x;
  if (v >= NN) return;
  dinv[v] = 1.0f / sqrtf((float)(degi[v] + 1));   // +1 for self loop
}

// ---------------- stage-1 GCN ----------------
template<int CIN>
__global__ __launch_bounds__(256) void k_mm30(const float* __restrict__ x, const float* __restrict__ w,
                                              float* __restrict__ h, int nrow){
  __shared__ float ws[CIN*30];
  int t = threadIdx.x;
  for (int i=t;i<CIN*30;i+=256) ws[i] = w[i];
  __syncthreads();
  int id = blockIdx.x*256 + t;
  if (id >= nrow*30) return;
  int v = id/30, j = id - v*30;
  const float* xr = x + v*CIN;
  float acc = 0.f;
  #pragma unroll
  for (int k=0;k<CIN;k++) acc += xr[k]*ws[k*30+j];
  h[id] = acc;
}

// thread-per-element + XCD-resident mapping + chunk-4 prefetch (MLP).
__global__ __launch_bounds__(256) void k_gcn_agg(const float* __restrict__ h, const int* __restrict__ rp,
    const int* __restrict__ col, const float* __restrict__ dinv, const float* __restrict__ bias,
    float* __restrict__ y){
  int b = blockIdx.x;
  int xcd = b & 7, i = b >> 3;       // 960 per xcd
  int gs = i/120, j = i - gs*120;
  int graph = gs*8 + xcd;
  int id = graph*30720 + j*256 + threadIdx.x;
  int v = id/30, jc = id - v*30;
  float dv = dinv[v];
  float acc = 0.f;
  int a = rp[v], e = rp[v+1];
  for (; a+4<=e; a+=4){
    int s0=col[a], s1=col[a+1], s2=col[a+2], s3=col[a+3];
    float d0=dinv[s0], d1=dinv[s1], d2=dinv[s2], d3=dinv[s3];
    float h0=h[s0*30+jc], h1=h[s1*30+jc], h2=h[s2*30+jc], h3=h[s3*30+jc];
    acc += h0*(d0*dv);
    acc += h1*(d1*dv);
    acc += h2*(d2*dv);
    acc += h3*(d3*dv);
  }
  for (; a<e; ++a){
    int s = col[a];
    acc += h[s*30 + jc] * (dinv[s]*dv);
  }
  acc += h[id]*(dv*dv);      // self loop appended last (matches JAX concat order)
  y[id] = acc + bias[jc];
}

// ---------------- BatchNorm (two-pass, biased var) ----------------
__global__ __launch_bounds__(256) void k_bn_part(const float* __restrict__ x, int nrow,
    const float* __restrict__ mean, int pass, float* __restrict__ part){
  __shared__ float lds[256*31];
  int b = blockIdx.x, t = threadIdx.x;
  int rows = nrow >> 8;              // rows per block (nrow divisible by 256)
  float acc[30];
  #pragma unroll
  for (int f=0;f<30;f++) acc[f] = 0.f;
  for (int r=t; r<rows; r+=256){
    const float* xr = x + (b*rows + r)*30;
    if (pass == 0){
      #pragma unroll
      for (int f=0;f<30;f++) acc[f] += xr[f];
    } else {
      #pragma unroll
      for (int f=0;f<30;f++){ float d = xr[f]-mean[f]; acc[f] += d*d; }
    }
  }
  #pragma unroll
  for (int f=0;f<30;f++) lds[t*31+f] = acc[f];
  __syncthreads();
  for (int s=128;s>0;s>>=1){
    if (t<s){
      #pragma unroll
      for (int f=0;f<30;f++) lds[t*31+f] += lds[(t+s)*31+f];
    }
    __syncthreads();
  }
  if (t<30) part[b*30+t] = lds[t];
}

__global__ void k_bn_red(const float* __restrict__ part, float n, float* __restrict__ out){
  int f = threadIdx.x;
  if (f >= 30) return;
  float s = 0.f;
  for (int b=0;b<256;b++) s += part[b*30+f];
  out[f] = s / n;
}

__global__ __launch_bounds__(256) void k_bn_apply(const float* __restrict__ x, const float* __restrict__ mean,
    const float* __restrict__ var, const float* __restrict__ g, const float* __restrict__ be,
    float* __restrict__ out, int nrow){
  int id = blockIdx.x*256 + threadIdx.x;
  if (id >= nrow*30) return;
  int f = id % 30;
  out[id] = g[f]*(x[id]-mean[f]) * (1.0f/sqrtf(var[f]+1e-5f)) + be[f];
}

// ---------------- belief propagation (thread-per-element, XCD-resident) ----
__device__ __forceinline__ void bp_decode(int b, int& graph, int& run, int& jj){
  int xcd = b & 7, i = b >> 3;
  int gs = i/504, j = i - gs*504;
  if      (j <   8){ run=0; jj=j;     }
  else if (j <  24){ run=1; jj=j-8;   }
  else if (j <  56){ run=2; jj=j-24;  }
  else if (j < 120){ run=3; jj=j-56;  }
  else if (j < 248){ run=4; jj=j-120; }
  else             { run=5; jj=j-248; }
  graph = gs*8 + xcd;
}

template<int Q, int CO, int L2Q>
__device__ __forceinline__ void bp_first_elem(int graph, int jj, float* __restrict__ psi,
                                              float* __restrict__ lg, float eb,
                                              uint32_t k0, uint32_t k1){
  int elem = jj*256 + threadIdx.x;          // [0, 1024*Q)
  int rg = elem >> L2Q, c = elem & (Q-1);
  int row = graph*1024 + rg;
  uint32_t b0, b1;
  tf2x32(k0, k1, 0u, (uint32_t)(row*Q + c), b0, b1);   // counter = (0, idx)
  uint32_t bits = b0 ^ b1;
  float f = __uint_as_float((bits>>9) | 0x3F800000u) - 1.0f;     // [0,1)
  const float lo = __uint_as_float(0xBF7FFFFFu);                 // nextafter(-1,0)
  float u = fmaxf(lo, f*2.0f + lo);
  float v = __uint_as_float(0x3FB504F3u) * erfinv32(u);          // sqrt(2)*erfinv
  // softmax over q-lane group (same shuffle sequence as R1)
  float m = v;
  #pragma unroll
  for (int off=Q>>1; off; off>>=1) m = fmaxf(m, __shfl_xor(m, off, Q));
  float e = expf(v - m);
  float ss = e;
  #pragma unroll
  for (int off=Q>>1; off; off>>=1) ss += __shfl_xor(ss, off, Q);
  float pn = e / ss;
  psi[row*126 + CO + c] = pn;
  lg [row*126 + CO + c] = log1pf(eb*pn);
}

__global__ __launch_bounds__(256) void k_bp_first(float* __restrict__ psi, float* __restrict__ lg,
                                                  const float* __restrict__ betas){
  int graph, run, jj;
  bp_decode(blockIdx.x, graph, run, jj);
  uint32_t k0, k1;
  tf2x32(0u, 42u, 0u, (uint32_t)run, k0, k1);          // fold_in(key(42), run)
  float eb = expm1f(betas[run]);
  switch(run){
    case 0: bp_first_elem< 2, 0,1>(graph, jj, psi, lg, eb, k0, k1); break;
    case 1: bp_first_elem< 4, 2,2>(graph, jj, psi, lg, eb, k0, k1); break;
    case 2: bp_first_elem< 8, 6,3>(graph, jj, psi, lg, eb, k0, k1); break;
    case 3: bp_first_elem<16,14,4>(graph, jj, psi, lg, eb, k0, k1); break;
    case 4: bp_first_elem<32,30,5>(graph, jj, psi, lg, eb, k0, k1); break;
    default:bp_first_elem<64,62,6>(graph, jj, psi, lg, eb, k0, k1); break;
  }
}

// edge loop gathers PRECOMPUTED L = log1p(eb*psi) and just sums (order ==
// ascending edge id, bit-identical); epilogue writes psi_new and L_new.
template<int Q, int CO, int L2Q>
__device__ __forceinline__ void bp_step_elem(int graph, int run, int jj,
    const float* __restrict__ lcur, float* __restrict__ nxt, float* __restrict__ lnxt,
    const int* __restrict__ rp, const int* __restrict__ col,
    const float* __restrict__ field, float eb, int writeL){
  int elem = jj*256 + threadIdx.x;
  int rg = elem >> L2Q, c = elem & (Q-1);
  int row = graph*1024 + rg;
  const float* base = lcur + CO + c;
  float acc = 0.f;
  int a = rp[row], b2 = rp[row+1];
  for (; a+8<=b2; a+=8){
    int s0=col[a],s1=col[a+1],s2=col[a+2],s3=col[a+3];
    int s4=col[a+4],s5=col[a+5],s6=col[a+6],s7=col[a+7];
    float v0=base[s0*126],v1=base[s1*126],v2=base[s2*126],v3=base[s3*126];
    float v4=base[s4*126],v5=base[s5*126],v6=base[s6*126],v7=base[s7*126];
    acc += v0; acc += v1; acc += v2; acc += v3;
    acc += v4; acc += v5; acc += v6; acc += v7;
  }
  for (; a+4<=b2; a+=4){
    int s0=col[a],s1=col[a+1],s2=col[a+2],s3=col[a+3];
    float v0=base[s0*126],v1=base[s1*126],v2=base[s2*126],v3=base[s3*126];
    acc += v0; acc += v1; acc += v2; acc += v3;
  }
  for (; a<b2; ++a){
    acc += base[col[a]*126];
  }
  float v = acc - field[run*64 + c];
  float m = v;
  #pragma unroll
  for (int off=Q>>1; off; off>>=1) m = fmaxf(m, __shfl_xor(m, off, Q));
  float e = expf(v - m);
  float ss = e;
  #pragma unroll
  for (int off=Q>>1; off; off>>=1) ss += __shfl_xor(ss, off, Q);
  float pn = e / ss;
  nxt [row*126 + CO + c] = pn;
  if (writeL) lnxt[row*126 + CO + c] = log1pf(eb*pn);
}

__global__ __launch_bounds__(256) void k_bp_step(
    float* __restrict__ nxt, const float* __restrict__ lcur, float* __restrict__ lnxt,
    const int* __restrict__ rp, const int* __restrict__ col,
    const float* __restrict__ field, const float* __restrict__ betas, int writeL){
  int graph, run, jj;
  bp_decode(blockIdx.x, graph, run, jj);
  float eb = expm1f(betas[run]);
  switch(run){
    case 0: bp_step_elem< 2, 0,1>(graph, run, jj, lcur, nxt, lnxt, rp, col, field, eb, writeL); break;
    case 1: bp_step_elem< 4, 2,2>(graph, run, jj, lcur, nxt, lnxt, rp, col, field, eb, writeL); break;
    case 2: bp_step_elem< 8, 6,3>(graph, run, jj, lcur, nxt, lnxt, rp, col, field, eb, writeL); break;
    case 3: bp_step_elem<16,14,4>(graph, run, jj, lcur, nxt, lnxt, rp, col, field, eb, writeL); break;
    case 4: bp_step_elem<32,30,5>(graph, run, jj, lcur, nxt, lnxt, rp, col, field, eb, writeL); break;
    default:bp_step_elem<64,62,6>(graph, run, jj, lcur, nxt, lnxt, rp, col, field, eb, writeL); break;
  }
}

// column sums, sequential row order within 256-row chunks (order == R1);
__global__ __launch_bounds__(64) void k_colsum_part(const float* __restrict__ cur, float* __restrict__ part){
  int b = blockIdx.x;
  int xcd = b & 7, i = b >> 3;       // i in [0,192)
  int gs = i/24, rem = i - gs*24;
  int run = rem >> 2, cg = rem & 3;
  int graph = gs*8 + xcd;
  int chunk = graph*4 + cg;          // global 256-row chunk id (== R1 "b")
  int q = cQS[run];
  int co = (run==0)?0:(run==1)?2:(run==2)?6:(run==3)?14:(run==4)?30:62;
  int c = threadIdx.x;
  if (c >= q) return;
  float s = 0.f;
  const float* p = cur + (size_t)chunk*256*126 + co + c;
  #pragma unroll 8
  for (int r=0;r<256;r++) s += p[r*126];
  part[(run*256 + chunk)*64 + c] = s;
}

__global__ void k_field(const float* __restrict__ part, const float* __restrict__ betas,
                        float* __restrict__ field){
  int id = threadIdx.x;              // 384 threads: 6 runs x 64 cols
  int run = id >> 6, c = id & 63;
  if (c >= cQS[run]) return;
  float s = 0.f;
  for (int b=0;b<256;b++) s += part[(run*256 + b)*64 + c];
  float beta = betas[run];
  field[id] = s * (3.8f*beta/65536.0f);
}

// ---------------- diff-pool ----------------
__global__ __launch_bounds__(256) void k_s1(const float* __restrict__ cat, const float* __restrict__ pw,
                                            const float* __restrict__ pb, float* __restrict__ s1){
  __shared__ float wl[12600];
  __shared__ float rowb[2][126];
  __shared__ float red[8];
  int t = threadIdx.x;
  for (int i=t;i<12600;i+=256) wl[i] = pw[i];
  int half = t>>7, tl = t&127, wid = t>>6;
  __syncthreads();
  for (int it=0; it<16; ++it){
    int v = blockIdx.x*32 + it*2 + half;
    if (tl < 126) rowb[half][tl] = cat[v*126 + tl];
    __syncthreads();
    float acc = -3.402823466e38f;
    if (tl < 100){
      acc = pb[tl];
      for (int j=0;j<126;j++) acc += rowb[half][j]*wl[j*100+tl];
    }
    float m = acc;
    for (int off=32; off; off>>=1) m = fmaxf(m, __shfl_xor(m, off, 64));
    if ((t&63)==0) red[wid] = m;
    __syncthreads();
    m = fmaxf(red[half*2], red[half*2+1]);
    float e = (tl<100)? expf(acc - m) : 0.f;
    float ss = e;
    for (int off=32; off; off>>=1) ss += __shfl_xor(ss, off, 64);
    if ((t&63)==0) red[4+wid] = ss;
    __syncthreads();
    float stot = red[4+half*2] + red[4+half*2+1];
    if (tl<100) s1[v*100+tl] = e/stot;
    __syncthreads();
  }
}

// thread-per-element + XCD mapping + chunk-4 prefetch.
__global__ __launch_bounds__(256) void k_T(const float* __restrict__ s1, const int* __restrict__ rp,
                                           const int* __restrict__ col, float* __restrict__ T){
  int b = blockIdx.x;
  int xcd = b & 7, i = b >> 3;       // 3200 per xcd
  int gs = i/400, j = i - gs*400;
  int graph = gs*8 + xcd;
  int id = graph*102400 + j*256 + threadIdx.x;
  int v = id/100, l = id - v*100;
  float acc = 0.f;
  int a = rp[v], e = rp[v+1];
  for (; a+4<=e; a+=4){
    int s0=col[a], s1_=col[a+1], s2=col[a+2], s3=col[a+3];
    float v0=s1[s0*100+l], v1=s1[s1_*100+l], v2=s1[s2*100+l], v3=s1[s3*100+l];
    acc += v0; acc += v1; acc += v2; acc += v3;
  }
  for (; a<e; ++a) acc += s1[col[a]*100 + l];
  T[id] = acc;
}

__global__ __launch_bounds__(128) void k_p1adj(const float* __restrict__ s1, const float* __restrict__ T,
                                               float* __restrict__ padj){
  int b  = blockIdx.x/25;
  int k0 = (blockIdx.x%25)*4;
  int l  = threadIdx.x;
  const float* s1b = s1 + b*1024*100;
  const float* Tb  = T  + b*1024*100;
  float a0=0.f,a1=0.f,a2=0.f,a3=0.f;
  #pragma unroll 4
  for (int n=0;n<1024;n++){
    float tv = (l<100)? Tb[n*100+l] : 0.f;
    const float* sr = s1b + n*100 + k0;
    a0 += sr[0]*tv; a1 += sr[1]*tv; a2 += sr[2]*tv; a3 += sr[3]*tv;
  }
  if (l<100){
    float* o = padj + b*10000 + k0*100 + l;
    o[0]=a0; o[100]=a1; o[200]=a2; o[300]=a3;
  }
}

__global__ __launch_bounds__(128) void k_p1x(const float* __restrict__ s1, const float* __restrict__ x13,
                                             float* __restrict__ px){
  int b  = blockIdx.x/25;
  int k0 = (blockIdx.x%25)*4;
  int t = threadIdx.x;
  int j = t>>5, d = t&31;
  float acc = 0.f;
  #pragma unroll 4
  for (int n=0;n<1024;n++){
    float xv = (d<30)? x13[(b*1024+n)*30 + d] : 0.f;
    acc += s1[(b*1024+n)*100 + k0 + j]*xv;
  }
  if (d<30) px[(b*100 + k0 + j)*30 + d] = acc;
}

// ---------------- stage-2 dense GCN ----------------
__global__ __launch_bounds__(256) void k_dinv2(const float* __restrict__ padj, float* __restrict__ dv){
  int id = blockIdx.x*256 + threadIdx.x;
  if (id >= NBG*100) return;
  const float* r = padj + id*100;
  int k = id % 100;
  float s = 0.f;
  for (int l=0;l<100;l++){
    float v = r[l];
    if (l==k) v += 1.0f;     // A = adj + I
    s += v;
  }
  dv[id] = 1.0f/sqrtf(s);
}

__global__ __launch_bounds__(256) void k_Ank(const float* __restrict__ padj, const float* __restrict__ dv,
                                             float* __restrict__ An){
  int id = blockIdx.x*256 + threadIdx.x;
  if (id >= NBG*10000) return;
  int b = id/10000;
  int rem = id - b*10000;
  int k = rem/100, l = rem - k*100;
  float a = padj[id] + ((k==l)? 1.0f : 0.0f);
  An[id] = (dv[b*100+k]*a)*dv[b*100+l];
}

__global__ __launch_bounds__(256) void k_y2(const float* __restrict__ An, const float* __restrict__ h,
    const float* __restrict__ bias, float* __restrict__ y){
  int id = blockIdx.x*256 + threadIdx.x;
  if (id >= NBG*100*30) return;
  int d = id % 30;
  int bk = id / 30;
  int b = bk / 100;
  const float* Ar = An + bk*100;
  const float* hb = h + b*100*30;
  float acc = 0.f;
  for (int l=0;l<100;l++) acc += Ar[l]*hb[l*30+d];
  y[id] = acc + bias[d];
}

// ---------------- pools + FC ----------------
// parallel max-pool: grid (NBG, 3 arrays) x 256 threads, LDS tree reduce.
// fmax is order-independent -> bit-exact vs serial version.
__global__ __launch_bounds__(256) void k_pool2(const float* __restrict__ A,
    const float* __restrict__ Bv, const float* __restrict__ Cv,
    int rows, float* __restrict__ conv, int coff){
  __shared__ float lds[256*31];
  int b = blockIdx.x, a = blockIdx.y, t = threadIdx.x;
  const float* X = (a==0)? A : ((a==1)? Bv : Cv);
  float acc[30];
  #pragma unroll
  for (int f=0;f<30;f++) acc[f] = -FLT_MAX;
  for (int r=t; r<rows; r+=256){
    const float* xr = X + (size_t)(b*rows + r)*30;
    #pragma unroll
    for (int f=0;f<30;f++) acc[f] = fmaxf(acc[f], xr[f]);
  }
  #pragma unroll
  for (int f=0;f<30;f++) lds[t*31+f] = acc[f];
  __syncthreads();
  for (int s=128;s>0;s>>=1){
    if (t<s){
      #pragma unroll
      for (int f=0;f<30;f++) lds[t*31+f] = fmaxf(lds[t*31+f], lds[(t+s)*31+f]);
    }
    __syncthreads();
  }
  if (t<30) conv[b*180 + coff + a*30 + t] = lds[t];
}

__global__ __launch_bounds__(64) void k_fc(const float* __restrict__ conv,
    const float* __restrict__ w1, const float* __restrict__ b1,
    const float* __restrict__ w2, const float* __restrict__ b2, float* __restrict__ out){
  __shared__ float row[180];
  __shared__ float hid[50];
  int b = blockIdx.x, t = threadIdx.x;
  for (int i=t;i<180;i+=64) row[i] = conv[b*180+i];
  __syncthreads();
  if (t < 50){
    float a = b1[t];
    for (int i=0;i<180;i++) a += row[i]*w1[i*50+t];
    hid[t] = fmaxf(a, 0.f);
  }
  __syncthreads();
  if (t < 6){
    float a = b2[t];
    for (int i=0;i<50;i++) a += hid[i]*w2[i*6+t];
    out[b*6+t] = a;
  }
  if (b==0 && t==63) out[NBG*6] = 0.0f;   // second tuple output: zeros((1,))
}

// ---------------------------------------------------------------------------
extern "C" void kernel_launch(void* const* d_in, const int* in_sizes, int n_in,
                              void* d_out, int out_size, void* d_ws, size_t ws_size,
                              hipStream_t stream)
{
  (void)in_sizes; (void)n_in; (void)out_size; (void)ws_size;
  const float* x   = (const float*)d_in[0];
  const int*   src = (const int*)d_in[1];
  const int*   dst = src + NEDGE;
  const float* w11=(const float*)d_in[3],  *b11=(const float*)d_in[4],  *g11=(const float*)d_in[5],  *be11=(const float*)d_in[6];
  const float* w12=(const float*)d_in[7],  *b12=(const float*)d_in[8],  *g12=(const float*)d_in[9],  *be12=(const float*)d_in[10];
  const float* w13=(const float*)d_in[11], *b13=(const float*)d_in[12], *g13=(const float*)d_in[13], *be13=(const float*)d_in[14];
  const float* w21=(const float*)d_in[15], *b21=(const float*)d_in[16], *g21=(const float*)d_in[17], *be21=(const float*)d_in[18];
  const float* w22=(const float*)d_in[19], *b22=(const float*)d_in[20], *g22=(const float*)d_in[21], *be22=(const float*)d_in[22];
  const float* w23=(const float*)d_in[23], *b23=(const float*)d_in[24], *g23=(const float*)d_in[25], *be23=(const float*)d_in[26];
  const float* betas=(const float*)d_in[27];
  const float* poolw=(const float*)d_in[28], *poolb=(const float*)d_in[29];
  const float* fc1w=(const float*)d_in[30], *fc1b=(const float*)d_in[31];
  const float* fc2w=(const float*)d_in[32], *fc2b=(const float*)d_in[33];
  float* out = (float*)d_out;

  uint8_t* basep = (uint8_t*)d_ws;
  size_t off = 0;
  auto take = [&](size_t bytes)->void*{
    void* p = basep + off;
    off = (off + bytes + 255) & ~(size_t)255;
    return p;
  };
  int* degi    = (int*)take((size_t)NN*4);
  int* dego    = (int*)take((size_t)NN*4);
  int* cntA    = (int*)take((size_t)NN*4);
  int* cntB    = (int*)take((size_t)NN*4);
  int* rp_in   = (int*)take((size_t)(NN+1)*4);
  int* rp_out  = (int*)take((size_t)(NN+1)*4);
  int* bsum    = (int*)take(256*4);
  int* col_in  = (int*)take((size_t)NEDGE*4);
  int* col_out = (int*)take((size_t)NEDGE*4);
  float* dinv  = (float*)take((size_t)NN*4);
  float* hbuf  = (float*)take((size_t)NN*30*4);
  float* tmpY  = (float*)take((size_t)NN*30*4);
  float* X1    = (float*)take((size_t)NN*30*4);
  float* X2    = (float*)take((size_t)NN*30*4);
  float* X3    = (float*)take((size_t)NN*30*4);
  float* bufA  = (float*)take((size_t)NN*126*4);
  float* bufB  = (float*)take((size_t)NN*126*4);
  float* logA  = (float*)take((size_t)NN*126*4);
  float* logB  = (float*)take((size_t)NN*126*4);
  float* partCS= (float*)take((size_t)6*256*64*4);
  float* fieldv= (float*)take(384*4);
  float* partBN= (float*)take(256*30*4);
  float* meanv = (float*)take(128);
  float* varv  = (float*)take(128);
  float* px    = (float*)take(192000*4);
  float* padj  = (float*)take(640000*4);
  float* An    = (float*)take(640000*4);
  float* dinv2 = (float*)take(6400*4);
  float* h2    = (float*)take(192000*4);
  float* y2    = (float*)take(192000*4);
  float* X21   = (float*)take(192000*4);
  float* X22   = (float*)take(192000*4);
  float* X23   = (float*)take(192000*4);
  float* conv  = (float*)take(64*180*4);

  // ---- CSR setup ----
  hipMemsetAsync(degi, 0, (size_t)NN*4, stream);
  hipMemsetAsync(dego, 0, (size_t)NN*4, stream);
  hipMemsetAsync(cntA, 0, (size_t)NN*4, stream);
  hipMemsetAsync(cntB, 0, (size_t)NN*4, stream);
  k_count<<<2048,256,0,stream>>>(src,dst,degi,dego);
  k_scan1<<<256,256,0,stream>>>(degi, rp_in, bsum);
  k_scan2<<<1,256,0,stream>>>(bsum);
  k_scan3<<<256,256,0,stream>>>(rp_in, bsum);
  k_scan1<<<256,256,0,stream>>>(dego, rp_out, bsum);
  k_scan2<<<1,256,0,stream>>>(bsum);
  k_scan3<<<256,256,0,stream>>>(rp_out, bsum);
  k_fill<<<2048,256,0,stream>>>(dst, rp_in, cntA, col_in);
  k_fill<<<2048,256,0,stream>>>(src, rp_out, cntB, col_out);
  k_sortrow<<<256,256,0,stream>>>(rp_in,  col_in,  src);
  k_sortrow<<<256,256,0,stream>>>(rp_out, col_out, dst);
  k_dinv<<<256,256,0,stream>>>(degi, dinv);

  auto run_bn = [&](const float* yin, float* xout, const float* g, const float* be, int nrow){
    k_bn_part<<<256,256,0,stream>>>(yin, nrow, meanv, 0, partBN);
    k_bn_red<<<1,32,0,stream>>>(partBN, (float)nrow, meanv);
    k_bn_part<<<256,256,0,stream>>>(yin, nrow, meanv, 1, partBN);
    k_bn_red<<<1,32,0,stream>>>(partBN, (float)nrow, varv);
    k_bn_apply<<<(nrow*30)/256,256,0,stream>>>(yin, meanv, varv, g, be, xout, nrow);
  };

  // ---- stage 1: sparse GCN + BN x3 ----
  k_mm30<3><<<7680,256,0,stream>>>(x, w11, hbuf, NN);
  k_gcn_agg<<<7680,256,0,stream>>>(hbuf, rp_in, col_in, dinv, b11, tmpY);
  run_bn(tmpY, X1, g11, be11, NN);
  k_mm30<30><<<7680,256,0,stream>>>(X1, w12, hbuf, NN);
  k_gcn_agg<<<7680,256,0,stream>>>(hbuf, rp_in, col_in, dinv, b12, tmpY);
  run_bn(tmpY, X2, g12, be12, NN);
  k_mm30<30><<<7680,256,0,stream>>>(X2, w13, hbuf, NN);
  k_gcn_agg<<<7680,256,0,stream>>>(hbuf, rp_in, col_in, dinv, b13, tmpY);
  run_bn(tmpY, X3, g13, be13, NN);
  k_pool2<<<dim3(NBG,3),256,0,stream>>>(X1, X2, X3, 1024, conv, 0);

  // ---- belief propagation ([NN][126] psi + L ping-pong) ----
  k_bp_first<<<32256,256,0,stream>>>(bufA, logA, betas);
  float* cur = bufA;  float* nxt = bufB;
  float* lcur = logA; float* lnxt = logB;
  for (int it=0; it<10; ++it){
    k_colsum_part<<<1536,64,0,stream>>>(cur, partCS);
    k_field<<<1,384,0,stream>>>(partCS, betas, fieldv);
    k_bp_step<<<32256,256,0,stream>>>(nxt, lcur, lnxt, rp_in, col_in, fieldv, betas, it<9);
    float* tp = cur;  cur = nxt;   nxt = tp;
    float* tl = lcur; lcur = lnxt; lnxt = tl;
  }
  // final concatenated psi [NN][126] now in bufA (10 swaps -> back to bufA)

  // ---- diff-pool ----
  k_s1<<<2048,256,0,stream>>>(bufA, poolw, poolb, bufB);      // s1 [n,100] -> bufB
  k_T<<<25600,256,0,stream>>>(bufB, rp_out, col_out, bufA);   // T = A*s1   -> bufA
  k_p1adj<<<1600,128,0,stream>>>(bufB, bufA, padj);
  k_p1x<<<1600,128,0,stream>>>(bufB, X3, px);
  k_dinv2<<<25,256,0,stream>>>(padj, dinv2);
  k_Ank<<<2500,256,0,stream>>>(padj, dinv2, An);

  // ---- stage 2: dense GCN + BN x3 ----
  auto gcn2 = [&](const float* xin, const float* w, const float* bb, const float* g,
                  const float* be, float* xout){
    k_mm30<30><<<750,256,0,stream>>>(xin, w, h2, NBG*100);
    k_y2<<<750,256,0,stream>>>(An, h2, bb, y2);
    run_bn(y2, xout, g, be, NBG*100);
  };
  gcn2(px,  w21, b21, g21, be21, X21);
  gcn2(X21, w22, b22, g22, be22, X22);
  gcn2(X22, w23, b23, g23, be23, X23);
  k_pool2<<<dim3(NBG,3),256,0,stream>>>(X21, X22, X23, 100, conv, 90);

  // ---- FC head ----
  k_fc<<<64,64,0,stream>>>(conv, fc1w, fc1b, fc2w, fc2b, out);
}

// Round 7
// 1751.754 us; speedup vs baseline: 2.0854x; 1.0464x over previous
//
#include <hip/hip_runtime.h>
#include <stdint.h>
#include <float.h>

// ---------------------------------------------------------------------------
// Net_57604101374728: GCN(x3)+BN -> maxpool | 6x belief-prop -> diffpool ->
// dense GCN(x3)+BN -> maxpool -> FC. Full fp32 port of the JAX reference.
//
// R7: (1) k_s1 rewritten: wave-per-4-rows, x in registers (readlane
// broadcast), float2 weight reads, 512-thr blocks -> LDS ops /16, no
// per-row barriers. Matmul FP order exact; softmax denom order changes
// (post-BP, benign). (2) BP L-buffer packed per-run [NN][q] so small-q
// gathers become L1-resident (bit patterns & add order unchanged).
// ---------------------------------------------------------------------------

constexpr int NN    = 65536;    // total nodes
constexpr int NEDGE = 524288;   // edges
constexpr int NBG   = 64;       // graphs

__constant__ int cQS[6]   = {2,4,8,16,32,64};

// ---------------- threefry2x32 (20 rounds) ----------------
__device__ __forceinline__ void tf2x32(uint32_t k0, uint32_t k1, uint32_t x0, uint32_t x1,
                                       uint32_t& o0, uint32_t& o1){
  uint32_t ks[3] = {k0, k1, k0 ^ k1 ^ 0x1BD11BDAu};
  x0 += ks[0]; x1 += ks[1];
  const int RA[4] = {13,15,26,6}, RB[4] = {17,29,16,24};
  #pragma unroll
  for (int i=0;i<5;i++){
    const int* r = (i&1)? RB : RA;
    #pragma unroll
    for (int j=0;j<4;j++){
      x0 += x1;
      x1 = (x1 << r[j]) | (x1 >> (32 - r[j]));
      x1 ^= x0;
    }
    x0 += ks[(i+1)%3];
    x1 += ks[(i+2)%3] + (uint32_t)(i+1);
  }
  o0 = x0; o1 = x1;
}

// ---------------- XLA ErfInv32 (Giles), contraction off ----------------
__device__ __forceinline__ float erfinv32(float xx){
  #pragma clang fp contract(off)
  float w = -log1pf(-xx*xx);
  float p;
  if (w < 5.0f){
    w = w - 2.5f;
    p = 2.81022636e-08f;
    p = 3.43273939e-07f  + p*w;
    p = -3.5233877e-06f  + p*w;
    p = -4.39150654e-06f + p*w;
    p = 0.00021858087f   + p*w;
    p = -0.00125372503f  + p*w;
    p = -0.00417768164f  + p*w;
    p = 0.246640727f     + p*w;
    p = 1.50140941f      + p*w;
  } else {
    w = sqrtf(w) - 3.0f;
    p = -0.000200214257f;
    p = 0.000100950558f  + p*w;
    p = 0.00134934322f   + p*w;
    p = -0.00367342844f  + p*w;
    p = 0.00573950773f   + p*w;
    p = -0.0076224613f   + p*w;
    p = 0.00943887047f   + p*w;
    p = 1.00167406f      + p*w;
    p = 2.83297682f      + p*w;
  }
  return p*xx;
}

// ---------------- CSR construction ----------------
__global__ __launch_bounds__(256) void k_count(const int* __restrict__ src, const int* __restrict__ dst,
                                               int* __restrict__ degi, int* __restrict__ dego){
  int e = blockIdx.x*256 + threadIdx.x;
  if (e >= NEDGE) return;
  atomicAdd(&degi[dst[e]], 1);
  atomicAdd(&dego[src[e]], 1);
}

__global__ __launch_bounds__(256) void k_scan1(const int* __restrict__ deg, int* __restrict__ rp,
                                               int* __restrict__ bsum){
  __shared__ int lds[256];
  int b = blockIdx.x, t = threadIdx.x;
  lds[t] = deg[b*256 + t];
  __syncthreads();
  for (int s=1;s<256;s<<=1){
    int add = (t>=s)? lds[t-s] : 0;
    __syncthreads();
    lds[t] += add;
    __syncthreads();
  }
  rp[b*256 + t + 1] = lds[t];
  if (t==0 && b==0) rp[0] = 0;
  if (t==255) bsum[b] = lds[255];
}

__global__ __launch_bounds__(256) void k_scan2(int* __restrict__ bsum){
  __shared__ int lds[256];
  int t = threadIdx.x;
  lds[t] = bsum[t];
  __syncthreads();
  for (int s=1;s<256;s<<=1){
    int add = (t>=s)? lds[t-s] : 0;
    __syncthreads();
    lds[t] += add;
    __syncthreads();
  }
  bsum[t] = (t==0)? 0 : lds[t-1];
}

__global__ __launch_bounds__(256) void k_scan3(int* __restrict__ rp, const int* __restrict__ bsum){
  int b = blockIdx.x, t = threadIdx.x;
  rp[b*256 + t + 1] += bsum[b];
}

__global__ __launch_bounds__(256) void k_fill(const int* __restrict__ key, const int* __restrict__ rp,
                                              int* __restrict__ cnt, int* __restrict__ colbuf){
  int e = blockIdx.x*256 + threadIdx.x;
  if (e >= NEDGE) return;
  int d = key[e];
  int p = atomicAdd(&cnt[d], 1);
  colbuf[rp[d] + p] = e;             // store edge id (sorted next for determinism)
}

__global__ __launch_bounds__(256) void k_sortrow(const int* __restrict__ rp, int* __restrict__ colbuf,
                                                 const int* __restrict__ other){
  int v = blockIdx.x*256 + threadIdx.x;
  if (v >= NN) return;
  int s0 = rp[v], s1 = rp[v+1];
  for (int i=s0+1;i<s1;i++){         // insertion sort by edge id ascending
    int key = colbuf[i]; int j = i-1;
    while (j>=s0 && colbuf[j]>key){ colbuf[j+1]=colbuf[j]; j--; }
    colbuf[j+1] = key;
  }
  for (int i=s0;i<s1;i++) colbuf[i] = other[colbuf[i]];
}

__global__ __launch_bounds__(256) void k_dinv(const int* __restrict__ degi, float* __restrict__ dinv){
  int v = blockIdx.x*256 + threadIdx.x;
  if (v >= NN) return;
  dinv[v] = 1.0f / sqrtf((float)(degi[v] + 1));   // +1 for self loop
}

// ---------------- stage-1 GCN ----------------
template<int CIN>
__global__ __launch_bounds__(256) void k_mm30(const float* __restrict__ x, const float* __restrict__ w,
                                              float* __restrict__ h, int nrow){
  __shared__ float ws[CIN*30];
  int t = threadIdx.x;
  for (int i=t;i<CIN*30;i+=256) ws[i] = w[i];
  __syncthreads();
  int id = blockIdx.x*256 + t;
  if (id >= nrow*30) return;
  int v = id/30, j = id - v*30;
  const float* xr = x + v*CIN;
  float acc = 0.f;
  #pragma unroll
  for (int k=0;k<CIN;k++) acc += xr[k]*ws[k*30+j];
  h[id] = acc;
}

// thread-per-element + XCD-resident mapping + chunk-4 prefetch (MLP).
__global__ __launch_bounds__(256) void k_gcn_agg(const float* __restrict__ h, const int* __restrict__ rp,
    const int* __restrict__ col, const float* __restrict__ dinv, const float* __restrict__ bias,
    float* __restrict__ y){
  int b = blockIdx.x;
  int xcd = b & 7, i = b >> 3;       // 960 per xcd
  int gs = i/120, j = i - gs*120;
  int graph = gs*8 + xcd;
  int id = graph*30720 + j*256 + threadIdx.x;
  int v = id/30, jc = id - v*30;
  float dv = dinv[v];
  float acc = 0.f;
  int a = rp[v], e = rp[v+1];
  for (; a+4<=e; a+=4){
    int s0=col[a], s1=col[a+1], s2=col[a+2], s3=col[a+3];
    float d0=dinv[s0], d1=dinv[s1], d2=dinv[s2], d3=dinv[s3];
    float h0=h[s0*30+jc], h1=h[s1*30+jc], h2=h[s2*30+jc], h3=h[s3*30+jc];
    acc += h0*(d0*dv);
    acc += h1*(d1*dv);
    acc += h2*(d2*dv);
    acc += h3*(d3*dv);
  }
  for (; a<e; ++a){
    int s = col[a];
    acc += h[s*30 + jc] * (dinv[s]*dv);
  }
  acc += h[id]*(dv*dv);      // self loop appended last (matches JAX concat order)
  y[id] = acc + bias[jc];
}

// ---------------- BatchNorm (two-pass, biased var) ----------------
__global__ __launch_bounds__(256) void k_bn_part(const float* __restrict__ x, int nrow,
    const float* __restrict__ mean, int pass, float* __restrict__ part){
  __shared__ float lds[256*31];
  int b = blockIdx.x, t = threadIdx.x;
  int rows = nrow >> 8;              // rows per block (nrow divisible by 256)
  float acc[30];
  #pragma unroll
  for (int f=0;f<30;f++) acc[f] = 0.f;
  for (int r=t; r<rows; r+=256){
    const float* xr = x + (b*rows + r)*30;
    if (pass == 0){
      #pragma unroll
      for (int f=0;f<30;f++) acc[f] += xr[f];
    } else {
      #pragma unroll
      for (int f=0;f<30;f++){ float d = xr[f]-mean[f]; acc[f] += d*d; }
    }
  }
  #pragma unroll
  for (int f=0;f<30;f++) lds[t*31+f] = acc[f];
  __syncthreads();
  for (int s=128;s>0;s>>=1){
    if (t<s){
      #pragma unroll
      for (int f=0;f<30;f++) lds[t*31+f] += lds[(t+s)*31+f];
    }
    __syncthreads();
  }
  if (t<30) part[b*30+t] = lds[t];
}

__global__ void k_bn_red(const float* __restrict__ part, float n, float* __restrict__ out){
  int f = threadIdx.x;
  if (f >= 30) return;
  float s = 0.f;
  for (int b=0;b<256;b++) s += part[b*30+f];
  out[f] = s / n;
}

__global__ __launch_bounds__(256) void k_bn_apply(const float* __restrict__ x, const float* __restrict__ mean,
    const float* __restrict__ var, const float* __restrict__ g, const float* __restrict__ be,
    float* __restrict__ out, int nrow){
  int id = blockIdx.x*256 + threadIdx.x;
  if (id >= nrow*30) return;
  int f = id % 30;
  out[id] = g[f]*(x[id]-mean[f]) * (1.0f/sqrtf(var[f]+1e-5f)) + be[f];
}

// ---------------- belief propagation (thread-per-element, XCD-resident) ----
// psi stays [NN][126]; L = log1p(eb*psi) is packed PER RUN: base NN*CO,
// row stride Q -> small-q runs' gather footprint 8-32KB/graph (L1-resident).
__device__ __forceinline__ void bp_decode(int b, int& graph, int& run, int& jj){
  int xcd = b & 7, i = b >> 3;
  int gs = i/504, j = i - gs*504;
  if      (j <   8){ run=0; jj=j;     }
  else if (j <  24){ run=1; jj=j-8;   }
  else if (j <  56){ run=2; jj=j-24;  }
  else if (j < 120){ run=3; jj=j-56;  }
  else if (j < 248){ run=4; jj=j-120; }
  else             { run=5; jj=j-248; }
  graph = gs*8 + xcd;
}

template<int Q, int CO, int L2Q>
__device__ __forceinline__ void bp_first_elem(int graph, int jj, float* __restrict__ psi,
                                              float* __restrict__ lg, float eb,
                                              uint32_t k0, uint32_t k1){
  int elem = jj*256 + threadIdx.x;          // [0, 1024*Q)
  int rg = elem >> L2Q, c = elem & (Q-1);
  int row = graph*1024 + rg;
  uint32_t b0, b1;
  tf2x32(k0, k1, 0u, (uint32_t)(row*Q + c), b0, b1);   // counter = (0, idx)
  uint32_t bits = b0 ^ b1;
  float f = __uint_as_float((bits>>9) | 0x3F800000u) - 1.0f;     // [0,1)
  const float lo = __uint_as_float(0xBF7FFFFFu);                 // nextafter(-1,0)
  float u = fmaxf(lo, f*2.0f + lo);
  float v = __uint_as_float(0x3FB504F3u) * erfinv32(u);          // sqrt(2)*erfinv
  // softmax over q-lane group (same shuffle sequence as R1)
  float m = v;
  #pragma unroll
  for (int off=Q>>1; off; off>>=1) m = fmaxf(m, __shfl_xor(m, off, Q));
  float e = expf(v - m);
  float ss = e;
  #pragma unroll
  for (int off=Q>>1; off; off>>=1) ss += __shfl_xor(ss, off, Q);
  float pn = e / ss;
  psi[row*126 + CO + c] = pn;
  lg [(size_t)NN*CO + (size_t)row*Q + c] = log1pf(eb*pn);   // per-run packed
}

__global__ __launch_bounds__(256) void k_bp_first(float* __restrict__ psi, float* __restrict__ lg,
                                                  const float* __restrict__ betas){
  int graph, run, jj;
  bp_decode(blockIdx.x, graph, run, jj);
  uint32_t k0, k1;
  tf2x32(0u, 42u, 0u, (uint32_t)run, k0, k1);          // fold_in(key(42), run)
  float eb = expm1f(betas[run]);
  switch(run){
    case 0: bp_first_elem< 2, 0,1>(graph, jj, psi, lg, eb, k0, k1); break;
    case 1: bp_first_elem< 4, 2,2>(graph, jj, psi, lg, eb, k0, k1); break;
    case 2: bp_first_elem< 8, 6,3>(graph, jj, psi, lg, eb, k0, k1); break;
    case 3: bp_first_elem<16,14,4>(graph, jj, psi, lg, eb, k0, k1); break;
    case 4: bp_first_elem<32,30,5>(graph, jj, psi, lg, eb, k0, k1); break;
    default:bp_first_elem<64,62,6>(graph, jj, psi, lg, eb, k0, k1); break;
  }
}

// edge loop gathers PRECOMPUTED L (per-run packed) and sums in ascending
// edge order (bit-identical); epilogue writes psi_new and L_new.
template<int Q, int CO, int L2Q>
__device__ __forceinline__ void bp_step_elem(int graph, int run, int jj,
    const float* __restrict__ lcur, float* __restrict__ nxt, float* __restrict__ lnxt,
    const int* __restrict__ rp, const int* __restrict__ col,
    const float* __restrict__ field, float eb, int writeL){
  int elem = jj*256 + threadIdx.x;
  int rg = elem >> L2Q, c = elem & (Q-1);
  int row = graph*1024 + rg;
  const float* base = lcur + (size_t)NN*CO + c;
  float acc = 0.f;
  int a = rp[row], b2 = rp[row+1];
  for (; a+8<=b2; a+=8){
    int s0=col[a],s1=col[a+1],s2=col[a+2],s3=col[a+3];
    int s4=col[a+4],s5=col[a+5],s6=col[a+6],s7=col[a+7];
    float v0=base[s0*Q],v1=base[s1*Q],v2=base[s2*Q],v3=base[s3*Q];
    float v4=base[s4*Q],v5=base[s5*Q],v6=base[s6*Q],v7=base[s7*Q];
    acc += v0; acc += v1; acc += v2; acc += v3;
    acc += v4; acc += v5; acc += v6; acc += v7;
  }
  for (; a+4<=b2; a+=4){
    int s0=col[a],s1=col[a+1],s2=col[a+2],s3=col[a+3];
    float v0=base[s0*Q],v1=base[s1*Q],v2=base[s2*Q],v3=base[s3*Q];
    acc += v0; acc += v1; acc += v2; acc += v3;
  }
  for (; a<b2; ++a){
    acc += base[col[a]*Q];
  }
  float v = acc - field[run*64 + c];
  float m = v;
  #pragma unroll
  for (int off=Q>>1; off; off>>=1) m = fmaxf(m, __shfl_xor(m, off, Q));
  float e = expf(v - m);
  float ss = e;
  #pragma unroll
  for (int off=Q>>1; off; off>>=1) ss += __shfl_xor(ss, off, Q);
  float pn = e / ss;
  nxt [row*126 + CO + c] = pn;
  if (writeL) lnxt[(size_t)NN*CO + (size_t)row*Q + c] = log1pf(eb*pn);
}

__global__ __launch_bounds__(256) void k_bp_step(
    float* __restrict__ nxt, const float* __restrict__ lcur, float* __restrict__ lnxt,
    const int* __restrict__ rp, const int* __restrict__ col,
    const float* __restrict__ field, const float* __restrict__ betas, int writeL){
  int graph, run, jj;
  bp_decode(blockIdx.x, graph, run, jj);
  float eb = expm1f(betas[run]);
  switch(run){
    case 0: bp_step_elem< 2, 0,1>(graph, run, jj, lcur, nxt, lnxt, rp, col, field, eb, writeL); break;
    case 1: bp_step_elem< 4, 2,2>(graph, run, jj, lcur, nxt, lnxt, rp, col, field, eb, writeL); break;
    case 2: bp_step_elem< 8, 6,3>(graph, run, jj, lcur, nxt, lnxt, rp, col, field, eb, writeL); break;
    case 3: bp_step_elem<16,14,4>(graph, run, jj, lcur, nxt, lnxt, rp, col, field, eb, writeL); break;
    case 4: bp_step_elem<32,30,5>(graph, run, jj, lcur, nxt, lnxt, rp, col, field, eb, writeL); break;
    default:bp_step_elem<64,62,6>(graph, run, jj, lcur, nxt, lnxt, rp, col, field, eb, writeL); break;
  }
}

// column sums, sequential row order within 256-row chunks (order == R1);
__global__ __launch_bounds__(64) void k_colsum_part(const float* __restrict__ cur, float* __restrict__ part){
  int b = blockIdx.x;
  int xcd = b & 7, i = b >> 3;       // i in [0,192)
  int gs = i/24, rem = i - gs*24;
  int run = rem >> 2, cg = rem & 3;
  int graph = gs*8 + xcd;
  int chunk = graph*4 + cg;          // global 256-row chunk id (== R1 "b")
  int q = cQS[run];
  int co = (run==0)?0:(run==1)?2:(run==2)?6:(run==3)?14:(run==4)?30:62;
  int c = threadIdx.x;
  if (c >= q) return;
  float s = 0.f;
  const float* p = cur + (size_t)chunk*256*126 + co + c;
  #pragma unroll 8
  for (int r=0;r<256;r++) s += p[r*126];
  part[(run*256 + chunk)*64 + c] = s;
}

__global__ void k_field(const float* __restrict__ part, const float* __restrict__ betas,
                        float* __restrict__ field){
  int id = threadIdx.x;              // 384 threads: 6 runs x 64 cols
  int run = id >> 6, c = id & 63;
  if (c >= cQS[run]) return;
  float s = 0.f;
  for (int b=0;b<256;b++) s += part[(run*256 + b)*64 + c];
  float beta = betas[run];
  field[id] = s * (3.8f*beta/65536.0f);
}

// ---------------- diff-pool ----------------
// wave-per-4-rows; x in registers (readlane broadcast), float2 weights from
// LDS, no per-row barriers. Matmul FP order == reference (pb + ascending j).
__global__ __launch_bounds__(512) void k_s1(const float* __restrict__ cat, const float* __restrict__ pw,
                                            const float* __restrict__ pb, float* __restrict__ s1){
  __shared__ float wl[12600];
  int t = threadIdx.x;
  for (int i=t;i<12600;i+=512) wl[i] = pw[i];
  int w = t>>6, tl = t&63;
  bool act = tl < 50;
  float pb0 = act? pb[2*tl]   : 0.f;
  float pb1 = act? pb[2*tl+1] : 0.f;
  __syncthreads();
  #pragma unroll
  for (int p=0;p<2;p++){
    int row0 = blockIdx.x*64 + p*32 + w*4;
    float x0[4], x1[4];
    #pragma unroll
    for (int r=0;r<4;r++){
      if (tl < 63){
        float2 xv = *reinterpret_cast<const float2*>(cat + (size_t)(row0+r)*126 + 2*tl);
        x0[r]=xv.x; x1[r]=xv.y;
      } else { x0[r]=0.f; x1[r]=0.f; }
    }
    float a0[4], a1[4];
    #pragma unroll
    for (int r=0;r<4;r++){ a0[r]=pb0; a1[r]=pb1; }
    #pragma unroll 3
    for (int jj=0;jj<63;jj++){
      float2 wA = *reinterpret_cast<const float2*>(&wl[(2*jj  )*100 + 2*tl]);
      float2 wB = *reinterpret_cast<const float2*>(&wl[(2*jj+1)*100 + 2*tl]);
      #pragma unroll
      for (int r=0;r<4;r++){
        float xa = __int_as_float(__builtin_amdgcn_readlane(__float_as_int(x0[r]), jj));
        float xb = __int_as_float(__builtin_amdgcn_readlane(__float_as_int(x1[r]), jj));
        a0[r] += xa*wA.x;   // j = 2jj
        a1[r] += xa*wA.y;
        a0[r] += xb*wB.x;   // j = 2jj+1
        a1[r] += xb*wB.y;
      }
    }
    #pragma unroll
    for (int r=0;r<4;r++){
      float m = act? fmaxf(a0[r], a1[r]) : -FLT_MAX;
      #pragma unroll
      for (int off=32; off; off>>=1) m = fmaxf(m, __shfl_xor(m, off, 64));
      float e0 = act? expf(a0[r]-m) : 0.f;
      float e1 = act? expf(a1[r]-m) : 0.f;
      float ss = e0+e1;
      #pragma unroll
      for (int off=32; off; off>>=1) ss += __shfl_xor(ss, off, 64);
      if (act){
        float2 o; o.x = e0/ss; o.y = e1/ss;
        *reinterpret_cast<float2*>(s1 + (size_t)(row0+r)*100 + 2*tl) = o;
      }
    }
  }
}

// thread-per-element + XCD mapping + chunk-4 prefetch.
__global__ __launch_bounds__(256) void k_T(const float* __restrict__ s1, const int* __restrict__ rp,
                                           const int* __restrict__ col, float* __restrict__ T){
  int b = blockIdx.x;
  int xcd = b & 7, i = b >> 3;       // 3200 per xcd
  int gs = i/400, j = i - gs*400;
  int graph = gs*8 + xcd;
  int id = graph*102400 + j*256 + threadIdx.x;
  int v = id/100, l = id - v*100;
  float acc = 0.f;
  int a = rp[v], e = rp[v+1];
  for (; a+4<=e; a+=4){
    int s0=col[a], s1_=col[a+1], s2=col[a+2], s3=col[a+3];
    float v0=s1[s0*100+l], v1=s1[s1_*100+l], v2=s1[s2*100+l], v3=s1[s3*100+l];
    acc += v0; acc += v1; acc += v2; acc += v3;
  }
  for (; a<e; ++a) acc += s1[col[a]*100 + l];
  T[id] = acc;
}

__global__ __launch_bounds__(128) void k_p1adj(const float* __restrict__ s1, const float* __restrict__ T,
                                               float* __restrict__ padj){
  int b  = blockIdx.x/25;
  int k0 = (blockIdx.x%25)*4;
  int l  = threadIdx.x;
  const float* s1b = s1 + b*1024*100;
  const float* Tb  = T  + b*1024*100;
  float a0=0.f,a1=0.f,a2=0.f,a3=0.f;
  #pragma unroll 4
  for (int n=0;n<1024;n++){
    float tv = (l<100)? Tb[n*100+l] : 0.f;
    const float* sr = s1b + n*100 + k0;
    a0 += sr[0]*tv; a1 += sr[1]*tv; a2 += sr[2]*tv; a3 += sr[3]*tv;
  }
  if (l<100){
    float* o = padj + b*10000 + k0*100 + l;
    o[0]=a0; o[100]=a1; o[200]=a2; o[300]=a3;
  }
}

__global__ __launch_bounds__(128) void k_p1x(const float* __restrict__ s1, const float* __restrict__ x13,
                                             float* __restrict__ px){
  int b  = blockIdx.x/25;
  int k0 = (blockIdx.x%25)*4;
  int t = threadIdx.x;
  int j = t>>5, d = t&31;
  float acc = 0.f;
  #pragma unroll 4
  for (int n=0;n<1024;n++){
    float xv = (d<30)? x13[(b*1024+n)*30 + d] : 0.f;
    acc += s1[(b*1024+n)*100 + k0 + j]*xv;
  }
  if (d<30) px[(b*100 + k0 + j)*30 + d] = acc;
}

// ---------------- stage-2 dense GCN ----------------
__global__ __launch_bounds__(256) void k_dinv2(const float* __restrict__ padj, float* __restrict__ dv){
  int id = blockIdx.x*256 + threadIdx.x;
  if (id >= NBG*100) return;
  const float* r = padj + id*100;
  int k = id % 100;
  float s = 0.f;
  for (int l=0;l<100;l++){
    float v = r[l];
    if (l==k) v += 1.0f;     // A = adj + I
    s += v;
  }
  dv[id] = 1.0f/sqrtf(s);
}

__global__ __launch_bounds__(256) void k_Ank(const float* __restrict__ padj, const float* __restrict__ dv,
                                             float* __restrict__ An){
  int id = blockIdx.x*256 + threadIdx.x;
  if (id >= NBG*10000) return;
  int b = id/10000;
  int rem = id - b*10000;
  int k = rem/100, l = rem - k*100;
  float a = padj[id] + ((k==l)? 1.0f : 0.0f);
  An[id] = (dv[b*100+k]*a)*dv[b*100+l];
}

__global__ __launch_bounds__(256) void k_y2(const float* __restrict__ An, const float* __restrict__ h,
    const float* __restrict__ bias, float* __restrict__ y){
  int id = blockIdx.x*256 + threadIdx.x;
  if (id >= NBG*100*30) return;
  int d = id % 30;
  int bk = id / 30;
  int b = bk / 100;
  const float* Ar = An + bk*100;
  const float* hb = h + b*100*30;
  float acc = 0.f;
  for (int l=0;l<100;l++) acc += Ar[l]*hb[l*30+d];
  y[id] = acc + bias[d];
}

// ---------------- pools + FC ----------------
__global__ __launch_bounds__(256) void k_pool2(const float* __restrict__ A,
    const float* __restrict__ Bv, const float* __restrict__ Cv,
    int rows, float* __restrict__ conv, int coff){
  __shared__ float lds[256*31];
  int b = blockIdx.x, a = blockIdx.y, t = threadIdx.x;
  const float* X = (a==0)? A : ((a==1)? Bv : Cv);
  float acc[30];
  #pragma unroll
  for (int f=0;f<30;f++) acc[f] = -FLT_MAX;
  for (int r=t; r<rows; r+=256){
    const float* xr = X + (size_t)(b*rows + r)*30;
    #pragma unroll
    for (int f=0;f<30;f++) acc[f] = fmaxf(acc[f], xr[f]);
  }
  #pragma unroll
  for (int f=0;f<30;f++) lds[t*31+f] = acc[f];
  __syncthreads();
  for (int s=128;s>0;s>>=1){
    if (t<s){
      #pragma unroll
      for (int f=0;f<30;f++) lds[t*31+f] = fmaxf(lds[t*31+f], lds[(t+s)*31+f]);
    }
    __syncthreads();
  }
  if (t<30) conv[b*180 + coff + a*30 + t] = lds[t];
}

__global__ __launch_bounds__(64) void k_fc(const float* __restrict__ conv,
    const float* __restrict__ w1, const float* __restrict__ b1,
    const float* __restrict__ w2, const float* __restrict__ b2, float* __restrict__ out){
  __shared__ float row[180];
  __shared__ float hid[50];
  int b = blockIdx.x, t = threadIdx.x;
  for (int i=t;i<180;i+=64) row[i] = conv[b*180+i];
  __syncthreads();
  if (t < 50){
    float a = b1[t];
    for (int i=0;i<180;i++) a += row[i]*w1[i*50+t];
    hid[t] = fmaxf(a, 0.f);
  }
  __syncthreads();
  if (t < 6){
    float a = b2[t];
    for (int i=0;i<50;i++) a += hid[i]*w2[i*6+t];
    out[b*6+t] = a;
  }
  if (b==0 && t==63) out[NBG*6] = 0.0f;   // second tuple output: zeros((1,))
}

// ---------------------------------------------------------------------------
extern "C" void kernel_launch(void* const* d_in, const int* in_sizes, int n_in,
                              void* d_out, int out_size, void* d_ws, size_t ws_size,
                              hipStream_t stream)
{
  (void)in_sizes; (void)n_in; (void)out_size; (void)ws_size;
  const float* x   = (const float*)d_in[0];
  const int*   src = (const int*)d_in[1];
  const int*   dst = src + NEDGE;
  const float* w11=(const float*)d_in[3],  *b11=(const float*)d_in[4],  *g11=(const float*)d_in[5],  *be11=(const float*)d_in[6];
  const float* w12=(const float*)d_in[7],  *b12=(const float*)d_in[8],  *g12=(const float*)d_in[9],  *be12=(const float*)d_in[10];
  const float* w13=(const float*)d_in[11], *b13=(const float*)d_in[12], *g13=(const float*)d_in[13], *be13=(const float*)d_in[14];
  const float* w21=(const float*)d_in[15], *b21=(const float*)d_in[16], *g21=(const float*)d_in[17], *be21=(const float*)d_in[18];
  const float* w22=(const float*)d_in[19], *b22=(const float*)d_in[20], *g22=(const float*)d_in[21], *be22=(const float*)d_in[22];
  const float* w23=(const float*)d_in[23], *b23=(const float*)d_in[24], *g23=(const float*)d_in[25], *be23=(const float*)d_in[26];
  const float* betas=(const float*)d_in[27];
  const float* poolw=(const float*)d_in[28], *poolb=(const float*)d_in[29];
  const float* fc1w=(const float*)d_in[30], *fc1b=(const float*)d_in[31];
  const float* fc2w=(const float*)d_in[32], *fc2b=(const float*)d_in[33];
  float* out = (float*)d_out;

  uint8_t* basep = (uint8_t*)d_ws;
  size_t off = 0;
  auto take = [&](size_t bytes)->void*{
    void* p = basep + off;
    off = (off + bytes + 255) & ~(size_t)255;
    return p;
  };
  int* degi    = (int*)take((size_t)NN*4);
  int* dego    = (int*)take((size_t)NN*4);
  int* cntA    = (int*)take((size_t)NN*4);
  int* cntB    = (int*)take((size_t)NN*4);
  int* rp_in   = (int*)take((size_t)(NN+1)*4);
  int* rp_out  = (int*)take((size_t)(NN+1)*4);
  int* bsum    = (int*)take(256*4);
  int* col_in  = (int*)take((size_t)NEDGE*4);
  int* col_out = (int*)take((size_t)NEDGE*4);
  float* dinv  = (float*)take((size_t)NN*4);
  float* hbuf  = (float*)take((size_t)NN*30*4);
  float* tmpY  = (float*)take((size_t)NN*30*4);
  float* X1    = (float*)take((size_t)NN*30*4);
  float* X2    = (float*)take((size_t)NN*30*4);
  float* X3    = (float*)take((size_t)NN*30*4);
  float* bufA  = (float*)take((size_t)NN*126*4);
  float* bufB  = (float*)take((size_t)NN*126*4);
  float* logA  = (float*)take((size_t)NN*126*4);
  float* logB  = (float*)take((size_t)NN*126*4);
  float* partCS= (float*)take((size_t)6*256*64*4);
  float* fieldv= (float*)take(384*4);
  float* partBN= (float*)take(256*30*4);
  float* meanv = (float*)take(128);
  float* varv  = (float*)take(128);
  float* px    = (float*)take(192000*4);
  float* padj  = (float*)take(640000*4);
  float* An    = (float*)take(640000*4);
  float* dinv2 = (float*)take(6400*4);
  float* h2    = (float*)take(192000*4);
  float* y2    = (float*)take(192000*4);
  float* X21   = (float*)take(192000*4);
  float* X22   = (float*)take(192000*4);
  float* X23   = (float*)take(192000*4);
  float* conv  = (float*)take(64*180*4);

  // ---- CSR setup ----
  hipMemsetAsync(degi, 0, (size_t)NN*4, stream);
  hipMemsetAsync(dego, 0, (size_t)NN*4, stream);
  hipMemsetAsync(cntA, 0, (size_t)NN*4, stream);
  hipMemsetAsync(cntB, 0, (size_t)NN*4, stream);
  k_count<<<2048,256,0,stream>>>(src,dst,degi,dego);
  k_scan1<<<256,256,0,stream>>>(degi, rp_in, bsum);
  k_scan2<<<1,256,0,stream>>>(bsum);
  k_scan3<<<256,256,0,stream>>>(rp_in, bsum);
  k_scan1<<<256,256,0,stream>>>(dego, rp_out, bsum);
  k_scan2<<<1,256,0,stream>>>(bsum);
  k_scan3<<<256,256,0,stream>>>(rp_out, bsum);
  k_fill<<<2048,256,0,stream>>>(dst, rp_in, cntA, col_in);
  k_fill<<<2048,256,0,stream>>>(src, rp_out, cntB, col_out);
  k_sortrow<<<256,256,0,stream>>>(rp_in,  col_in,  src);
  k_sortrow<<<256,256,0,stream>>>(rp_out, col_out, dst);
  k_dinv<<<256,256,0,stream>>>(degi, dinv);

  auto run_bn = [&](const float* yin, float* xout, const float* g, const float* be, int nrow){
    k_bn_part<<<256,256,0,stream>>>(yin, nrow, meanv, 0, partBN);
    k_bn_red<<<1,32,0,stream>>>(partBN, (float)nrow, meanv);
    k_bn_part<<<256,256,0,stream>>>(yin, nrow, meanv, 1, partBN);
    k_bn_red<<<1,32,0,stream>>>(partBN, (float)nrow, varv);
    k_bn_apply<<<(nrow*30)/256,256,0,stream>>>(yin, meanv, varv, g, be, xout, nrow);
  };

  // ---- stage 1: sparse GCN + BN x3 ----
  k_mm30<3><<<7680,256,0,stream>>>(x, w11, hbuf, NN);
  k_gcn_agg<<<7680,256,0,stream>>>(hbuf, rp_in, col_in, dinv, b11, tmpY);
  run_bn(tmpY, X1, g11, be11, NN);
  k_mm30<30><<<7680,256,0,stream>>>(X1, w12, hbuf, NN);
  k_gcn_agg<<<7680,256,0,stream>>>(hbuf, rp_in, col_in, dinv, b12, tmpY);
  run_bn(tmpY, X2, g12, be12, NN);
  k_mm30<30><<<7680,256,0,stream>>>(X2, w13, hbuf, NN);
  k_gcn_agg<<<7680,256,0,stream>>>(hbuf, rp_in, col_in, dinv, b13, tmpY);
  run_bn(tmpY, X3, g13, be13, NN);
  k_pool2<<<dim3(NBG,3),256,0,stream>>>(X1, X2, X3, 1024, conv, 0);

  // ---- belief propagation ([NN][126] psi + per-run-packed L, ping-pong) ----
  k_bp_first<<<32256,256,0,stream>>>(bufA, logA, betas);
  float* cur = bufA;  float* nxt = bufB;
  float* lcur = logA; float* lnxt = logB;
  for (int it=0; it<10; ++it){
    k_colsum_part<<<1536,64,0,stream>>>(cur, partCS);
    k_field<<<1,384,0,stream>>>(partCS, betas, fieldv);
    k_bp_step<<<32256,256,0,stream>>>(nxt, lcur, lnxt, rp_in, col_in, fieldv, betas, it<9);
    float* tp = cur;  cur = nxt;   nxt = tp;
    float* tl = lcur; lcur = lnxt; lnxt = tl;
  }
  // final concatenated psi [NN][126] now in bufA (10 swaps -> back to bufA)

  // ---- diff-pool ----
  k_s1<<<1024,512,0,stream>>>(bufA, poolw, poolb, bufB);      // s1 [n,100] -> bufB
  k_T<<<25600,256,0,stream>>>(bufB, rp_out, col_out, bufA);   // T = A*s1   -> bufA
  k_p1adj<<<1600,128,0,stream>>>(bufB, bufA, padj);
  k_p1x<<<1600,128,0,stream>>>(bufB, X3, px);
  k_dinv2<<<25,256,0,stream>>>(padj, dinv2);
  k_Ank<<<2500,256,0,stream>>>(padj, dinv2, An);

  // ---- stage 2: dense GCN + BN x3 ----
  auto gcn2 = [&](const float* xin, const float* w, const float* bb, const float* g,
                  const float* be, float* xout){
    k_mm30<30><<<750,256,0,stream>>>(xin, w, h2, NBG*100);
    k_y2<<<750,256,0,stream>>>(An, h2, bb, y2);
    run_bn(y2, xout, g, be, NBG*100);
  };
  gcn2(px,  w21, b21, g21, be21, X21);
  gcn2(X21, w22, b22, g22, be22, X22);
  gcn2(X22, w23, b23, g23, be23, X23);
  k_pool2<<<dim3(NBG,3),256,0,stream>>>(X21, X22, X23, 100, conv, 90);

  // ---- FC head ----
  k_fc<<<64,64,0,stream>>>(conv, fc1w, fc1b, fc2w, fc2b, out);
}

// Round 8
// 1702.619 us; speedup vs baseline: 2.1456x; 1.0289x over previous
//
#include <hip/hip_runtime.h>
#include <stdint.h>
#include <float.h>

// ---------------------------------------------------------------------------
// Net_57604101374728: GCN(x3)+BN -> maxpool | 6x belief-prop -> diffpool ->
// dense GCN(x3)+BN -> maxpool -> FC. Full fp32 port of the JAX reference.
//
// R8: k_p1adj / k_p1x rewritten as one-block-per-graph LDS-tiled GEMMs
// (each graph's s1/T/x13 slab fetched from HBM exactly once; was 25x
// re-read -> 201MB FETCH). Per-output accumulation: single thread, n
// ascending, one accumulator -> FP bit-identical to R7 (absmax 0.0).
// ---------------------------------------------------------------------------

constexpr int NN    = 65536;    // total nodes
constexpr int NEDGE = 524288;   // edges
constexpr int NBG   = 64;       // graphs

__constant__ int cQS[6]   = {2,4,8,16,32,64};

// ---------------- threefry2x32 (20 rounds) ----------------
__device__ __forceinline__ void tf2x32(uint32_t k0, uint32_t k1, uint32_t x0, uint32_t x1,
                                       uint32_t& o0, uint32_t& o1){
  uint32_t ks[3] = {k0, k1, k0 ^ k1 ^ 0x1BD11BDAu};
  x0 += ks[0]; x1 += ks[1];
  const int RA[4] = {13,15,26,6}, RB[4] = {17,29,16,24};
  #pragma unroll
  for (int i=0;i<5;i++){
    const int* r = (i&1)? RB : RA;
    #pragma unroll
    for (int j=0;j<4;j++){
      x0 += x1;
      x1 = (x1 << r[j]) | (x1 >> (32 - r[j]));
      x1 ^= x0;
    }
    x0 += ks[(i+1)%3];
    x1 += ks[(i+2)%3] + (uint32_t)(i+1);
  }
  o0 = x0; o1 = x1;
}

// ---------------- XLA ErfInv32 (Giles), contraction off ----------------
__device__ __forceinline__ float erfinv32(float xx){
  #pragma clang fp contract(off)
  float w = -log1pf(-xx*xx);
  float p;
  if (w < 5.0f){
    w = w - 2.5f;
    p = 2.81022636e-08f;
    p = 3.43273939e-07f  + p*w;
    p = -3.5233877e-06f  + p*w;
    p = -4.39150654e-06f + p*w;
    p = 0.00021858087f   + p*w;
    p = -0.00125372503f  + p*w;
    p = -0.00417768164f  + p*w;
    p = 0.246640727f     + p*w;
    p = 1.50140941f      + p*w;
  } else {
    w = sqrtf(w) - 3.0f;
    p = -0.000200214257f;
    p = 0.000100950558f  + p*w;
    p = 0.00134934322f   + p*w;
    p = -0.00367342844f  + p*w;
    p = 0.00573950773f   + p*w;
    p = -0.0076224613f   + p*w;
    p = 0.00943887047f   + p*w;
    p = 1.00167406f      + p*w;
    p = 2.83297682f      + p*w;
  }
  return p*xx;
}

// ---------------- CSR construction ----------------
__global__ __launch_bounds__(256) void k_count(const int* __restrict__ src, const int* __restrict__ dst,
                                               int* __restrict__ degi, int* __restrict__ dego){
  int e = blockIdx.x*256 + threadIdx.x;
  if (e >= NEDGE) return;
  atomicAdd(&degi[dst[e]], 1);
  atomicAdd(&dego[src[e]], 1);
}

__global__ __launch_bounds__(256) void k_scan1(const int* __restrict__ deg, int* __restrict__ rp,
                                               int* __restrict__ bsum){
  __shared__ int lds[256];
  int b = blockIdx.x, t = threadIdx.x;
  lds[t] = deg[b*256 + t];
  __syncthreads();
  for (int s=1;s<256;s<<=1){
    int add = (t>=s)? lds[t-s] : 0;
    __syncthreads();
    lds[t] += add;
    __syncthreads();
  }
  rp[b*256 + t + 1] = lds[t];
  if (t==0 && b==0) rp[0] = 0;
  if (t==255) bsum[b] = lds[255];
}

__global__ __launch_bounds__(256) void k_scan2(int* __restrict__ bsum){
  __shared__ int lds[256];
  int t = threadIdx.x;
  lds[t] = bsum[t];
  __syncthreads();
  for (int s=1;s<256;s<<=1){
    int add = (t>=s)? lds[t-s] : 0;
    __syncthreads();
    lds[t] += add;
    __syncthreads();
  }
  bsum[t] = (t==0)? 0 : lds[t-1];
}

__global__ __launch_bounds__(256) void k_scan3(int* __restrict__ rp, const int* __restrict__ bsum){
  int b = blockIdx.x, t = threadIdx.x;
  rp[b*256 + t + 1] += bsum[b];
}

__global__ __launch_bounds__(256) void k_fill(const int* __restrict__ key, const int* __restrict__ rp,
                                              int* __restrict__ cnt, int* __restrict__ colbuf){
  int e = blockIdx.x*256 + threadIdx.x;
  if (e >= NEDGE) return;
  int d = key[e];
  int p = atomicAdd(&cnt[d], 1);
  colbuf[rp[d] + p] = e;             // store edge id (sorted next for determinism)
}

__global__ __launch_bounds__(256) void k_sortrow(const int* __restrict__ rp, int* __restrict__ colbuf,
                                                 const int* __restrict__ other){
  int v = blockIdx.x*256 + threadIdx.x;
  if (v >= NN) return;
  int s0 = rp[v], s1 = rp[v+1];
  for (int i=s0+1;i<s1;i++){         // insertion sort by edge id ascending
    int key = colbuf[i]; int j = i-1;
    while (j>=s0 && colbuf[j]>key){ colbuf[j+1]=colbuf[j]; j--; }
    colbuf[j+1] = key;
  }
  for (int i=s0;i<s1;i++) colbuf[i] = other[colbuf[i]];
}

__global__ __launch_bounds__(256) void k_dinv(const int* __restrict__ degi, float* __restrict__ dinv){
  int v = blockIdx.x*256 + threadIdx.x;
  if (v >= NN) return;
  dinv[v] = 1.0f / sqrtf((float)(degi[v] + 1));   // +1 for self loop
}

// ---------------- stage-1 GCN ----------------
template<int CIN>
__global__ __launch_bounds__(256) void k_mm30(const float* __restrict__ x, const float* __restrict__ w,
                                              float* __restrict__ h, int nrow){
  __shared__ float ws[CIN*30];
  int t = threadIdx.x;
  for (int i=t;i<CIN*30;i+=256) ws[i] = w[i];
  __syncthreads();
  int id = blockIdx.x*256 + t;
  if (id >= nrow*30) return;
  int v = id/30, j = id - v*30;
  const float* xr = x + v*CIN;
  float acc = 0.f;
  #pragma unroll
  for (int k=0;k<CIN;k++) acc += xr[k]*ws[k*30+j];
  h[id] = acc;
}

// thread-per-element + XCD-resident mapping + chunk-4 prefetch (MLP).
__global__ __launch_bounds__(256) void k_gcn_agg(const float* __restrict__ h, const int* __restrict__ rp,
    const int* __restrict__ col, const float* __restrict__ dinv, const float* __restrict__ bias,
    float* __restrict__ y){
  int b = blockIdx.x;
  int xcd = b & 7, i = b >> 3;       // 960 per xcd
  int gs = i/120, j = i - gs*120;
  int graph = gs*8 + xcd;
  int id = graph*30720 + j*256 + threadIdx.x;
  int v = id/30, jc = id - v*30;
  float dv = dinv[v];
  float acc = 0.f;
  int a = rp[v], e = rp[v+1];
  for (; a+4<=e; a+=4){
    int s0=col[a], s1=col[a+1], s2=col[a+2], s3=col[a+3];
    float d0=dinv[s0], d1=dinv[s1], d2=dinv[s2], d3=dinv[s3];
    float h0=h[s0*30+jc], h1=h[s1*30+jc], h2=h[s2*30+jc], h3=h[s3*30+jc];
    acc += h0*(d0*dv);
    acc += h1*(d1*dv);
    acc += h2*(d2*dv);
    acc += h3*(d3*dv);
  }
  for (; a<e; ++a){
    int s = col[a];
    acc += h[s*30 + jc] * (dinv[s]*dv);
  }
  acc += h[id]*(dv*dv);      // self loop appended last (matches JAX concat order)
  y[id] = acc + bias[jc];
}

// ---------------- BatchNorm (two-pass, biased var) ----------------
__global__ __launch_bounds__(256) void k_bn_part(const float* __restrict__ x, int nrow,
    const float* __restrict__ mean, int pass, float* __restrict__ part){
  __shared__ float lds[256*31];
  int b = blockIdx.x, t = threadIdx.x;
  int rows = nrow >> 8;              // rows per block (nrow divisible by 256)
  float acc[30];
  #pragma unroll
  for (int f=0;f<30;f++) acc[f] = 0.f;
  for (int r=t; r<rows; r+=256){
    const float* xr = x + (b*rows + r)*30;
    if (pass == 0){
      #pragma unroll
      for (int f=0;f<30;f++) acc[f] += xr[f];
    } else {
      #pragma unroll
      for (int f=0;f<30;f++){ float d = xr[f]-mean[f]; acc[f] += d*d; }
    }
  }
  #pragma unroll
  for (int f=0;f<30;f++) lds[t*31+f] = acc[f];
  __syncthreads();
  for (int s=128;s>0;s>>=1){
    if (t<s){
      #pragma unroll
      for (int f=0;f<30;f++) lds[t*31+f] += lds[(t+s)*31+f];
    }
    __syncthreads();
  }
  if (t<30) part[b*30+t] = lds[t];
}

__global__ void k_bn_red(const float* __restrict__ part, float n, float* __restrict__ out){
  int f = threadIdx.x;
  if (f >= 30) return;
  float s = 0.f;
  for (int b=0;b<256;b++) s += part[b*30+f];
  out[f] = s / n;
}

__global__ __launch_bounds__(256) void k_bn_apply(const float* __restrict__ x, const float* __restrict__ mean,
    const float* __restrict__ var, const float* __restrict__ g, const float* __restrict__ be,
    float* __restrict__ out, int nrow){
  int id = blockIdx.x*256 + threadIdx.x;
  if (id >= nrow*30) return;
  int f = id % 30;
  out[id] = g[f]*(x[id]-mean[f]) * (1.0f/sqrtf(var[f]+1e-5f)) + be[f];
}

// ---------------- belief propagation (thread-per-element, XCD-resident) ----
// psi stays [NN][126]; L = log1p(eb*psi) is packed PER RUN: base NN*CO,
// row stride Q -> small-q runs' gather footprint 8-32KB/graph (L1-resident).
__device__ __forceinline__ void bp_decode(int b, int& graph, int& run, int& jj){
  int xcd = b & 7, i = b >> 3;
  int gs = i/504, j = i - gs*504;
  if      (j <   8){ run=0; jj=j;     }
  else if (j <  24){ run=1; jj=j-8;   }
  else if (j <  56){ run=2; jj=j-24;  }
  else if (j < 120){ run=3; jj=j-56;  }
  else if (j < 248){ run=4; jj=j-120; }
  else             { run=5; jj=j-248; }
  graph = gs*8 + xcd;
}

template<int Q, int CO, int L2Q>
__device__ __forceinline__ void bp_first_elem(int graph, int jj, float* __restrict__ psi,
                                              float* __restrict__ lg, float eb,
                                              uint32_t k0, uint32_t k1){
  int elem = jj*256 + threadIdx.x;          // [0, 1024*Q)
  int rg = elem >> L2Q, c = elem & (Q-1);
  int row = graph*1024 + rg;
  uint32_t b0, b1;
  tf2x32(k0, k1, 0u, (uint32_t)(row*Q + c), b0, b1);   // counter = (0, idx)
  uint32_t bits = b0 ^ b1;
  float f = __uint_as_float((bits>>9) | 0x3F800000u) - 1.0f;     // [0,1)
  const float lo = __uint_as_float(0xBF7FFFFFu);                 // nextafter(-1,0)
  float u = fmaxf(lo, f*2.0f + lo);
  float v = __uint_as_float(0x3FB504F3u) * erfinv32(u);          // sqrt(2)*erfinv
  // softmax over q-lane group (same shuffle sequence as R1)
  float m = v;
  #pragma unroll
  for (int off=Q>>1; off; off>>=1) m = fmaxf(m, __shfl_xor(m, off, Q));
  float e = expf(v - m);
  float ss = e;
  #pragma unroll
  for (int off=Q>>1; off; off>>=1) ss += __shfl_xor(ss, off, Q);
  float pn = e / ss;
  psi[row*126 + CO + c] = pn;
  lg [(size_t)NN*CO + (size_t)row*Q + c] = log1pf(eb*pn);   // per-run packed
}

__global__ __launch_bounds__(256) void k_bp_first(float* __restrict__ psi, float* __restrict__ lg,
                                                  const float* __restrict__ betas){
  int graph, run, jj;
  bp_decode(blockIdx.x, graph, run, jj);
  uint32_t k0, k1;
  tf2x32(0u, 42u, 0u, (uint32_t)run, k0, k1);          // fold_in(key(42), run)
  float eb = expm1f(betas[run]);
  switch(run){
    case 0: bp_first_elem< 2, 0,1>(graph, jj, psi, lg, eb, k0, k1); break;
    case 1: bp_first_elem< 4, 2,2>(graph, jj, psi, lg, eb, k0, k1); break;
    case 2: bp_first_elem< 8, 6,3>(graph, jj, psi, lg, eb, k0, k1); break;
    case 3: bp_first_elem<16,14,4>(graph, jj, psi, lg, eb, k0, k1); break;
    case 4: bp_first_elem<32,30,5>(graph, jj, psi, lg, eb, k0, k1); break;
    default:bp_first_elem<64,62,6>(graph, jj, psi, lg, eb, k0, k1); break;
  }
}

// edge loop gathers PRECOMPUTED L (per-run packed) and sums in ascending
// edge order (bit-identical); epilogue writes psi_new and L_new.
template<int Q, int CO, int L2Q>
__device__ __forceinline__ void bp_step_elem(int graph, int run, int jj,
    const float* __restrict__ lcur, float* __restrict__ nxt, float* __restrict__ lnxt,
    const int* __restrict__ rp, const int* __restrict__ col,
    const float* __restrict__ field, float eb, int writeL){
  int elem = jj*256 + threadIdx.x;
  int rg = elem >> L2Q, c = elem & (Q-1);
  int row = graph*1024 + rg;
  const float* base = lcur + (size_t)NN*CO + c;
  float acc = 0.f;
  int a = rp[row], b2 = rp[row+1];
  for (; a+8<=b2; a+=8){
    int s0=col[a],s1=col[a+1],s2=col[a+2],s3=col[a+3];
    int s4=col[a+4],s5=col[a+5],s6=col[a+6],s7=col[a+7];
    float v0=base[s0*Q],v1=base[s1*Q],v2=base[s2*Q],v3=base[s3*Q];
    float v4=base[s4*Q],v5=base[s5*Q],v6=base[s6*Q],v7=base[s7*Q];
    acc += v0; acc += v1; acc += v2; acc += v3;
    acc += v4; acc += v5; acc += v6; acc += v7;
  }
  for (; a+4<=b2; a+=4){
    int s0=col[a],s1=col[a+1],s2=col[a+2],s3=col[a+3];
    float v0=base[s0*Q],v1=base[s1*Q],v2=base[s2*Q],v3=base[s3*Q];
    acc += v0; acc += v1; acc += v2; acc += v3;
  }
  for (; a<b2; ++a){
    acc += base[col[a]*Q];
  }
  float v = acc - field[run*64 + c];
  float m = v;
  #pragma unroll
  for (int off=Q>>1; off; off>>=1) m = fmaxf(m, __shfl_xor(m, off, Q));
  float e = expf(v - m);
  float ss = e;
  #pragma unroll
  for (int off=Q>>1; off; off>>=1) ss += __shfl_xor(ss, off, Q);
  float pn = e / ss;
  nxt [row*126 + CO + c] = pn;
  if (writeL) lnxt[(size_t)NN*CO + (size_t)row*Q + c] = log1pf(eb*pn);
}

__global__ __launch_bounds__(256) void k_bp_step(
    float* __restrict__ nxt, const float* __restrict__ lcur, float* __restrict__ lnxt,
    const int* __restrict__ rp, const int* __restrict__ col,
    const float* __restrict__ field, const float* __restrict__ betas, int writeL){
  int graph, run, jj;
  bp_decode(blockIdx.x, graph, run, jj);
  float eb = expm1f(betas[run]);
  switch(run){
    case 0: bp_step_elem< 2, 0,1>(graph, run, jj, lcur, nxt, lnxt, rp, col, field, eb, writeL); break;
    case 1: bp_step_elem< 4, 2,2>(graph, run, jj, lcur, nxt, lnxt, rp, col, field, eb, writeL); break;
    case 2: bp_step_elem< 8, 6,3>(graph, run, jj, lcur, nxt, lnxt, rp, col, field, eb, writeL); break;
    case 3: bp_step_elem<16,14,4>(graph, run, jj, lcur, nxt, lnxt, rp, col, field, eb, writeL); break;
    case 4: bp_step_elem<32,30,5>(graph, run, jj, lcur, nxt, lnxt, rp, col, field, eb, writeL); break;
    default:bp_step_elem<64,62,6>(graph, run, jj, lcur, nxt, lnxt, rp, col, field, eb, writeL); break;
  }
}

// column sums, sequential row order within 256-row chunks (order == R1);
__global__ __launch_bounds__(64) void k_colsum_part(const float* __restrict__ cur, float* __restrict__ part){
  int b = blockIdx.x;
  int xcd = b & 7, i = b >> 3;       // i in [0,192)
  int gs = i/24, rem = i - gs*24;
  int run = rem >> 2, cg = rem & 3;
  int graph = gs*8 + xcd;
  int chunk = graph*4 + cg;          // global 256-row chunk id (== R1 "b")
  int q = cQS[run];
  int co = (run==0)?0:(run==1)?2:(run==2)?6:(run==3)?14:(run==4)?30:62;
  int c = threadIdx.x;
  if (c >= q) return;
  float s = 0.f;
  const float* p = cur + (size_t)chunk*256*126 + co + c;
  #pragma unroll 8
  for (int r=0;r<256;r++) s += p[r*126];
  part[(run*256 + chunk)*64 + c] = s;
}

__global__ void k_field(const float* __restrict__ part, const float* __restrict__ betas,
                        float* __restrict__ field){
  int id = threadIdx.x;              // 384 threads: 6 runs x 64 cols
  int run = id >> 6, c = id & 63;
  if (c >= cQS[run]) return;
  float s = 0.f;
  for (int b=0;b<256;b++) s += part[(run*256 + b)*64 + c];
  float beta = betas[run];
  field[id] = s * (3.8f*beta/65536.0f);
}

// ---------------- diff-pool ----------------
// wave-per-4-rows; x in registers (readlane broadcast), float2 weights from
// LDS, no per-row barriers. Matmul FP order == reference (pb + ascending j).
__global__ __launch_bounds__(512) void k_s1(const float* __restrict__ cat, const float* __restrict__ pw,
                                            const float* __restrict__ pb, float* __restrict__ s1){
  __shared__ float wl[12600];
  int t = threadIdx.x;
  for (int i=t;i<12600;i+=512) wl[i] = pw[i];
  int w = t>>6, tl = t&63;
  bool act = tl < 50;
  float pb0 = act? pb[2*tl]   : 0.f;
  float pb1 = act? pb[2*tl+1] : 0.f;
  __syncthreads();
  #pragma unroll
  for (int p=0;p<2;p++){
    int row0 = blockIdx.x*64 + p*32 + w*4;
    float x0[4], x1[4];
    #pragma unroll
    for (int r=0;r<4;r++){
      if (tl < 63){
        float2 xv = *reinterpret_cast<const float2*>(cat + (size_t)(row0+r)*126 + 2*tl);
        x0[r]=xv.x; x1[r]=xv.y;
      } else { x0[r]=0.f; x1[r]=0.f; }
    }
    float a0[4], a1[4];
    #pragma unroll
    for (int r=0;r<4;r++){ a0[r]=pb0; a1[r]=pb1; }
    #pragma unroll 3
    for (int jj=0;jj<63;jj++){
      float2 wA = *reinterpret_cast<const float2*>(&wl[(2*jj  )*100 + 2*tl]);
      float2 wB = *reinterpret_cast<const float2*>(&wl[(2*jj+1)*100 + 2*tl]);
      #pragma unroll
      for (int r=0;r<4;r++){
        float xa = __int_as_float(__builtin_amdgcn_readlane(__float_as_int(x0[r]), jj));
        float xb = __int_as_float(__builtin_amdgcn_readlane(__float_as_int(x1[r]), jj));
        a0[r] += xa*wA.x;   // j = 2jj
        a1[r] += xa*wA.y;
        a0[r] += xb*wB.x;   // j = 2jj+1
        a1[r] += xb*wB.y;
      }
    }
    #pragma unroll
    for (int r=0;r<4;r++){
      float m = act? fmaxf(a0[r], a1[r]) : -FLT_MAX;
      #pragma unroll
      for (int off=32; off; off>>=1) m = fmaxf(m, __shfl_xor(m, off, 64));
      float e0 = act? expf(a0[r]-m) : 0.f;
      float e1 = act? expf(a1[r]-m) : 0.f;
      float ss = e0+e1;
      #pragma unroll
      for (int off=32; off; off>>=1) ss += __shfl_xor(ss, off, 64);
      if (act){
        float2 o; o.x = e0/ss; o.y = e1/ss;
        *reinterpret_cast<float2*>(s1 + (size_t)(row0+r)*100 + 2*tl) = o;
      }
    }
  }
}

// thread-per-element + XCD mapping + chunk-4 prefetch.
__global__ __launch_bounds__(256) void k_T(const float* __restrict__ s1, const int* __restrict__ rp,
                                           const int* __restrict__ col, float* __restrict__ T){
  int b = blockIdx.x;
  int xcd = b & 7, i = b >> 3;       // 3200 per xcd
  int gs = i/400, j = i - gs*400;
  int graph = gs*8 + xcd;
  int id = graph*102400 + j*256 + threadIdx.x;
  int v = id/100, l = id - v*100;
  float acc = 0.f;
  int a = rp[v], e = rp[v+1];
  for (; a+4<=e; a+=4){
    int s0=col[a], s1_=col[a+1], s2=col[a+2], s3=col[a+3];
    float v0=s1[s0*100+l], v1=s1[s1_*100+l], v2=s1[s2*100+l], v3=s1[s3*100+l];
    acc += v0; acc += v1; acc += v2; acc += v3;
  }
  for (; a<e; ++a) acc += s1[col[a]*100 + l];
  T[id] = acc;
}

// one block per graph; LDS-tiled 100x1024x100 GEMM: padj = s1^T * T.
// Each output owned by ONE thread, accumulated over n ascending (FP order
// == previous passing version).
__global__ __launch_bounds__(512) void k_p1adj(const float* __restrict__ s1, const float* __restrict__ T,
                                               float* __restrict__ padj){
  __shared__ float sS[6400];   // 64 rows x 100 of s1
  __shared__ float sT[6400];   // 64 rows x 100 of T
  int b = blockIdx.x, t = threadIdx.x;
  int tk = t/20, tl = t - tk*20;       // tk<25 -> k0, tl<20 -> l0
  bool act = t < 500;
  int k0 = tk*4, l0 = tl*5;
  float acc[4][5];
  #pragma unroll
  for (int i=0;i<4;i++)
    #pragma unroll
    for (int j=0;j<5;j++) acc[i][j] = 0.f;
  const float* s1b = s1 + (size_t)b*102400;
  const float* Tb  = T  + (size_t)b*102400;
  for (int c=0;c<16;c++){
    for (int i=t;i<6400;i+=512){ sS[i] = s1b[c*6400+i]; sT[i] = Tb[c*6400+i]; }
    __syncthreads();
    if (act){
      #pragma unroll 2
      for (int n=0;n<64;n++){
        const float* sr = &sS[n*100 + k0];
        const float* tr = &sT[n*100 + l0];
        float s0=sr[0], s1v=sr[1], s2=sr[2], s3=sr[3];
        float t0=tr[0], t1=tr[1], t2=tr[2], t3=tr[3], t4=tr[4];
        acc[0][0]+=s0*t0; acc[0][1]+=s0*t1; acc[0][2]+=s0*t2; acc[0][3]+=s0*t3; acc[0][4]+=s0*t4;
        acc[1][0]+=s1v*t0; acc[1][1]+=s1v*t1; acc[1][2]+=s1v*t2; acc[1][3]+=s1v*t3; acc[1][4]+=s1v*t4;
        acc[2][0]+=s2*t0; acc[2][1]+=s2*t1; acc[2][2]+=s2*t2; acc[2][3]+=s2*t3; acc[2][4]+=s2*t4;
        acc[3][0]+=s3*t0; acc[3][1]+=s3*t1; acc[3][2]+=s3*t2; acc[3][3]+=s3*t3; acc[3][4]+=s3*t4;
      }
    }
    __syncthreads();
  }
  if (act){
    #pragma unroll
    for (int i=0;i<4;i++){
      float* o = padj + (size_t)b*10000 + (k0+i)*100 + l0;
      #pragma unroll
      for (int j=0;j<5;j++) o[j] = acc[i][j];
    }
  }
}

// one block per graph; px = s1^T * x13 (100x1024x30), LDS-tiled, same
// per-output single-accumulator ascending-n order.
__global__ __launch_bounds__(256) void k_p1x(const float* __restrict__ s1, const float* __restrict__ x13,
                                             float* __restrict__ px){
  __shared__ float sS[6400];   // 64 x 100 of s1
  __shared__ float sX[1920];   // 64 x 30 of x13
  int b = blockIdx.x, t = threadIdx.x;
  int tk = t/10, tl = t - tk*10;       // tk<25 -> k0, tl<10 -> d0
  bool act = t < 250;
  int k0 = tk*4, d0 = tl*3;
  float acc[4][3];
  #pragma unroll
  for (int i=0;i<4;i++)
    #pragma unroll
    for (int j=0;j<3;j++) acc[i][j] = 0.f;
  const float* s1b = s1 + (size_t)b*102400;
  const float* xb  = x13 + (size_t)b*30720;
  for (int c=0;c<16;c++){
    for (int i=t;i<6400;i+=256) sS[i] = s1b[c*6400+i];
    for (int i=t;i<1920;i+=256) sX[i] = xb[c*1920+i];
    __syncthreads();
    if (act){
      #pragma unroll 2
      for (int n=0;n<64;n++){
        const float* sr = &sS[n*100 + k0];
        const float* xr = &sX[n*30 + d0];
        float s0=sr[0], s1v=sr[1], s2=sr[2], s3=sr[3];
        float x0=xr[0], x1=xr[1], x2=xr[2];
        acc[0][0]+=s0*x0; acc[0][1]+=s0*x1; acc[0][2]+=s0*x2;
        acc[1][0]+=s1v*x0; acc[1][1]+=s1v*x1; acc[1][2]+=s1v*x2;
        acc[2][0]+=s2*x0; acc[2][1]+=s2*x1; acc[2][2]+=s2*x2;
        acc[3][0]+=s3*x0; acc[3][1]+=s3*x1; acc[3][2]+=s3*x2;
      }
    }
    __syncthreads();
  }
  if (act){
    #pragma unroll
    for (int i=0;i<4;i++){
      float* o = px + ((size_t)b*100 + k0+i)*30 + d0;
      #pragma unroll
      for (int j=0;j<3;j++) o[j] = acc[i][j];
    }
  }
}

// ---------------- stage-2 dense GCN ----------------
__global__ __launch_bounds__(256) void k_dinv2(const float* __restrict__ padj, float* __restrict__ dv){
  int id = blockIdx.x*256 + threadIdx.x;
  if (id >= NBG*100) return;
  const float* r = padj + id*100;
  int k = id % 100;
  float s = 0.f;
  for (int l=0;l<100;l++){
    float v = r[l];
    if (l==k) v += 1.0f;     // A = adj + I
    s += v;
  }
  dv[id] = 1.0f/sqrtf(s);
}

__global__ __launch_bounds__(256) void k_Ank(const float* __restrict__ padj, const float* __restrict__ dv,
                                             float* __restrict__ An){
  int id = blockIdx.x*256 + threadIdx.x;
  if (id >= NBG*10000) return;
  int b = id/10000;
  int rem = id - b*10000;
  int k = rem/100, l = rem - k*100;
  float a = padj[id] + ((k==l)? 1.0f : 0.0f);
  An[id] = (dv[b*100+k]*a)*dv[b*100+l];
}

__global__ __launch_bounds__(256) void k_y2(const float* __restrict__ An, const float* __restrict__ h,
    const float* __restrict__ bias, float* __restrict__ y){
  int id = blockIdx.x*256 + threadIdx.x;
  if (id >= NBG*100*30) return;
  int d = id % 30;
  int bk = id / 30;
  int b = bk / 100;
  const float* Ar = An + bk*100;
  const float* hb = h + b*100*30;
  float acc = 0.f;
  for (int l=0;l<100;l++) acc += Ar[l]*hb[l*30+d];
  y[id] = acc + bias[d];
}

// ---------------- pools + FC ----------------
__global__ __launch_bounds__(256) void k_pool2(const float* __restrict__ A,
    const float* __restrict__ Bv, const float* __restrict__ Cv,
    int rows, float* __restrict__ conv, int coff){
  __shared__ float lds[256*31];
  int b = blockIdx.x, a = blockIdx.y, t = threadIdx.x;
  const float* X = (a==0)? A : ((a==1)? Bv : Cv);
  float acc[30];
  #pragma unroll
  for (int f=0;f<30;f++) acc[f] = -FLT_MAX;
  for (int r=t; r<rows; r+=256){
    const float* xr = X + (size_t)(b*rows + r)*30;
    #pragma unroll
    for (int f=0;f<30;f++) acc[f] = fmaxf(acc[f], xr[f]);
  }
  #pragma unroll
  for (int f=0;f<30;f++) lds[t*31+f] = acc[f];
  __syncthreads();
  for (int s=128;s>0;s>>=1){
    if (t<s){
      #pragma unroll
      for (int f=0;f<30;f++) lds[t*31+f] = fmaxf(lds[t*31+f], lds[(t+s)*31+f]);
    }
    __syncthreads();
  }
  if (t<30) conv[b*180 + coff + a*30 + t] = lds[t];
}

__global__ __launch_bounds__(64) void k_fc(const float* __restrict__ conv,
    const float* __restrict__ w1, const float* __restrict__ b1,
    const float* __restrict__ w2, const float* __restrict__ b2, float* __restrict__ out){
  __shared__ float row[180];
  __shared__ float hid[50];
  int b = blockIdx.x, t = threadIdx.x;
  for (int i=t;i<180;i+=64) row[i] = conv[b*180+i];
  __syncthreads();
  if (t < 50){
    float a = b1[t];
    for (int i=0;i<180;i++) a += row[i]*w1[i*50+t];
    hid[t] = fmaxf(a, 0.f);
  }
  __syncthreads();
  if (t < 6){
    float a = b2[t];
    for (int i=0;i<50;i++) a += hid[i]*w2[i*6+t];
    out[b*6+t] = a;
  }
  if (b==0 && t==63) out[NBG*6] = 0.0f;   // second tuple output: zeros((1,))
}

// ---------------------------------------------------------------------------
extern "C" void kernel_launch(void* const* d_in, const int* in_sizes, int n_in,
                              void* d_out, int out_size, void* d_ws, size_t ws_size,
                              hipStream_t stream)
{
  (void)in_sizes; (void)n_in; (void)out_size; (void)ws_size;
  const float* x   = (const float*)d_in[0];
  const int*   src = (const int*)d_in[1];
  const int*   dst = src + NEDGE;
  const float* w11=(const float*)d_in[3],  *b11=(const float*)d_in[4],  *g11=(const float*)d_in[5],  *be11=(const float*)d_in[6];
  const float* w12=(const float*)d_in[7],  *b12=(const float*)d_in[8],  *g12=(const float*)d_in[9],  *be12=(const float*)d_in[10];
  const float* w13=(const float*)d_in[11], *b13=(const float*)d_in[12], *g13=(const float*)d_in[13], *be13=(const float*)d_in[14];
  const float* w21=(const float*)d_in[15], *b21=(const float*)d_in[16], *g21=(const float*)d_in[17], *be21=(const float*)d_in[18];
  const float* w22=(const float*)d_in[19], *b22=(const float*)d_in[20], *g22=(const float*)d_in[21], *be22=(const float*)d_in[22];
  const float* w23=(const float*)d_in[23], *b23=(const float*)d_in[24], *g23=(const float*)d_in[25], *be23=(const float*)d_in[26];
  const float* betas=(const float*)d_in[27];
  const float* poolw=(const float*)d_in[28], *poolb=(const float*)d_in[29];
  const float* fc1w=(const float*)d_in[30], *fc1b=(const float*)d_in[31];
  const float* fc2w=(const float*)d_in[32], *fc2b=(const float*)d_in[33];
  float* out = (float*)d_out;

  uint8_t* basep = (uint8_t*)d_ws;
  size_t off = 0;
  auto take = [&](size_t bytes)->void*{
    void* p = basep + off;
    off = (off + bytes + 255) & ~(size_t)255;
    return p;
  };
  int* degi    = (int*)take((size_t)NN*4);
  int* dego    = (int*)take((size_t)NN*4);
  int* cntA    = (int*)take((size_t)NN*4);
  int* cntB    = (int*)take((size_t)NN*4);
  int* rp_in   = (int*)take((size_t)(NN+1)*4);
  int* rp_out  = (int*)take((size_t)(NN+1)*4);
  int* bsum    = (int*)take(256*4);
  int* col_in  = (int*)take((size_t)NEDGE*4);
  int* col_out = (int*)take((size_t)NEDGE*4);
  float* dinv  = (float*)take((size_t)NN*4);
  float* hbuf  = (float*)take((size_t)NN*30*4);
  float* tmpY  = (float*)take((size_t)NN*30*4);
  float* X1    = (float*)take((size_t)NN*30*4);
  float* X2    = (float*)take((size_t)NN*30*4);
  float* X3    = (float*)take((size_t)NN*30*4);
  float* bufA  = (float*)take((size_t)NN*126*4);
  float* bufB  = (float*)take((size_t)NN*126*4);
  float* logA  = (float*)take((size_t)NN*126*4);
  float* logB  = (float*)take((size_t)NN*126*4);
  float* partCS= (float*)take((size_t)6*256*64*4);
  float* fieldv= (float*)take(384*4);
  float* partBN= (float*)take(256*30*4);
  float* meanv = (float*)take(128);
  float* varv  = (float*)take(128);
  float* px    = (float*)take(192000*4);
  float* padj  = (float*)take(640000*4);
  float* An    = (float*)take(640000*4);
  float* dinv2 = (float*)take(6400*4);
  float* h2    = (float*)take(192000*4);
  float* y2    = (float*)take(192000*4);
  float* X21   = (float*)take(192000*4);
  float* X22   = (float*)take(192000*4);
  float* X23   = (float*)take(192000*4);
  float* conv  = (float*)take(64*180*4);

  // ---- CSR setup ----
  hipMemsetAsync(degi, 0, (size_t)NN*4, stream);
  hipMemsetAsync(dego, 0, (size_t)NN*4, stream);
  hipMemsetAsync(cntA, 0, (size_t)NN*4, stream);
  hipMemsetAsync(cntB, 0, (size_t)NN*4, stream);
  k_count<<<2048,256,0,stream>>>(src,dst,degi,dego);
  k_scan1<<<256,256,0,stream>>>(degi, rp_in, bsum);
  k_scan2<<<1,256,0,stream>>>(bsum);
  k_scan3<<<256,256,0,stream>>>(rp_in, bsum);
  k_scan1<<<256,256,0,stream>>>(dego, rp_out, bsum);
  k_scan2<<<1,256,0,stream>>>(bsum);
  k_scan3<<<256,256,0,stream>>>(rp_out, bsum);
  k_fill<<<2048,256,0,stream>>>(dst, rp_in, cntA, col_in);
  k_fill<<<2048,256,0,stream>>>(src, rp_out, cntB, col_out);
  k_sortrow<<<256,256,0,stream>>>(rp_in,  col_in,  src);
  k_sortrow<<<256,256,0,stream>>>(rp_out, col_out, dst);
  k_dinv<<<256,256,0,stream>>>(degi, dinv);

  auto run_bn = [&](const float* yin, float* xout, const float* g, const float* be, int nrow){
    k_bn_part<<<256,256,0,stream>>>(yin, nrow, meanv, 0, partBN);
    k_bn_red<<<1,32,0,stream>>>(partBN, (float)nrow, meanv);
    k_bn_part<<<256,256,0,stream>>>(yin, nrow, meanv, 1, partBN);
    k_bn_red<<<1,32,0,stream>>>(partBN, (float)nrow, varv);
    k_bn_apply<<<(nrow*30)/256,256,0,stream>>>(yin, meanv, varv, g, be, xout, nrow);
  };

  // ---- stage 1: sparse GCN + BN x3 ----
  k_mm30<3><<<7680,256,0,stream>>>(x, w11, hbuf, NN);
  k_gcn_agg<<<7680,256,0,stream>>>(hbuf, rp_in, col_in, dinv, b11, tmpY);
  run_bn(tmpY, X1, g11, be11, NN);
  k_mm30<30><<<7680,256,0,stream>>>(X1, w12, hbuf, NN);
  k_gcn_agg<<<7680,256,0,stream>>>(hbuf, rp_in, col_in, dinv, b12, tmpY);
  run_bn(tmpY, X2, g12, be12, NN);
  k_mm30<30><<<7680,256,0,stream>>>(X2, w13, hbuf, NN);
  k_gcn_agg<<<7680,256,0,stream>>>(hbuf, rp_in, col_in, dinv, b13, tmpY);
  run_bn(tmpY, X3, g13, be13, NN);
  k_pool2<<<dim3(NBG,3),256,0,stream>>>(X1, X2, X3, 1024, conv, 0);

  // ---- belief propagation ([NN][126] psi + per-run-packed L, ping-pong) ----
  k_bp_first<<<32256,256,0,stream>>>(bufA, logA, betas);
  float* cur = bufA;  float* nxt = bufB;
  float* lcur = logA; float* lnxt = logB;
  for (int it=0; it<10; ++it){
    k_colsum_part<<<1536,64,0,stream>>>(cur, partCS);
    k_field<<<1,384,0,stream>>>(partCS, betas, fieldv);
    k_bp_step<<<32256,256,0,stream>>>(nxt, lcur, lnxt, rp_in, col_in, fieldv, betas, it<9);
    float* tp = cur;  cur = nxt;   nxt = tp;
    float* tl = lcur; lcur = lnxt; lnxt = tl;
  }
  // final concatenated psi [NN][126] now in bufA (10 swaps -> back to bufA)

  // ---- diff-pool ----
  k_s1<<<1024,512,0,stream>>>(bufA, poolw, poolb, bufB);      // s1 [n,100] -> bufB
  k_T<<<25600,256,0,stream>>>(bufB, rp_out, col_out, bufA);   // T = A*s1   -> bufA
  k_p1adj<<<64,512,0,stream>>>(bufB, bufA, padj);
  k_p1x<<<64,256,0,stream>>>(bufB, X3, px);
  k_dinv2<<<25,256,0,stream>>>(padj, dinv2);
  k_Ank<<<2500,256,0,stream>>>(padj, dinv2, An);

  // ---- stage 2: dense GCN + BN x3 ----
  auto gcn2 = [&](const float* xin, const float* w, const float* bb, const float* g,
                  const float* be, float* xout){
    k_mm30<30><<<750,256,0,stream>>>(xin, w, h2, NBG*100);
    k_y2<<<750,256,0,stream>>>(An, h2, bb, y2);
    run_bn(y2, xout, g, be, NBG*100);
  };
  gcn2(px,  w21, b21, g21, be21, X21);
  gcn2(X21, w22, b22, g22, be22, X22);
  gcn2(X22, w23, b23, g23, be23, X23);
  k_pool2<<<dim3(NBG,3),256,0,stream>>>(X21, X22, X23, 100, conv, 90);

  // ---- FC head ----
  k_fc<<<64,64,0,stream>>>(conv, fc1w, fc1b, fc2w, fc2b, out);
}

// Round 9
// 1564.678 us; speedup vs baseline: 2.3347x; 1.0882x over previous
//
#include <hip/hip_runtime.h>
#include <stdint.h>
#include <float.h>

// ---------------------------------------------------------------------------
// Net_57604101374728: GCN(x3)+BN -> maxpool | 6x belief-prop -> diffpool ->
// dense GCN(x3)+BN -> maxpool -> FC. Full fp32 port of the JAX reference.
//
// R9: (1) k_p1adj/k_p1x split-K: 4 blocks/graph (grid 256, all CUs) with
// ascending-quarter deterministic reduce (FP tree changes ONLY for these
// post-BP GEMMs; BP stays bit-exact). (2) psi kept in per-run packed layout
// for colsum (coalesced; same values, same add order -> field bit-exact);
// [NN][126] concat written only on the final BP iter for k_s1.
// ---------------------------------------------------------------------------

constexpr int NN    = 65536;    // total nodes
constexpr int NEDGE = 524288;   // edges
constexpr int NBG   = 64;       // graphs

__constant__ int cQS[6]   = {2,4,8,16,32,64};

// ---------------- threefry2x32 (20 rounds) ----------------
__device__ __forceinline__ void tf2x32(uint32_t k0, uint32_t k1, uint32_t x0, uint32_t x1,
                                       uint32_t& o0, uint32_t& o1){
  uint32_t ks[3] = {k0, k1, k0 ^ k1 ^ 0x1BD11BDAu};
  x0 += ks[0]; x1 += ks[1];
  const int RA[4] = {13,15,26,6}, RB[4] = {17,29,16,24};
  #pragma unroll
  for (int i=0;i<5;i++){
    const int* r = (i&1)? RB : RA;
    #pragma unroll
    for (int j=0;j<4;j++){
      x0 += x1;
      x1 = (x1 << r[j]) | (x1 >> (32 - r[j]));
      x1 ^= x0;
    }
    x0 += ks[(i+1)%3];
    x1 += ks[(i+2)%3] + (uint32_t)(i+1);
  }
  o0 = x0; o1 = x1;
}

// ---------------- XLA ErfInv32 (Giles), contraction off ----------------
__device__ __forceinline__ float erfinv32(float xx){
  #pragma clang fp contract(off)
  float w = -log1pf(-xx*xx);
  float p;
  if (w < 5.0f){
    w = w - 2.5f;
    p = 2.81022636e-08f;
    p = 3.43273939e-07f  + p*w;
    p = -3.5233877e-06f  + p*w;
    p = -4.39150654e-06f + p*w;
    p = 0.00021858087f   + p*w;
    p = -0.00125372503f  + p*w;
    p = -0.00417768164f  + p*w;
    p = 0.246640727f     + p*w;
    p = 1.50140941f      + p*w;
  } else {
    w = sqrtf(w) - 3.0f;
    p = -0.000200214257f;
    p = 0.000100950558f  + p*w;
    p = 0.00134934322f   + p*w;
    p = -0.00367342844f  + p*w;
    p = 0.00573950773f   + p*w;
    p = -0.0076224613f   + p*w;
    p = 0.00943887047f   + p*w;
    p = 1.00167406f      + p*w;
    p = 2.83297682f      + p*w;
  }
  return p*xx;
}

// ---------------- CSR construction ----------------
__global__ __launch_bounds__(256) void k_count(const int* __restrict__ src, const int* __restrict__ dst,
                                               int* __restrict__ degi, int* __restrict__ dego){
  int e = blockIdx.x*256 + threadIdx.x;
  if (e >= NEDGE) return;
  atomicAdd(&degi[dst[e]], 1);
  atomicAdd(&dego[src[e]], 1);
}

__global__ __launch_bounds__(256) void k_scan1(const int* __restrict__ deg, int* __restrict__ rp,
                                               int* __restrict__ bsum){
  __shared__ int lds[256];
  int b = blockIdx.x, t = threadIdx.x;
  lds[t] = deg[b*256 + t];
  __syncthreads();
  for (int s=1;s<256;s<<=1){
    int add = (t>=s)? lds[t-s] : 0;
    __syncthreads();
    lds[t] += add;
    __syncthreads();
  }
  rp[b*256 + t + 1] = lds[t];
  if (t==0 && b==0) rp[0] = 0;
  if (t==255) bsum[b] = lds[255];
}

__global__ __launch_bounds__(256) void k_scan2(int* __restrict__ bsum){
  __shared__ int lds[256];
  int t = threadIdx.x;
  lds[t] = bsum[t];
  __syncthreads();
  for (int s=1;s<256;s<<=1){
    int add = (t>=s)? lds[t-s] : 0;
    __syncthreads();
    lds[t] += add;
    __syncthreads();
  }
  bsum[t] = (t==0)? 0 : lds[t-1];
}

__global__ __launch_bounds__(256) void k_scan3(int* __restrict__ rp, const int* __restrict__ bsum){
  int b = blockIdx.x, t = threadIdx.x;
  rp[b*256 + t + 1] += bsum[b];
}

__global__ __launch_bounds__(256) void k_fill(const int* __restrict__ key, const int* __restrict__ rp,
                                              int* __restrict__ cnt, int* __restrict__ colbuf){
  int e = blockIdx.x*256 + threadIdx.x;
  if (e >= NEDGE) return;
  int d = key[e];
  int p = atomicAdd(&cnt[d], 1);
  colbuf[rp[d] + p] = e;             // store edge id (sorted next for determinism)
}

__global__ __launch_bounds__(256) void k_sortrow(const int* __restrict__ rp, int* __restrict__ colbuf,
                                                 const int* __restrict__ other){
  int v = blockIdx.x*256 + threadIdx.x;
  if (v >= NN) return;
  int s0 = rp[v], s1 = rp[v+1];
  for (int i=s0+1;i<s1;i++){         // insertion sort by edge id ascending
    int key = colbuf[i]; int j = i-1;
    while (j>=s0 && colbuf[j]>key){ colbuf[j+1]=colbuf[j]; j--; }
    colbuf[j+1] = key;
  }
  for (int i=s0;i<s1;i++) colbuf[i] = other[colbuf[i]];
}

__global__ __launch_bounds__(256) void k_dinv(const int* __restrict__ degi, float* __restrict__ dinv){
  int v = blockIdx.x*256 + threadIdx.x;
  if (v >= NN) return;
  dinv[v] = 1.0f / sqrtf((float)(degi[v] + 1));   // +1 for self loop
}

// ---------------- stage-1 GCN ----------------
template<int CIN>
__global__ __launch_bounds__(256) void k_mm30(const float* __restrict__ x, const float* __restrict__ w,
                                              float* __restrict__ h, int nrow){
  __shared__ float ws[CIN*30];
  int t = threadIdx.x;
  for (int i=t;i<CIN*30;i+=256) ws[i] = w[i];
  __syncthreads();
  int id = blockIdx.x*256 + t;
  if (id >= nrow*30) return;
  int v = id/30, j = id - v*30;
  const float* xr = x + v*CIN;
  float acc = 0.f;
  #pragma unroll
  for (int k=0;k<CIN;k++) acc += xr[k]*ws[k*30+j];
  h[id] = acc;
}

// thread-per-element + XCD-resident mapping + chunk-4 prefetch (MLP).
__global__ __launch_bounds__(256) void k_gcn_agg(const float* __restrict__ h, const int* __restrict__ rp,
    const int* __restrict__ col, const float* __restrict__ dinv, const float* __restrict__ bias,
    float* __restrict__ y){
  int b = blockIdx.x;
  int xcd = b & 7, i = b >> 3;       // 960 per xcd
  int gs = i/120, j = i - gs*120;
  int graph = gs*8 + xcd;
  int id = graph*30720 + j*256 + threadIdx.x;
  int v = id/30, jc = id - v*30;
  float dv = dinv[v];
  float acc = 0.f;
  int a = rp[v], e = rp[v+1];
  for (; a+4<=e; a+=4){
    int s0=col[a], s1=col[a+1], s2=col[a+2], s3=col[a+3];
    float d0=dinv[s0], d1=dinv[s1], d2=dinv[s2], d3=dinv[s3];
    float h0=h[s0*30+jc], h1=h[s1*30+jc], h2=h[s2*30+jc], h3=h[s3*30+jc];
    acc += h0*(d0*dv);
    acc += h1*(d1*dv);
    acc += h2*(d2*dv);
    acc += h3*(d3*dv);
  }
  for (; a<e; ++a){
    int s = col[a];
    acc += h[s*30 + jc] * (dinv[s]*dv);
  }
  acc += h[id]*(dv*dv);      // self loop appended last (matches JAX concat order)
  y[id] = acc + bias[jc];
}

// ---------------- BatchNorm (two-pass, biased var) ----------------
__global__ __launch_bounds__(256) void k_bn_part(const float* __restrict__ x, int nrow,
    const float* __restrict__ mean, int pass, float* __restrict__ part){
  __shared__ float lds[256*31];
  int b = blockIdx.x, t = threadIdx.x;
  int rows = nrow >> 8;              // rows per block (nrow divisible by 256)
  float acc[30];
  #pragma unroll
  for (int f=0;f<30;f++) acc[f] = 0.f;
  for (int r=t; r<rows; r+=256){
    const float* xr = x + (b*rows + r)*30;
    if (pass == 0){
      #pragma unroll
      for (int f=0;f<30;f++) acc[f] += xr[f];
    } else {
      #pragma unroll
      for (int f=0;f<30;f++){ float d = xr[f]-mean[f]; acc[f] += d*d; }
    }
  }
  #pragma unroll
  for (int f=0;f<30;f++) lds[t*31+f] = acc[f];
  __syncthreads();
  for (int s=128;s>0;s>>=1){
    if (t<s){
      #pragma unroll
      for (int f=0;f<30;f++) lds[t*31+f] += lds[(t+s)*31+f];
    }
    __syncthreads();
  }
  if (t<30) part[b*30+t] = lds[t];
}

__global__ void k_bn_red(const float* __restrict__ part, float n, float* __restrict__ out){
  int f = threadIdx.x;
  if (f >= 30) return;
  float s = 0.f;
  for (int b=0;b<256;b++) s += part[b*30+f];
  out[f] = s / n;
}

__global__ __launch_bounds__(256) void k_bn_apply(const float* __restrict__ x, const float* __restrict__ mean,
    const float* __restrict__ var, const float* __restrict__ g, const float* __restrict__ be,
    float* __restrict__ out, int nrow){
  int id = blockIdx.x*256 + threadIdx.x;
  if (id >= nrow*30) return;
  int f = id % 30;
  out[id] = g[f]*(x[id]-mean[f]) * (1.0f/sqrtf(var[f]+1e-5f)) + be[f];
}

// ---------------- belief propagation (thread-per-element, XCD-resident) ----
// psi AND L both kept in per-run packed layout (base NN*CO, row stride Q):
// coalesced colsum reads and L1-resident small-q gathers. Final iter writes
// the [NN][126] concat for k_s1.
__device__ __forceinline__ void bp_decode(int b, int& graph, int& run, int& jj){
  int xcd = b & 7, i = b >> 3;
  int gs = i/504, j = i - gs*504;
  if      (j <   8){ run=0; jj=j;     }
  else if (j <  24){ run=1; jj=j-8;   }
  else if (j <  56){ run=2; jj=j-24;  }
  else if (j < 120){ run=3; jj=j-56;  }
  else if (j < 248){ run=4; jj=j-120; }
  else             { run=5; jj=j-248; }
  graph = gs*8 + xcd;
}

template<int Q, int CO, int L2Q>
__device__ __forceinline__ void bp_first_elem(int graph, int jj, float* __restrict__ psi_pk,
                                              float* __restrict__ lg, float eb,
                                              uint32_t k0, uint32_t k1){
  int elem = jj*256 + threadIdx.x;          // [0, 1024*Q)
  int rg = elem >> L2Q, c = elem & (Q-1);
  int row = graph*1024 + rg;
  uint32_t b0, b1;
  tf2x32(k0, k1, 0u, (uint32_t)(row*Q + c), b0, b1);   // counter = (0, idx)
  uint32_t bits = b0 ^ b1;
  float f = __uint_as_float((bits>>9) | 0x3F800000u) - 1.0f;     // [0,1)
  const float lo = __uint_as_float(0xBF7FFFFFu);                 // nextafter(-1,0)
  float u = fmaxf(lo, f*2.0f + lo);
  float v = __uint_as_float(0x3FB504F3u) * erfinv32(u);          // sqrt(2)*erfinv
  // softmax over q-lane group (same shuffle sequence as R1)
  float m = v;
  #pragma unroll
  for (int off=Q>>1; off; off>>=1) m = fmaxf(m, __shfl_xor(m, off, Q));
  float e = expf(v - m);
  float ss = e;
  #pragma unroll
  for (int off=Q>>1; off; off>>=1) ss += __shfl_xor(ss, off, Q);
  float pn = e / ss;
  psi_pk[(size_t)NN*CO + (size_t)row*Q + c] = pn;
  lg    [(size_t)NN*CO + (size_t)row*Q + c] = log1pf(eb*pn);
}

__global__ __launch_bounds__(256) void k_bp_first(float* __restrict__ psi_pk, float* __restrict__ lg,
                                                  const float* __restrict__ betas){
  int graph, run, jj;
  bp_decode(blockIdx.x, graph, run, jj);
  uint32_t k0, k1;
  tf2x32(0u, 42u, 0u, (uint32_t)run, k0, k1);          // fold_in(key(42), run)
  float eb = expm1f(betas[run]);
  switch(run){
    case 0: bp_first_elem< 2, 0,1>(graph, jj, psi_pk, lg, eb, k0, k1); break;
    case 1: bp_first_elem< 4, 2,2>(graph, jj, psi_pk, lg, eb, k0, k1); break;
    case 2: bp_first_elem< 8, 6,3>(graph, jj, psi_pk, lg, eb, k0, k1); break;
    case 3: bp_first_elem<16,14,4>(graph, jj, psi_pk, lg, eb, k0, k1); break;
    case 4: bp_first_elem<32,30,5>(graph, jj, psi_pk, lg, eb, k0, k1); break;
    default:bp_first_elem<64,62,6>(graph, jj, psi_pk, lg, eb, k0, k1); break;
  }
}

// edge loop gathers PRECOMPUTED L (per-run packed) and sums in ascending
// edge order (bit-identical). Non-final: write packed psi + packed L.
// Final: write [NN][126] concat only.
template<int Q, int CO, int L2Q>
__device__ __forceinline__ void bp_step_elem(int graph, int run, int jj,
    const float* __restrict__ lcur, float* __restrict__ nxt, float* __restrict__ lnxt,
    const int* __restrict__ rp, const int* __restrict__ col,
    const float* __restrict__ field, float eb, int fin){
  int elem = jj*256 + threadIdx.x;
  int rg = elem >> L2Q, c = elem & (Q-1);
  int row = graph*1024 + rg;
  const float* base = lcur + (size_t)NN*CO + c;
  float acc = 0.f;
  int a = rp[row], b2 = rp[row+1];
  for (; a+8<=b2; a+=8){
    int s0=col[a],s1=col[a+1],s2=col[a+2],s3=col[a+3];
    int s4=col[a+4],s5=col[a+5],s6=col[a+6],s7=col[a+7];
    float v0=base[s0*Q],v1=base[s1*Q],v2=base[s2*Q],v3=base[s3*Q];
    float v4=base[s4*Q],v5=base[s5*Q],v6=base[s6*Q],v7=base[s7*Q];
    acc += v0; acc += v1; acc += v2; acc += v3;
    acc += v4; acc += v5; acc += v6; acc += v7;
  }
  for (; a+4<=b2; a+=4){
    int s0=col[a],s1=col[a+1],s2=col[a+2],s3=col[a+3];
    float v0=base[s0*Q],v1=base[s1*Q],v2=base[s2*Q],v3=base[s3*Q];
    acc += v0; acc += v1; acc += v2; acc += v3;
  }
  for (; a<b2; ++a){
    acc += base[col[a]*Q];
  }
  float v = acc - field[run*64 + c];
  float m = v;
  #pragma unroll
  for (int off=Q>>1; off; off>>=1) m = fmaxf(m, __shfl_xor(m, off, Q));
  float e = expf(v - m);
  float ss = e;
  #pragma unroll
  for (int off=Q>>1; off; off>>=1) ss += __shfl_xor(ss, off, Q);
  float pn = e / ss;
  if (fin){
    nxt[(size_t)row*126 + CO + c] = pn;                    // concat for k_s1
  } else {
    nxt [(size_t)NN*CO + (size_t)row*Q + c] = pn;          // packed psi
    lnxt[(size_t)NN*CO + (size_t)row*Q + c] = log1pf(eb*pn);
  }
}

__global__ __launch_bounds__(256) void k_bp_step(
    float* __restrict__ nxt, const float* __restrict__ lcur, float* __restrict__ lnxt,
    const int* __restrict__ rp, const int* __restrict__ col,
    const float* __restrict__ field, const float* __restrict__ betas, int fin){
  int graph, run, jj;
  bp_decode(blockIdx.x, graph, run, jj);
  float eb = expm1f(betas[run]);
  switch(run){
    case 0: bp_step_elem< 2, 0,1>(graph, run, jj, lcur, nxt, lnxt, rp, col, field, eb, fin); break;
    case 1: bp_step_elem< 4, 2,2>(graph, run, jj, lcur, nxt, lnxt, rp, col, field, eb, fin); break;
    case 2: bp_step_elem< 8, 6,3>(graph, run, jj, lcur, nxt, lnxt, rp, col, field, eb, fin); break;
    case 3: bp_step_elem<16,14,4>(graph, run, jj, lcur, nxt, lnxt, rp, col, field, eb, fin); break;
    case 4: bp_step_elem<32,30,5>(graph, run, jj, lcur, nxt, lnxt, rp, col, field, eb, fin); break;
    default:bp_step_elem<64,62,6>(graph, run, jj, lcur, nxt, lnxt, rp, col, field, eb, fin); break;
  }
}

// column sums over PACKED psi; per 256-row chunk, rows ascending (order ==
// R1, bit-identical field). Coalesced: row stride is q floats.
__global__ __launch_bounds__(64) void k_colsum_part(const float* __restrict__ psi_pk, float* __restrict__ part){
  int b = blockIdx.x;
  int xcd = b & 7, i = b >> 3;       // i in [0,192)
  int gs = i/24, rem = i - gs*24;
  int run = rem >> 2, cg = rem & 3;
  int graph = gs*8 + xcd;
  int chunk = graph*4 + cg;          // global 256-row chunk id (== R1 "b")
  int q = cQS[run];
  int co = (run==0)?0:(run==1)?2:(run==2)?6:(run==3)?14:(run==4)?30:62;
  int c = threadIdx.x;
  if (c >= q) return;
  float s = 0.f;
  const float* p = psi_pk + (size_t)NN*co + (size_t)chunk*256*q + c;
  #pragma unroll 8
  for (int r=0;r<256;r++) s += p[r*q];
  part[(run*256 + chunk)*64 + c] = s;
}

__global__ void k_field(const float* __restrict__ part, const float* __restrict__ betas,
                        float* __restrict__ field){
  int id = threadIdx.x;              // 384 threads: 6 runs x 64 cols
  int run = id >> 6, c = id & 63;
  if (c >= cQS[run]) return;
  float s = 0.f;
  for (int b=0;b<256;b++) s += part[(run*256 + b)*64 + c];
  float beta = betas[run];
  field[id] = s * (3.8f*beta/65536.0f);
}

// ---------------- diff-pool ----------------
// wave-per-4-rows; x in registers (readlane broadcast), float2 weights from
// LDS, no per-row barriers. Matmul FP order == reference (pb + ascending j).
__global__ __launch_bounds__(512) void k_s1(const float* __restrict__ cat, const float* __restrict__ pw,
                                            const float* __restrict__ pb, float* __restrict__ s1){
  __shared__ float wl[12600];
  int t = threadIdx.x;
  for (int i=t;i<12600;i+=512) wl[i] = pw[i];
  int w = t>>6, tl = t&63;
  bool act = tl < 50;
  float pb0 = act? pb[2*tl]   : 0.f;
  float pb1 = act? pb[2*tl+1] : 0.f;
  __syncthreads();
  #pragma unroll
  for (int p=0;p<2;p++){
    int row0 = blockIdx.x*64 + p*32 + w*4;
    float x0[4], x1[4];
    #pragma unroll
    for (int r=0;r<4;r++){
      if (tl < 63){
        float2 xv = *reinterpret_cast<const float2*>(cat + (size_t)(row0+r)*126 + 2*tl);
        x0[r]=xv.x; x1[r]=xv.y;
      } else { x0[r]=0.f; x1[r]=0.f; }
    }
    float a0[4], a1[4];
    #pragma unroll
    for (int r=0;r<4;r++){ a0[r]=pb0; a1[r]=pb1; }
    #pragma unroll 3
    for (int jj=0;jj<63;jj++){
      float2 wA = *reinterpret_cast<const float2*>(&wl[(2*jj  )*100 + 2*tl]);
      float2 wB = *reinterpret_cast<const float2*>(&wl[(2*jj+1)*100 + 2*tl]);
      #pragma unroll
      for (int r=0;r<4;r++){
        float xa = __int_as_float(__builtin_amdgcn_readlane(__float_as_int(x0[r]), jj));
        float xb = __int_as_float(__builtin_amdgcn_readlane(__float_as_int(x1[r]), jj));
        a0[r] += xa*wA.x;   // j = 2jj
        a1[r] += xa*wA.y;
        a0[r] += xb*wB.x;   // j = 2jj+1
        a1[r] += xb*wB.y;
      }
    }
    #pragma unroll
    for (int r=0;r<4;r++){
      float m = act? fmaxf(a0[r], a1[r]) : -FLT_MAX;
      #pragma unroll
      for (int off=32; off; off>>=1) m = fmaxf(m, __shfl_xor(m, off, 64));
      float e0 = act? expf(a0[r]-m) : 0.f;
      float e1 = act? expf(a1[r]-m) : 0.f;
      float ss = e0+e1;
      #pragma unroll
      for (int off=32; off; off>>=1) ss += __shfl_xor(ss, off, 64);
      if (act){
        float2 o; o.x = e0/ss; o.y = e1/ss;
        *reinterpret_cast<float2*>(s1 + (size_t)(row0+r)*100 + 2*tl) = o;
      }
    }
  }
}

// thread-per-element + XCD mapping + chunk-4 prefetch.
__global__ __launch_bounds__(256) void k_T(const float* __restrict__ s1, const int* __restrict__ rp,
                                           const int* __restrict__ col, float* __restrict__ T){
  int b = blockIdx.x;
  int xcd = b & 7, i = b >> 3;       // 3200 per xcd
  int gs = i/400, j = i - gs*400;
  int graph = gs*8 + xcd;
  int id = graph*102400 + j*256 + threadIdx.x;
  int v = id/100, l = id - v*100;
  float acc = 0.f;
  int a = rp[v], e = rp[v+1];
  for (; a+4<=e; a+=4){
    int s0=col[a], s1_=col[a+1], s2=col[a+2], s3=col[a+3];
    float v0=s1[s0*100+l], v1=s1[s1_*100+l], v2=s1[s2*100+l], v3=s1[s3*100+l];
    acc += v0; acc += v1; acc += v2; acc += v3;
  }
  for (; a<e; ++a) acc += s1[col[a]*100 + l];
  T[id] = acc;
}

// split-K LDS-tiled GEMM: padj_part[qtr] = s1^T * T over n-quarter.
// grid (graph,qtr) flattened = 256 blocks; each output element owned by one
// thread, n ascending within its quarter.
__global__ __launch_bounds__(512) void k_p1adj_sk(const float* __restrict__ s1, const float* __restrict__ T,
                                                  float* __restrict__ part){
  __shared__ float sS[6400];   // 64 rows x 100 of s1
  __shared__ float sT[6400];   // 64 rows x 100 of T
  int blk = blockIdx.x;
  int b = blk >> 2, qtr = blk & 3;
  int t = threadIdx.x;
  int tk = t/20, tl = t - tk*20;       // tk<25 -> k0, tl<20 -> l0
  bool act = t < 500;
  int k0 = tk*4, l0 = tl*5;
  float acc[4][5];
  #pragma unroll
  for (int i=0;i<4;i++)
    #pragma unroll
    for (int j=0;j<5;j++) acc[i][j] = 0.f;
  const float* s1b = s1 + (size_t)b*102400;
  const float* Tb  = T  + (size_t)b*102400;
  for (int c=qtr*4; c<qtr*4+4; c++){
    for (int i=t;i<6400;i+=512){ sS[i] = s1b[c*6400+i]; sT[i] = Tb[c*6400+i]; }
    __syncthreads();
    if (act){
      #pragma unroll 2
      for (int n=0;n<64;n++){
        const float* sr = &sS[n*100 + k0];
        const float* tr = &sT[n*100 + l0];
        float s0=sr[0], s1v=sr[1], s2=sr[2], s3=sr[3];
        float t0=tr[0], t1=tr[1], t2=tr[2], t3=tr[3], t4=tr[4];
        acc[0][0]+=s0*t0; acc[0][1]+=s0*t1; acc[0][2]+=s0*t2; acc[0][3]+=s0*t3; acc[0][4]+=s0*t4;
        acc[1][0]+=s1v*t0; acc[1][1]+=s1v*t1; acc[1][2]+=s1v*t2; acc[1][3]+=s1v*t3; acc[1][4]+=s1v*t4;
        acc[2][0]+=s2*t0; acc[2][1]+=s2*t1; acc[2][2]+=s2*t2; acc[2][3]+=s2*t3; acc[2][4]+=s2*t4;
        acc[3][0]+=s3*t0; acc[3][1]+=s3*t1; acc[3][2]+=s3*t2; acc[3][3]+=s3*t3; acc[3][4]+=s3*t4;
      }
    }
    __syncthreads();
  }
  if (act){
    float* pp = part + (size_t)qtr*640000 + (size_t)b*10000;
    #pragma unroll
    for (int i=0;i<4;i++){
      float* o = pp + (k0+i)*100 + l0;
      #pragma unroll
      for (int j=0;j<5;j++) o[j] = acc[i][j];
    }
  }
}

__global__ __launch_bounds__(256) void k_p1adj_red(const float* __restrict__ part, float* __restrict__ padj){
  int id = blockIdx.x*256 + threadIdx.x;
  if (id >= NBG*10000) return;
  float s = part[id];
  s += part[640000 + id];
  s += part[1280000 + id];
  s += part[1920000 + id];
  padj[id] = s;
}

// split-K px = s1^T * x13 over n-quarter. grid 256 = (graph,qtr).
__global__ __launch_bounds__(256) void k_p1x_sk(const float* __restrict__ s1, const float* __restrict__ x13,
                                                float* __restrict__ part){
  __shared__ float sS[6400];   // 64 x 100 of s1
  __shared__ float sX[1920];   // 64 x 30 of x13
  int blk = blockIdx.x;
  int b = blk >> 2, qtr = blk & 3;
  int t = threadIdx.x;
  int tk = t/10, tl = t - tk*10;       // tk<25 -> k0, tl<10 -> d0
  bool act = t < 250;
  int k0 = tk*4, d0 = tl*3;
  float acc[4][3];
  #pragma unroll
  for (int i=0;i<4;i++)
    #pragma unroll
    for (int j=0;j<3;j++) acc[i][j] = 0.f;
  const float* s1b = s1 + (size_t)b*102400;
  const float* xb  = x13 + (size_t)b*30720;
  for (int c=qtr*4; c<qtr*4+4; c++){
    for (int i=t;i<6400;i+=256) sS[i] = s1b[c*6400+i];
    for (int i=t;i<1920;i+=256) sX[i] = xb[c*1920+i];
    __syncthreads();
    if (act){
      #pragma unroll 2
      for (int n=0;n<64;n++){
        const float* sr = &sS[n*100 + k0];
        const float* xr = &sX[n*30 + d0];
        float s0=sr[0], s1v=sr[1], s2=sr[2], s3=sr[3];
        float x0=xr[0], x1=xr[1], x2=xr[2];
        acc[0][0]+=s0*x0; acc[0][1]+=s0*x1; acc[0][2]+=s0*x2;
        acc[1][0]+=s1v*x0; acc[1][1]+=s1v*x1; acc[1][2]+=s1v*x2;
        acc[2][0]+=s2*x0; acc[2][1]+=s2*x1; acc[2][2]+=s2*x2;
        acc[3][0]+=s3*x0; acc[3][1]+=s3*x1; acc[3][2]+=s3*x2;
      }
    }
    __syncthreads();
  }
  if (act){
    float* pp = part + (size_t)qtr*192000 + (size_t)b*3000;
    #pragma unroll
    for (int i=0;i<4;i++){
      float* o = pp + (k0+i)*30 + d0;
      #pragma unroll
      for (int j=0;j<3;j++) o[j] = acc[i][j];
    }
  }
}

__global__ __launch_bounds__(256) void k_p1x_red(const float* __restrict__ part, float* __restrict__ px){
  int id = blockIdx.x*256 + threadIdx.x;
  if (id >= NBG*3000) return;
  float s = part[id];
  s += part[192000 + id];
  s += part[384000 + id];
  s += part[576000 + id];
  px[id] = s;
}

// ---------------- stage-2 dense GCN ----------------
__global__ __launch_bounds__(256) void k_dinv2(const float* __restrict__ padj, float* __restrict__ dv){
  int id = blockIdx.x*256 + threadIdx.x;
  if (id >= NBG*100) return;
  const float* r = padj + id*100;
  int k = id % 100;
  float s = 0.f;
  for (int l=0;l<100;l++){
    float v = r[l];
    if (l==k) v += 1.0f;     // A = adj + I
    s += v;
  }
  dv[id] = 1.0f/sqrtf(s);
}

__global__ __launch_bounds__(256) void k_Ank(const float* __restrict__ padj, const float* __restrict__ dv,
                                             float* __restrict__ An){
  int id = blockIdx.x*256 + threadIdx.x;
  if (id >= NBG*10000) return;
  int b = id/10000;
  int rem = id - b*10000;
  int k = rem/100, l = rem - k*100;
  float a = padj[id] + ((k==l)? 1.0f : 0.0f);
  An[id] = (dv[b*100+k]*a)*dv[b*100+l];
}

__global__ __launch_bounds__(256) void k_y2(const float* __restrict__ An, const float* __restrict__ h,
    const float* __restrict__ bias, float* __restrict__ y){
  int id = blockIdx.x*256 + threadIdx.x;
  if (id >= NBG*100*30) return;
  int d = id % 30;
  int bk = id / 30;
  int b = bk / 100;
  const float* Ar = An + bk*100;
  const float* hb = h + b*100*30;
  float acc = 0.f;
  for (int l=0;l<100;l++) acc += Ar[l]*hb[l*30+d];
  y[id] = acc + bias[d];
}

// ---------------- pools + FC ----------------
__global__ __launch_bounds__(256) void k_pool2(const float* __restrict__ A,
    const float* __restrict__ Bv, const float* __restrict__ Cv,
    int rows, float* __restrict__ conv, int coff){
  __shared__ float lds[256*31];
  int b = blockIdx.x, a = blockIdx.y, t = threadIdx.x;
  const float* X = (a==0)? A : ((a==1)? Bv : Cv);
  float acc[30];
  #pragma unroll
  for (int f=0;f<30;f++) acc[f] = -FLT_MAX;
  for (int r=t; r<rows; r+=256){
    const float* xr = X + (size_t)(b*rows + r)*30;
    #pragma unroll
    for (int f=0;f<30;f++) acc[f] = fmaxf(acc[f], xr[f]);
  }
  #pragma unroll
  for (int f=0;f<30;f++) lds[t*31+f] = acc[f];
  __syncthreads();
  for (int s=128;s>0;s>>=1){
    if (t<s){
      #pragma unroll
      for (int f=0;f<30;f++) lds[t*31+f] = fmaxf(lds[t*31+f], lds[(t+s)*31+f]);
    }
    __syncthreads();
  }
  if (t<30) conv[b*180 + coff + a*30 + t] = lds[t];
}

__global__ __launch_bounds__(64) void k_fc(const float* __restrict__ conv,
    const float* __restrict__ w1, const float* __restrict__ b1,
    const float* __restrict__ w2, const float* __restrict__ b2, float* __restrict__ out){
  __shared__ float row[180];
  __shared__ float hid[50];
  int b = blockIdx.x, t = threadIdx.x;
  for (int i=t;i<180;i+=64) row[i] = conv[b*180+i];
  __syncthreads();
  if (t < 50){
    float a = b1[t];
    for (int i=0;i<180;i++) a += row[i]*w1[i*50+t];
    hid[t] = fmaxf(a, 0.f);
  }
  __syncthreads();
  if (t < 6){
    float a = b2[t];
    for (int i=0;i<50;i++) a += hid[i]*w2[i*6+t];
    out[b*6+t] = a;
  }
  if (b==0 && t==63) out[NBG*6] = 0.0f;   // second tuple output: zeros((1,))
}

// ---------------------------------------------------------------------------
extern "C" void kernel_launch(void* const* d_in, const int* in_sizes, int n_in,
                              void* d_out, int out_size, void* d_ws, size_t ws_size,
                              hipStream_t stream)
{
  (void)in_sizes; (void)n_in; (void)out_size; (void)ws_size;
  const float* x   = (const float*)d_in[0];
  const int*   src = (const int*)d_in[1];
  const int*   dst = src + NEDGE;
  const float* w11=(const float*)d_in[3],  *b11=(const float*)d_in[4],  *g11=(const float*)d_in[5],  *be11=(const float*)d_in[6];
  const float* w12=(const float*)d_in[7],  *b12=(const float*)d_in[8],  *g12=(const float*)d_in[9],  *be12=(const float*)d_in[10];
  const float* w13=(const float*)d_in[11], *b13=(const float*)d_in[12], *g13=(const float*)d_in[13], *be13=(const float*)d_in[14];
  const float* w21=(const float*)d_in[15], *b21=(const float*)d_in[16], *g21=(const float*)d_in[17], *be21=(const float*)d_in[18];
  const float* w22=(const float*)d_in[19], *b22=(const float*)d_in[20], *g22=(const float*)d_in[21], *be22=(const float*)d_in[22];
  const float* w23=(const float*)d_in[23], *b23=(const float*)d_in[24], *g23=(const float*)d_in[25], *be23=(const float*)d_in[26];
  const float* betas=(const float*)d_in[27];
  const float* poolw=(const float*)d_in[28], *poolb=(const float*)d_in[29];
  const float* fc1w=(const float*)d_in[30], *fc1b=(const float*)d_in[31];
  const float* fc2w=(const float*)d_in[32], *fc2b=(const float*)d_in[33];
  float* out = (float*)d_out;

  uint8_t* basep = (uint8_t*)d_ws;
  size_t off = 0;
  auto take = [&](size_t bytes)->void*{
    void* p = basep + off;
    off = (off + bytes + 255) & ~(size_t)255;
    return p;
  };
  int* degi    = (int*)take((size_t)NN*4);
  int* dego    = (int*)take((size_t)NN*4);
  int* cntA    = (int*)take((size_t)NN*4);
  int* cntB    = (int*)take((size_t)NN*4);
  int* rp_in   = (int*)take((size_t)(NN+1)*4);
  int* rp_out  = (int*)take((size_t)(NN+1)*4);
  int* bsum    = (int*)take(256*4);
  int* col_in  = (int*)take((size_t)NEDGE*4);
  int* col_out = (int*)take((size_t)NEDGE*4);
  float* dinv  = (float*)take((size_t)NN*4);
  float* hbuf  = (float*)take((size_t)NN*30*4);
  float* tmpY  = (float*)take((size_t)NN*30*4);
  float* X1    = (float*)take((size_t)NN*30*4);
  float* X2    = (float*)take((size_t)NN*30*4);
  float* X3    = (float*)take((size_t)NN*30*4);
  float* bufA  = (float*)take((size_t)NN*126*4);
  float* bufB  = (float*)take((size_t)NN*126*4);
  float* logA  = (float*)take((size_t)NN*126*4);
  float* logB  = (float*)take((size_t)NN*126*4);
  float* partCS= (float*)take((size_t)6*256*64*4);
  float* fieldv= (float*)take(384*4);
  float* partBN= (float*)take(256*30*4);
  float* meanv = (float*)take(128);
  float* varv  = (float*)take(128);
  float* px    = (float*)take(192000*4);
  float* padj  = (float*)take(640000*4);
  float* An    = (float*)take(640000*4);
  float* dinv2 = (float*)take(6400*4);
  float* h2    = (float*)take(192000*4);
  float* y2    = (float*)take(192000*4);
  float* X21   = (float*)take(192000*4);
  float* X22   = (float*)take(192000*4);
  float* X23   = (float*)take(192000*4);
  float* conv  = (float*)take(64*180*4);

  // split-K partial buffers live in logB (dead after BP: final iter writes no L)
  float* pAdjPart = logB;               // 4*640000 floats
  float* pPxPart  = logB + 2560000;     // 4*192000 floats

  // ---- CSR setup ----
  hipMemsetAsync(degi, 0, (size_t)NN*4, stream);
  hipMemsetAsync(dego, 0, (size_t)NN*4, stream);
  hipMemsetAsync(cntA, 0, (size_t)NN*4, stream);
  hipMemsetAsync(cntB, 0, (size_t)NN*4, stream);
  k_count<<<2048,256,0,stream>>>(src,dst,degi,dego);
  k_scan1<<<256,256,0,stream>>>(degi, rp_in, bsum);
  k_scan2<<<1,256,0,stream>>>(bsum);
  k_scan3<<<256,256,0,stream>>>(rp_in, bsum);
  k_scan1<<<256,256,0,stream>>>(dego, rp_out, bsum);
  k_scan2<<<1,256,0,stream>>>(bsum);
  k_scan3<<<256,256,0,stream>>>(rp_out, bsum);
  k_fill<<<2048,256,0,stream>>>(dst, rp_in, cntA, col_in);
  k_fill<<<2048,256,0,stream>>>(src, rp_out, cntB, col_out);
  k_sortrow<<<256,256,0,stream>>>(rp_in,  col_in,  src);
  k_sortrow<<<256,256,0,stream>>>(rp_out, col_out, dst);
  k_dinv<<<256,256,0,stream>>>(degi, dinv);

  auto run_bn = [&](const float* yin, float* xout, const float* g, const float* be, int nrow){
    k_bn_part<<<256,256,0,stream>>>(yin, nrow, meanv, 0, partBN);
    k_bn_red<<<1,32,0,stream>>>(partBN, (float)nrow, meanv);
    k_bn_part<<<256,256,0,stream>>>(yin, nrow, meanv, 1, partBN);
    k_bn_red<<<1,32,0,stream>>>(partBN, (float)nrow, varv);
    k_bn_apply<<<(nrow*30)/256,256,0,stream>>>(yin, meanv, varv, g, be, xout, nrow);
  };

  // ---- stage 1: sparse GCN + BN x3 ----
  k_mm30<3><<<7680,256,0,stream>>>(x, w11, hbuf, NN);
  k_gcn_agg<<<7680,256,0,stream>>>(hbuf, rp_in, col_in, dinv, b11, tmpY);
  run_bn(tmpY, X1, g11, be11, NN);
  k_mm30<30><<<7680,256,0,stream>>>(X1, w12, hbuf, NN);
  k_gcn_agg<<<7680,256,0,stream>>>(hbuf, rp_in, col_in, dinv, b12, tmpY);
  run_bn(tmpY, X2, g12, be12, NN);
  k_mm30<30><<<7680,256,0,stream>>>(X2, w13, hbuf, NN);
  k_gcn_agg<<<7680,256,0,stream>>>(hbuf, rp_in, col_in, dinv, b13, tmpY);
  run_bn(tmpY, X3, g13, be13, NN);
  k_pool2<<<dim3(NBG,3),256,0,stream>>>(X1, X2, X3, 1024, conv, 0);

  // ---- belief propagation (packed psi + packed L, ping-pong) ----
  k_bp_first<<<32256,256,0,stream>>>(bufA, logA, betas);
  float* cur = bufA;  float* nxt = bufB;
  float* lcur = logA; float* lnxt = logB;
  for (int it=0; it<10; ++it){
    k_colsum_part<<<1536,64,0,stream>>>(cur, partCS);
    k_field<<<1,384,0,stream>>>(partCS, betas, fieldv);
    int fin = (it==9);
    k_bp_step<<<32256,256,0,stream>>>(nxt, lcur, lnxt, rp_in, col_in, fieldv, betas, fin);
    float* tp = cur;  cur = nxt;   nxt = tp;
    float* tl = lcur; lcur = lnxt; lnxt = tl;
  }
  // final concatenated psi [NN][126] now in bufA (it9 wrote nxt=bufA as [126])

  // ---- diff-pool ----
  k_s1<<<1024,512,0,stream>>>(bufA, poolw, poolb, bufB);      // s1 [n,100] -> bufB
  k_T<<<25600,256,0,stream>>>(bufB, rp_out, col_out, bufA);   // T = A*s1   -> bufA
  k_p1adj_sk<<<256,512,0,stream>>>(bufB, bufA, pAdjPart);
  k_p1adj_red<<<2500,256,0,stream>>>(pAdjPart, padj);
  k_p1x_sk<<<256,256,0,stream>>>(bufB, X3, pPxPart);
  k_p1x_red<<<750,256,0,stream>>>(pPxPart, px);
  k_dinv2<<<25,256,0,stream>>>(padj, dinv2);
  k_Ank<<<2500,256,0,stream>>>(padj, dinv2, An);

  // ---- stage 2: dense GCN + BN x3 ----
  auto gcn2 = [&](const float* xin, const float* w, const float* bb, const float* g,
                  const float* be, float* xout){
    k_mm30<30><<<750,256,0,stream>>>(xin, w, h2, NBG*100);
    k_y2<<<750,256,0,stream>>>(An, h2, bb, y2);
    run_bn(y2, xout, g, be, NBG*100);
  };
  gcn2(px,  w21, b21, g21, be21, X21);
  gcn2(X21, w22, b22, g22, be22, X22);
  gcn2(X22, w23, b23, g23, be23, X23);
  k_pool2<<<dim3(NBG,3),256,0,stream>>>(X21, X22, X23, 100, conv, 90);

  // ---- FC head ----
  k_fc<<<64,64,0,stream>>>(conv, fc1w, fc1b, fc2w, fc2b, out);
}

// Round 10
// 1362.633 us; speedup vs baseline: 2.6809x; 1.1483x over previous
//
#include <hip/hip_runtime.h>
#include <stdint.h>
#include <float.h>

// ---------------------------------------------------------------------------
// Net_57604101374728: GCN(x3)+BN -> maxpool | 6x belief-prop -> diffpool ->
// dense GCN(x3)+BN -> maxpool -> FC. Full fp32 port of the JAX reference.
//
// R10: (1) BP column-vectorized: thread owns 4 cols (float4 gathers, 4x fewer
// loads/threads); softmax butterfly emulated bit-exactly (cross-lane shfl for
// off>=4, in-register temps for off=2,1; same descending-off order). (2) k_T
// float4 col-quads, k_gcn_agg float2 col-pairs (per-col order unchanged).
// (3) BN mean+var in ONE pass (E[x2]-m^2; sub-bf16 deviation, smooth path).
// BP remains bit-exact end-to-end.
// ---------------------------------------------------------------------------

constexpr int NN    = 65536;    // total nodes
constexpr int NEDGE = 524288;   // edges
constexpr int NBG   = 64;       // graphs

__constant__ int cQS[6]   = {2,4,8,16,32,64};

// ---------------- threefry2x32 (20 rounds) ----------------
__device__ __forceinline__ void tf2x32(uint32_t k0, uint32_t k1, uint32_t x0, uint32_t x1,
                                       uint32_t& o0, uint32_t& o1){
  uint32_t ks[3] = {k0, k1, k0 ^ k1 ^ 0x1BD11BDAu};
  x0 += ks[0]; x1 += ks[1];
  const int RA[4] = {13,15,26,6}, RB[4] = {17,29,16,24};
  #pragma unroll
  for (int i=0;i<5;i++){
    const int* r = (i&1)? RB : RA;
    #pragma unroll
    for (int j=0;j<4;j++){
      x0 += x1;
      x1 = (x1 << r[j]) | (x1 >> (32 - r[j]));
      x1 ^= x0;
    }
    x0 += ks[(i+1)%3];
    x1 += ks[(i+2)%3] + (uint32_t)(i+1);
  }
  o0 = x0; o1 = x1;
}

// ---------------- XLA ErfInv32 (Giles), contraction off ----------------
__device__ __forceinline__ float erfinv32(float xx){
  #pragma clang fp contract(off)
  float w = -log1pf(-xx*xx);
  float p;
  if (w < 5.0f){
    w = w - 2.5f;
    p = 2.81022636e-08f;
    p = 3.43273939e-07f  + p*w;
    p = -3.5233877e-06f  + p*w;
    p = -4.39150654e-06f + p*w;
    p = 0.00021858087f   + p*w;
    p = -0.00125372503f  + p*w;
    p = -0.00417768164f  + p*w;
    p = 0.246640727f     + p*w;
    p = 1.50140941f      + p*w;
  } else {
    w = sqrtf(w) - 3.0f;
    p = -0.000200214257f;
    p = 0.000100950558f  + p*w;
    p = 0.00134934322f   + p*w;
    p = -0.00367342844f  + p*w;
    p = 0.00573950773f   + p*w;
    p = -0.0076224613f   + p*w;
    p = 0.00943887047f   + p*w;
    p = 1.00167406f      + p*w;
    p = 2.83297682f      + p*w;
  }
  return p*xx;
}

// ---------------- CSR construction ----------------
__global__ __launch_bounds__(256) void k_count(const int* __restrict__ src, const int* __restrict__ dst,
                                               int* __restrict__ degi, int* __restrict__ dego){
  int e = blockIdx.x*256 + threadIdx.x;
  if (e >= NEDGE) return;
  atomicAdd(&degi[dst[e]], 1);
  atomicAdd(&dego[src[e]], 1);
}

__global__ __launch_bounds__(256) void k_scan1(const int* __restrict__ deg, int* __restrict__ rp,
                                               int* __restrict__ bsum){
  __shared__ int lds[256];
  int b = blockIdx.x, t = threadIdx.x;
  lds[t] = deg[b*256 + t];
  __syncthreads();
  for (int s=1;s<256;s<<=1){
    int add = (t>=s)? lds[t-s] : 0;
    __syncthreads();
    lds[t] += add;
    __syncthreads();
  }
  rp[b*256 + t + 1] = lds[t];
  if (t==0 && b==0) rp[0] = 0;
  if (t==255) bsum[b] = lds[255];
}

__global__ __launch_bounds__(256) void k_scan2(int* __restrict__ bsum){
  __shared__ int lds[256];
  int t = threadIdx.x;
  lds[t] = bsum[t];
  __syncthreads();
  for (int s=1;s<256;s<<=1){
    int add = (t>=s)? lds[t-s] : 0;
    __syncthreads();
    lds[t] += add;
    __syncthreads();
  }
  bsum[t] = (t==0)? 0 : lds[t-1];
}

__global__ __launch_bounds__(256) void k_scan3(int* __restrict__ rp, const int* __restrict__ bsum){
  int b = blockIdx.x, t = threadIdx.x;
  rp[b*256 + t + 1] += bsum[b];
}

__global__ __launch_bounds__(256) void k_fill(const int* __restrict__ key, const int* __restrict__ rp,
                                              int* __restrict__ cnt, int* __restrict__ colbuf){
  int e = blockIdx.x*256 + threadIdx.x;
  if (e >= NEDGE) return;
  int d = key[e];
  int p = atomicAdd(&cnt[d], 1);
  colbuf[rp[d] + p] = e;             // store edge id (sorted next for determinism)
}

__global__ __launch_bounds__(256) void k_sortrow(const int* __restrict__ rp, int* __restrict__ colbuf,
                                                 const int* __restrict__ other){
  int v = blockIdx.x*256 + threadIdx.x;
  if (v >= NN) return;
  int s0 = rp[v], s1 = rp[v+1];
  for (int i=s0+1;i<s1;i++){         // insertion sort by edge id ascending
    int key = colbuf[i]; int j = i-1;
    while (j>=s0 && colbuf[j]>key){ colbuf[j+1]=colbuf[j]; j--; }
    colbuf[j+1] = key;
  }
  for (int i=s0;i<s1;i++) colbuf[i] = other[colbuf[i]];
}

__global__ __launch_bounds__(256) void k_dinv(const int* __restrict__ degi, float* __restrict__ dinv){
  int v = blockIdx.x*256 + threadIdx.x;
  if (v >= NN) return;
  dinv[v] = 1.0f / sqrtf((float)(degi[v] + 1));   // +1 for self loop
}

// ---------------- stage-1 GCN ----------------
template<int CIN>
__global__ __launch_bounds__(256) void k_mm30(const float* __restrict__ x, const float* __restrict__ w,
                                              float* __restrict__ h, int nrow){
  __shared__ float ws[CIN*30];
  int t = threadIdx.x;
  for (int i=t;i<CIN*30;i+=256) ws[i] = w[i];
  __syncthreads();
  int id = blockIdx.x*256 + t;
  if (id >= nrow*30) return;
  int v = id/30, j = id - v*30;
  const float* xr = x + v*CIN;
  float acc = 0.f;
  #pragma unroll
  for (int k=0;k<CIN;k++) acc += xr[k]*ws[k*30+j];
  h[id] = acc;
}

// thread per (row, col-pair): float2 gathers, per-col order == before.
// 3840 blocks: 60 per graph, XCD-resident.
__global__ __launch_bounds__(256) void k_gcn_agg(const float* __restrict__ h, const int* __restrict__ rp,
    const int* __restrict__ col, const float* __restrict__ dinv, const float* __restrict__ bias,
    float* __restrict__ y){
  int b = blockIdx.x;
  int xcd = b & 7, i = b >> 3;       // 480 per xcd
  int gs = i/60, j = i - gs*60;
  int graph = gs*8 + xcd;
  int idwg = j*256 + threadIdx.x;    // [0, 15360)
  int rw = idwg/15, pr = idwg - rw*15;
  int v = graph*1024 + rw;
  float dv = dinv[v];
  float accx = 0.f, accy = 0.f;
  int a = rp[v], e = rp[v+1];
  for (; a+4<=e; a+=4){
    int s0=col[a], s1=col[a+1], s2=col[a+2], s3=col[a+3];
    float d0=dinv[s0], d1=dinv[s1], d2=dinv[s2], d3=dinv[s3];
    float2 h0=*(const float2*)(h+s0*30+2*pr), h1=*(const float2*)(h+s1*30+2*pr);
    float2 h2=*(const float2*)(h+s2*30+2*pr), h3=*(const float2*)(h+s3*30+2*pr);
    accx += h0.x*(d0*dv); accy += h0.y*(d0*dv);
    accx += h1.x*(d1*dv); accy += h1.y*(d1*dv);
    accx += h2.x*(d2*dv); accy += h2.y*(d2*dv);
    accx += h3.x*(d3*dv); accy += h3.y*(d3*dv);
  }
  for (; a<e; ++a){
    int s = col[a];
    float w = dinv[s]*dv;
    float2 hv = *(const float2*)(h+s*30+2*pr);
    accx += hv.x*w; accy += hv.y*w;
  }
  float2 hs = *(const float2*)(h + v*30 + 2*pr);
  float w2 = dv*dv;
  accx += hs.x*w2; accy += hs.y*w2;   // self loop last (JAX concat order)
  float2 o; o.x = accx + bias[2*pr]; o.y = accy + bias[2*pr+1];
  *(float2*)(y + v*30 + 2*pr) = o;
}

// ---------------- BatchNorm (single pass: sum + sumsq) ----------------
__global__ __launch_bounds__(256) void k_bn_stat(const float* __restrict__ x, int nrow,
    float* __restrict__ partS, float* __restrict__ partQ){
  __shared__ float lds[256*31];
  int b = blockIdx.x, t = threadIdx.x;
  int rows = nrow >> 8;
  float as[30], aq[30];
  #pragma unroll
  for (int f=0;f<30;f++){ as[f]=0.f; aq[f]=0.f; }
  for (int r=t; r<rows; r+=256){
    const float* xr = x + (b*rows + r)*30;
    #pragma unroll
    for (int f=0;f<30;f++){ float v = xr[f]; as[f] += v; aq[f] += v*v; }
  }
  #pragma unroll
  for (int f=0;f<30;f++) lds[t*31+f] = as[f];
  __syncthreads();
  for (int s=128;s>0;s>>=1){
    if (t<s){
      #pragma unroll
      for (int f=0;f<30;f++) lds[t*31+f] += lds[(t+s)*31+f];
    }
    __syncthreads();
  }
  if (t<30) partS[b*30+t] = lds[t];
  __syncthreads();
  #pragma unroll
  for (int f=0;f<30;f++) lds[t*31+f] = aq[f];
  __syncthreads();
  for (int s=128;s>0;s>>=1){
    if (t<s){
      #pragma unroll
      for (int f=0;f<30;f++) lds[t*31+f] += lds[(t+s)*31+f];
    }
    __syncthreads();
  }
  if (t<30) partQ[b*30+t] = lds[t];
}

__global__ void k_bn_red2(const float* __restrict__ partS, const float* __restrict__ partQ,
                          float n, float* __restrict__ mean, float* __restrict__ var){
  int f = threadIdx.x;
  if (f >= 30) return;
  float s = 0.f, q = 0.f;
  for (int b=0;b<256;b++){ s += partS[b*30+f]; q += partQ[b*30+f]; }
  float m = s / n;
  mean[f] = m;
  var[f]  = q / n - m*m;
}

__global__ __launch_bounds__(256) void k_bn_apply(const float* __restrict__ x, const float* __restrict__ mean,
    const float* __restrict__ var, const float* __restrict__ g, const float* __restrict__ be,
    float* __restrict__ out, int nrow){
  int id = blockIdx.x*256 + threadIdx.x;
  if (id >= nrow*30) return;
  int f = id % 30;
  out[id] = g[f]*(x[id]-mean[f]) * (1.0f/sqrtf(var[f]+1e-5f)) + be[f];
}

// ---------------- belief propagation (col-vectorized, XCD-resident) -------
// Thread owns VEC=4 cols (VEC=2 for q=2). Gathers are float4 from per-run
// packed L. Softmax butterfly emulated bit-exactly: cross-lane shfl for
// off>=4 (lm=off/4), in-register temps for off=2,1; descending-off order
// identical to the lane-wise original.
// 128 blocks/graph: run offsets {0,4,8,16,32,64} -> 8192 blocks total.
__device__ __forceinline__ void bp_decode2(int b, int& graph, int& run, int& jj){
  int xcd = b & 7, i = b >> 3;
  int gs = i >> 7, j = i & 127;
  if      (j <   4){ run=0; jj=j;    }
  else if (j <   8){ run=1; jj=j-4;  }
  else if (j <  16){ run=2; jj=j-8;  }
  else if (j <  32){ run=3; jj=j-16; }
  else if (j <  64){ run=4; jj=j-32; }
  else             { run=5; jj=j-64; }
  graph = gs*8 + xcd;
}

template<int TPR>
__device__ __forceinline__ void bfly_max4(float& m0, float& m1, float& m2, float& m3){
  if constexpr (TPR > 1){
    #pragma unroll
    for (int lm = TPR>>1; lm; lm >>= 1){
      float p0=__shfl_xor(m0,lm,64), p1=__shfl_xor(m1,lm,64);
      float p2=__shfl_xor(m2,lm,64), p3=__shfl_xor(m3,lm,64);
      m0=fmaxf(m0,p0); m1=fmaxf(m1,p1); m2=fmaxf(m2,p2); m3=fmaxf(m3,p3);
    }
  }
  { float t0=fmaxf(m0,m2), t1=fmaxf(m1,m3), t2=fmaxf(m2,m0), t3=fmaxf(m3,m1);
    m0=t0; m1=t1; m2=t2; m3=t3; }
  { float t0=fmaxf(m0,m1), t1=fmaxf(m1,m0), t2=fmaxf(m2,m3), t3=fmaxf(m3,m2);
    m0=t0; m1=t1; m2=t2; m3=t3; }
}

template<int TPR>
__device__ __forceinline__ void bfly_sum4(float& s0, float& s1, float& s2, float& s3){
  if constexpr (TPR > 1){
    #pragma unroll
    for (int lm = TPR>>1; lm; lm >>= 1){
      float p0=__shfl_xor(s0,lm,64), p1=__shfl_xor(s1,lm,64);
      float p2=__shfl_xor(s2,lm,64), p3=__shfl_xor(s3,lm,64);
      s0 += p0; s1 += p1; s2 += p2; s3 += p3;
    }
  }
  { float t0=s0+s2, t1=s1+s3, t2=s2+s0, t3=s3+s1;
    s0=t0; s1=t1; s2=t2; s3=t3; }
  { float t0=s0+s1, t1=s1+s0, t2=s2+s3, t3=s3+s2;
    s0=t0; s1=t1; s2=t2; s3=t3; }
}

template<int Q, int CO, int TPR, int L2T>
__device__ __forceinline__ void bp_first_elem2(int graph, int jj, float* __restrict__ psi_pk,
                                               float* __restrict__ lg, float eb,
                                               uint32_t k0, uint32_t k1){
  int idx = jj*256 + (int)threadIdx.x;
  if constexpr (Q == 2){
    int row = graph*1024 + idx;
    float z[2];
    #pragma unroll
    for (int r=0;r<2;r++){
      uint32_t b0,b1;
      tf2x32(k0,k1, 0u, (uint32_t)(row*2 + r), b0,b1);
      uint32_t bits = b0 ^ b1;
      float f = __uint_as_float((bits>>9) | 0x3F800000u) - 1.0f;
      const float lo = __uint_as_float(0xBF7FFFFFu);
      float u = fmaxf(lo, f*2.0f + lo);
      z[r] = __uint_as_float(0x3FB504F3u) * erfinv32(u);
    }
    float m0=fmaxf(z[0],z[1]), m1=fmaxf(z[1],z[0]);
    float e0=expf(z[0]-m0), e1=expf(z[1]-m1);
    float s0=e0+e1, s1=e1+e0;
    float p0=e0/s0, p1=e1/s1;
    ((float2*)(psi_pk + (size_t)NN*CO))[row] = make_float2(p0,p1);
    ((float2*)(lg     + (size_t)NN*CO))[row] = make_float2(log1pf(eb*p0), log1pf(eb*p1));
  } else {
    int rw = idx >> L2T, ct = idx & (TPR-1);
    int row = graph*1024 + rw;
    float z[4];
    #pragma unroll
    for (int r=0;r<4;r++){
      uint32_t b0,b1;
      tf2x32(k0,k1, 0u, (uint32_t)(row*Q + 4*ct + r), b0,b1);
      uint32_t bits = b0 ^ b1;
      float f = __uint_as_float((bits>>9) | 0x3F800000u) - 1.0f;
      const float lo = __uint_as_float(0xBF7FFFFFu);
      float u = fmaxf(lo, f*2.0f + lo);
      z[r] = __uint_as_float(0x3FB504F3u) * erfinv32(u);
    }
    float m0=z[0],m1=z[1],m2=z[2],m3=z[3];
    bfly_max4<TPR>(m0,m1,m2,m3);
    float e0=expf(z[0]-m0), e1=expf(z[1]-m1), e2=expf(z[2]-m2), e3=expf(z[3]-m3);
    float s0=e0,s1=e1,s2=e2,s3=e3;
    bfly_sum4<TPR>(s0,s1,s2,s3);
    float p0=e0/s0, p1=e1/s1, p2=e2/s2, p3=e3/s3;
    ((float4*)(psi_pk + (size_t)NN*CO))[(size_t)row*TPR + ct] = make_float4(p0,p1,p2,p3);
    ((float4*)(lg     + (size_t)NN*CO))[(size_t)row*TPR + ct] =
        make_float4(log1pf(eb*p0), log1pf(eb*p1), log1pf(eb*p2), log1pf(eb*p3));
  }
}

__global__ __launch_bounds__(256) void k_bp_first(float* __restrict__ psi_pk, float* __restrict__ lg,
                                                  const float* __restrict__ betas){
  int graph, run, jj;
  bp_decode2(blockIdx.x, graph, run, jj);
  uint32_t k0, k1;
  tf2x32(0u, 42u, 0u, (uint32_t)run, k0, k1);          // fold_in(key(42), run)
  float eb = expm1f(betas[run]);
  switch(run){
    case 0: bp_first_elem2< 2, 0, 1,0>(graph, jj, psi_pk, lg, eb, k0, k1); break;
    case 1: bp_first_elem2< 4, 2, 1,0>(graph, jj, psi_pk, lg, eb, k0, k1); break;
    case 2: bp_first_elem2< 8, 6, 2,1>(graph, jj, psi_pk, lg, eb, k0, k1); break;
    case 3: bp_first_elem2<16,14, 4,2>(graph, jj, psi_pk, lg, eb, k0, k1); break;
    case 4: bp_first_elem2<32,30, 8,3>(graph, jj, psi_pk, lg, eb, k0, k1); break;
    default:bp_first_elem2<64,62,16,4>(graph, jj, psi_pk, lg, eb, k0, k1); break;
  }
}

template<int Q, int CO, int TPR, int L2T>
__device__ __forceinline__ void bp_step_elem2(int graph, int run, int jj,
    const float* __restrict__ lcur, float* __restrict__ nxt, float* __restrict__ lnxt,
    const int* __restrict__ rp, const int* __restrict__ col,
    const float* __restrict__ field, float eb, int fin){
  int idx = jj*256 + (int)threadIdx.x;
  if constexpr (Q == 2){
    int row = graph*1024 + idx;
    const float2* B2 = (const float2*)(lcur + (size_t)NN*CO);
    float a0=0.f, a1=0.f;
    int a = rp[row], b2 = rp[row+1];
    for (; a+4<=b2; a+=4){
      int s0=col[a],s1=col[a+1],s2=col[a+2],s3=col[a+3];
      float2 u0=B2[s0], u1=B2[s1], u2=B2[s2], u3=B2[s3];
      a0+=u0.x; a1+=u0.y;
      a0+=u1.x; a1+=u1.y;
      a0+=u2.x; a1+=u2.y;
      a0+=u3.x; a1+=u3.y;
    }
    for (; a<b2; ++a){ float2 u=B2[col[a]]; a0+=u.x; a1+=u.y; }
    float v0 = a0 - field[run*64 + 0];
    float v1 = a1 - field[run*64 + 1];
    float m0=fmaxf(v0,v1), m1=fmaxf(v1,v0);
    float e0=expf(v0-m0), e1=expf(v1-m1);
    float s0=e0+e1, s1=e1+e0;
    float p0=e0/s0, p1=e1/s1;
    if (fin){
      float* o = nxt + (size_t)row*126 + CO;
      o[0]=p0; o[1]=p1;
    } else {
      ((float2*)(nxt  + (size_t)NN*CO))[row] = make_float2(p0,p1);
      ((float2*)(lnxt + (size_t)NN*CO))[row] = make_float2(log1pf(eb*p0), log1pf(eb*p1));
    }
  } else {
    int rw = idx >> L2T, ct = idx & (TPR-1);
    int row = graph*1024 + rw;
    const float4* B4 = (const float4*)(lcur + (size_t)NN*CO);
    float a0=0.f,a1=0.f,a2=0.f,a3=0.f;
    int a = rp[row], b2 = rp[row+1];
    for (; a+4<=b2; a+=4){
      int s0=col[a],s1=col[a+1],s2=col[a+2],s3=col[a+3];
      float4 u0=B4[(size_t)s0*TPR+ct], u1=B4[(size_t)s1*TPR+ct];
      float4 u2=B4[(size_t)s2*TPR+ct], u3=B4[(size_t)s3*TPR+ct];
      a0+=u0.x; a1+=u0.y; a2+=u0.z; a3+=u0.w;
      a0+=u1.x; a1+=u1.y; a2+=u1.z; a3+=u1.w;
      a0+=u2.x; a1+=u2.y; a2+=u2.z; a3+=u2.w;
      a0+=u3.x; a1+=u3.y; a2+=u3.z; a3+=u3.w;
    }
    for (; a<b2; ++a){
      float4 u = B4[(size_t)col[a]*TPR+ct];
      a0+=u.x; a1+=u.y; a2+=u.z; a3+=u.w;
    }
    const float4 fld = *(const float4*)(field + run*64 + 4*ct);
    float v0 = a0 - fld.x, v1 = a1 - fld.y, v2 = a2 - fld.z, v3 = a3 - fld.w;
    float m0=v0,m1=v1,m2=v2,m3=v3;
    bfly_max4<TPR>(m0,m1,m2,m3);
    float e0=expf(v0-m0), e1=expf(v1-m1), e2=expf(v2-m2), e3=expf(v3-m3);
    float s0=e0,s1=e1,s2=e2,s3=e3;
    bfly_sum4<TPR>(s0,s1,s2,s3);
    float p0=e0/s0, p1=e1/s1, p2=e2/s2, p3=e3/s3;
    if (fin){
      float* o = nxt + (size_t)row*126 + CO + 4*ct;
      o[0]=p0; o[1]=p1; o[2]=p2; o[3]=p3;
    } else {
      ((float4*)(nxt  + (size_t)NN*CO))[(size_t)row*TPR+ct] = make_float4(p0,p1,p2,p3);
      ((float4*)(lnxt + (size_t)NN*CO))[(size_t)row*TPR+ct] =
          make_float4(log1pf(eb*p0), log1pf(eb*p1), log1pf(eb*p2), log1pf(eb*p3));
    }
  }
}

__global__ __launch_bounds__(256) void k_bp_step(
    float* __restrict__ nxt, const float* __restrict__ lcur, float* __restrict__ lnxt,
    const int* __restrict__ rp, const int* __restrict__ col,
    const float* __restrict__ field, const float* __restrict__ betas, int fin){
  int graph, run, jj;
  bp_decode2(blockIdx.x, graph, run, jj);
  float eb = expm1f(betas[run]);
  switch(run){
    case 0: bp_step_elem2< 2, 0, 1,0>(graph, run, jj, lcur, nxt, lnxt, rp, col, field, eb, fin); break;
    case 1: bp_step_elem2< 4, 2, 1,0>(graph, run, jj, lcur, nxt, lnxt, rp, col, field, eb, fin); break;
    case 2: bp_step_elem2< 8, 6, 2,1>(graph, run, jj, lcur, nxt, lnxt, rp, col, field, eb, fin); break;
    case 3: bp_step_elem2<16,14, 4,2>(graph, run, jj, lcur, nxt, lnxt, rp, col, field, eb, fin); break;
    case 4: bp_step_elem2<32,30, 8,3>(graph, run, jj, lcur, nxt, lnxt, rp, col, field, eb, fin); break;
    default:bp_step_elem2<64,62,16,4>(graph, run, jj, lcur, nxt, lnxt, rp, col, field, eb, fin); break;
  }
}

// column sums over PACKED psi; per 256-row chunk, rows ascending (order ==
// R1, bit-identical field). Coalesced: row stride is q floats.
__global__ __launch_bounds__(64) void k_colsum_part(const float* __restrict__ psi_pk, float* __restrict__ part){
  int b = blockIdx.x;
  int xcd = b & 7, i = b >> 3;       // i in [0,192)
  int gs = i/24, rem = i - gs*24;
  int run = rem >> 2, cg = rem & 3;
  int graph = gs*8 + xcd;
  int chunk = graph*4 + cg;          // global 256-row chunk id (== R1 "b")
  int q = cQS[run];
  int co = (run==0)?0:(run==1)?2:(run==2)?6:(run==3)?14:(run==4)?30:62;
  int c = threadIdx.x;
  if (c >= q) return;
  float s = 0.f;
  const float* p = psi_pk + (size_t)NN*co + (size_t)chunk*256*q + c;
  #pragma unroll 8
  for (int r=0;r<256;r++) s += p[r*q];
  part[(run*256 + chunk)*64 + c] = s;
}

__global__ void k_field(const float* __restrict__ part, const float* __restrict__ betas,
                        float* __restrict__ field){
  int id = threadIdx.x;              // 384 threads: 6 runs x 64 cols
  int run = id >> 6, c = id & 63;
  if (c >= cQS[run]) return;
  float s = 0.f;
  for (int b=0;b<256;b++) s += part[(run*256 + b)*64 + c];
  float beta = betas[run];
  field[id] = s * (3.8f*beta/65536.0f);
}

// ---------------- diff-pool ----------------
__global__ __launch_bounds__(512) void k_s1(const float* __restrict__ cat, const float* __restrict__ pw,
                                            const float* __restrict__ pb, float* __restrict__ s1){
  __shared__ float wl[12600];
  int t = threadIdx.x;
  for (int i=t;i<12600;i+=512) wl[i] = pw[i];
  int w = t>>6, tl = t&63;
  bool act = tl < 50;
  float pb0 = act? pb[2*tl]   : 0.f;
  float pb1 = act? pb[2*tl+1] : 0.f;
  __syncthreads();
  #pragma unroll
  for (int p=0;p<2;p++){
    int row0 = blockIdx.x*64 + p*32 + w*4;
    float x0[4], x1[4];
    #pragma unroll
    for (int r=0;r<4;r++){
      if (tl < 63){
        float2 xv = *reinterpret_cast<const float2*>(cat + (size_t)(row0+r)*126 + 2*tl);
        x0[r]=xv.x; x1[r]=xv.y;
      } else { x0[r]=0.f; x1[r]=0.f; }
    }
    float a0[4], a1[4];
    #pragma unroll
    for (int r=0;r<4;r++){ a0[r]=pb0; a1[r]=pb1; }
    #pragma unroll 3
    for (int jj=0;jj<63;jj++){
      float2 wA = *reinterpret_cast<const float2*>(&wl[(2*jj  )*100 + 2*tl]);
      float2 wB = *reinterpret_cast<const float2*>(&wl[(2*jj+1)*100 + 2*tl]);
      #pragma unroll
      for (int r=0;r<4;r++){
        float xa = __int_as_float(__builtin_amdgcn_readlane(__float_as_int(x0[r]), jj));
        float xb = __int_as_float(__builtin_amdgcn_readlane(__float_as_int(x1[r]), jj));
        a0[r] += xa*wA.x;
        a1[r] += xa*wA.y;
        a0[r] += xb*wB.x;
        a1[r] += xb*wB.y;
      }
    }
    #pragma unroll
    for (int r=0;r<4;r++){
      float m = act? fmaxf(a0[r], a1[r]) : -FLT_MAX;
      #pragma unroll
      for (int off=32; off; off>>=1) m = fmaxf(m, __shfl_xor(m, off, 64));
      float e0 = act? expf(a0[r]-m) : 0.f;
      float e1 = act? expf(a1[r]-m) : 0.f;
      float ss = e0+e1;
      #pragma unroll
      for (int off=32; off; off>>=1) ss += __shfl_xor(ss, off, 64);
      if (act){
        float2 o; o.x = e0/ss; o.y = e1/ss;
        *reinterpret_cast<float2*>(s1 + (size_t)(row0+r)*100 + 2*tl) = o;
      }
    }
  }
}

// thread per (row, col-quad): float4 gathers. 6400 blocks, XCD-resident.
__global__ __launch_bounds__(256) void k_T(const float* __restrict__ s1, const int* __restrict__ rp,
                                           const int* __restrict__ col, float* __restrict__ T){
  int b = blockIdx.x;
  int xcd = b & 7, i = b >> 3;       // 800 per xcd
  int gs = i/100, j = i - gs*100;
  int graph = gs*8 + xcd;
  int idwg = j*256 + threadIdx.x;    // [0, 25600)
  int rw = idwg/25, quad = idwg - rw*25;
  int v = graph*1024 + rw;
  float a0=0.f,a1=0.f,a2=0.f,a3=0.f;
  const float4* S4 = (const float4*)s1;
  int a = rp[v], e = rp[v+1];
  for (; a+4<=e; a+=4){
    int s0=col[a], s1_=col[a+1], s2=col[a+2], s3=col[a+3];
    float4 u0=S4[(size_t)s0*25+quad], u1=S4[(size_t)s1_*25+quad];
    float4 u2=S4[(size_t)s2*25+quad], u3=S4[(size_t)s3*25+quad];
    a0+=u0.x; a1+=u0.y; a2+=u0.z; a3+=u0.w;
    a0+=u1.x; a1+=u1.y; a2+=u1.z; a3+=u1.w;
    a0+=u2.x; a1+=u2.y; a2+=u2.z; a3+=u2.w;
    a0+=u3.x; a1+=u3.y; a2+=u3.z; a3+=u3.w;
  }
  for (; a<e; ++a){
    float4 u = S4[(size_t)col[a]*25+quad];
    a0+=u.x; a1+=u.y; a2+=u.z; a3+=u.w;
  }
  ((float4*)T)[(size_t)v*25 + quad] = make_float4(a0,a1,a2,a3);
}

// split-K LDS-tiled GEMM: padj_part[qtr] = s1^T * T over n-quarter.
__global__ __launch_bounds__(512) void k_p1adj_sk(const float* __restrict__ s1, const float* __restrict__ T,
                                                  float* __restrict__ part){
  __shared__ float sS[6400];
  __shared__ float sT[6400];
  int blk = blockIdx.x;
  int b = blk >> 2, qtr = blk & 3;
  int t = threadIdx.x;
  int tk = t/20, tl = t - tk*20;
  bool act = t < 500;
  int k0 = tk*4, l0 = tl*5;
  float acc[4][5];
  #pragma unroll
  for (int i=0;i<4;i++)
    #pragma unroll
    for (int j=0;j<5;j++) acc[i][j] = 0.f;
  const float* s1b = s1 + (size_t)b*102400;
  const float* Tb  = T  + (size_t)b*102400;
  for (int c=qtr*4; c<qtr*4+4; c++){
    for (int i=t;i<6400;i+=512){ sS[i] = s1b[c*6400+i]; sT[i] = Tb[c*6400+i]; }
    __syncthreads();
    if (act){
      #pragma unroll 2
      for (int n=0;n<64;n++){
        const float* sr = &sS[n*100 + k0];
        const float* tr = &sT[n*100 + l0];
        float s0=sr[0], s1v=sr[1], s2=sr[2], s3=sr[3];
        float t0=tr[0], t1=tr[1], t2=tr[2], t3=tr[3], t4=tr[4];
        acc[0][0]+=s0*t0; acc[0][1]+=s0*t1; acc[0][2]+=s0*t2; acc[0][3]+=s0*t3; acc[0][4]+=s0*t4;
        acc[1][0]+=s1v*t0; acc[1][1]+=s1v*t1; acc[1][2]+=s1v*t2; acc[1][3]+=s1v*t3; acc[1][4]+=s1v*t4;
        acc[2][0]+=s2*t0; acc[2][1]+=s2*t1; acc[2][2]+=s2*t2; acc[2][3]+=s2*t3; acc[2][4]+=s2*t4;
        acc[3][0]+=s3*t0; acc[3][1]+=s3*t1; acc[3][2]+=s3*t2; acc[3][3]+=s3*t3; acc[3][4]+=s3*t4;
      }
    }
    __syncthreads();
  }
  if (act){
    float* pp = part + (size_t)qtr*640000 + (size_t)b*10000;
    #pragma unroll
    for (int i=0;i<4;i++){
      float* o = pp + (k0+i)*100 + l0;
      #pragma unroll
      for (int j=0;j<5;j++) o[j] = acc[i][j];
    }
  }
}

__global__ __launch_bounds__(256) void k_p1adj_red(const float* __restrict__ part, float* __restrict__ padj){
  int id = blockIdx.x*256 + threadIdx.x;
  if (id >= NBG*10000) return;
  float s = part[id];
  s += part[640000 + id];
  s += part[1280000 + id];
  s += part[1920000 + id];
  padj[id] = s;
}

__global__ __launch_bounds__(256) void k_p1x_sk(const float* __restrict__ s1, const float* __restrict__ x13,
                                                float* __restrict__ part){
  __shared__ float sS[6400];
  __shared__ float sX[1920];
  int blk = blockIdx.x;
  int b = blk >> 2, qtr = blk & 3;
  int t = threadIdx.x;
  int tk = t/10, tl = t - tk*10;
  bool act = t < 250;
  int k0 = tk*4, d0 = tl*3;
  float acc[4][3];
  #pragma unroll
  for (int i=0;i<4;i++)
    #pragma unroll
    for (int j=0;j<3;j++) acc[i][j] = 0.f;
  const float* s1b = s1 + (size_t)b*102400;
  const float* xb  = x13 + (size_t)b*30720;
  for (int c=qtr*4; c<qtr*4+4; c++){
    for (int i=t;i<6400;i+=256) sS[i] = s1b[c*6400+i];
    for (int i=t;i<1920;i+=256) sX[i] = xb[c*1920+i];
    __syncthreads();
    if (act){
      #pragma unroll 2
      for (int n=0;n<64;n++){
        const float* sr = &sS[n*100 + k0];
        const float* xr = &sX[n*30 + d0];
        float s0=sr[0], s1v=sr[1], s2=sr[2], s3=sr[3];
        float x0=xr[0], x1=xr[1], x2=xr[2];
        acc[0][0]+=s0*x0; acc[0][1]+=s0*x1; acc[0][2]+=s0*x2;
        acc[1][0]+=s1v*x0; acc[1][1]+=s1v*x1; acc[1][2]+=s1v*x2;
        acc[2][0]+=s2*x0; acc[2][1]+=s2*x1; acc[2][2]+=s2*x2;
        acc[3][0]+=s3*x0; acc[3][1]+=s3*x1; acc[3][2]+=s3*x2;
      }
    }
    __syncthreads();
  }
  if (act){
    float* pp = part + (size_t)qtr*192000 + (size_t)b*3000;
    #pragma unroll
    for (int i=0;i<4;i++){
      float* o = pp + (k0+i)*30 + d0;
      #pragma unroll
      for (int j=0;j<3;j++) o[j] = acc[i][j];
    }
  }
}

__global__ __launch_bounds__(256) void k_p1x_red(const float* __restrict__ part, float* __restrict__ px){
  int id = blockIdx.x*256 + threadIdx.x;
  if (id >= NBG*3000) return;
  float s = part[id];
  s += part[192000 + id];
  s += part[384000 + id];
  s += part[576000 + id];
  px[id] = s;
}

// ---------------- stage-2 dense GCN ----------------
__global__ __launch_bounds__(256) void k_dinv2(const float* __restrict__ padj, float* __restrict__ dv){
  int id = blockIdx.x*256 + threadIdx.x;
  if (id >= NBG*100) return;
  const float* r = padj + id*100;
  int k = id % 100;
  float s = 0.f;
  for (int l=0;l<100;l++){
    float v = r[l];
    if (l==k) v += 1.0f;     // A = adj + I
    s += v;
  }
  dv[id] = 1.0f/sqrtf(s);
}

__global__ __launch_bounds__(256) void k_Ank(const float* __restrict__ padj, const float* __restrict__ dv,
                                             float* __restrict__ An){
  int id = blockIdx.x*256 + threadIdx.x;
  if (id >= NBG*10000) return;
  int b = id/10000;
  int rem = id - b*10000;
  int k = rem/100, l = rem - k*100;
  float a = padj[id] + ((k==l)? 1.0f : 0.0f);
  An[id] = (dv[b*100+k]*a)*dv[b*100+l];
}

__global__ __launch_bounds__(256) void k_y2(const float* __restrict__ An, const float* __restrict__ h,
    const float* __restrict__ bias, float* __restrict__ y){
  int id = blockIdx.x*256 + threadIdx.x;
  if (id >= NBG*100*30) return;
  int d = id % 30;
  int bk = id / 30;
  int b = bk / 100;
  const float* Ar = An + bk*100;
  const float* hb = h + b*100*30;
  float acc = 0.f;
  for (int l=0;l<100;l++) acc += Ar[l]*hb[l*30+d];
  y[id] = acc + bias[d];
}

// ---------------- pools + FC ----------------
__global__ __launch_bounds__(256) void k_pool2(const float* __restrict__ A,
    const float* __restrict__ Bv, const float* __restrict__ Cv,
    int rows, float* __restrict__ conv, int coff){
  __shared__ float lds[256*31];
  int b = blockIdx.x, a = blockIdx.y, t = threadIdx.x;
  const float* X = (a==0)? A : ((a==1)? Bv : Cv);
  float acc[30];
  #pragma unroll
  for (int f=0;f<30;f++) acc[f] = -FLT_MAX;
  for (int r=t; r<rows; r+=256){
    const float* xr = X + (size_t)(b*rows + r)*30;
    #pragma unroll
    for (int f=0;f<30;f++) acc[f] = fmaxf(acc[f], xr[f]);
  }
  #pragma unroll
  for (int f=0;f<30;f++) lds[t*31+f] = acc[f];
  __syncthreads();
  for (int s=128;s>0;s>>=1){
    if (t<s){
      #pragma unroll
      for (int f=0;f<30;f++) lds[t*31+f] = fmaxf(lds[t*31+f], lds[(t+s)*31+f]);
    }
    __syncthreads();
  }
  if (t<30) conv[b*180 + coff + a*30 + t] = lds[t];
}

__global__ __launch_bounds__(64) void k_fc(const float* __restrict__ conv,
    const float* __restrict__ w1, const float* __restrict__ b1,
    const float* __restrict__ w2, const float* __restrict__ b2, float* __restrict__ out){
  __shared__ float row[180];
  __shared__ float hid[50];
  int b = blockIdx.x, t = threadIdx.x;
  for (int i=t;i<180;i+=64) row[i] = conv[b*180+i];
  __syncthreads();
  if (t < 50){
    float a = b1[t];
    for (int i=0;i<180;i++) a += row[i]*w1[i*50+t];
    hid[t] = fmaxf(a, 0.f);
  }
  __syncthreads();
  if (t < 6){
    float a = b2[t];
    for (int i=0;i<50;i++) a += hid[i]*w2[i*6+t];
    out[b*6+t] = a;
  }
  if (b==0 && t==63) out[NBG*6] = 0.0f;   // second tuple output: zeros((1,))
}

// ---------------------------------------------------------------------------
extern "C" void kernel_launch(void* const* d_in, const int* in_sizes, int n_in,
                              void* d_out, int out_size, void* d_ws, size_t ws_size,
                              hipStream_t stream)
{
  (void)in_sizes; (void)n_in; (void)out_size; (void)ws_size;
  const float* x   = (const float*)d_in[0];
  const int*   src = (const int*)d_in[1];
  const int*   dst = src + NEDGE;
  const float* w11=(const float*)d_in[3],  *b11=(const float*)d_in[4],  *g11=(const float*)d_in[5],  *be11=(const float*)d_in[6];
  const float* w12=(const float*)d_in[7],  *b12=(const float*)d_in[8],  *g12=(const float*)d_in[9],  *be12=(const float*)d_in[10];
  const float* w13=(const float*)d_in[11], *b13=(const float*)d_in[12], *g13=(const float*)d_in[13], *be13=(const float*)d_in[14];
  const float* w21=(const float*)d_in[15], *b21=(const float*)d_in[16], *g21=(const float*)d_in[17], *be21=(const float*)d_in[18];
  const float* w22=(const float*)d_in[19], *b22=(const float*)d_in[20], *g22=(const float*)d_in[21], *be22=(const float*)d_in[22];
  const float* w23=(const float*)d_in[23], *b23=(const float*)d_in[24], *g23=(const float*)d_in[25], *be23=(const float*)d_in[26];
  const float* betas=(const float*)d_in[27];
  const float* poolw=(const float*)d_in[28], *poolb=(const float*)d_in[29];
  const float* fc1w=(const float*)d_in[30], *fc1b=(const float*)d_in[31];
  const float* fc2w=(const float*)d_in[32], *fc2b=(const float*)d_in[33];
  float* out = (float*)d_out;

  uint8_t* basep = (uint8_t*)d_ws;
  size_t off = 0;
  auto take = [&](size_t bytes)->void*{
    void* p = basep + off;
    off = (off + bytes + 255) & ~(size_t)255;
    return p;
  };
  int* degi    = (int*)take((size_t)NN*4);
  int* dego    = (int*)take((size_t)NN*4);
  int* cntA    = (int*)take((size_t)NN*4);
  int* cntB    = (int*)take((size_t)NN*4);
  int* rp_in   = (int*)take((size_t)(NN+1)*4);
  int* rp_out  = (int*)take((size_t)(NN+1)*4);
  int* bsum    = (int*)take(256*4);
  int* col_in  = (int*)take((size_t)NEDGE*4);
  int* col_out = (int*)take((size_t)NEDGE*4);
  float* dinv  = (float*)take((size_t)NN*4);
  float* hbuf  = (float*)take((size_t)NN*30*4);
  float* tmpY  = (float*)take((size_t)NN*30*4);
  float* X1    = (float*)take((size_t)NN*30*4);
  float* X2    = (float*)take((size_t)NN*30*4);
  float* X3    = (float*)take((size_t)NN*30*4);
  float* bufA  = (float*)take((size_t)NN*126*4);
  float* bufB  = (float*)take((size_t)NN*126*4);
  float* logA  = (float*)take((size_t)NN*126*4);
  float* logB  = (float*)take((size_t)NN*126*4);
  float* partCS= (float*)take((size_t)6*256*64*4);
  float* fieldv= (float*)take(384*4);
  float* partBN= (float*)take(256*30*4);
  float* partBN2=(float*)take(256*30*4);
  float* meanv = (float*)take(128);
  float* varv  = (float*)take(128);
  float* px    = (float*)take(192000*4);
  float* padj  = (float*)take(640000*4);
  float* An    = (float*)take(640000*4);
  float* dinv2 = (float*)take(6400*4);
  float* h2    = (float*)take(192000*4);
  float* y2    = (float*)take(192000*4);
  float* X21   = (float*)take(192000*4);
  float* X22   = (float*)take(192000*4);
  float* X23   = (float*)take(192000*4);
  float* conv  = (float*)take(64*180*4);

  // split-K partial buffers live in logB (dead after BP: final iter writes no L)
  float* pAdjPart = logB;               // 4*640000 floats
  float* pPxPart  = logB + 2560000;     // 4*192000 floats

  // ---- CSR setup ----
  hipMemsetAsync(degi, 0, (size_t)NN*4, stream);
  hipMemsetAsync(dego, 0, (size_t)NN*4, stream);
  hipMemsetAsync(cntA, 0, (size_t)NN*4, stream);
  hipMemsetAsync(cntB, 0, (size_t)NN*4, stream);
  k_count<<<2048,256,0,stream>>>(src,dst,degi,dego);
  k_scan1<<<256,256,0,stream>>>(degi, rp_in, bsum);
  k_scan2<<<1,256,0,stream>>>(bsum);
  k_scan3<<<256,256,0,stream>>>(rp_in, bsum);
  k_scan1<<<256,256,0,stream>>>(dego, rp_out, bsum);
  k_scan2<<<1,256,0,stream>>>(bsum);
  k_scan3<<<256,256,0,stream>>>(rp_out, bsum);
  k_fill<<<2048,256,0,stream>>>(dst, rp_in, cntA, col_in);
  k_fill<<<2048,256,0,stream>>>(src, rp_out, cntB, col_out);
  k_sortrow<<<256,256,0,stream>>>(rp_in,  col_in,  src);
  k_sortrow<<<256,256,0,stream>>>(rp_out, col_out, dst);
  k_dinv<<<256,256,0,stream>>>(degi, dinv);

  auto run_bn = [&](const float* yin, float* xout, const float* g, const float* be, int nrow){
    k_bn_stat<<<256,256,0,stream>>>(yin, nrow, partBN, partBN2);
    k_bn_red2<<<1,32,0,stream>>>(partBN, partBN2, (float)nrow, meanv, varv);
    k_bn_apply<<<(nrow*30)/256,256,0,stream>>>(yin, meanv, varv, g, be, xout, nrow);
  };

  // ---- stage 1: sparse GCN + BN x3 ----
  k_mm30<3><<<7680,256,0,stream>>>(x, w11, hbuf, NN);
  k_gcn_agg<<<3840,256,0,stream>>>(hbuf, rp_in, col_in, dinv, b11, tmpY);
  run_bn(tmpY, X1, g11, be11, NN);
  k_mm30<30><<<7680,256,0,stream>>>(X1, w12, hbuf, NN);
  k_gcn_agg<<<3840,256,0,stream>>>(hbuf, rp_in, col_in, dinv, b12, tmpY);
  run_bn(tmpY, X2, g12, be12, NN);
  k_mm30<30><<<7680,256,0,stream>>>(X2, w13, hbuf, NN);
  k_gcn_agg<<<3840,256,0,stream>>>(hbuf, rp_in, col_in, dinv, b13, tmpY);
  run_bn(tmpY, X3, g13, be13, NN);
  k_pool2<<<dim3(NBG,3),256,0,stream>>>(X1, X2, X3, 1024, conv, 0);

  // ---- belief propagation (packed psi + packed L, ping-pong) ----
  k_bp_first<<<8192,256,0,stream>>>(bufA, logA, betas);
  float* cur = bufA;  float* nxt = bufB;
  float* lcur = logA; float* lnxt = logB;
  for (int it=0; it<10; ++it){
    k_colsum_part<<<1536,64,0,stream>>>(cur, partCS);
    k_field<<<1,384,0,stream>>>(partCS, betas, fieldv);
    int fin = (it==9);
    k_bp_step<<<8192,256,0,stream>>>(nxt, lcur, lnxt, rp_in, col_in, fieldv, betas, fin);
    float* tp = cur;  cur = nxt;   nxt = tp;
    float* tl = lcur; lcur = lnxt; lnxt = tl;
  }
  // final concatenated psi [NN][126] now in bufA (it9 wrote nxt=bufA as [126])

  // ---- diff-pool ----
  k_s1<<<1024,512,0,stream>>>(bufA, poolw, poolb, bufB);      // s1 [n,100] -> bufB
  k_T<<<6400,256,0,stream>>>(bufB, rp_out, col_out, bufA);    // T = A*s1   -> bufA
  k_p1adj_sk<<<256,512,0,stream>>>(bufB, bufA, pAdjPart);
  k_p1adj_red<<<2500,256,0,stream>>>(pAdjPart, padj);
  k_p1x_sk<<<256,256,0,stream>>>(bufB, X3, pPxPart);
  k_p1x_red<<<750,256,0,stream>>>(pPxPart, px);
  k_dinv2<<<25,256,0,stream>>>(padj, dinv2);
  k_Ank<<<2500,256,0,stream>>>(padj, dinv2, An);

  // ---- stage 2: dense GCN + BN x3 ----
  auto gcn2 = [&](const float* xin, const float* w, const float* bb, const float* g,
                  const float* be, float* xout){
    k_mm30<30><<<750,256,0,stream>>>(xin, w, h2, NBG*100);
    k_y2<<<750,256,0,stream>>>(An, h2, bb, y2);
    run_bn(y2, xout, g, be, NBG*100);
  };
  gcn2(px,  w21, b21, g21, be21, X21);
  gcn2(X21, w22, b22, g22, be22, X22);
  gcn2(X22, w23, b23, g23, be23, X23);
  k_pool2<<<dim3(NBG,3),256,0,stream>>>(X21, X22, X23, 100, conv, 90);

  // ---- FC head ----
  k_fc<<<64,64,0,stream>>>(conv, fc1w, fc1b, fc2w, fc2b, out);
}

// Round 11
// 1345.056 us; speedup vs baseline: 2.7160x; 1.0131x over previous
//
#include <hip/hip_runtime.h>
#include <stdint.h>
#include <float.h>

// ---------------------------------------------------------------------------
// Net_57604101374728: GCN(x3)+BN -> maxpool | 6x belief-prop -> diffpool ->
// dense GCN(x3)+BN -> maxpool -> FC. Full fp32 port of the JAX reference.
//
// R11: (1) k_s1 -> transpose (k_catT) + row-per-lane GEMM (k_s1t): lanes=rows,
// W broadcast via uniform LDS reads, all 64 lanes useful, 512 fully-resident
// blocks. Per-output FMA order identical (pb + ascending k). (2) chunk-8
// float4 gathers in bp_step/k_T (ascending order -> bit-exact). (3) colsum
// float4 (per-col accs unchanged). (4) CSR launch fusion (16 -> 8 launches).
// ---------------------------------------------------------------------------

constexpr int NN    = 65536;    // total nodes
constexpr int NEDGE = 524288;   // edges
constexpr int NBG   = 64;       // graphs

__constant__ int cQS[6]   = {2,4,8,16,32,64};

// ---------------- threefry2x32 (20 rounds) ----------------
__device__ __forceinline__ void tf2x32(uint32_t k0, uint32_t k1, uint32_t x0, uint32_t x1,
                                       uint32_t& o0, uint32_t& o1){
  uint32_t ks[3] = {k0, k1, k0 ^ k1 ^ 0x1BD11BDAu};
  x0 += ks[0]; x1 += ks[1];
  const int RA[4] = {13,15,26,6}, RB[4] = {17,29,16,24};
  #pragma unroll
  for (int i=0;i<5;i++){
    const int* r = (i&1)? RB : RA;
    #pragma unroll
    for (int j=0;j<4;j++){
      x0 += x1;
      x1 = (x1 << r[j]) | (x1 >> (32 - r[j]));
      x1 ^= x0;
    }
    x0 += ks[(i+1)%3];
    x1 += ks[(i+2)%3] + (uint32_t)(i+1);
  }
  o0 = x0; o1 = x1;
}

// ---------------- XLA ErfInv32 (Giles), contraction off ----------------
__device__ __forceinline__ float erfinv32(float xx){
  #pragma clang fp contract(off)
  float w = -log1pf(-xx*xx);
  float p;
  if (w < 5.0f){
    w = w - 2.5f;
    p = 2.81022636e-08f;
    p = 3.43273939e-07f  + p*w;
    p = -3.5233877e-06f  + p*w;
    p = -4.39150654e-06f + p*w;
    p = 0.00021858087f   + p*w;
    p = -0.00125372503f  + p*w;
    p = -0.00417768164f  + p*w;
    p = 0.246640727f     + p*w;
    p = 1.50140941f      + p*w;
  } else {
    w = sqrtf(w) - 3.0f;
    p = -0.000200214257f;
    p = 0.000100950558f  + p*w;
    p = 0.00134934322f   + p*w;
    p = -0.00367342844f  + p*w;
    p = 0.00573950773f   + p*w;
    p = -0.0076224613f   + p*w;
    p = 0.00943887047f   + p*w;
    p = 1.00167406f      + p*w;
    p = 2.83297682f      + p*w;
  }
  return p*xx;
}

// ---------------- CSR construction (fused pairs via blockIdx.y) ----------
__global__ __launch_bounds__(256) void k_count(const int* __restrict__ src, const int* __restrict__ dst,
                                               int* __restrict__ degi, int* __restrict__ dego){
  int e = blockIdx.x*256 + threadIdx.x;
  if (e >= NEDGE) return;
  atomicAdd(&degi[dst[e]], 1);
  atomicAdd(&dego[src[e]], 1);
}

__global__ __launch_bounds__(256) void k_scan1(const int* __restrict__ degi, const int* __restrict__ dego,
                                               int* __restrict__ rpi, int* __restrict__ rpo,
                                               int* __restrict__ bsum){
  __shared__ int lds[256];
  const int* deg = blockIdx.y? dego : degi;
  int* rp = blockIdx.y? rpo : rpi;
  int* bs = bsum + blockIdx.y*256;
  int b = blockIdx.x, t = threadIdx.x;
  lds[t] = deg[b*256 + t];
  __syncthreads();
  for (int s=1;s<256;s<<=1){
    int add = (t>=s)? lds[t-s] : 0;
    __syncthreads();
    lds[t] += add;
    __syncthreads();
  }
  rp[b*256 + t + 1] = lds[t];
  if (t==0 && b==0) rp[0] = 0;
  if (t==255) bs[b] = lds[255];
}

__global__ __launch_bounds__(256) void k_scan2(int* __restrict__ bsum){
  __shared__ int lds[256];
  int* bs = bsum + blockIdx.x*256;
  int t = threadIdx.x;
  lds[t] = bs[t];
  __syncthreads();
  for (int s=1;s<256;s<<=1){
    int add = (t>=s)? lds[t-s] : 0;
    __syncthreads();
    lds[t] += add;
    __syncthreads();
  }
  bs[t] = (t==0)? 0 : lds[t-1];
}

__global__ __launch_bounds__(256) void k_scan3(int* __restrict__ rpi, int* __restrict__ rpo,
                                               const int* __restrict__ bsum){
  int* rp = blockIdx.y? rpo : rpi;
  const int* bs = bsum + blockIdx.y*256;
  int b = blockIdx.x, t = threadIdx.x;
  rp[b*256 + t + 1] += bs[b];
}

__global__ __launch_bounds__(256) void k_fill(const int* __restrict__ src, const int* __restrict__ dst,
                                              const int* __restrict__ rpi, const int* __restrict__ rpo,
                                              int* __restrict__ cntA, int* __restrict__ cntB,
                                              int* __restrict__ colI, int* __restrict__ colO){
  int e = blockIdx.x*256 + threadIdx.x;
  if (e >= NEDGE) return;
  if (blockIdx.y == 0){
    int d = dst[e];
    int p = atomicAdd(&cntA[d], 1);
    colI[rpi[d] + p] = e;
  } else {
    int d = src[e];
    int p = atomicAdd(&cntB[d], 1);
    colO[rpo[d] + p] = e;
  }
}

__global__ __launch_bounds__(256) void k_sortrow(const int* __restrict__ rpi, const int* __restrict__ rpo,
                                                 int* __restrict__ colI, int* __restrict__ colO,
                                                 const int* __restrict__ src, const int* __restrict__ dst){
  const int* rp = blockIdx.y? rpo : rpi;
  int* colbuf   = blockIdx.y? colO : colI;
  const int* other = blockIdx.y? dst : src;
  int v = blockIdx.x*256 + threadIdx.x;
  if (v >= NN) return;
  int s0 = rp[v], s1 = rp[v+1];
  for (int i=s0+1;i<s1;i++){
    int key = colbuf[i]; int j = i-1;
    while (j>=s0 && colbuf[j]>key){ colbuf[j+1]=colbuf[j]; j--; }
    colbuf[j+1] = key;
  }
  for (int i=s0;i<s1;i++) colbuf[i] = other[colbuf[i]];
}

__global__ __launch_bounds__(256) void k_dinv(const int* __restrict__ degi, float* __restrict__ dinv){
  int v = blockIdx.x*256 + threadIdx.x;
  if (v >= NN) return;
  dinv[v] = 1.0f / sqrtf((float)(degi[v] + 1));
}

// ---------------- stage-1 GCN ----------------
template<int CIN>
__global__ __launch_bounds__(256) void k_mm30(const float* __restrict__ x, const float* __restrict__ w,
                                              float* __restrict__ h, int nrow){
  __shared__ float ws[CIN*30];
  int t = threadIdx.x;
  for (int i=t;i<CIN*30;i+=256) ws[i] = w[i];
  __syncthreads();
  int id = blockIdx.x*256 + t;
  if (id >= nrow*30) return;
  int v = id/30, j = id - v*30;
  const float* xr = x + v*CIN;
  float acc = 0.f;
  #pragma unroll
  for (int k=0;k<CIN;k++) acc += xr[k]*ws[k*30+j];
  h[id] = acc;
}

__global__ __launch_bounds__(256) void k_gcn_agg(const float* __restrict__ h, const int* __restrict__ rp,
    const int* __restrict__ col, const float* __restrict__ dinv, const float* __restrict__ bias,
    float* __restrict__ y){
  int b = blockIdx.x;
  int xcd = b & 7, i = b >> 3;
  int gs = i/60, j = i - gs*60;
  int graph = gs*8 + xcd;
  int idwg = j*256 + threadIdx.x;
  int rw = idwg/15, pr = idwg - rw*15;
  int v = graph*1024 + rw;
  float dv = dinv[v];
  float accx = 0.f, accy = 0.f;
  int a = rp[v], e = rp[v+1];
  for (; a+4<=e; a+=4){
    int s0=col[a], s1=col[a+1], s2=col[a+2], s3=col[a+3];
    float d0=dinv[s0], d1=dinv[s1], d2=dinv[s2], d3=dinv[s3];
    float2 h0=*(const float2*)(h+s0*30+2*pr), h1=*(const float2*)(h+s1*30+2*pr);
    float2 h2=*(const float2*)(h+s2*30+2*pr), h3=*(const float2*)(h+s3*30+2*pr);
    accx += h0.x*(d0*dv); accy += h0.y*(d0*dv);
    accx += h1.x*(d1*dv); accy += h1.y*(d1*dv);
    accx += h2.x*(d2*dv); accy += h2.y*(d2*dv);
    accx += h3.x*(d3*dv); accy += h3.y*(d3*dv);
  }
  for (; a<e; ++a){
    int s = col[a];
    float w = dinv[s]*dv;
    float2 hv = *(const float2*)(h+s*30+2*pr);
    accx += hv.x*w; accy += hv.y*w;
  }
  float2 hs = *(const float2*)(h + v*30 + 2*pr);
  float w2 = dv*dv;
  accx += hs.x*w2; accy += hs.y*w2;
  float2 o; o.x = accx + bias[2*pr]; o.y = accy + bias[2*pr+1];
  *(float2*)(y + v*30 + 2*pr) = o;
}

// ---------------- BatchNorm (single pass: sum + sumsq) ----------------
__global__ __launch_bounds__(256) void k_bn_stat(const float* __restrict__ x, int nrow,
    float* __restrict__ partS, float* __restrict__ partQ){
  __shared__ float lds[256*31];
  int b = blockIdx.x, t = threadIdx.x;
  int rows = nrow >> 8;
  float as[30], aq[30];
  #pragma unroll
  for (int f=0;f<30;f++){ as[f]=0.f; aq[f]=0.f; }
  for (int r=t; r<rows; r+=256){
    const float* xr = x + (b*rows + r)*30;
    #pragma unroll
    for (int f=0;f<30;f++){ float v = xr[f]; as[f] += v; aq[f] += v*v; }
  }
  #pragma unroll
  for (int f=0;f<30;f++) lds[t*31+f] = as[f];
  __syncthreads();
  for (int s=128;s>0;s>>=1){
    if (t<s){
      #pragma unroll
      for (int f=0;f<30;f++) lds[t*31+f] += lds[(t+s)*31+f];
    }
    __syncthreads();
  }
  if (t<30) partS[b*30+t] = lds[t];
  __syncthreads();
  #pragma unroll
  for (int f=0;f<30;f++) lds[t*31+f] = aq[f];
  __syncthreads();
  for (int s=128;s>0;s>>=1){
    if (t<s){
      #pragma unroll
      for (int f=0;f<30;f++) lds[t*31+f] += lds[(t+s)*31+f];
    }
    __syncthreads();
  }
  if (t<30) partQ[b*30+t] = lds[t];
}

__global__ void k_bn_red2(const float* __restrict__ partS, const float* __restrict__ partQ,
                          float n, float* __restrict__ mean, float* __restrict__ var){
  int f = threadIdx.x;
  if (f >= 30) return;
  float s = 0.f, q = 0.f;
  for (int b=0;b<256;b++){ s += partS[b*30+f]; q += partQ[b*30+f]; }
  float m = s / n;
  mean[f] = m;
  var[f]  = q / n - m*m;
}

__global__ __launch_bounds__(256) void k_bn_apply(const float* __restrict__ x, const float* __restrict__ mean,
    const float* __restrict__ var, const float* __restrict__ g, const float* __restrict__ be,
    float* __restrict__ out, int nrow){
  int id = blockIdx.x*256 + threadIdx.x;
  if (id >= nrow*30) return;
  int f = id % 30;
  out[id] = g[f]*(x[id]-mean[f]) * (1.0f/sqrtf(var[f]+1e-5f)) + be[f];
}

// ---------------- belief propagation (col-vectorized, XCD-resident) -------
__device__ __forceinline__ void bp_decode2(int b, int& graph, int& run, int& jj){
  int xcd = b & 7, i = b >> 3;
  int gs = i >> 7, j = i & 127;
  if      (j <   4){ run=0; jj=j;    }
  else if (j <   8){ run=1; jj=j-4;  }
  else if (j <  16){ run=2; jj=j-8;  }
  else if (j <  32){ run=3; jj=j-16; }
  else if (j <  64){ run=4; jj=j-32; }
  else             { run=5; jj=j-64; }
  graph = gs*8 + xcd;
}

template<int TPR>
__device__ __forceinline__ void bfly_max4(float& m0, float& m1, float& m2, float& m3){
  if constexpr (TPR > 1){
    #pragma unroll
    for (int lm = TPR>>1; lm; lm >>= 1){
      float p0=__shfl_xor(m0,lm,64), p1=__shfl_xor(m1,lm,64);
      float p2=__shfl_xor(m2,lm,64), p3=__shfl_xor(m3,lm,64);
      m0=fmaxf(m0,p0); m1=fmaxf(m1,p1); m2=fmaxf(m2,p2); m3=fmaxf(m3,p3);
    }
  }
  { float t0=fmaxf(m0,m2), t1=fmaxf(m1,m3), t2=fmaxf(m2,m0), t3=fmaxf(m3,m1);
    m0=t0; m1=t1; m2=t2; m3=t3; }
  { float t0=fmaxf(m0,m1), t1=fmaxf(m1,m0), t2=fmaxf(m2,m3), t3=fmaxf(m3,m2);
    m0=t0; m1=t1; m2=t2; m3=t3; }
}

template<int TPR>
__device__ __forceinline__ void bfly_sum4(float& s0, float& s1, float& s2, float& s3){
  if constexpr (TPR > 1){
    #pragma unroll
    for (int lm = TPR>>1; lm; lm >>= 1){
      float p0=__shfl_xor(s0,lm,64), p1=__shfl_xor(s1,lm,64);
      float p2=__shfl_xor(s2,lm,64), p3=__shfl_xor(s3,lm,64);
      s0 += p0; s1 += p1; s2 += p2; s3 += p3;
    }
  }
  { float t0=s0+s2, t1=s1+s3, t2=s2+s0, t3=s3+s1;
    s0=t0; s1=t1; s2=t2; s3=t3; }
  { float t0=s0+s1, t1=s1+s0, t2=s2+s3, t3=s3+s2;
    s0=t0; s1=t1; s2=t2; s3=t3; }
}

template<int Q, int CO, int TPR, int L2T>
__device__ __forceinline__ void bp_first_elem2(int graph, int jj, float* __restrict__ psi_pk,
                                               float* __restrict__ lg, float eb,
                                               uint32_t k0, uint32_t k1){
  int idx = jj*256 + (int)threadIdx.x;
  if constexpr (Q == 2){
    int row = graph*1024 + idx;
    float z[2];
    #pragma unroll
    for (int r=0;r<2;r++){
      uint32_t b0,b1;
      tf2x32(k0,k1, 0u, (uint32_t)(row*2 + r), b0,b1);
      uint32_t bits = b0 ^ b1;
      float f = __uint_as_float((bits>>9) | 0x3F800000u) - 1.0f;
      const float lo = __uint_as_float(0xBF7FFFFFu);
      float u = fmaxf(lo, f*2.0f + lo);
      z[r] = __uint_as_float(0x3FB504F3u) * erfinv32(u);
    }
    float m0=fmaxf(z[0],z[1]), m1=fmaxf(z[1],z[0]);
    float e0=expf(z[0]-m0), e1=expf(z[1]-m1);
    float s0=e0+e1, s1=e1+e0;
    float p0=e0/s0, p1=e1/s1;
    ((float2*)(psi_pk + (size_t)NN*CO))[row] = make_float2(p0,p1);
    ((float2*)(lg     + (size_t)NN*CO))[row] = make_float2(log1pf(eb*p0), log1pf(eb*p1));
  } else {
    int rw = idx >> L2T, ct = idx & (TPR-1);
    int row = graph*1024 + rw;
    float z[4];
    #pragma unroll
    for (int r=0;r<4;r++){
      uint32_t b0,b1;
      tf2x32(k0,k1, 0u, (uint32_t)(row*Q + 4*ct + r), b0,b1);
      uint32_t bits = b0 ^ b1;
      float f = __uint_as_float((bits>>9) | 0x3F800000u) - 1.0f;
      const float lo = __uint_as_float(0xBF7FFFFFu);
      float u = fmaxf(lo, f*2.0f + lo);
      z[r] = __uint_as_float(0x3FB504F3u) * erfinv32(u);
    }
    float m0=z[0],m1=z[1],m2=z[2],m3=z[3];
    bfly_max4<TPR>(m0,m1,m2,m3);
    float e0=expf(z[0]-m0), e1=expf(z[1]-m1), e2=expf(z[2]-m2), e3=expf(z[3]-m3);
    float s0=e0,s1=e1,s2=e2,s3=e3;
    bfly_sum4<TPR>(s0,s1,s2,s3);
    float p0=e0/s0, p1=e1/s1, p2=e2/s2, p3=e3/s3;
    ((float4*)(psi_pk + (size_t)NN*CO))[(size_t)row*TPR + ct] = make_float4(p0,p1,p2,p3);
    ((float4*)(lg     + (size_t)NN*CO))[(size_t)row*TPR + ct] =
        make_float4(log1pf(eb*p0), log1pf(eb*p1), log1pf(eb*p2), log1pf(eb*p3));
  }
}

__global__ __launch_bounds__(256) void k_bp_first(float* __restrict__ psi_pk, float* __restrict__ lg,
                                                  const float* __restrict__ betas){
  int graph, run, jj;
  bp_decode2(blockIdx.x, graph, run, jj);
  uint32_t k0, k1;
  tf2x32(0u, 42u, 0u, (uint32_t)run, k0, k1);
  float eb = expm1f(betas[run]);
  switch(run){
    case 0: bp_first_elem2< 2, 0, 1,0>(graph, jj, psi_pk, lg, eb, k0, k1); break;
    case 1: bp_first_elem2< 4, 2, 1,0>(graph, jj, psi_pk, lg, eb, k0, k1); break;
    case 2: bp_first_elem2< 8, 6, 2,1>(graph, jj, psi_pk, lg, eb, k0, k1); break;
    case 3: bp_first_elem2<16,14, 4,2>(graph, jj, psi_pk, lg, eb, k0, k1); break;
    case 4: bp_first_elem2<32,30, 8,3>(graph, jj, psi_pk, lg, eb, k0, k1); break;
    default:bp_first_elem2<64,62,16,4>(graph, jj, psi_pk, lg, eb, k0, k1); break;
  }
}

template<int Q, int CO, int TPR, int L2T>
__device__ __forceinline__ void bp_step_elem2(int graph, int run, int jj,
    const float* __restrict__ lcur, float* __restrict__ nxt, float* __restrict__ lnxt,
    const int* __restrict__ rp, const int* __restrict__ col,
    const float* __restrict__ field, float eb, int fin){
  int idx = jj*256 + (int)threadIdx.x;
  if constexpr (Q == 2){
    int row = graph*1024 + idx;
    const float2* B2 = (const float2*)(lcur + (size_t)NN*CO);
    float a0=0.f, a1=0.f;
    int a = rp[row], b2 = rp[row+1];
    for (; a+8<=b2; a+=8){
      int s0=col[a],s1=col[a+1],s2=col[a+2],s3=col[a+3];
      int s4=col[a+4],s5=col[a+5],s6=col[a+6],s7=col[a+7];
      float2 u0=B2[s0], u1=B2[s1], u2=B2[s2], u3=B2[s3];
      float2 u4=B2[s4], u5=B2[s5], u6=B2[s6], u7=B2[s7];
      a0+=u0.x; a1+=u0.y; a0+=u1.x; a1+=u1.y;
      a0+=u2.x; a1+=u2.y; a0+=u3.x; a1+=u3.y;
      a0+=u4.x; a1+=u4.y; a0+=u5.x; a1+=u5.y;
      a0+=u6.x; a1+=u6.y; a0+=u7.x; a1+=u7.y;
    }
    for (; a+4<=b2; a+=4){
      int s0=col[a],s1=col[a+1],s2=col[a+2],s3=col[a+3];
      float2 u0=B2[s0], u1=B2[s1], u2=B2[s2], u3=B2[s3];
      a0+=u0.x; a1+=u0.y; a0+=u1.x; a1+=u1.y;
      a0+=u2.x; a1+=u2.y; a0+=u3.x; a1+=u3.y;
    }
    for (; a<b2; ++a){ float2 u=B2[col[a]]; a0+=u.x; a1+=u.y; }
    float v0 = a0 - field[run*64 + 0];
    float v1 = a1 - field[run*64 + 1];
    float m0=fmaxf(v0,v1), m1=fmaxf(v1,v0);
    float e0=expf(v0-m0), e1=expf(v1-m1);
    float s0=e0+e1, s1=e1+e0;
    float p0=e0/s0, p1=e1/s1;
    if (fin){
      float* o = nxt + (size_t)row*126 + CO;
      o[0]=p0; o[1]=p1;
    } else {
      ((float2*)(nxt  + (size_t)NN*CO))[row] = make_float2(p0,p1);
      ((float2*)(lnxt + (size_t)NN*CO))[row] = make_float2(log1pf(eb*p0), log1pf(eb*p1));
    }
  } else {
    int rw = idx >> L2T, ct = idx & (TPR-1);
    int row = graph*1024 + rw;
    const float4* B4 = (const float4*)(lcur + (size_t)NN*CO);
    float a0=0.f,a1=0.f,a2=0.f,a3=0.f;
    int a = rp[row], b2 = rp[row+1];
    for (; a+8<=b2; a+=8){
      int s0=col[a],s1=col[a+1],s2=col[a+2],s3=col[a+3];
      int s4=col[a+4],s5=col[a+5],s6=col[a+6],s7=col[a+7];
      float4 u0=B4[(size_t)s0*TPR+ct], u1=B4[(size_t)s1*TPR+ct];
      float4 u2=B4[(size_t)s2*TPR+ct], u3=B4[(size_t)s3*TPR+ct];
      float4 u4=B4[(size_t)s4*TPR+ct], u5=B4[(size_t)s5*TPR+ct];
      float4 u6=B4[(size_t)s6*TPR+ct], u7=B4[(size_t)s7*TPR+ct];
      a0+=u0.x; a1+=u0.y; a2+=u0.z; a3+=u0.w;
      a0+=u1.x; a1+=u1.y; a2+=u1.z; a3+=u1.w;
      a0+=u2.x; a1+=u2.y; a2+=u2.z; a3+=u2.w;
      a0+=u3.x; a1+=u3.y; a2+=u3.z; a3+=u3.w;
      a0+=u4.x; a1+=u4.y; a2+=u4.z; a3+=u4.w;
      a0+=u5.x; a1+=u5.y; a2+=u5.z; a3+=u5.w;
      a0+=u6.x; a1+=u6.y; a2+=u6.z; a3+=u6.w;
      a0+=u7.x; a1+=u7.y; a2+=u7.z; a3+=u7.w;
    }
    for (; a+4<=b2; a+=4){
      int s0=col[a],s1=col[a+1],s2=col[a+2],s3=col[a+3];
      float4 u0=B4[(size_t)s0*TPR+ct], u1=B4[(size_t)s1*TPR+ct];
      float4 u2=B4[(size_t)s2*TPR+ct], u3=B4[(size_t)s3*TPR+ct];
      a0+=u0.x; a1+=u0.y; a2+=u0.z; a3+=u0.w;
      a0+=u1.x; a1+=u1.y; a2+=u1.z; a3+=u1.w;
      a0+=u2.x; a1+=u2.y; a2+=u2.z; a3+=u2.w;
      a0+=u3.x; a1+=u3.y; a2+=u3.z; a3+=u3.w;
    }
    for (; a<b2; ++a){
      float4 u = B4[(size_t)col[a]*TPR+ct];
      a0+=u.x; a1+=u.y; a2+=u.z; a3+=u.w;
    }
    const float4 fld = *(const float4*)(field + run*64 + 4*ct);
    float v0 = a0 - fld.x, v1 = a1 - fld.y, v2 = a2 - fld.z, v3 = a3 - fld.w;
    float m0=v0,m1=v1,m2=v2,m3=v3;
    bfly_max4<TPR>(m0,m1,m2,m3);
    float e0=expf(v0-m0), e1=expf(v1-m1), e2=expf(v2-m2), e3=expf(v3-m3);
    float s0=e0,s1=e1,s2=e2,s3=e3;
    bfly_sum4<TPR>(s0,s1,s2,s3);
    float p0=e0/s0, p1=e1/s1, p2=e2/s2, p3=e3/s3;
    if (fin){
      float* o = nxt + (size_t)row*126 + CO + 4*ct;
      o[0]=p0; o[1]=p1; o[2]=p2; o[3]=p3;
    } else {
      ((float4*)(nxt  + (size_t)NN*CO))[(size_t)row*TPR+ct] = make_float4(p0,p1,p2,p3);
      ((float4*)(lnxt + (size_t)NN*CO))[(size_t)row*TPR+ct] =
          make_float4(log1pf(eb*p0), log1pf(eb*p1), log1pf(eb*p2), log1pf(eb*p3));
    }
  }
}

__global__ __launch_bounds__(256) void k_bp_step(
    float* __restrict__ nxt, const float* __restrict__ lcur, float* __restrict__ lnxt,
    const int* __restrict__ rp, const int* __restrict__ col,
    const float* __restrict__ field, const float* __restrict__ betas, int fin){
  int graph, run, jj;
  bp_decode2(blockIdx.x, graph, run, jj);
  float eb = expm1f(betas[run]);
  switch(run){
    case 0: bp_step_elem2< 2, 0, 1,0>(graph, run, jj, lcur, nxt, lnxt, rp, col, field, eb, fin); break;
    case 1: bp_step_elem2< 4, 2, 1,0>(graph, run, jj, lcur, nxt, lnxt, rp, col, field, eb, fin); break;
    case 2: bp_step_elem2< 8, 6, 2,1>(graph, run, jj, lcur, nxt, lnxt, rp, col, field, eb, fin); break;
    case 3: bp_step_elem2<16,14, 4,2>(graph, run, jj, lcur, nxt, lnxt, rp, col, field, eb, fin); break;
    case 4: bp_step_elem2<32,30, 8,3>(graph, run, jj, lcur, nxt, lnxt, rp, col, field, eb, fin); break;
    default:bp_step_elem2<64,62,16,4>(graph, run, jj, lcur, nxt, lnxt, rp, col, field, eb, fin); break;
  }
}

// column sums over PACKED psi; per-column accumulators, rows 0..255 ascending
// (bit-identical); float4 loads for q>=4.
__global__ __launch_bounds__(64) void k_colsum_part(const float* __restrict__ psi_pk, float* __restrict__ part){
  int b = blockIdx.x;
  int xcd = b & 7, i = b >> 3;
  int gs = i/24, rem = i - gs*24;
  int run = rem >> 2, cg = rem & 3;
  int graph = gs*8 + xcd;
  int chunk = graph*4 + cg;
  int q = cQS[run];
  int co = (run==0)?0:(run==1)?2:(run==2)?6:(run==3)?14:(run==4)?30:62;
  int c = threadIdx.x;
  if (q >= 4){
    int nq = q >> 2;
    if (c >= nq) return;
    const float4* p4 = (const float4*)(psi_pk + (size_t)NN*co + (size_t)chunk*256*q) + c;
    float s0=0.f,s1=0.f,s2=0.f,s3=0.f;
    #pragma unroll 8
    for (int r=0;r<256;r++){
      float4 u = p4[(size_t)r*nq];
      s0+=u.x; s1+=u.y; s2+=u.z; s3+=u.w;
    }
    float* o = part + (run*256 + chunk)*64 + 4*c;
    o[0]=s0; o[1]=s1; o[2]=s2; o[3]=s3;
  } else {
    if (c >= q) return;
    float s = 0.f;
    const float* p = psi_pk + (size_t)NN*co + (size_t)chunk*256*q + c;
    #pragma unroll 8
    for (int r=0;r<256;r++) s += p[r*q];
    part[(run*256 + chunk)*64 + c] = s;
  }
}

__global__ void k_field(const float* __restrict__ part, const float* __restrict__ betas,
                        float* __restrict__ field){
  int id = threadIdx.x;
  int run = id >> 6, c = id & 63;
  if (c >= cQS[run]) return;
  float s = 0.f;
  for (int b=0;b<256;b++) s += part[(run*256 + b)*64 + c];
  float beta = betas[run];
  field[id] = s * (3.8f*beta/65536.0f);
}

// ---------------- diff-pool ----------------
// transpose cat [NN][126] -> catT [126][NN] (pure data movement)
__global__ __launch_bounds__(256) void k_catT(const float* __restrict__ cat, float* __restrict__ catT){
  __shared__ float tile[64*127];
  int b = blockIdx.x, t = threadIdx.x;
  const float* src = cat + (size_t)b*64*126;
  for (int i=t;i<8064;i+=256){
    int r = i/126, k = i - r*126;
    tile[r*127 + k] = src[i];
  }
  __syncthreads();
  for (int i=t;i<8064;i+=256){
    int k = i>>6, r = i&63;
    catT[(size_t)k*65536 + b*64 + r] = tile[r*127 + k];
  }
}

// row-per-lane GEMM + softmax. Block 256 thr = 4 waves: (rowhalf, colhalf).
// Per-output order: acc = pb[col] then += x[k]*w[k][col], k ascending (== R7).
__global__ __launch_bounds__(256) void k_s1t(const float* __restrict__ catT, const float* __restrict__ pw,
                                             const float* __restrict__ pb, float* __restrict__ s1){
  __shared__ float wl[12600];
  __shared__ float pbl[100];
  __shared__ float redM[2][128];
  __shared__ float redS[2][128];
  int t = threadIdx.x;
  for (int i=t;i<12600;i+=256) wl[i] = pw[i];
  if (t < 100) pbl[t] = pb[t];
  int w = t>>6, lane = t&63;
  int rh = w&1, chh = w>>1;
  int ch = chh*50;
  int row = blockIdx.x*128 + rh*64 + lane;
  __syncthreads();
  float acc[50];
  #pragma unroll
  for (int j=0;j<50;j++) acc[j] = pbl[ch+j];
  for (int k=0;k<126;k++){
    float xv = catT[(size_t)k*65536 + row];
    const float* wr = &wl[k*100 + ch];
    #pragma unroll
    for (int j=0;j<50;j+=2){
      float2 wv = *(const float2*)&wr[j];
      acc[j]   += xv*wv.x;
      acc[j+1] += xv*wv.y;
    }
  }
  // softmax over 100 cols of this row (split across wave pair); reduce order
  // differs from reference only in the max/denom tree (tolerated class).
  float m = acc[0];
  #pragma unroll
  for (int j=1;j<50;j++) m = fmaxf(m, acc[j]);
  redM[chh][rh*64 + lane] = m;
  __syncthreads();
  float mm = fmaxf(redM[0][rh*64 + lane], redM[1][rh*64 + lane]);
  float s = 0.f;
  #pragma unroll
  for (int j=0;j<50;j++){ acc[j] = expf(acc[j]-mm); s += acc[j]; }
  redS[chh][rh*64 + lane] = s;
  __syncthreads();
  float tot = redS[0][rh*64 + lane] + redS[1][rh*64 + lane];
  float* o = s1 + (size_t)row*100 + ch;
  #pragma unroll
  for (int j=0;j<50;j+=2){
    float2 ov; ov.x = acc[j]/tot; ov.y = acc[j+1]/tot;
    *(float2*)&o[j] = ov;
  }
}

// thread per (row, col-quad): float4 gathers, chunk-8.
__global__ __launch_bounds__(256) void k_T(const float* __restrict__ s1, const int* __restrict__ rp,
                                           const int* __restrict__ col, float* __restrict__ T){
  int b = blockIdx.x;
  int xcd = b & 7, i = b >> 3;
  int gs = i/100, j = i - gs*100;
  int graph = gs*8 + xcd;
  int idwg = j*256 + threadIdx.x;
  int rw = idwg/25, quad = idwg - rw*25;
  int v = graph*1024 + rw;
  float a0=0.f,a1=0.f,a2=0.f,a3=0.f;
  const float4* S4 = (const float4*)s1;
  int a = rp[v], e = rp[v+1];
  for (; a+8<=e; a+=8){
    int s0=col[a], s1_=col[a+1], s2=col[a+2], s3=col[a+3];
    int s4=col[a+4], s5=col[a+5], s6=col[a+6], s7=col[a+7];
    float4 u0=S4[(size_t)s0*25+quad], u1=S4[(size_t)s1_*25+quad];
    float4 u2=S4[(size_t)s2*25+quad], u3=S4[(size_t)s3*25+quad];
    float4 u4=S4[(size_t)s4*25+quad], u5=S4[(size_t)s5*25+quad];
    float4 u6=S4[(size_t)s6*25+quad], u7=S4[(size_t)s7*25+quad];
    a0+=u0.x; a1+=u0.y; a2+=u0.z; a3+=u0.w;
    a0+=u1.x; a1+=u1.y; a2+=u1.z; a3+=u1.w;
    a0+=u2.x; a1+=u2.y; a2+=u2.z; a3+=u2.w;
    a0+=u3.x; a1+=u3.y; a2+=u3.z; a3+=u3.w;
    a0+=u4.x; a1+=u4.y; a2+=u4.z; a3+=u4.w;
    a0+=u5.x; a1+=u5.y; a2+=u5.z; a3+=u5.w;
    a0+=u6.x; a1+=u6.y; a2+=u6.z; a3+=u6.w;
    a0+=u7.x; a1+=u7.y; a2+=u7.z; a3+=u7.w;
  }
  for (; a+4<=e; a+=4){
    int s0=col[a], s1_=col[a+1], s2=col[a+2], s3=col[a+3];
    float4 u0=S4[(size_t)s0*25+quad], u1=S4[(size_t)s1_*25+quad];
    float4 u2=S4[(size_t)s2*25+quad], u3=S4[(size_t)s3*25+quad];
    a0+=u0.x; a1+=u0.y; a2+=u0.z; a3+=u0.w;
    a0+=u1.x; a1+=u1.y; a2+=u1.z; a3+=u1.w;
    a0+=u2.x; a1+=u2.y; a2+=u2.z; a3+=u2.w;
    a0+=u3.x; a1+=u3.y; a2+=u3.z; a3+=u3.w;
  }
  for (; a<e; ++a){
    float4 u = S4[(size_t)col[a]*25+quad];
    a0+=u.x; a1+=u.y; a2+=u.z; a3+=u.w;
  }
  ((float4*)T)[(size_t)v*25 + quad] = make_float4(a0,a1,a2,a3);
}

// split-K LDS-tiled GEMM: padj_part[qtr] = s1^T * T over n-quarter.
__global__ __launch_bounds__(512) void k_p1adj_sk(const float* __restrict__ s1, const float* __restrict__ T,
                                                  float* __restrict__ part){
  __shared__ float sS[6400];
  __shared__ float sT[6400];
  int blk = blockIdx.x;
  int b = blk >> 2, qtr = blk & 3;
  int t = threadIdx.x;
  int tk = t/20, tl = t - tk*20;
  bool act = t < 500;
  int k0 = tk*4, l0 = tl*5;
  float acc[4][5];
  #pragma unroll
  for (int i=0;i<4;i++)
    #pragma unroll
    for (int j=0;j<5;j++) acc[i][j] = 0.f;
  const float* s1b = s1 + (size_t)b*102400;
  const float* Tb  = T  + (size_t)b*102400;
  for (int c=qtr*4; c<qtr*4+4; c++){
    for (int i=t;i<6400;i+=512){ sS[i] = s1b[c*6400+i]; sT[i] = Tb[c*6400+i]; }
    __syncthreads();
    if (act){
      #pragma unroll 2
      for (int n=0;n<64;n++){
        const float* sr = &sS[n*100 + k0];
        const float* tr = &sT[n*100 + l0];
        float s0=sr[0], s1v=sr[1], s2=sr[2], s3=sr[3];
        float t0=tr[0], t1=tr[1], t2=tr[2], t3=tr[3], t4=tr[4];
        acc[0][0]+=s0*t0; acc[0][1]+=s0*t1; acc[0][2]+=s0*t2; acc[0][3]+=s0*t3; acc[0][4]+=s0*t4;
        acc[1][0]+=s1v*t0; acc[1][1]+=s1v*t1; acc[1][2]+=s1v*t2; acc[1][3]+=s1v*t3; acc[1][4]+=s1v*t4;
        acc[2][0]+=s2*t0; acc[2][1]+=s2*t1; acc[2][2]+=s2*t2; acc[2][3]+=s2*t3; acc[2][4]+=s2*t4;
        acc[3][0]+=s3*t0; acc[3][1]+=s3*t1; acc[3][2]+=s3*t2; acc[3][3]+=s3*t3; acc[3][4]+=s3*t4;
      }
    }
    __syncthreads();
  }
  if (act){
    float* pp = part + (size_t)qtr*640000 + (size_t)b*10000;
    #pragma unroll
    for (int i=0;i<4;i++){
      float* o = pp + (k0+i)*100 + l0;
      #pragma unroll
      for (int j=0;j<5;j++) o[j] = acc[i][j];
    }
  }
}

__global__ __launch_bounds__(256) void k_p1adj_red(const float* __restrict__ part, float* __restrict__ padj){
  int id = blockIdx.x*256 + threadIdx.x;
  if (id >= NBG*10000) return;
  float s = part[id];
  s += part[640000 + id];
  s += part[1280000 + id];
  s += part[1920000 + id];
  padj[id] = s;
}

__global__ __launch_bounds__(256) void k_p1x_sk(const float* __restrict__ s1, const float* __restrict__ x13,
                                                float* __restrict__ part){
  __shared__ float sS[6400];
  __shared__ float sX[1920];
  int blk = blockIdx.x;
  int b = blk >> 2, qtr = blk & 3;
  int t = threadIdx.x;
  int tk = t/10, tl = t - tk*10;
  bool act = t < 250;
  int k0 = tk*4, d0 = tl*3;
  float acc[4][3];
  #pragma unroll
  for (int i=0;i<4;i++)
    #pragma unroll
    for (int j=0;j<3;j++) acc[i][j] = 0.f;
  const float* s1b = s1 + (size_t)b*102400;
  const float* xb  = x13 + (size_t)b*30720;
  for (int c=qtr*4; c<qtr*4+4; c++){
    for (int i=t;i<6400;i+=256) sS[i] = s1b[c*6400+i];
    for (int i=t;i<1920;i+=256) sX[i] = xb[c*1920+i];
    __syncthreads();
    if (act){
      #pragma unroll 2
      for (int n=0;n<64;n++){
        const float* sr = &sS[n*100 + k0];
        const float* xr = &sX[n*30 + d0];
        float s0=sr[0], s1v=sr[1], s2=sr[2], s3=sr[3];
        float x0=xr[0], x1=xr[1], x2=xr[2];
        acc[0][0]+=s0*x0; acc[0][1]+=s0*x1; acc[0][2]+=s0*x2;
        acc[1][0]+=s1v*x0; acc[1][1]+=s1v*x1; acc[1][2]+=s1v*x2;
        acc[2][0]+=s2*x0; acc[2][1]+=s2*x1; acc[2][2]+=s2*x2;
        acc[3][0]+=s3*x0; acc[3][1]+=s3*x1; acc[3][2]+=s3*x2;
      }
    }
    __syncthreads();
  }
  if (act){
    float* pp = part + (size_t)qtr*192000 + (size_t)b*3000;
    #pragma unroll
    for (int i=0;i<4;i++){
      float* o = pp + (k0+i)*30 + d0;
      #pragma unroll
      for (int j=0;j<3;j++) o[j] = acc[i][j];
    }
  }
}

__global__ __launch_bounds__(256) void k_p1x_red(const float* __restrict__ part, float* __restrict__ px){
  int id = blockIdx.x*256 + threadIdx.x;
  if (id >= NBG*3000) return;
  float s = part[id];
  s += part[192000 + id];
  s += part[384000 + id];
  s += part[576000 + id];
  px[id] = s;
}

// ---------------- stage-2 dense GCN ----------------
__global__ __launch_bounds__(256) void k_dinv2(const float* __restrict__ padj, float* __restrict__ dv){
  int id = blockIdx.x*256 + threadIdx.x;
  if (id >= NBG*100) return;
  const float* r = padj + id*100;
  int k = id % 100;
  float s = 0.f;
  for (int l=0;l<100;l++){
    float v = r[l];
    if (l==k) v += 1.0f;
    s += v;
  }
  dv[id] = 1.0f/sqrtf(s);
}

__global__ __launch_bounds__(256) void k_Ank(const float* __restrict__ padj, const float* __restrict__ dv,
                                             float* __restrict__ An){
  int id = blockIdx.x*256 + threadIdx.x;
  if (id >= NBG*10000) return;
  int b = id/10000;
  int rem = id - b*10000;
  int k = rem/100, l = rem - k*100;
  float a = padj[id] + ((k==l)? 1.0f : 0.0f);
  An[id] = (dv[b*100+k]*a)*dv[b*100+l];
}

__global__ __launch_bounds__(256) void k_y2(const float* __restrict__ An, const float* __restrict__ h,
    const float* __restrict__ bias, float* __restrict__ y){
  int id = blockIdx.x*256 + threadIdx.x;
  if (id >= NBG*100*30) return;
  int d = id % 30;
  int bk = id / 30;
  int b = bk / 100;
  const float* Ar = An + bk*100;
  const float* hb = h + b*100*30;
  float acc = 0.f;
  for (int l=0;l<100;l++) acc += Ar[l]*hb[l*30+d];
  y[id] = acc + bias[d];
}

// ---------------- pools + FC ----------------
__global__ __launch_bounds__(256) void k_pool2(const float* __restrict__ A,
    const float* __restrict__ Bv, const float* __restrict__ Cv,
    int rows, float* __restrict__ conv, int coff){
  __shared__ float lds[256*31];
  int b = blockIdx.x, a = blockIdx.y, t = threadIdx.x;
  const float* X = (a==0)? A : ((a==1)? Bv : Cv);
  float acc[30];
  #pragma unroll
  for (int f=0;f<30;f++) acc[f] = -FLT_MAX;
  for (int r=t; r<rows; r+=256){
    const float* xr = X + (size_t)(b*rows + r)*30;
    #pragma unroll
    for (int f=0;f<30;f++) acc[f] = fmaxf(acc[f], xr[f]);
  }
  #pragma unroll
  for (int f=0;f<30;f++) lds[t*31+f] = acc[f];
  __syncthreads();
  for (int s=128;s>0;s>>=1){
    if (t<s){
      #pragma unroll
      for (int f=0;f<30;f++) lds[t*31+f] = fmaxf(lds[t*31+f], lds[(t+s)*31+f]);
    }
    __syncthreads();
  }
  if (t<30) conv[b*180 + coff + a*30 + t] = lds[t];
}

__global__ __launch_bounds__(64) void k_fc(const float* __restrict__ conv,
    const float* __restrict__ w1, const float* __restrict__ b1,
    const float* __restrict__ w2, const float* __restrict__ b2, float* __restrict__ out){
  __shared__ float row[180];
  __shared__ float hid[50];
  int b = blockIdx.x, t = threadIdx.x;
  for (int i=t;i<180;i+=64) row[i] = conv[b*180+i];
  __syncthreads();
  if (t < 50){
    float a = b1[t];
    for (int i=0;i<180;i++) a += row[i]*w1[i*50+t];
    hid[t] = fmaxf(a, 0.f);
  }
  __syncthreads();
  if (t < 6){
    float a = b2[t];
    for (int i=0;i<50;i++) a += hid[i]*w2[i*6+t];
    out[b*6+t] = a;
  }
  if (b==0 && t==63) out[NBG*6] = 0.0f;
}

// ---------------------------------------------------------------------------
extern "C" void kernel_launch(void* const* d_in, const int* in_sizes, int n_in,
                              void* d_out, int out_size, void* d_ws, size_t ws_size,
                              hipStream_t stream)
{
  (void)in_sizes; (void)n_in; (void)out_size; (void)ws_size;
  const float* x   = (const float*)d_in[0];
  const int*   src = (const int*)d_in[1];
  const int*   dst = src + NEDGE;
  const float* w11=(const float*)d_in[3],  *b11=(const float*)d_in[4],  *g11=(const float*)d_in[5],  *be11=(const float*)d_in[6];
  const float* w12=(const float*)d_in[7],  *b12=(const float*)d_in[8],  *g12=(const float*)d_in[9],  *be12=(const float*)d_in[10];
  const float* w13=(const float*)d_in[11], *b13=(const float*)d_in[12], *g13=(const float*)d_in[13], *be13=(const float*)d_in[14];
  const float* w21=(const float*)d_in[15], *b21=(const float*)d_in[16], *g21=(const float*)d_in[17], *be21=(const float*)d_in[18];
  const float* w22=(const float*)d_in[19], *b22=(const float*)d_in[20], *g22=(const float*)d_in[21], *be22=(const float*)d_in[22];
  const float* w23=(const float*)d_in[23], *b23=(const float*)d_in[24], *g23=(const float*)d_in[25], *be23=(const float*)d_in[26];
  const float* betas=(const float*)d_in[27];
  const float* poolw=(const float*)d_in[28], *poolb=(const float*)d_in[29];
  const float* fc1w=(const float*)d_in[30], *fc1b=(const float*)d_in[31];
  const float* fc2w=(const float*)d_in[32], *fc2b=(const float*)d_in[33];
  float* out = (float*)d_out;

  uint8_t* basep = (uint8_t*)d_ws;
  size_t off = 0;
  auto take = [&](size_t bytes)->void*{
    void* p = basep + off;
    off = (off + bytes + 255) & ~(size_t)255;
    return p;
  };
  int* degi    = (int*)take((size_t)NN*4);
  int* dego    = (int*)take((size_t)NN*4);
  int* cntA    = (int*)take((size_t)NN*4);
  int* cntB    = (int*)take((size_t)NN*4);
  int* rp_in   = (int*)take((size_t)(NN+1)*4);
  int* rp_out  = (int*)take((size_t)(NN+1)*4);
  int* bsum    = (int*)take(512*4);
  int* col_in  = (int*)take((size_t)NEDGE*4);
  int* col_out = (int*)take((size_t)NEDGE*4);
  float* dinv  = (float*)take((size_t)NN*4);
  float* hbuf  = (float*)take((size_t)NN*30*4);
  float* tmpY  = (float*)take((size_t)NN*30*4);
  float* X1    = (float*)take((size_t)NN*30*4);
  float* X2    = (float*)take((size_t)NN*30*4);
  float* X3    = (float*)take((size_t)NN*30*4);
  float* bufA  = (float*)take((size_t)NN*126*4);
  float* bufB  = (float*)take((size_t)NN*126*4);
  float* logA  = (float*)take((size_t)NN*126*4);
  float* logB  = (float*)take((size_t)NN*126*4);
  float* partCS= (float*)take((size_t)6*256*64*4);
  float* fieldv= (float*)take(384*4);
  float* partBN= (float*)take(256*30*4);
  float* partBN2=(float*)take(256*30*4);
  float* meanv = (float*)take(128);
  float* varv  = (float*)take(128);
  float* px    = (float*)take(192000*4);
  float* padj  = (float*)take(640000*4);
  float* An    = (float*)take(640000*4);
  float* dinv2 = (float*)take(6400*4);
  float* h2    = (float*)take(192000*4);
  float* y2    = (float*)take(192000*4);
  float* X21   = (float*)take(192000*4);
  float* X22   = (float*)take(192000*4);
  float* X23   = (float*)take(192000*4);
  float* conv  = (float*)take(64*180*4);

  // post-BP scratch reuse: catT -> logA; split-K partials -> logB
  float* catT     = logA;
  float* pAdjPart = logB;               // 4*640000 floats
  float* pPxPart  = logB + 2560000;     // 4*192000 floats

  // ---- CSR setup (degi..cntB contiguous -> single memset) ----
  hipMemsetAsync(degi, 0, (size_t)4*NN*4, stream);
  k_count<<<2048,256,0,stream>>>(src,dst,degi,dego);
  k_scan1<<<dim3(256,2),256,0,stream>>>(degi, dego, rp_in, rp_out, bsum);
  k_scan2<<<2,256,0,stream>>>(bsum);
  k_scan3<<<dim3(256,2),256,0,stream>>>(rp_in, rp_out, bsum);
  k_fill<<<dim3(2048,2),256,0,stream>>>(src, dst, rp_in, rp_out, cntA, cntB, col_in, col_out);
  k_sortrow<<<dim3(256,2),256,0,stream>>>(rp_in, rp_out, col_in, col_out, src, dst);
  k_dinv<<<256,256,0,stream>>>(degi, dinv);

  auto run_bn = [&](const float* yin, float* xout, const float* g, const float* be, int nrow){
    k_bn_stat<<<256,256,0,stream>>>(yin, nrow, partBN, partBN2);
    k_bn_red2<<<1,32,0,stream>>>(partBN, partBN2, (float)nrow, meanv, varv);
    k_bn_apply<<<(nrow*30)/256,256,0,stream>>>(yin, meanv, varv, g, be, xout, nrow);
  };

  // ---- stage 1: sparse GCN + BN x3 ----
  k_mm30<3><<<7680,256,0,stream>>>(x, w11, hbuf, NN);
  k_gcn_agg<<<3840,256,0,stream>>>(hbuf, rp_in, col_in, dinv, b11, tmpY);
  run_bn(tmpY, X1, g11, be11, NN);
  k_mm30<30><<<7680,256,0,stream>>>(X1, w12, hbuf, NN);
  k_gcn_agg<<<3840,256,0,stream>>>(hbuf, rp_in, col_in, dinv, b12, tmpY);
  run_bn(tmpY, X2, g12, be12, NN);
  k_mm30<30><<<7680,256,0,stream>>>(X2, w13, hbuf, NN);
  k_gcn_agg<<<3840,256,0,stream>>>(hbuf, rp_in, col_in, dinv, b13, tmpY);
  run_bn(tmpY, X3, g13, be13, NN);
  k_pool2<<<dim3(NBG,3),256,0,stream>>>(X1, X2, X3, 1024, conv, 0);

  // ---- belief propagation (packed psi + packed L, ping-pong) ----
  k_bp_first<<<8192,256,0,stream>>>(bufA, logA, betas);
  float* cur = bufA;  float* nxt = bufB;
  float* lcur = logA; float* lnxt = logB;
  for (int it=0; it<10; ++it){
    k_colsum_part<<<1536,64,0,stream>>>(cur, partCS);
    k_field<<<1,384,0,stream>>>(partCS, betas, fieldv);
    int fin = (it==9);
    k_bp_step<<<8192,256,0,stream>>>(nxt, lcur, lnxt, rp_in, col_in, fieldv, betas, fin);
    float* tp = cur;  cur = nxt;   nxt = tp;
    float* tl = lcur; lcur = lnxt; lnxt = tl;
  }
  // final concatenated psi [NN][126] now in bufA

  // ---- diff-pool ----
  k_catT<<<1024,256,0,stream>>>(bufA, catT);                  // cat^T -> logA
  k_s1t<<<512,256,0,stream>>>(catT, poolw, poolb, bufB);      // s1 [n,100] -> bufB
  k_T<<<6400,256,0,stream>>>(bufB, rp_out, col_out, bufA);    // T = A*s1   -> bufA
  k_p1adj_sk<<<256,512,0,stream>>>(bufB, bufA, pAdjPart);
  k_p1adj_red<<<2500,256,0,stream>>>(pAdjPart, padj);
  k_p1x_sk<<<256,256,0,stream>>>(bufB, X3, pPxPart);
  k_p1x_red<<<750,256,0,stream>>>(pPxPart, px);
  k_dinv2<<<25,256,0,stream>>>(padj, dinv2);
  k_Ank<<<2500,256,0,stream>>>(padj, dinv2, An);

  // ---- stage 2: dense GCN + BN x3 ----
  auto gcn2 = [&](const float* xin, const float* w, const float* bb, const float* g,
                  const float* be, float* xout){
    k_mm30<30><<<750,256,0,stream>>>(xin, w, h2, NBG*100);
    k_y2<<<750,256,0,stream>>>(An, h2, bb, y2);
    run_bn(y2, xout, g, be, NBG*100);
  };
  gcn2(px,  w21, b21, g21, be21, X21);
  gcn2(X21, w22, b22, g22, be22, X22);
  gcn2(X22, w23, b23, g23, be23, X23);
  k_pool2<<<dim3(NBG,3),256,0,stream>>>(X21, X22, X23, 100, conv, 90);

  // ---- FC head ----
  k_fc<<<64,64,0,stream>>>(conv, fc1w, fc1b, fc2w, fc2b, out);
}

// Round 12
// 1287.717 us; speedup vs baseline: 2.8369x; 1.0445x over previous
//
#include <hip/hip_runtime.h>
#include <stdint.h>
#include <float.h>

// ---------------------------------------------------------------------------
// Net_57604101374728: GCN(x3)+BN -> maxpool | 6x belief-prop -> diffpool ->
// dense GCN(x3)+BN -> maxpool -> FC. Full fp32 port of the JAX reference.
//
// R12: BN folded into next-layer weights (k_bnw); stats fused into
// k_gcn_agg/k_y2 epilogues (LDS bins + 64-slot atomics, smooth path);
// pool/p1x apply BN affine on the fly; dinv fused into sortrow; dinv2+Ank
// merged; split-K reduces merged. BP kernels byte-identical -> BP bit-exact.
// ---------------------------------------------------------------------------

constexpr int NN    = 65536;    // total nodes
constexpr int NEDGE = 524288;   // edges
constexpr int NBG   = 64;       // graphs

__constant__ int cQS[6]   = {2,4,8,16,32,64};

// ---------------- threefry2x32 (20 rounds) ----------------
__device__ __forceinline__ void tf2x32(uint32_t k0, uint32_t k1, uint32_t x0, uint32_t x1,
                                       uint32_t& o0, uint32_t& o1){
  uint32_t ks[3] = {k0, k1, k0 ^ k1 ^ 0x1BD11BDAu};
  x0 += ks[0]; x1 += ks[1];
  const int RA[4] = {13,15,26,6}, RB[4] = {17,29,16,24};
  #pragma unroll
  for (int i=0;i<5;i++){
    const int* r = (i&1)? RB : RA;
    #pragma unroll
    for (int j=0;j<4;j++){
      x0 += x1;
      x1 = (x1 << r[j]) | (x1 >> (32 - r[j]));
      x1 ^= x0;
    }
    x0 += ks[(i+1)%3];
    x1 += ks[(i+2)%3] + (uint32_t)(i+1);
  }
  o0 = x0; o1 = x1;
}

// ---------------- XLA ErfInv32 (Giles), contraction off ----------------
__device__ __forceinline__ float erfinv32(float xx){
  #pragma clang fp contract(off)
  float w = -log1pf(-xx*xx);
  float p;
  if (w < 5.0f){
    w = w - 2.5f;
    p = 2.81022636e-08f;
    p = 3.43273939e-07f  + p*w;
    p = -3.5233877e-06f  + p*w;
    p = -4.39150654e-06f + p*w;
    p = 0.00021858087f   + p*w;
    p = -0.00125372503f  + p*w;
    p = -0.00417768164f  + p*w;
    p = 0.246640727f     + p*w;
    p = 1.50140941f      + p*w;
  } else {
    w = sqrtf(w) - 3.0f;
    p = -0.000200214257f;
    p = 0.000100950558f  + p*w;
    p = 0.00134934322f   + p*w;
    p = -0.00367342844f  + p*w;
    p = 0.00573950773f   + p*w;
    p = -0.0076224613f   + p*w;
    p = 0.00943887047f   + p*w;
    p = 1.00167406f      + p*w;
    p = 2.83297682f      + p*w;
  }
  return p*xx;
}

// ---------------- CSR construction (fused pairs via blockIdx.y) ----------
__global__ __launch_bounds__(256) void k_count(const int* __restrict__ src, const int* __restrict__ dst,
                                               int* __restrict__ degi, int* __restrict__ dego){
  int e = blockIdx.x*256 + threadIdx.x;
  if (e >= NEDGE) return;
  atomicAdd(&degi[dst[e]], 1);
  atomicAdd(&dego[src[e]], 1);
}

__global__ __launch_bounds__(256) void k_scan1(const int* __restrict__ degi, const int* __restrict__ dego,
                                               int* __restrict__ rpi, int* __restrict__ rpo,
                                               int* __restrict__ bsum){
  __shared__ int lds[256];
  const int* deg = blockIdx.y? dego : degi;
  int* rp = blockIdx.y? rpo : rpi;
  int* bs = bsum + blockIdx.y*256;
  int b = blockIdx.x, t = threadIdx.x;
  lds[t] = deg[b*256 + t];
  __syncthreads();
  for (int s=1;s<256;s<<=1){
    int add = (t>=s)? lds[t-s] : 0;
    __syncthreads();
    lds[t] += add;
    __syncthreads();
  }
  rp[b*256 + t + 1] = lds[t];
  if (t==0 && b==0) rp[0] = 0;
  if (t==255) bs[b] = lds[255];
}

__global__ __launch_bounds__(256) void k_scan2(int* __restrict__ bsum){
  __shared__ int lds[256];
  int* bs = bsum + blockIdx.x*256;
  int t = threadIdx.x;
  lds[t] = bs[t];
  __syncthreads();
  for (int s=1;s<256;s<<=1){
    int add = (t>=s)? lds[t-s] : 0;
    __syncthreads();
    lds[t] += add;
    __syncthreads();
  }
  bs[t] = (t==0)? 0 : lds[t-1];
}

__global__ __launch_bounds__(256) void k_scan3(int* __restrict__ rpi, int* __restrict__ rpo,
                                               const int* __restrict__ bsum){
  int* rp = blockIdx.y? rpo : rpi;
  const int* bs = bsum + blockIdx.y*256;
  int b = blockIdx.x, t = threadIdx.x;
  rp[b*256 + t + 1] += bs[b];
}

__global__ __launch_bounds__(256) void k_fill(const int* __restrict__ src, const int* __restrict__ dst,
                                              const int* __restrict__ rpi, const int* __restrict__ rpo,
                                              int* __restrict__ cntA, int* __restrict__ cntB,
                                              int* __restrict__ colI, int* __restrict__ colO){
  int e = blockIdx.x*256 + threadIdx.x;
  if (e >= NEDGE) return;
  if (blockIdx.y == 0){
    int d = dst[e];
    int p = atomicAdd(&cntA[d], 1);
    colI[rpi[d] + p] = e;
  } else {
    int d = src[e];
    int p = atomicAdd(&cntB[d], 1);
    colO[rpo[d] + p] = e;
  }
}

// sortrow + dinv (dinv computed by the y==0 pass)
__global__ __launch_bounds__(256) void k_sortrow(const int* __restrict__ rpi, const int* __restrict__ rpo,
                                                 int* __restrict__ colI, int* __restrict__ colO,
                                                 const int* __restrict__ src, const int* __restrict__ dst,
                                                 const int* __restrict__ degi, float* __restrict__ dinv){
  const int* rp = blockIdx.y? rpo : rpi;
  int* colbuf   = blockIdx.y? colO : colI;
  const int* other = blockIdx.y? dst : src;
  int v = blockIdx.x*256 + threadIdx.x;
  if (v >= NN) return;
  int s0 = rp[v], s1 = rp[v+1];
  for (int i=s0+1;i<s1;i++){
    int key = colbuf[i]; int j = i-1;
    while (j>=s0 && colbuf[j]>key){ colbuf[j+1]=colbuf[j]; j--; }
    colbuf[j+1] = key;
  }
  for (int i=s0;i<s1;i++) colbuf[i] = other[colbuf[i]];
  if (blockIdx.y == 0) dinv[v] = 1.0f / sqrtf((float)(degi[v] + 1));
}

// ---------------- stage-1 GCN ----------------
template<int CIN>
__global__ __launch_bounds__(256) void k_mm30(const float* __restrict__ x, const float* __restrict__ w,
                                              float* __restrict__ h, int nrow){
  __shared__ float ws[CIN*30];
  int t = threadIdx.x;
  for (int i=t;i<CIN*30;i+=256) ws[i] = w[i];
  __syncthreads();
  int id = blockIdx.x*256 + t;
  if (id >= nrow*30) return;
  int v = id/30, j = id - v*30;
  const float* xr = x + v*CIN;
  float acc = 0.f;
  #pragma unroll
  for (int k=0;k<CIN;k++) acc += xr[k]*ws[k*30+j];
  h[id] = acc;
}

// mm30 with folded BN: h = y @ wfold + cvec
__global__ __launch_bounds__(256) void k_mm30c(const float* __restrict__ x, const float* __restrict__ wfold,
                                               const float* __restrict__ cvec, float* __restrict__ h, int nrow){
  __shared__ float ws[900];
  __shared__ float cl[30];
  int t = threadIdx.x;
  for (int i=t;i<900;i+=256) ws[i] = wfold[i];
  if (t < 30) cl[t] = cvec[t];
  __syncthreads();
  int id = blockIdx.x*256 + t;
  if (id >= nrow*30) return;
  int v = id/30, j = id - v*30;
  const float* xr = x + v*30;
  float acc = cl[j];
  #pragma unroll
  for (int k=0;k<30;k++) acc += xr[k]*ws[k*30+j];
  h[id] = acc;
}

// gcn_agg + fused BN stats (LDS bins -> 64-slot global atomics; smooth path)
__global__ __launch_bounds__(256) void k_gcn_agg(const float* __restrict__ h, const int* __restrict__ rp,
    const int* __restrict__ col, const float* __restrict__ dinv, const float* __restrict__ bias,
    float* __restrict__ y, float* __restrict__ gS, float* __restrict__ gQ){
  __shared__ float binS[30], binQ[30];
  int t = threadIdx.x;
  if (t < 30){ binS[t]=0.f; binQ[t]=0.f; }
  __syncthreads();
  int b = blockIdx.x;
  int xcd = b & 7, i = b >> 3;
  int gs = i/60, j = i - gs*60;
  int graph = gs*8 + xcd;
  int idwg = j*256 + t;
  int rw = idwg/15, pr = idwg - rw*15;
  int v = graph*1024 + rw;
  float dv = dinv[v];
  float accx = 0.f, accy = 0.f;
  int a = rp[v], e = rp[v+1];
  for (; a+4<=e; a+=4){
    int s0=col[a], s1=col[a+1], s2=col[a+2], s3=col[a+3];
    float d0=dinv[s0], d1=dinv[s1], d2=dinv[s2], d3=dinv[s3];
    float2 h0=*(const float2*)(h+s0*30+2*pr), h1=*(const float2*)(h+s1*30+2*pr);
    float2 h2=*(const float2*)(h+s2*30+2*pr), h3=*(const float2*)(h+s3*30+2*pr);
    accx += h0.x*(d0*dv); accy += h0.y*(d0*dv);
    accx += h1.x*(d1*dv); accy += h1.y*(d1*dv);
    accx += h2.x*(d2*dv); accy += h2.y*(d2*dv);
    accx += h3.x*(d3*dv); accy += h3.y*(d3*dv);
  }
  for (; a<e; ++a){
    int s = col[a];
    float w = dinv[s]*dv;
    float2 hv = *(const float2*)(h+s*30+2*pr);
    accx += hv.x*w; accy += hv.y*w;
  }
  float2 hs = *(const float2*)(h + v*30 + 2*pr);
  float w2 = dv*dv;
  accx += hs.x*w2; accy += hs.y*w2;   // self loop last (JAX concat order)
  float2 o; o.x = accx + bias[2*pr]; o.y = accy + bias[2*pr+1];
  *(float2*)(y + v*30 + 2*pr) = o;
  atomicAdd(&binS[2*pr],   o.x); atomicAdd(&binQ[2*pr],   o.x*o.x);
  atomicAdd(&binS[2*pr+1], o.y); atomicAdd(&binQ[2*pr+1], o.y*o.y);
  __syncthreads();
  if (t < 30){
    int slot = (b & 63)*30 + t;
    atomicAdd(&gS[slot], binS[t]);
    atomicAdd(&gQ[slot], binQ[t]);
  }
}

// BN finalize: mean/var -> scale/shift (sfc slot); optionally fold next W.
// Zeroes the stat slots for the next layer.
template<int FOLD>
__global__ __launch_bounds__(256) void k_bnw(float* __restrict__ gS, float* __restrict__ gQ, float n,
    const float* __restrict__ g, const float* __restrict__ be,
    const float* __restrict__ wnext, float* __restrict__ sfc,
    float* __restrict__ wfold, float* __restrict__ cvec){
  __shared__ float s_l[30], c_l[30];
  int t = threadIdx.x;
  if (t < 30){
    float s=0.f, q=0.f;
    for (int u=0;u<64;u++){ s += gS[u*30+t]; q += gQ[u*30+t]; }
    float m = s/n;
    float var = q/n - m*m;
    float sc = g[t]*(1.0f/sqrtf(var+1e-5f));
    float c0 = be[t] - sc*m;
    s_l[t]=sc; c_l[t]=c0;
    sfc[t]=sc; sfc[32+t]=c0;
    for (int u=0;u<64;u++){ gS[u*30+t]=0.f; gQ[u*30+t]=0.f; }
  }
  __syncthreads();
  if (FOLD){
    for (int i=t;i<900;i+=256) wfold[i] = s_l[i/30]*wnext[i];
    if (t<30){
      float c=0.f;
      for (int k=0;k<30;k++) c += c_l[k]*wnext[k*30+t];
      cvec[t]=c;
    }
  }
}

// ---------------- belief propagation (col-vectorized, XCD-resident) -------
__device__ __forceinline__ void bp_decode2(int b, int& graph, int& run, int& jj){
  int xcd = b & 7, i = b >> 3;
  int gs = i >> 7, j = i & 127;
  if      (j <   4){ run=0; jj=j;    }
  else if (j <   8){ run=1; jj=j-4;  }
  else if (j <  16){ run=2; jj=j-8;  }
  else if (j <  32){ run=3; jj=j-16; }
  else if (j <  64){ run=4; jj=j-32; }
  else             { run=5; jj=j-64; }
  graph = gs*8 + xcd;
}

template<int TPR>
__device__ __forceinline__ void bfly_max4(float& m0, float& m1, float& m2, float& m3){
  if constexpr (TPR > 1){
    #pragma unroll
    for (int lm = TPR>>1; lm; lm >>= 1){
      float p0=__shfl_xor(m0,lm,64), p1=__shfl_xor(m1,lm,64);
      float p2=__shfl_xor(m2,lm,64), p3=__shfl_xor(m3,lm,64);
      m0=fmaxf(m0,p0); m1=fmaxf(m1,p1); m2=fmaxf(m2,p2); m3=fmaxf(m3,p3);
    }
  }
  { float t0=fmaxf(m0,m2), t1=fmaxf(m1,m3), t2=fmaxf(m2,m0), t3=fmaxf(m3,m1);
    m0=t0; m1=t1; m2=t2; m3=t3; }
  { float t0=fmaxf(m0,m1), t1=fmaxf(m1,m0), t2=fmaxf(m2,m3), t3=fmaxf(m3,m2);
    m0=t0; m1=t1; m2=t2; m3=t3; }
}

template<int TPR>
__device__ __forceinline__ void bfly_sum4(float& s0, float& s1, float& s2, float& s3){
  if constexpr (TPR > 1){
    #pragma unroll
    for (int lm = TPR>>1; lm; lm >>= 1){
      float p0=__shfl_xor(s0,lm,64), p1=__shfl_xor(s1,lm,64);
      float p2=__shfl_xor(s2,lm,64), p3=__shfl_xor(s3,lm,64);
      s0 += p0; s1 += p1; s2 += p2; s3 += p3;
    }
  }
  { float t0=s0+s2, t1=s1+s3, t2=s2+s0, t3=s3+s1;
    s0=t0; s1=t1; s2=t2; s3=t3; }
  { float t0=s0+s1, t1=s1+s0, t2=s2+s3, t3=s3+s2;
    s0=t0; s1=t1; s2=t2; s3=t3; }
}

template<int Q, int CO, int TPR, int L2T>
__device__ __forceinline__ void bp_first_elem2(int graph, int jj, float* __restrict__ psi_pk,
                                               float* __restrict__ lg, float eb,
                                               uint32_t k0, uint32_t k1){
  int idx = jj*256 + (int)threadIdx.x;
  if constexpr (Q == 2){
    int row = graph*1024 + idx;
    float z[2];
    #pragma unroll
    for (int r=0;r<2;r++){
      uint32_t b0,b1;
      tf2x32(k0,k1, 0u, (uint32_t)(row*2 + r), b0,b1);
      uint32_t bits = b0 ^ b1;
      float f = __uint_as_float((bits>>9) | 0x3F800000u) - 1.0f;
      const float lo = __uint_as_float(0xBF7FFFFFu);
      float u = fmaxf(lo, f*2.0f + lo);
      z[r] = __uint_as_float(0x3FB504F3u) * erfinv32(u);
    }
    float m0=fmaxf(z[0],z[1]), m1=fmaxf(z[1],z[0]);
    float e0=expf(z[0]-m0), e1=expf(z[1]-m1);
    float s0=e0+e1, s1=e1+e0;
    float p0=e0/s0, p1=e1/s1;
    ((float2*)(psi_pk + (size_t)NN*CO))[row] = make_float2(p0,p1);
    ((float2*)(lg     + (size_t)NN*CO))[row] = make_float2(log1pf(eb*p0), log1pf(eb*p1));
  } else {
    int rw = idx >> L2T, ct = idx & (TPR-1);
    int row = graph*1024 + rw;
    float z[4];
    #pragma unroll
    for (int r=0;r<4;r++){
      uint32_t b0,b1;
      tf2x32(k0,k1, 0u, (uint32_t)(row*Q + 4*ct + r), b0,b1);
      uint32_t bits = b0 ^ b1;
      float f = __uint_as_float((bits>>9) | 0x3F800000u) - 1.0f;
      const float lo = __uint_as_float(0xBF7FFFFFu);
      float u = fmaxf(lo, f*2.0f + lo);
      z[r] = __uint_as_float(0x3FB504F3u) * erfinv32(u);
    }
    float m0=z[0],m1=z[1],m2=z[2],m3=z[3];
    bfly_max4<TPR>(m0,m1,m2,m3);
    float e0=expf(z[0]-m0), e1=expf(z[1]-m1), e2=expf(z[2]-m2), e3=expf(z[3]-m3);
    float s0=e0,s1=e1,s2=e2,s3=e3;
    bfly_sum4<TPR>(s0,s1,s2,s3);
    float p0=e0/s0, p1=e1/s1, p2=e2/s2, p3=e3/s3;
    ((float4*)(psi_pk + (size_t)NN*CO))[(size_t)row*TPR + ct] = make_float4(p0,p1,p2,p3);
    ((float4*)(lg     + (size_t)NN*CO))[(size_t)row*TPR + ct] =
        make_float4(log1pf(eb*p0), log1pf(eb*p1), log1pf(eb*p2), log1pf(eb*p3));
  }
}

__global__ __launch_bounds__(256) void k_bp_first(float* __restrict__ psi_pk, float* __restrict__ lg,
                                                  const float* __restrict__ betas){
  int graph, run, jj;
  bp_decode2(blockIdx.x, graph, run, jj);
  uint32_t k0, k1;
  tf2x32(0u, 42u, 0u, (uint32_t)run, k0, k1);
  float eb = expm1f(betas[run]);
  switch(run){
    case 0: bp_first_elem2< 2, 0, 1,0>(graph, jj, psi_pk, lg, eb, k0, k1); break;
    case 1: bp_first_elem2< 4, 2, 1,0>(graph, jj, psi_pk, lg, eb, k0, k1); break;
    case 2: bp_first_elem2< 8, 6, 2,1>(graph, jj, psi_pk, lg, eb, k0, k1); break;
    case 3: bp_first_elem2<16,14, 4,2>(graph, jj, psi_pk, lg, eb, k0, k1); break;
    case 4: bp_first_elem2<32,30, 8,3>(graph, jj, psi_pk, lg, eb, k0, k1); break;
    default:bp_first_elem2<64,62,16,4>(graph, jj, psi_pk, lg, eb, k0, k1); break;
  }
}

template<int Q, int CO, int TPR, int L2T>
__device__ __forceinline__ void bp_step_elem2(int graph, int run, int jj,
    const float* __restrict__ lcur, float* __restrict__ nxt, float* __restrict__ lnxt,
    const int* __restrict__ rp, const int* __restrict__ col,
    const float* __restrict__ field, float eb, int fin){
  int idx = jj*256 + (int)threadIdx.x;
  if constexpr (Q == 2){
    int row = graph*1024 + idx;
    const float2* B2 = (const float2*)(lcur + (size_t)NN*CO);
    float a0=0.f, a1=0.f;
    int a = rp[row], b2 = rp[row+1];
    for (; a+8<=b2; a+=8){
      int s0=col[a],s1=col[a+1],s2=col[a+2],s3=col[a+3];
      int s4=col[a+4],s5=col[a+5],s6=col[a+6],s7=col[a+7];
      float2 u0=B2[s0], u1=B2[s1], u2=B2[s2], u3=B2[s3];
      float2 u4=B2[s4], u5=B2[s5], u6=B2[s6], u7=B2[s7];
      a0+=u0.x; a1+=u0.y; a0+=u1.x; a1+=u1.y;
      a0+=u2.x; a1+=u2.y; a0+=u3.x; a1+=u3.y;
      a0+=u4.x; a1+=u4.y; a0+=u5.x; a1+=u5.y;
      a0+=u6.x; a1+=u6.y; a0+=u7.x; a1+=u7.y;
    }
    for (; a+4<=b2; a+=4){
      int s0=col[a],s1=col[a+1],s2=col[a+2],s3=col[a+3];
      float2 u0=B2[s0], u1=B2[s1], u2=B2[s2], u3=B2[s3];
      a0+=u0.x; a1+=u0.y; a0+=u1.x; a1+=u1.y;
      a0+=u2.x; a1+=u2.y; a0+=u3.x; a1+=u3.y;
    }
    for (; a<b2; ++a){ float2 u=B2[col[a]]; a0+=u.x; a1+=u.y; }
    float v0 = a0 - field[run*64 + 0];
    float v1 = a1 - field[run*64 + 1];
    float m0=fmaxf(v0,v1), m1=fmaxf(v1,v0);
    float e0=expf(v0-m0), e1=expf(v1-m1);
    float s0=e0+e1, s1=e1+e0;
    float p0=e0/s0, p1=e1/s1;
    if (fin){
      float* o = nxt + (size_t)row*126 + CO;
      o[0]=p0; o[1]=p1;
    } else {
      ((float2*)(nxt  + (size_t)NN*CO))[row] = make_float2(p0,p1);
      ((float2*)(lnxt + (size_t)NN*CO))[row] = make_float2(log1pf(eb*p0), log1pf(eb*p1));
    }
  } else {
    int rw = idx >> L2T, ct = idx & (TPR-1);
    int row = graph*1024 + rw;
    const float4* B4 = (const float4*)(lcur + (size_t)NN*CO);
    float a0=0.f,a1=0.f,a2=0.f,a3=0.f;
    int a = rp[row], b2 = rp[row+1];
    for (; a+8<=b2; a+=8){
      int s0=col[a],s1=col[a+1],s2=col[a+2],s3=col[a+3];
      int s4=col[a+4],s5=col[a+5],s6=col[a+6],s7=col[a+7];
      float4 u0=B4[(size_t)s0*TPR+ct], u1=B4[(size_t)s1*TPR+ct];
      float4 u2=B4[(size_t)s2*TPR+ct], u3=B4[(size_t)s3*TPR+ct];
      float4 u4=B4[(size_t)s4*TPR+ct], u5=B4[(size_t)s5*TPR+ct];
      float4 u6=B4[(size_t)s6*TPR+ct], u7=B4[(size_t)s7*TPR+ct];
      a0+=u0.x; a1+=u0.y; a2+=u0.z; a3+=u0.w;
      a0+=u1.x; a1+=u1.y; a2+=u1.z; a3+=u1.w;
      a0+=u2.x; a1+=u2.y; a2+=u2.z; a3+=u2.w;
      a0+=u3.x; a1+=u3.y; a2+=u3.z; a3+=u3.w;
      a0+=u4.x; a1+=u4.y; a2+=u4.z; a3+=u4.w;
      a0+=u5.x; a1+=u5.y; a2+=u5.z; a3+=u5.w;
      a0+=u6.x; a1+=u6.y; a2+=u6.z; a3+=u6.w;
      a0+=u7.x; a1+=u7.y; a2+=u7.z; a3+=u7.w;
    }
    for (; a+4<=b2; a+=4){
      int s0=col[a],s1=col[a+1],s2=col[a+2],s3=col[a+3];
      float4 u0=B4[(size_t)s0*TPR+ct], u1=B4[(size_t)s1*TPR+ct];
      float4 u2=B4[(size_t)s2*TPR+ct], u3=B4[(size_t)s3*TPR+ct];
      a0+=u0.x; a1+=u0.y; a2+=u0.z; a3+=u0.w;
      a0+=u1.x; a1+=u1.y; a2+=u1.z; a3+=u1.w;
      a0+=u2.x; a1+=u2.y; a2+=u2.z; a3+=u2.w;
      a0+=u3.x; a1+=u3.y; a2+=u3.z; a3+=u3.w;
    }
    for (; a<b2; ++a){
      float4 u = B4[(size_t)col[a]*TPR+ct];
      a0+=u.x; a1+=u.y; a2+=u.z; a3+=u.w;
    }
    const float4 fld = *(const float4*)(field + run*64 + 4*ct);
    float v0 = a0 - fld.x, v1 = a1 - fld.y, v2 = a2 - fld.z, v3 = a3 - fld.w;
    float m0=v0,m1=v1,m2=v2,m3=v3;
    bfly_max4<TPR>(m0,m1,m2,m3);
    float e0=expf(v0-m0), e1=expf(v1-m1), e2=expf(v2-m2), e3=expf(v3-m3);
    float s0=e0,s1=e1,s2=e2,s3=e3;
    bfly_sum4<TPR>(s0,s1,s2,s3);
    float p0=e0/s0, p1=e1/s1, p2=e2/s2, p3=e3/s3;
    if (fin){
      float* o = nxt + (size_t)row*126 + CO + 4*ct;
      o[0]=p0; o[1]=p1; o[2]=p2; o[3]=p3;
    } else {
      ((float4*)(nxt  + (size_t)NN*CO))[(size_t)row*TPR+ct] = make_float4(p0,p1,p2,p3);
      ((float4*)(lnxt + (size_t)NN*CO))[(size_t)row*TPR+ct] =
          make_float4(log1pf(eb*p0), log1pf(eb*p1), log1pf(eb*p2), log1pf(eb*p3));
    }
  }
}

__global__ __launch_bounds__(256) void k_bp_step(
    float* __restrict__ nxt, const float* __restrict__ lcur, float* __restrict__ lnxt,
    const int* __restrict__ rp, const int* __restrict__ col,
    const float* __restrict__ field, const float* __restrict__ betas, int fin){
  int graph, run, jj;
  bp_decode2(blockIdx.x, graph, run, jj);
  float eb = expm1f(betas[run]);
  switch(run){
    case 0: bp_step_elem2< 2, 0, 1,0>(graph, run, jj, lcur, nxt, lnxt, rp, col, field, eb, fin); break;
    case 1: bp_step_elem2< 4, 2, 1,0>(graph, run, jj, lcur, nxt, lnxt, rp, col, field, eb, fin); break;
    case 2: bp_step_elem2< 8, 6, 2,1>(graph, run, jj, lcur, nxt, lnxt, rp, col, field, eb, fin); break;
    case 3: bp_step_elem2<16,14, 4,2>(graph, run, jj, lcur, nxt, lnxt, rp, col, field, eb, fin); break;
    case 4: bp_step_elem2<32,30, 8,3>(graph, run, jj, lcur, nxt, lnxt, rp, col, field, eb, fin); break;
    default:bp_step_elem2<64,62,16,4>(graph, run, jj, lcur, nxt, lnxt, rp, col, field, eb, fin); break;
  }
}

// column sums over PACKED psi; per-column accumulators, rows 0..255 ascending
// (bit-identical); float4 loads for q>=4.
__global__ __launch_bounds__(64) void k_colsum_part(const float* __restrict__ psi_pk, float* __restrict__ part){
  int b = blockIdx.x;
  int xcd = b & 7, i = b >> 3;
  int gs = i/24, rem = i - gs*24;
  int run = rem >> 2, cg = rem & 3;
  int graph = gs*8 + xcd;
  int chunk = graph*4 + cg;
  int q = cQS[run];
  int co = (run==0)?0:(run==1)?2:(run==2)?6:(run==3)?14:(run==4)?30:62;
  int c = threadIdx.x;
  if (q >= 4){
    int nq = q >> 2;
    if (c >= nq) return;
    const float4* p4 = (const float4*)(psi_pk + (size_t)NN*co + (size_t)chunk*256*q) + c;
    float s0=0.f,s1=0.f,s2=0.f,s3=0.f;
    #pragma unroll 8
    for (int r=0;r<256;r++){
      float4 u = p4[(size_t)r*nq];
      s0+=u.x; s1+=u.y; s2+=u.z; s3+=u.w;
    }
    float* o = part + (run*256 + chunk)*64 + 4*c;
    o[0]=s0; o[1]=s1; o[2]=s2; o[3]=s3;
  } else {
    if (c >= q) return;
    float s = 0.f;
    const float* p = psi_pk + (size_t)NN*co + (size_t)chunk*256*q + c;
    #pragma unroll 8
    for (int r=0;r<256;r++) s += p[r*q];
    part[(run*256 + chunk)*64 + c] = s;
  }
}

__global__ void k_field(const float* __restrict__ part, const float* __restrict__ betas,
                        float* __restrict__ field){
  int id = threadIdx.x;
  int run = id >> 6, c = id & 63;
  if (c >= cQS[run]) return;
  float s = 0.f;
  for (int b=0;b<256;b++) s += part[(run*256 + b)*64 + c];
  float beta = betas[run];
  field[id] = s * (3.8f*beta/65536.0f);
}

// ---------------- diff-pool ----------------
__global__ __launch_bounds__(256) void k_catT(const float* __restrict__ cat, float* __restrict__ catT){
  __shared__ float tile[64*127];
  int b = blockIdx.x, t = threadIdx.x;
  const float* src = cat + (size_t)b*64*126;
  for (int i=t;i<8064;i+=256){
    int r = i/126, k = i - r*126;
    tile[r*127 + k] = src[i];
  }
  __syncthreads();
  for (int i=t;i<8064;i+=256){
    int k = i>>6, r = i&63;
    catT[(size_t)k*65536 + b*64 + r] = tile[r*127 + k];
  }
}

__global__ __launch_bounds__(256) void k_s1t(const float* __restrict__ catT, const float* __restrict__ pw,
                                             const float* __restrict__ pb, float* __restrict__ s1){
  __shared__ float wl[12600];
  __shared__ float pbl[100];
  __shared__ float redM[2][128];
  __shared__ float redS[2][128];
  int t = threadIdx.x;
  for (int i=t;i<12600;i+=256) wl[i] = pw[i];
  if (t < 100) pbl[t] = pb[t];
  int w = t>>6, lane = t&63;
  int rh = w&1, chh = w>>1;
  int ch = chh*50;
  int row = blockIdx.x*128 + rh*64 + lane;
  __syncthreads();
  float acc[50];
  #pragma unroll
  for (int j=0;j<50;j++) acc[j] = pbl[ch+j];
  for (int k=0;k<126;k++){
    float xv = catT[(size_t)k*65536 + row];
    const float* wr = &wl[k*100 + ch];
    #pragma unroll
    for (int j=0;j<50;j+=2){
      float2 wv = *(const float2*)&wr[j];
      acc[j]   += xv*wv.x;
      acc[j+1] += xv*wv.y;
    }
  }
  float m = acc[0];
  #pragma unroll
  for (int j=1;j<50;j++) m = fmaxf(m, acc[j]);
  redM[chh][rh*64 + lane] = m;
  __syncthreads();
  float mm = fmaxf(redM[0][rh*64 + lane], redM[1][rh*64 + lane]);
  float s = 0.f;
  #pragma unroll
  for (int j=0;j<50;j++){ acc[j] = expf(acc[j]-mm); s += acc[j]; }
  redS[chh][rh*64 + lane] = s;
  __syncthreads();
  float tot = redS[0][rh*64 + lane] + redS[1][rh*64 + lane];
  float* o = s1 + (size_t)row*100 + ch;
  #pragma unroll
  for (int j=0;j<50;j+=2){
    float2 ov; ov.x = acc[j]/tot; ov.y = acc[j+1]/tot;
    *(float2*)&o[j] = ov;
  }
}

__global__ __launch_bounds__(256) void k_T(const float* __restrict__ s1, const int* __restrict__ rp,
                                           const int* __restrict__ col, float* __restrict__ T){
  int b = blockIdx.x;
  int xcd = b & 7, i = b >> 3;
  int gs = i/100, j = i - gs*100;
  int graph = gs*8 + xcd;
  int idwg = j*256 + threadIdx.x;
  int rw = idwg/25, quad = idwg - rw*25;
  int v = graph*1024 + rw;
  float a0=0.f,a1=0.f,a2=0.f,a3=0.f;
  const float4* S4 = (const float4*)s1;
  int a = rp[v], e = rp[v+1];
  for (; a+8<=e; a+=8){
    int s0=col[a], s1_=col[a+1], s2=col[a+2], s3=col[a+3];
    int s4=col[a+4], s5=col[a+5], s6=col[a+6], s7=col[a+7];
    float4 u0=S4[(size_t)s0*25+quad], u1=S4[(size_t)s1_*25+quad];
    float4 u2=S4[(size_t)s2*25+quad], u3=S4[(size_t)s3*25+quad];
    float4 u4=S4[(size_t)s4*25+quad], u5=S4[(size_t)s5*25+quad];
    float4 u6=S4[(size_t)s6*25+quad], u7=S4[(size_t)s7*25+quad];
    a0+=u0.x; a1+=u0.y; a2+=u0.z; a3+=u0.w;
    a0+=u1.x; a1+=u1.y; a2+=u1.z; a3+=u1.w;
    a0+=u2.x; a1+=u2.y; a2+=u2.z; a3+=u2.w;
    a0+=u3.x; a1+=u3.y; a2+=u3.z; a3+=u3.w;
    a0+=u4.x; a1+=u4.y; a2+=u4.z; a3+=u4.w;
    a0+=u5.x; a1+=u5.y; a2+=u5.z; a3+=u5.w;
    a0+=u6.x; a1+=u6.y; a2+=u6.z; a3+=u6.w;
    a0+=u7.x; a1+=u7.y; a2+=u7.z; a3+=u7.w;
  }
  for (; a+4<=e; a+=4){
    int s0=col[a], s1_=col[a+1], s2=col[a+2], s3=col[a+3];
    float4 u0=S4[(size_t)s0*25+quad], u1=S4[(size_t)s1_*25+quad];
    float4 u2=S4[(size_t)s2*25+quad], u3=S4[(size_t)s3*25+quad];
    a0+=u0.x; a1+=u0.y; a2+=u0.z; a3+=u0.w;
    a0+=u1.x; a1+=u1.y; a2+=u1.z; a3+=u1.w;
    a0+=u2.x; a1+=u2.y; a2+=u2.z; a3+=u2.w;
    a0+=u3.x; a1+=u3.y; a2+=u3.z; a3+=u3.w;
  }
  for (; a<e; ++a){
    float4 u = S4[(size_t)col[a]*25+quad];
    a0+=u.x; a1+=u.y; a2+=u.z; a3+=u.w;
  }
  ((float4*)T)[(size_t)v*25 + quad] = make_float4(a0,a1,a2,a3);
}

__global__ __launch_bounds__(512) void k_p1adj_sk(const float* __restrict__ s1, const float* __restrict__ T,
                                                  float* __restrict__ part){
  __shared__ float sS[6400];
  __shared__ float sT[6400];
  int blk = blockIdx.x;
  int b = blk >> 2, qtr = blk & 3;
  int t = threadIdx.x;
  int tk = t/20, tl = t - tk*20;
  bool act = t < 500;
  int k0 = tk*4, l0 = tl*5;
  float acc[4][5];
  #pragma unroll
  for (int i=0;i<4;i++)
    #pragma unroll
    for (int j=0;j<5;j++) acc[i][j] = 0.f;
  const float* s1b = s1 + (size_t)b*102400;
  const float* Tb  = T  + (size_t)b*102400;
  for (int c=qtr*4; c<qtr*4+4; c++){
    for (int i=t;i<6400;i+=512){ sS[i] = s1b[c*6400+i]; sT[i] = Tb[c*6400+i]; }
    __syncthreads();
    if (act){
      #pragma unroll 2
      for (int n=0;n<64;n++){
        const float* sr = &sS[n*100 + k0];
        const float* tr = &sT[n*100 + l0];
        float s0=sr[0], s1v=sr[1], s2=sr[2], s3=sr[3];
        float t0=tr[0], t1=tr[1], t2=tr[2], t3=tr[3], t4=tr[4];
        acc[0][0]+=s0*t0; acc[0][1]+=s0*t1; acc[0][2]+=s0*t2; acc[0][3]+=s0*t3; acc[0][4]+=s0*t4;
        acc[1][0]+=s1v*t0; acc[1][1]+=s1v*t1; acc[1][2]+=s1v*t2; acc[1][3]+=s1v*t3; acc[1][4]+=s1v*t4;
        acc[2][0]+=s2*t0; acc[2][1]+=s2*t1; acc[2][2]+=s2*t2; acc[2][3]+=s2*t3; acc[2][4]+=s2*t4;
        acc[3][0]+=s3*t0; acc[3][1]+=s3*t1; acc[3][2]+=s3*t2; acc[3][3]+=s3*t3; acc[3][4]+=s3*t4;
      }
    }
    __syncthreads();
  }
  if (act){
    float* pp = part + (size_t)qtr*640000 + (size_t)b*10000;
    #pragma unroll
    for (int i=0;i<4;i++){
      float* o = pp + (k0+i)*100 + l0;
      #pragma unroll
      for (int j=0;j<5;j++) o[j] = acc[i][j];
    }
  }
}

// px = s1^T * BN(y3), affine applied on LDS fill (sfc slot of layer 13)
__global__ __launch_bounds__(256) void k_p1x_sk(const float* __restrict__ s1, const float* __restrict__ y3,
                                                const float* __restrict__ sfc, float* __restrict__ part){
  __shared__ float sS[6400];
  __shared__ float sX[1920];
  int blk = blockIdx.x;
  int b = blk >> 2, qtr = blk & 3;
  int t = threadIdx.x;
  int tk = t/10, tl = t - tk*10;
  bool act = t < 250;
  int k0 = tk*4, d0 = tl*3;
  float acc[4][3];
  #pragma unroll
  for (int i=0;i<4;i++)
    #pragma unroll
    for (int j=0;j<3;j++) acc[i][j] = 0.f;
  const float* s1b = s1 + (size_t)b*102400;
  const float* xb  = y3 + (size_t)b*30720;
  for (int c=qtr*4; c<qtr*4+4; c++){
    for (int i=t;i<6400;i+=256) sS[i] = s1b[c*6400+i];
    for (int i=t;i<1920;i+=256){
      int f = i % 30;
      sX[i] = sfc[f]*xb[c*1920+i] + sfc[32+f];
    }
    __syncthreads();
    if (act){
      #pragma unroll 2
      for (int n=0;n<64;n++){
        const float* sr = &sS[n*100 + k0];
        const float* xr = &sX[n*30 + d0];
        float s0=sr[0], s1v=sr[1], s2=sr[2], s3=sr[3];
        float x0=xr[0], x1=xr[1], x2=xr[2];
        acc[0][0]+=s0*x0; acc[0][1]+=s0*x1; acc[0][2]+=s0*x2;
        acc[1][0]+=s1v*x0; acc[1][1]+=s1v*x1; acc[1][2]+=s1v*x2;
        acc[2][0]+=s2*x0; acc[2][1]+=s2*x1; acc[2][2]+=s2*x2;
        acc[3][0]+=s3*x0; acc[3][1]+=s3*x1; acc[3][2]+=s3*x2;
      }
    }
    __syncthreads();
  }
  if (act){
    float* pp = part + (size_t)qtr*192000 + (size_t)b*3000;
    #pragma unroll
    for (int i=0;i<4;i++){
      float* o = pp + (k0+i)*30 + d0;
      #pragma unroll
      for (int j=0;j<3;j++) o[j] = acc[i][j];
    }
  }
}

// merged split-K reduces (padj then px)
__global__ __launch_bounds__(256) void k_ppred(const float* __restrict__ partA, const float* __restrict__ partX,
                                               float* __restrict__ padj, float* __restrict__ px){
  int id = blockIdx.x*256 + threadIdx.x;
  if (id < 640000){
    float s = partA[id] + partA[640000+id] + partA[1280000+id] + partA[1920000+id];
    padj[id] = s;
  } else if (id < 832000){
    int j = id - 640000;
    float s = partX[j] + partX[192000+j] + partX[384000+j] + partX[576000+j];
    px[j] = s;
  }
}

// ---------------- stage-2 dense GCN ----------------
// merged dinv2 + Ank: one block per graph
__global__ __launch_bounds__(256) void k_An1(const float* __restrict__ padj, float* __restrict__ An){
  __shared__ float dv[100];
  int b = blockIdx.x, t = threadIdx.x;
  if (t < 100){
    const float* r = padj + (size_t)b*10000 + t*100;
    float s = 0.f;
    for (int l=0;l<100;l++){
      float v = r[l];
      if (l==t) v += 1.0f;
      s += v;
    }
    dv[t] = 1.0f/sqrtf(s);
  }
  __syncthreads();
  for (int i=t;i<10000;i+=256){
    int k = i/100, l = i - k*100;
    float a = padj[(size_t)b*10000 + i] + ((k==l)? 1.0f : 0.0f);
    An[(size_t)b*10000 + i] = (dv[k]*a)*dv[l];
  }
}

// y2 = An*h + bias, with fused BN stats
__global__ __launch_bounds__(256) void k_y2(const float* __restrict__ An, const float* __restrict__ h,
    const float* __restrict__ bias, float* __restrict__ y,
    float* __restrict__ gS, float* __restrict__ gQ){
  __shared__ float binS[30], binQ[30];
  int t = threadIdx.x;
  if (t < 30){ binS[t]=0.f; binQ[t]=0.f; }
  __syncthreads();
  int id = blockIdx.x*256 + t;
  float val = 0.f;
  int d = 0;
  if (id < NBG*100*30){
    d = id % 30;
    int bk = id / 30;
    int b = bk / 100;
    const float* Ar = An + bk*100;
    const float* hb = h + b*100*30;
    float acc = 0.f;
    for (int l=0;l<100;l++) acc += Ar[l]*hb[l*30+d];
    val = acc + bias[d];
    y[id] = val;
    atomicAdd(&binS[d], val);
    atomicAdd(&binQ[d], val*val);
  }
  __syncthreads();
  if (t < 30){
    int slot = (blockIdx.x & 63)*30 + t;
    atomicAdd(&gS[slot], binS[t]);
    atomicAdd(&gQ[slot], binQ[t]);
  }
}

// ---------------- pools + FC ----------------
// pool applies BN affine per array (sfc slots a*64 from base)
__global__ __launch_bounds__(256) void k_pool2(const float* __restrict__ A,
    const float* __restrict__ Bv, const float* __restrict__ Cv,
    const float* __restrict__ sfcBase,
    int rows, float* __restrict__ conv, int coff){
  __shared__ float lds[256*31];
  int b = blockIdx.x, a = blockIdx.y, t = threadIdx.x;
  const float* X = (a==0)? A : ((a==1)? Bv : Cv);
  const float* sf = sfcBase + a*64;
  float acc[30];
  #pragma unroll
  for (int f=0;f<30;f++) acc[f] = -FLT_MAX;
  for (int r=t; r<rows; r+=256){
    const float* xr = X + (size_t)(b*rows + r)*30;
    #pragma unroll
    for (int f=0;f<30;f++) acc[f] = fmaxf(acc[f], sf[f]*xr[f] + sf[32+f]);
  }
  #pragma unroll
  for (int f=0;f<30;f++) lds[t*31+f] = acc[f];
  __syncthreads();
  for (int s=128;s>0;s>>=1){
    if (t<s){
      #pragma unroll
      for (int f=0;f<30;f++) lds[t*31+f] = fmaxf(lds[t*31+f], lds[(t+s)*31+f]);
    }
    __syncthreads();
  }
  if (t<30) conv[b*180 + coff + a*30 + t] = lds[t];
}

__global__ __launch_bounds__(64) void k_fc(const float* __restrict__ conv,
    const float* __restrict__ w1, const float* __restrict__ b1,
    const float* __restrict__ w2, const float* __restrict__ b2, float* __restrict__ out){
  __shared__ float row[180];
  __shared__ float hid[50];
  int b = blockIdx.x, t = threadIdx.x;
  for (int i=t;i<180;i+=64) row[i] = conv[b*180+i];
  __syncthreads();
  if (t < 50){
    float a = b1[t];
    for (int i=0;i<180;i++) a += row[i]*w1[i*50+t];
    hid[t] = fmaxf(a, 0.f);
  }
  __syncthreads();
  if (t < 6){
    float a = b2[t];
    for (int i=0;i<50;i++) a += hid[i]*w2[i*6+t];
    out[b*6+t] = a;
  }
  if (b==0 && t==63) out[NBG*6] = 0.0f;
}

// ---------------------------------------------------------------------------
extern "C" void kernel_launch(void* const* d_in, const int* in_sizes, int n_in,
                              void* d_out, int out_size, void* d_ws, size_t ws_size,
                              hipStream_t stream)
{
  (void)in_sizes; (void)n_in; (void)out_size; (void)ws_size;
  const float* x   = (const float*)d_in[0];
  const int*   src = (const int*)d_in[1];
  const int*   dst = src + NEDGE;
  const float* w11=(const float*)d_in[3],  *b11=(const float*)d_in[4],  *g11=(const float*)d_in[5],  *be11=(const float*)d_in[6];
  const float* w12=(const float*)d_in[7],  *b12=(const float*)d_in[8],  *g12=(const float*)d_in[9],  *be12=(const float*)d_in[10];
  const float* w13=(const float*)d_in[11], *b13=(const float*)d_in[12], *g13=(const float*)d_in[13], *be13=(const float*)d_in[14];
  const float* w21=(const float*)d_in[15], *b21=(const float*)d_in[16], *g21=(const float*)d_in[17], *be21=(const float*)d_in[18];
  const float* w22=(const float*)d_in[19], *b22=(const float*)d_in[20], *g22=(const float*)d_in[21], *be22=(const float*)d_in[22];
  const float* w23=(const float*)d_in[23], *b23=(const float*)d_in[24], *g23=(const float*)d_in[25], *be23=(const float*)d_in[26];
  const float* betas=(const float*)d_in[27];
  const float* poolw=(const float*)d_in[28], *poolb=(const float*)d_in[29];
  const float* fc1w=(const float*)d_in[30], *fc1b=(const float*)d_in[31];
  const float* fc2w=(const float*)d_in[32], *fc2b=(const float*)d_in[33];
  float* out = (float*)d_out;

  uint8_t* basep = (uint8_t*)d_ws;
  size_t off = 0;
  auto take = [&](size_t bytes)->void*{
    void* p = basep + off;
    off = (off + bytes + 255) & ~(size_t)255;
    return p;
  };
  int* degi    = (int*)take((size_t)NN*4);
  int* dego    = (int*)take((size_t)NN*4);
  int* cntA    = (int*)take((size_t)NN*4);
  int* cntB    = (int*)take((size_t)NN*4);
  float* gS    = (float*)take(64*30*4);     // BN stat slots (zeroed by memset)
  float* gQ    = (float*)take(64*30*4);
  int* rp_in   = (int*)take((size_t)(NN+1)*4);
  int* rp_out  = (int*)take((size_t)(NN+1)*4);
  int* bsum    = (int*)take(512*4);
  int* col_in  = (int*)take((size_t)NEDGE*4);
  int* col_out = (int*)take((size_t)NEDGE*4);
  float* dinv  = (float*)take((size_t)NN*4);
  float* hbuf  = (float*)take((size_t)NN*30*4);
  float* X1    = (float*)take((size_t)NN*30*4);   // pre-BN y1
  float* X2    = (float*)take((size_t)NN*30*4);   // pre-BN y2
  float* X3    = (float*)take((size_t)NN*30*4);   // pre-BN y3
  float* bufA  = (float*)take((size_t)NN*126*4);
  float* bufB  = (float*)take((size_t)NN*126*4);
  float* logA  = (float*)take((size_t)NN*126*4);
  float* logB  = (float*)take((size_t)NN*126*4);
  float* partCS= (float*)take((size_t)6*256*64*4);
  float* fieldv= (float*)take(384*4);
  float* sfcAll= (float*)take(6*64*4);
  float* wfold = (float*)take(960*4);
  float* cvec  = (float*)take(32*4);
  float* px    = (float*)take(192000*4);
  float* padj  = (float*)take(640000*4);
  float* An    = (float*)take(640000*4);
  float* h2    = (float*)take(192000*4);
  float* X21   = (float*)take(192000*4);  // pre-BN
  float* X22   = (float*)take(192000*4);
  float* X23   = (float*)take(192000*4);
  float* conv  = (float*)take(64*180*4);

  // post-BP scratch reuse: catT -> logA; split-K partials -> logB
  float* catT     = logA;
  float* pAdjPart = logB;               // 4*640000 floats
  float* pPxPart  = logB + 2560000;     // 4*192000 floats

  // ---- CSR + stat zero (degi..gQ contiguous -> single memset) ----
  hipMemsetAsync(degi, 0, (size_t)4*NN*4 + 2*64*30*4, stream);
  k_count<<<2048,256,0,stream>>>(src,dst,degi,dego);
  k_scan1<<<dim3(256,2),256,0,stream>>>(degi, dego, rp_in, rp_out, bsum);
  k_scan2<<<2,256,0,stream>>>(bsum);
  k_scan3<<<dim3(256,2),256,0,stream>>>(rp_in, rp_out, bsum);
  k_fill<<<dim3(2048,2),256,0,stream>>>(src, dst, rp_in, rp_out, cntA, cntB, col_in, col_out);
  k_sortrow<<<dim3(256,2),256,0,stream>>>(rp_in, rp_out, col_in, col_out, src, dst, degi, dinv);

  // ---- stage 1: GCN x3 with folded BN ----
  k_mm30<3><<<7680,256,0,stream>>>(x, w11, hbuf, NN);
  k_gcn_agg<<<3840,256,0,stream>>>(hbuf, rp_in, col_in, dinv, b11, X1, gS, gQ);
  k_bnw<1><<<1,256,0,stream>>>(gS, gQ, 65536.f, g11, be11, w12, sfcAll+0*64, wfold, cvec);
  k_mm30c<<<7680,256,0,stream>>>(X1, wfold, cvec, hbuf, NN);
  k_gcn_agg<<<3840,256,0,stream>>>(hbuf, rp_in, col_in, dinv, b12, X2, gS, gQ);
  k_bnw<1><<<1,256,0,stream>>>(gS, gQ, 65536.f, g12, be12, w13, sfcAll+1*64, wfold, cvec);
  k_mm30c<<<7680,256,0,stream>>>(X2, wfold, cvec, hbuf, NN);
  k_gcn_agg<<<3840,256,0,stream>>>(hbuf, rp_in, col_in, dinv, b13, X3, gS, gQ);
  k_bnw<0><<<1,256,0,stream>>>(gS, gQ, 65536.f, g13, be13, nullptr, sfcAll+2*64, nullptr, nullptr);
  k_pool2<<<dim3(NBG,3),256,0,stream>>>(X1, X2, X3, sfcAll, 1024, conv, 0);

  // ---- belief propagation (packed psi + packed L, ping-pong; bit-exact) ----
  k_bp_first<<<8192,256,0,stream>>>(bufA, logA, betas);
  float* cur = bufA;  float* nxt = bufB;
  float* lcur = logA; float* lnxt = logB;
  for (int it=0; it<10; ++it){
    k_colsum_part<<<1536,64,0,stream>>>(cur, partCS);
    k_field<<<1,384,0,stream>>>(partCS, betas, fieldv);
    int fin = (it==9);
    k_bp_step<<<8192,256,0,stream>>>(nxt, lcur, lnxt, rp_in, col_in, fieldv, betas, fin);
    float* tp = cur;  cur = nxt;   nxt = tp;
    float* tl = lcur; lcur = lnxt; lnxt = tl;
  }
  // final concatenated psi [NN][126] now in bufA

  // ---- diff-pool ----
  k_catT<<<1024,256,0,stream>>>(bufA, catT);
  k_s1t<<<512,256,0,stream>>>(catT, poolw, poolb, bufB);
  k_T<<<6400,256,0,stream>>>(bufB, rp_out, col_out, bufA);
  k_p1adj_sk<<<256,512,0,stream>>>(bufB, bufA, pAdjPart);
  k_p1x_sk<<<256,256,0,stream>>>(bufB, X3, sfcAll+2*64, pPxPart);
  k_ppred<<<3250,256,0,stream>>>(pAdjPart, pPxPart, padj, px);
  k_An1<<<64,256,0,stream>>>(padj, An);

  // ---- stage 2: dense GCN x3 with folded BN ----
  k_mm30<30><<<750,256,0,stream>>>(px, w21, h2, NBG*100);
  k_y2<<<750,256,0,stream>>>(An, h2, b21, X21, gS, gQ);
  k_bnw<1><<<1,256,0,stream>>>(gS, gQ, 6400.f, g21, be21, w22, sfcAll+3*64, wfold, cvec);
  k_mm30c<<<750,256,0,stream>>>(X21, wfold, cvec, h2, NBG*100);
  k_y2<<<750,256,0,stream>>>(An, h2, b22, X22, gS, gQ);
  k_bnw<1><<<1,256,0,stream>>>(gS, gQ, 6400.f, g22, be22, w23, sfcAll+4*64, wfold, cvec);
  k_mm30c<<<750,256,0,stream>>>(X22, wfold, cvec, h2, NBG*100);
  k_y2<<<750,256,0,stream>>>(An, h2, b23, X23, gS, gQ);
  k_bnw<0><<<1,256,0,stream>>>(gS, gQ, 6400.f, g23, be23, nullptr, sfcAll+5*64, nullptr, nullptr);
  k_pool2<<<dim3(NBG,3),256,0,stream>>>(X21, X22, X23, sfcAll+3*64, 100, conv, 90);

  // ---- FC head ----
  k_fc<<<64,64,0,stream>>>(conv, fc1w, fc1b, fc2w, fc2b, out);
}

// Round 13
// 1237.231 us; speedup vs baseline: 2.9527x; 1.0408x over previous
//
#include <hip/hip_runtime.h>
#include <stdint.h>
#include <float.h>

// ---------------------------------------------------------------------------
// Net_57604101374728: GCN(x3)+BN -> maxpool | 6x belief-prop -> diffpool ->
// dense GCN(x3)+BN -> maxpool -> FC. Full fp32 port of the JAX reference.
//
// R13: stage-1 hidden under BP via aux blocks: bp_first carries mm30<3>;
// bp_step #0..5 carry gcn_agg/mm30c/pool; k_field block1 carries bnw.
// p1adj+p1x merged; An1 reduces padj parts in LDS (+px reduce blocks).
// BP device code byte-identical to R12 -> BP bit-exact.
// ---------------------------------------------------------------------------

constexpr int NN    = 65536;    // total nodes
constexpr int NEDGE = 524288;   // edges
constexpr int NBG   = 64;       // graphs

__constant__ int cQS[6]   = {2,4,8,16,32,64};

// ---------------- threefry2x32 (20 rounds) ----------------
__device__ __forceinline__ void tf2x32(uint32_t k0, uint32_t k1, uint32_t x0, uint32_t x1,
                                       uint32_t& o0, uint32_t& o1){
  uint32_t ks[3] = {k0, k1, k0 ^ k1 ^ 0x1BD11BDAu};
  x0 += ks[0]; x1 += ks[1];
  const int RA[4] = {13,15,26,6}, RB[4] = {17,29,16,24};
  #pragma unroll
  for (int i=0;i<5;i++){
    const int* r = (i&1)? RB : RA;
    #pragma unroll
    for (int j=0;j<4;j++){
      x0 += x1;
      x1 = (x1 << r[j]) | (x1 >> (32 - r[j]));
      x1 ^= x0;
    }
    x0 += ks[(i+1)%3];
    x1 += ks[(i+2)%3] + (uint32_t)(i+1);
  }
  o0 = x0; o1 = x1;
}

// ---------------- XLA ErfInv32 (Giles), contraction off ----------------
__device__ __forceinline__ float erfinv32(float xx){
  #pragma clang fp contract(off)
  float w = -log1pf(-xx*xx);
  float p;
  if (w < 5.0f){
    w = w - 2.5f;
    p = 2.81022636e-08f;
    p = 3.43273939e-07f  + p*w;
    p = -3.5233877e-06f  + p*w;
    p = -4.39150654e-06f + p*w;
    p = 0.00021858087f   + p*w;
    p = -0.00125372503f  + p*w;
    p = -0.00417768164f  + p*w;
    p = 0.246640727f     + p*w;
    p = 1.50140941f      + p*w;
  } else {
    w = sqrtf(w) - 3.0f;
    p = -0.000200214257f;
    p = 0.000100950558f  + p*w;
    p = 0.00134934322f   + p*w;
    p = -0.00367342844f  + p*w;
    p = 0.00573950773f   + p*w;
    p = -0.0076224613f   + p*w;
    p = 0.00943887047f   + p*w;
    p = 1.00167406f      + p*w;
    p = 2.83297682f      + p*w;
  }
  return p*xx;
}

// ---------------- CSR construction (fused pairs via blockIdx.y) ----------
__global__ __launch_bounds__(256) void k_count(const int* __restrict__ src, const int* __restrict__ dst,
                                               int* __restrict__ degi, int* __restrict__ dego){
  int e = blockIdx.x*256 + threadIdx.x;
  if (e >= NEDGE) return;
  atomicAdd(&degi[dst[e]], 1);
  atomicAdd(&dego[src[e]], 1);
}

__global__ __launch_bounds__(256) void k_scan1(const int* __restrict__ degi, const int* __restrict__ dego,
                                               int* __restrict__ rpi, int* __restrict__ rpo,
                                               int* __restrict__ bsum){
  __shared__ int lds[256];
  const int* deg = blockIdx.y? dego : degi;
  int* rp = blockIdx.y? rpo : rpi;
  int* bs = bsum + blockIdx.y*256;
  int b = blockIdx.x, t = threadIdx.x;
  lds[t] = deg[b*256 + t];
  __syncthreads();
  for (int s=1;s<256;s<<=1){
    int add = (t>=s)? lds[t-s] : 0;
    __syncthreads();
    lds[t] += add;
    __syncthreads();
  }
  rp[b*256 + t + 1] = lds[t];
  if (t==0 && b==0) rp[0] = 0;
  if (t==255) bs[b] = lds[255];
}

__global__ __launch_bounds__(256) void k_scan2(int* __restrict__ bsum){
  __shared__ int lds[256];
  int* bs = bsum + blockIdx.x*256;
  int t = threadIdx.x;
  lds[t] = bs[t];
  __syncthreads();
  for (int s=1;s<256;s<<=1){
    int add = (t>=s)? lds[t-s] : 0;
    __syncthreads();
    lds[t] += add;
    __syncthreads();
  }
  bs[t] = (t==0)? 0 : lds[t-1];
}

__global__ __launch_bounds__(256) void k_scan3(int* __restrict__ rpi, int* __restrict__ rpo,
                                               const int* __restrict__ bsum){
  int* rp = blockIdx.y? rpo : rpi;
  const int* bs = bsum + blockIdx.y*256;
  int b = blockIdx.x, t = threadIdx.x;
  rp[b*256 + t + 1] += bs[b];
}

__global__ __launch_bounds__(256) void k_fill(const int* __restrict__ src, const int* __restrict__ dst,
                                              const int* __restrict__ rpi, const int* __restrict__ rpo,
                                              int* __restrict__ cntA, int* __restrict__ cntB,
                                              int* __restrict__ colI, int* __restrict__ colO){
  int e = blockIdx.x*256 + threadIdx.x;
  if (e >= NEDGE) return;
  if (blockIdx.y == 0){
    int d = dst[e];
    int p = atomicAdd(&cntA[d], 1);
    colI[rpi[d] + p] = e;
  } else {
    int d = src[e];
    int p = atomicAdd(&cntB[d], 1);
    colO[rpo[d] + p] = e;
  }
}

__global__ __launch_bounds__(256) void k_sortrow(const int* __restrict__ rpi, const int* __restrict__ rpo,
                                                 int* __restrict__ colI, int* __restrict__ colO,
                                                 const int* __restrict__ src, const int* __restrict__ dst,
                                                 const int* __restrict__ degi, float* __restrict__ dinv){
  const int* rp = blockIdx.y? rpo : rpi;
  int* colbuf   = blockIdx.y? colO : colI;
  const int* other = blockIdx.y? dst : src;
  int v = blockIdx.x*256 + threadIdx.x;
  if (v >= NN) return;
  int s0 = rp[v], s1 = rp[v+1];
  for (int i=s0+1;i<s1;i++){
    int key = colbuf[i]; int j = i-1;
    while (j>=s0 && colbuf[j]>key){ colbuf[j+1]=colbuf[j]; j--; }
    colbuf[j+1] = key;
  }
  for (int i=s0;i<s1;i++) colbuf[i] = other[colbuf[i]];
  if (blockIdx.y == 0) dinv[v] = 1.0f / sqrtf((float)(degi[v] + 1));
}

// ---------------- stage-2 GEMM helpers (standalone) ----------------
template<int CIN>
__global__ __launch_bounds__(256) void k_mm30(const float* __restrict__ x, const float* __restrict__ w,
                                              float* __restrict__ h, int nrow){
  __shared__ float ws[CIN*30];
  int t = threadIdx.x;
  for (int i=t;i<CIN*30;i+=256) ws[i] = w[i];
  __syncthreads();
  int id = blockIdx.x*256 + t;
  if (id >= nrow*30) return;
  int v = id/30, j = id - v*30;
  const float* xr = x + v*CIN;
  float acc = 0.f;
  #pragma unroll
  for (int k=0;k<CIN;k++) acc += xr[k]*ws[k*30+j];
  h[id] = acc;
}

__global__ __launch_bounds__(256) void k_mm30c(const float* __restrict__ x, const float* __restrict__ wfold,
                                               const float* __restrict__ cvec, float* __restrict__ h, int nrow){
  __shared__ float ws[900];
  __shared__ float cl[30];
  int t = threadIdx.x;
  for (int i=t;i<900;i+=256) ws[i] = wfold[i];
  if (t < 30) cl[t] = cvec[t];
  __syncthreads();
  int id = blockIdx.x*256 + t;
  if (id >= nrow*30) return;
  int v = id/30, j = id - v*30;
  const float* xr = x + v*30;
  float acc = cl[j];
  #pragma unroll
  for (int k=0;k<30;k++) acc += xr[k]*ws[k*30+j];
  h[id] = acc;
}

// BN finalize (standalone, stage-2)
template<int FOLD>
__global__ __launch_bounds__(256) void k_bnw(float* __restrict__ gS, float* __restrict__ gQ, float n,
    const float* __restrict__ g, const float* __restrict__ be,
    const float* __restrict__ wnext, float* __restrict__ sfc,
    float* __restrict__ wfold, float* __restrict__ cvec){
  __shared__ float s_l[30], c_l[30];
  int t = threadIdx.x;
  if (t < 30){
    float s=0.f, q=0.f;
    for (int u=0;u<64;u++){ s += gS[u*30+t]; q += gQ[u*30+t]; }
    float m = s/n;
    float var = q/n - m*m;
    float sc = g[t]*(1.0f/sqrtf(var+1e-5f));
    float c0 = be[t] - sc*m;
    s_l[t]=sc; c_l[t]=c0;
    sfc[t]=sc; sfc[32+t]=c0;
    for (int u=0;u<64;u++){ gS[u*30+t]=0.f; gQ[u*30+t]=0.f; }
  }
  __syncthreads();
  if (FOLD){
    for (int i=t;i<900;i+=256) wfold[i] = s_l[i/30]*wnext[i];
    if (t<30){
      float c=0.f;
      for (int k=0;k<30;k++) c += c_l[k]*wnext[k*30+t];
      cvec[t]=c;
    }
  }
}

// ---------------- belief propagation (col-vectorized, XCD-resident) -------
__device__ __forceinline__ void bp_decode2(int b, int& graph, int& run, int& jj){
  int xcd = b & 7, i = b >> 3;
  int gs = i >> 7, j = i & 127;
  if      (j <   4){ run=0; jj=j;    }
  else if (j <   8){ run=1; jj=j-4;  }
  else if (j <  16){ run=2; jj=j-8;  }
  else if (j <  32){ run=3; jj=j-16; }
  else if (j <  64){ run=4; jj=j-32; }
  else             { run=5; jj=j-64; }
  graph = gs*8 + xcd;
}

template<int TPR>
__device__ __forceinline__ void bfly_max4(float& m0, float& m1, float& m2, float& m3){
  if constexpr (TPR > 1){
    #pragma unroll
    for (int lm = TPR>>1; lm; lm >>= 1){
      float p0=__shfl_xor(m0,lm,64), p1=__shfl_xor(m1,lm,64);
      float p2=__shfl_xor(m2,lm,64), p3=__shfl_xor(m3,lm,64);
      m0=fmaxf(m0,p0); m1=fmaxf(m1,p1); m2=fmaxf(m2,p2); m3=fmaxf(m3,p3);
    }
  }
  { float t0=fmaxf(m0,m2), t1=fmaxf(m1,m3), t2=fmaxf(m2,m0), t3=fmaxf(m3,m1);
    m0=t0; m1=t1; m2=t2; m3=t3; }
  { float t0=fmaxf(m0,m1), t1=fmaxf(m1,m0), t2=fmaxf(m2,m3), t3=fmaxf(m3,m2);
    m0=t0; m1=t1; m2=t2; m3=t3; }
}

template<int TPR>
__device__ __forceinline__ void bfly_sum4(float& s0, float& s1, float& s2, float& s3){
  if constexpr (TPR > 1){
    #pragma unroll
    for (int lm = TPR>>1; lm; lm >>= 1){
      float p0=__shfl_xor(s0,lm,64), p1=__shfl_xor(s1,lm,64);
      float p2=__shfl_xor(s2,lm,64), p3=__shfl_xor(s3,lm,64);
      s0 += p0; s1 += p1; s2 += p2; s3 += p3;
    }
  }
  { float t0=s0+s2, t1=s1+s3, t2=s2+s0, t3=s3+s1;
    s0=t0; s1=t1; s2=t2; s3=t3; }
  { float t0=s0+s1, t1=s1+s0, t2=s2+s3, t3=s3+s2;
    s0=t0; s1=t1; s2=t2; s3=t3; }
}

template<int Q, int CO, int TPR, int L2T>
__device__ __forceinline__ void bp_first_elem2(int graph, int jj, float* __restrict__ psi_pk,
                                               float* __restrict__ lg, float eb,
                                               uint32_t k0, uint32_t k1){
  int idx = jj*256 + (int)threadIdx.x;
  if constexpr (Q == 2){
    int row = graph*1024 + idx;
    float z[2];
    #pragma unroll
    for (int r=0;r<2;r++){
      uint32_t b0,b1;
      tf2x32(k0,k1, 0u, (uint32_t)(row*2 + r), b0,b1);
      uint32_t bits = b0 ^ b1;
      float f = __uint_as_float((bits>>9) | 0x3F800000u) - 1.0f;
      const float lo = __uint_as_float(0xBF7FFFFFu);
      float u = fmaxf(lo, f*2.0f + lo);
      z[r] = __uint_as_float(0x3FB504F3u) * erfinv32(u);
    }
    float m0=fmaxf(z[0],z[1]), m1=fmaxf(z[1],z[0]);
    float e0=expf(z[0]-m0), e1=expf(z[1]-m1);
    float s0=e0+e1, s1=e1+e0;
    float p0=e0/s0, p1=e1/s1;
    ((float2*)(psi_pk + (size_t)NN*CO))[row] = make_float2(p0,p1);
    ((float2*)(lg     + (size_t)NN*CO))[row] = make_float2(log1pf(eb*p0), log1pf(eb*p1));
  } else {
    int rw = idx >> L2T, ct = idx & (TPR-1);
    int row = graph*1024 + rw;
    float z[4];
    #pragma unroll
    for (int r=0;r<4;r++){
      uint32_t b0,b1;
      tf2x32(k0,k1, 0u, (uint32_t)(row*Q + 4*ct + r), b0,b1);
      uint32_t bits = b0 ^ b1;
      float f = __uint_as_float((bits>>9) | 0x3F800000u) - 1.0f;
      const float lo = __uint_as_float(0xBF7FFFFFu);
      float u = fmaxf(lo, f*2.0f + lo);
      z[r] = __uint_as_float(0x3FB504F3u) * erfinv32(u);
    }
    float m0=z[0],m1=z[1],m2=z[2],m3=z[3];
    bfly_max4<TPR>(m0,m1,m2,m3);
    float e0=expf(z[0]-m0), e1=expf(z[1]-m1), e2=expf(z[2]-m2), e3=expf(z[3]-m3);
    float s0=e0,s1=e1,s2=e2,s3=e3;
    bfly_sum4<TPR>(s0,s1,s2,s3);
    float p0=e0/s0, p1=e1/s1, p2=e2/s2, p3=e3/s3;
    ((float4*)(psi_pk + (size_t)NN*CO))[(size_t)row*TPR + ct] = make_float4(p0,p1,p2,p3);
    ((float4*)(lg     + (size_t)NN*CO))[(size_t)row*TPR + ct] =
        make_float4(log1pf(eb*p0), log1pf(eb*p1), log1pf(eb*p2), log1pf(eb*p3));
  }
}

// bp_first + aux mm30<3> (blocks >= 8192)
__global__ __launch_bounds__(256) void k_bp_first(float* __restrict__ psi_pk, float* __restrict__ lg,
                                                  const float* __restrict__ betas,
                                                  const float* __restrict__ xin,
                                                  const float* __restrict__ w11,
                                                  float* __restrict__ hbuf){
  if (blockIdx.x >= 8192){
    __shared__ float ws[90];
    int t = threadIdx.x;
    for (int i=t;i<90;i+=256) ws[i] = w11[i];
    __syncthreads();
    int id = ((int)blockIdx.x - 8192)*256 + t;
    if (id >= NN*30) return;
    int v = id/30, j = id - v*30;
    const float* xr = xin + v*3;
    float acc = 0.f;
    #pragma unroll
    for (int k=0;k<3;k++) acc += xr[k]*ws[k*30+j];
    hbuf[id] = acc;
    return;
  }
  int graph, run, jj;
  bp_decode2(blockIdx.x, graph, run, jj);
  uint32_t k0, k1;
  tf2x32(0u, 42u, 0u, (uint32_t)run, k0, k1);
  float eb = expm1f(betas[run]);
  switch(run){
    case 0: bp_first_elem2< 2, 0, 1,0>(graph, jj, psi_pk, lg, eb, k0, k1); break;
    case 1: bp_first_elem2< 4, 2, 1,0>(graph, jj, psi_pk, lg, eb, k0, k1); break;
    case 2: bp_first_elem2< 8, 6, 2,1>(graph, jj, psi_pk, lg, eb, k0, k1); break;
    case 3: bp_first_elem2<16,14, 4,2>(graph, jj, psi_pk, lg, eb, k0, k1); break;
    case 4: bp_first_elem2<32,30, 8,3>(graph, jj, psi_pk, lg, eb, k0, k1); break;
    default:bp_first_elem2<64,62,16,4>(graph, jj, psi_pk, lg, eb, k0, k1); break;
  }
}

template<int Q, int CO, int TPR, int L2T>
__device__ __forceinline__ void bp_step_elem2(int graph, int run, int jj,
    const float* __restrict__ lcur, float* __restrict__ nxt, float* __restrict__ lnxt,
    const int* __restrict__ rp, const int* __restrict__ col,
    const float* __restrict__ field, float eb, int fin){
  int idx = jj*256 + (int)threadIdx.x;
  if constexpr (Q == 2){
    int row = graph*1024 + idx;
    const float2* B2 = (const float2*)(lcur + (size_t)NN*CO);
    float a0=0.f, a1=0.f;
    int a = rp[row], b2 = rp[row+1];
    for (; a+8<=b2; a+=8){
      int s0=col[a],s1=col[a+1],s2=col[a+2],s3=col[a+3];
      int s4=col[a+4],s5=col[a+5],s6=col[a+6],s7=col[a+7];
      float2 u0=B2[s0], u1=B2[s1], u2=B2[s2], u3=B2[s3];
      float2 u4=B2[s4], u5=B2[s5], u6=B2[s6], u7=B2[s7];
      a0+=u0.x; a1+=u0.y; a0+=u1.x; a1+=u1.y;
      a0+=u2.x; a1+=u2.y; a0+=u3.x; a1+=u3.y;
      a0+=u4.x; a1+=u4.y; a0+=u5.x; a1+=u5.y;
      a0+=u6.x; a1+=u6.y; a0+=u7.x; a1+=u7.y;
    }
    for (; a+4<=b2; a+=4){
      int s0=col[a],s1=col[a+1],s2=col[a+2],s3=col[a+3];
      float2 u0=B2[s0], u1=B2[s1], u2=B2[s2], u3=B2[s3];
      a0+=u0.x; a1+=u0.y; a0+=u1.x; a1+=u1.y;
      a0+=u2.x; a1+=u2.y; a0+=u3.x; a1+=u3.y;
    }
    for (; a<b2; ++a){ float2 u=B2[col[a]]; a0+=u.x; a1+=u.y; }
    float v0 = a0 - field[run*64 + 0];
    float v1 = a1 - field[run*64 + 1];
    float m0=fmaxf(v0,v1), m1=fmaxf(v1,v0);
    float e0=expf(v0-m0), e1=expf(v1-m1);
    float s0=e0+e1, s1=e1+e0;
    float p0=e0/s0, p1=e1/s1;
    if (fin){
      float* o = nxt + (size_t)row*126 + CO;
      o[0]=p0; o[1]=p1;
    } else {
      ((float2*)(nxt  + (size_t)NN*CO))[row] = make_float2(p0,p1);
      ((float2*)(lnxt + (size_t)NN*CO))[row] = make_float2(log1pf(eb*p0), log1pf(eb*p1));
    }
  } else {
    int rw = idx >> L2T, ct = idx & (TPR-1);
    int row = graph*1024 + rw;
    const float4* B4 = (const float4*)(lcur + (size_t)NN*CO);
    float a0=0.f,a1=0.f,a2=0.f,a3=0.f;
    int a = rp[row], b2 = rp[row+1];
    for (; a+8<=b2; a+=8){
      int s0=col[a],s1=col[a+1],s2=col[a+2],s3=col[a+3];
      int s4=col[a+4],s5=col[a+5],s6=col[a+6],s7=col[a+7];
      float4 u0=B4[(size_t)s0*TPR+ct], u1=B4[(size_t)s1*TPR+ct];
      float4 u2=B4[(size_t)s2*TPR+ct], u3=B4[(size_t)s3*TPR+ct];
      float4 u4=B4[(size_t)s4*TPR+ct], u5=B4[(size_t)s5*TPR+ct];
      float4 u6=B4[(size_t)s6*TPR+ct], u7=B4[(size_t)s7*TPR+ct];
      a0+=u0.x; a1+=u0.y; a2+=u0.z; a3+=u0.w;
      a0+=u1.x; a1+=u1.y; a2+=u1.z; a3+=u1.w;
      a0+=u2.x; a1+=u2.y; a2+=u2.z; a3+=u2.w;
      a0+=u3.x; a1+=u3.y; a2+=u3.z; a3+=u3.w;
      a0+=u4.x; a1+=u4.y; a2+=u4.z; a3+=u4.w;
      a0+=u5.x; a1+=u5.y; a2+=u5.z; a3+=u5.w;
      a0+=u6.x; a1+=u6.y; a2+=u6.z; a3+=u6.w;
      a0+=u7.x; a1+=u7.y; a2+=u7.z; a3+=u7.w;
    }
    for (; a+4<=b2; a+=4){
      int s0=col[a],s1=col[a+1],s2=col[a+2],s3=col[a+3];
      float4 u0=B4[(size_t)s0*TPR+ct], u1=B4[(size_t)s1*TPR+ct];
      float4 u2=B4[(size_t)s2*TPR+ct], u3=B4[(size_t)s3*TPR+ct];
      a0+=u0.x; a1+=u0.y; a2+=u0.z; a3+=u0.w;
      a0+=u1.x; a1+=u1.y; a2+=u1.z; a3+=u1.w;
      a0+=u2.x; a1+=u2.y; a2+=u2.z; a3+=u2.w;
      a0+=u3.x; a1+=u3.y; a2+=u3.z; a3+=u3.w;
    }
    for (; a<b2; ++a){
      float4 u = B4[(size_t)col[a]*TPR+ct];
      a0+=u.x; a1+=u.y; a2+=u.z; a3+=u.w;
    }
    const float4 fld = *(const float4*)(field + run*64 + 4*ct);
    float v0 = a0 - fld.x, v1 = a1 - fld.y, v2 = a2 - fld.z, v3 = a3 - fld.w;
    float m0=v0,m1=v1,m2=v2,m3=v3;
    bfly_max4<TPR>(m0,m1,m2,m3);
    float e0=expf(v0-m0), e1=expf(v1-m1), e2=expf(v2-m2), e3=expf(v3-m3);
    float s0=e0,s1=e1,s2=e2,s3=e3;
    bfly_sum4<TPR>(s0,s1,s2,s3);
    float p0=e0/s0, p1=e1/s1, p2=e2/s2, p3=e3/s3;
    if (fin){
      float* o = nxt + (size_t)row*126 + CO + 4*ct;
      o[0]=p0; o[1]=p1; o[2]=p2; o[3]=p3;
    } else {
      ((float4*)(nxt  + (size_t)NN*CO))[(size_t)row*TPR+ct] = make_float4(p0,p1,p2,p3);
      ((float4*)(lnxt + (size_t)NN*CO))[(size_t)row*TPR+ct] =
          make_float4(log1pf(eb*p0), log1pf(eb*p1), log1pf(eb*p2), log1pf(eb*p3));
    }
  }
}

// bp_step + aux blocks (>= 8192): 1=gcn_agg, 2=mm30c, 3=pool(stage-1)
__global__ __launch_bounds__(256) void k_bp_step(
    float* __restrict__ nxt, const float* __restrict__ lcur, float* __restrict__ lnxt,
    const int* __restrict__ rp, const int* __restrict__ col,
    const float* __restrict__ field, const float* __restrict__ betas, int fin,
    int auxType, const float* __restrict__ aA, const float* __restrict__ aB,
    const float* __restrict__ aC, float* __restrict__ aO,
    float* __restrict__ agS, float* __restrict__ agQ,
    const float* __restrict__ adinv, const float* __restrict__ asfc,
    float* __restrict__ aconv){
  if (blockIdx.x >= 8192){
    __shared__ float smem[960];
    int ab = (int)blockIdx.x - 8192;
    int t = threadIdx.x;
    if (auxType == 1){
      // gcn_agg: aA=h, aB=bias, aO=y, adinv, agS/agQ (stats)
      float* binS = smem; float* binQ = smem + 32;
      if (t < 30){ binS[t]=0.f; binQ[t]=0.f; }
      __syncthreads();
      int xcd = ab & 7, i = ab >> 3;
      int gs = i/60, j = i - gs*60;
      int graph = gs*8 + xcd;
      int idwg = j*256 + t;
      int rw = idwg/15, pr = idwg - rw*15;
      int v = graph*1024 + rw;
      float dv = adinv[v];
      float accx = 0.f, accy = 0.f;
      int a = rp[v], e = rp[v+1];
      for (; a+4<=e; a+=4){
        int s0=col[a], s1=col[a+1], s2=col[a+2], s3=col[a+3];
        float d0=adinv[s0], d1=adinv[s1], d2=adinv[s2], d3=adinv[s3];
        float2 h0=*(const float2*)(aA+s0*30+2*pr), h1=*(const float2*)(aA+s1*30+2*pr);
        float2 h2=*(const float2*)(aA+s2*30+2*pr), h3=*(const float2*)(aA+s3*30+2*pr);
        accx += h0.x*(d0*dv); accy += h0.y*(d0*dv);
        accx += h1.x*(d1*dv); accy += h1.y*(d1*dv);
        accx += h2.x*(d2*dv); accy += h2.y*(d2*dv);
        accx += h3.x*(d3*dv); accy += h3.y*(d3*dv);
      }
      for (; a<e; ++a){
        int s = col[a];
        float w = adinv[s]*dv;
        float2 hv = *(const float2*)(aA+s*30+2*pr);
        accx += hv.x*w; accy += hv.y*w;
      }
      float2 hs = *(const float2*)(aA + v*30 + 2*pr);
      float w2 = dv*dv;
      accx += hs.x*w2; accy += hs.y*w2;   // self loop last (JAX concat order)
      float2 o; o.x = accx + aB[2*pr]; o.y = accy + aB[2*pr+1];
      *(float2*)(aO + v*30 + 2*pr) = o;
      atomicAdd(&binS[2*pr],   o.x); atomicAdd(&binQ[2*pr],   o.x*o.x);
      atomicAdd(&binS[2*pr+1], o.y); atomicAdd(&binQ[2*pr+1], o.y*o.y);
      __syncthreads();
      if (t < 30){
        int slot = (ab & 63)*30 + t;
        atomicAdd(&agS[slot], binS[t]);
        atomicAdd(&agQ[slot], binQ[t]);
      }
    } else if (auxType == 2){
      // mm30c: aA=x, aB=wfold, aC=cvec, aO=h
      float* ws = smem; float* cl = smem + 904;
      for (int i=t;i<900;i+=256) ws[i] = aB[i];
      if (t < 30) cl[t] = aC[t];
      __syncthreads();
      int id = ab*256 + t;
      if (id < NN*30){
        int v = id/30, j = id - v*30;
        const float* xr = aA + v*30;
        float acc = cl[j];
        #pragma unroll
        for (int k=0;k<30;k++) acc += xr[k]*ws[k*30+j];
        aO[id] = acc;
      }
    } else if (auxType == 3){
      // stage-1 pool: aA=X1, aB=X2, aC=X3, asfc, aconv (coff=0, rows=1024)
      int b2 = ab & 63, a = ab >> 6;
      const float* X = (a==0)? aA : ((a==1)? aB : aC);
      const float* sf = asfc + a*64;
      float acc[30];
      #pragma unroll
      for (int f=0;f<30;f++) acc[f] = -FLT_MAX;
      for (int r=t; r<1024; r+=256){
        const float* xr = X + (size_t)(b2*1024 + r)*30;
        #pragma unroll
        for (int f=0;f<30;f++) acc[f] = fmaxf(acc[f], sf[f]*xr[f] + sf[32+f]);
      }
      #pragma unroll
      for (int off=32; off; off>>=1){
        #pragma unroll
        for (int f=0;f<30;f++) acc[f] = fmaxf(acc[f], __shfl_xor(acc[f], off, 64));
      }
      int w = t>>6, lane = t&63;
      if (lane == 0){
        #pragma unroll
        for (int f=0;f<30;f++) smem[w*30+f] = acc[f];
      }
      __syncthreads();
      if (t < 30)
        aconv[b2*180 + a*30 + t] =
          fmaxf(fmaxf(smem[t], smem[30+t]), fmaxf(smem[60+t], smem[90+t]));
    }
    return;
  }
  int graph, run, jj;
  bp_decode2(blockIdx.x, graph, run, jj);
  float eb = expm1f(betas[run]);
  switch(run){
    case 0: bp_step_elem2< 2, 0, 1,0>(graph, run, jj, lcur, nxt, lnxt, rp, col, field, eb, fin); break;
    case 1: bp_step_elem2< 4, 2, 1,0>(graph, run, jj, lcur, nxt, lnxt, rp, col, field, eb, fin); break;
    case 2: bp_step_elem2< 8, 6, 2,1>(graph, run, jj, lcur, nxt, lnxt, rp, col, field, eb, fin); break;
    case 3: bp_step_elem2<16,14, 4,2>(graph, run, jj, lcur, nxt, lnxt, rp, col, field, eb, fin); break;
    case 4: bp_step_elem2<32,30, 8,3>(graph, run, jj, lcur, nxt, lnxt, rp, col, field, eb, fin); break;
    default:bp_step_elem2<64,62,16,4>(graph, run, jj, lcur, nxt, lnxt, rp, col, field, eb, fin); break;
  }
}

// column sums over PACKED psi; order bit-identical
__global__ __launch_bounds__(64) void k_colsum_part(const float* __restrict__ psi_pk, float* __restrict__ part){
  int b = blockIdx.x;
  int xcd = b & 7, i = b >> 3;
  int gs = i/24, rem = i - gs*24;
  int run = rem >> 2, cg = rem & 3;
  int graph = gs*8 + xcd;
  int chunk = graph*4 + cg;
  int q = cQS[run];
  int co = (run==0)?0:(run==1)?2:(run==2)?6:(run==3)?14:(run==4)?30:62;
  int c = threadIdx.x;
  if (q >= 4){
    int nq = q >> 2;
    if (c >= nq) return;
    const float4* p4 = (const float4*)(psi_pk + (size_t)NN*co + (size_t)chunk*256*q) + c;
    float s0=0.f,s1=0.f,s2=0.f,s3=0.f;
    #pragma unroll 8
    for (int r=0;r<256;r++){
      float4 u = p4[(size_t)r*nq];
      s0+=u.x; s1+=u.y; s2+=u.z; s3+=u.w;
    }
    float* o = part + (run*256 + chunk)*64 + 4*c;
    o[0]=s0; o[1]=s1; o[2]=s2; o[3]=s3;
  } else {
    if (c >= q) return;
    float s = 0.f;
    const float* p = psi_pk + (size_t)NN*co + (size_t)chunk*256*q + c;
    #pragma unroll 8
    for (int r=0;r<256;r++) s += p[r*q];
    part[(run*256 + chunk)*64 + c] = s;
  }
}

// field (block 0) + optional bnw aux (block 1). 2 blocks x 384 thr.
__global__ void k_field(const float* __restrict__ part, const float* __restrict__ betas,
                        float* __restrict__ field,
                        int auxFold, float* __restrict__ gS, float* __restrict__ gQ, float n,
                        const float* __restrict__ g, const float* __restrict__ be,
                        const float* __restrict__ wnext, float* __restrict__ sfc,
                        float* __restrict__ wfold, float* __restrict__ cvec){
  if (blockIdx.x == 1){
    if (auxFold < 0) return;
    __shared__ float s_l[30], c_l[30];
    int t = threadIdx.x;
    if (t < 30){
      float s=0.f, q=0.f;
      for (int u=0;u<64;u++){ s += gS[u*30+t]; q += gQ[u*30+t]; }
      float m = s/n;
      float var = q/n - m*m;
      float sc = g[t]*(1.0f/sqrtf(var+1e-5f));
      float c0 = be[t] - sc*m;
      s_l[t]=sc; c_l[t]=c0;
      sfc[t]=sc; sfc[32+t]=c0;
      for (int u=0;u<64;u++){ gS[u*30+t]=0.f; gQ[u*30+t]=0.f; }
    }
    __syncthreads();
    if (auxFold == 1){
      for (int i=t;i<900;i+=384) wfold[i] = s_l[i/30]*wnext[i];
      if (t<30){
        float c=0.f;
        for (int k=0;k<30;k++) c += c_l[k]*wnext[k*30+t];
        cvec[t]=c;
      }
    }
    return;
  }
  int id = threadIdx.x;
  int run = id >> 6, c = id & 63;
  if (c >= cQS[run]) return;
  float s = 0.f;
  for (int b=0;b<256;b++) s += part[(run*256 + b)*64 + c];
  float beta = betas[run];
  field[id] = s * (3.8f*beta/65536.0f);
}

// ---------------- diff-pool ----------------
__global__ __launch_bounds__(256) void k_catT(const float* __restrict__ cat, float* __restrict__ catT){
  __shared__ float tile[64*127];
  int b = blockIdx.x, t = threadIdx.x;
  const float* src = cat + (size_t)b*64*126;
  for (int i=t;i<8064;i+=256){
    int r = i/126, k = i - r*126;
    tile[r*127 + k] = src[i];
  }
  __syncthreads();
  for (int i=t;i<8064;i+=256){
    int k = i>>6, r = i&63;
    catT[(size_t)k*65536 + b*64 + r] = tile[r*127 + k];
  }
}

__global__ __launch_bounds__(256) void k_s1t(const float* __restrict__ catT, const float* __restrict__ pw,
                                             const float* __restrict__ pb, float* __restrict__ s1){
  __shared__ float wl[12600];
  __shared__ float pbl[100];
  __shared__ float redM[2][128];
  __shared__ float redS[2][128];
  int t = threadIdx.x;
  for (int i=t;i<12600;i+=256) wl[i] = pw[i];
  if (t < 100) pbl[t] = pb[t];
  int w = t>>6, lane = t&63;
  int rh = w&1, chh = w>>1;
  int ch = chh*50;
  int row = blockIdx.x*128 + rh*64 + lane;
  __syncthreads();
  float acc[50];
  #pragma unroll
  for (int j=0;j<50;j++) acc[j] = pbl[ch+j];
  for (int k=0;k<126;k++){
    float xv = catT[(size_t)k*65536 + row];
    const float* wr = &wl[k*100 + ch];
    #pragma unroll
    for (int j=0;j<50;j+=2){
      float2 wv = *(const float2*)&wr[j];
      acc[j]   += xv*wv.x;
      acc[j+1] += xv*wv.y;
    }
  }
  float m = acc[0];
  #pragma unroll
  for (int j=1;j<50;j++) m = fmaxf(m, acc[j]);
  redM[chh][rh*64 + lane] = m;
  __syncthreads();
  float mm = fmaxf(redM[0][rh*64 + lane], redM[1][rh*64 + lane]);
  float s = 0.f;
  #pragma unroll
  for (int j=0;j<50;j++){ acc[j] = expf(acc[j]-mm); s += acc[j]; }
  redS[chh][rh*64 + lane] = s;
  __syncthreads();
  float tot = redS[0][rh*64 + lane] + redS[1][rh*64 + lane];
  float* o = s1 + (size_t)row*100 + ch;
  #pragma unroll
  for (int j=0;j<50;j+=2){
    float2 ov; ov.x = acc[j]/tot; ov.y = acc[j+1]/tot;
    *(float2*)&o[j] = ov;
  }
}

__global__ __launch_bounds__(256) void k_T(const float* __restrict__ s1, const int* __restrict__ rp,
                                           const int* __restrict__ col, float* __restrict__ T){
  int b = blockIdx.x;
  int xcd = b & 7, i = b >> 3;
  int gs = i/100, j = i - gs*100;
  int graph = gs*8 + xcd;
  int idwg = j*256 + threadIdx.x;
  int rw = idwg/25, quad = idwg - rw*25;
  int v = graph*1024 + rw;
  float a0=0.f,a1=0.f,a2=0.f,a3=0.f;
  const float4* S4 = (const float4*)s1;
  int a = rp[v], e = rp[v+1];
  for (; a+8<=e; a+=8){
    int s0=col[a], s1_=col[a+1], s2=col[a+2], s3=col[a+3];
    int s4=col[a+4], s5=col[a+5], s6=col[a+6], s7=col[a+7];
    float4 u0=S4[(size_t)s0*25+quad], u1=S4[(size_t)s1_*25+quad];
    float4 u2=S4[(size_t)s2*25+quad], u3=S4[(size_t)s3*25+quad];
    float4 u4=S4[(size_t)s4*25+quad], u5=S4[(size_t)s5*25+quad];
    float4 u6=S4[(size_t)s6*25+quad], u7=S4[(size_t)s7*25+quad];
    a0+=u0.x; a1+=u0.y; a2+=u0.z; a3+=u0.w;
    a0+=u1.x; a1+=u1.y; a2+=u1.z; a3+=u1.w;
    a0+=u2.x; a1+=u2.y; a2+=u2.z; a3+=u2.w;
    a0+=u3.x; a1+=u3.y; a2+=u3.z; a3+=u3.w;
    a0+=u4.x; a1+=u4.y; a2+=u4.z; a3+=u4.w;
    a0+=u5.x; a1+=u5.y; a2+=u5.z; a3+=u5.w;
    a0+=u6.x; a1+=u6.y; a2+=u6.z; a3+=u6.w;
    a0+=u7.x; a1+=u7.y; a2+=u7.z; a3+=u7.w;
  }
  for (; a+4<=e; a+=4){
    int s0=col[a], s1_=col[a+1], s2=col[a+2], s3=col[a+3];
    float4 u0=S4[(size_t)s0*25+quad], u1=S4[(size_t)s1_*25+quad];
    float4 u2=S4[(size_t)s2*25+quad], u3=S4[(size_t)s3*25+quad];
    a0+=u0.x; a1+=u0.y; a2+=u0.z; a3+=u0.w;
    a0+=u1.x; a1+=u1.y; a2+=u1.z; a3+=u1.w;
    a0+=u2.x; a1+=u2.y; a2+=u2.z; a3+=u2.w;
    a0+=u3.x; a1+=u3.y; a2+=u3.z; a3+=u3.w;
  }
  for (; a<e; ++a){
    float4 u = S4[(size_t)col[a]*25+quad];
    a0+=u.x; a1+=u.y; a2+=u.z; a3+=u.w;
  }
  ((float4*)T)[(size_t)v*25 + quad] = make_float4(a0,a1,a2,a3);
}

// merged split-K: blocks 0..255 = p1adj, 256..511 = p1x (BN affine on fill)
__global__ __launch_bounds__(512) void k_p1ax(const float* __restrict__ s1, const float* __restrict__ T,
                                              const float* __restrict__ y3, const float* __restrict__ sfc,
                                              float* __restrict__ partA, float* __restrict__ partX){
  __shared__ float sS[6400];
  __shared__ float sT[6400];
  int t = threadIdx.x;
  if (blockIdx.x < 256){
    int blk = blockIdx.x;
    int b = blk >> 2, qtr = blk & 3;
    int tk = t/20, tl = t - tk*20;
    bool act = t < 500;
    int k0 = tk*4, l0 = tl*5;
    float acc[4][5];
    #pragma unroll
    for (int i=0;i<4;i++)
      #pragma unroll
      for (int j=0;j<5;j++) acc[i][j] = 0.f;
    const float* s1b = s1 + (size_t)b*102400;
    const float* Tb  = T  + (size_t)b*102400;
    for (int c=qtr*4; c<qtr*4+4; c++){
      for (int i=t;i<6400;i+=512){ sS[i] = s1b[c*6400+i]; sT[i] = Tb[c*6400+i]; }
      __syncthreads();
      if (act){
        #pragma unroll 2
        for (int n=0;n<64;n++){
          const float* sr = &sS[n*100 + k0];
          const float* tr = &sT[n*100 + l0];
          float s0=sr[0], s1v=sr[1], s2=sr[2], s3=sr[3];
          float t0=tr[0], t1=tr[1], t2=tr[2], t3=tr[3], t4=tr[4];
          acc[0][0]+=s0*t0; acc[0][1]+=s0*t1; acc[0][2]+=s0*t2; acc[0][3]+=s0*t3; acc[0][4]+=s0*t4;
          acc[1][0]+=s1v*t0; acc[1][1]+=s1v*t1; acc[1][2]+=s1v*t2; acc[1][3]+=s1v*t3; acc[1][4]+=s1v*t4;
          acc[2][0]+=s2*t0; acc[2][1]+=s2*t1; acc[2][2]+=s2*t2; acc[2][3]+=s2*t3; acc[2][4]+=s2*t4;
          acc[3][0]+=s3*t0; acc[3][1]+=s3*t1; acc[3][2]+=s3*t2; acc[3][3]+=s3*t3; acc[3][4]+=s3*t4;
        }
      }
      __syncthreads();
    }
    if (act){
      float* pp = partA + (size_t)qtr*640000 + (size_t)b*10000;
      #pragma unroll
      for (int i=0;i<4;i++){
        float* o = pp + (k0+i)*100 + l0;
        #pragma unroll
        for (int j=0;j<5;j++) o[j] = acc[i][j];
      }
    }
  } else {
    int blk = blockIdx.x - 256;
    int b = blk >> 2, qtr = blk & 3;
    float* sX = sT;                       // reuse sT's first 1920 as sX
    int tk = t/10, tl = t - tk*10;
    bool act = t < 250;
    int k0 = tk*4, d0 = tl*3;
    float acc[4][3];
    #pragma unroll
    for (int i=0;i<4;i++)
      #pragma unroll
      for (int j=0;j<3;j++) acc[i][j] = 0.f;
    const float* s1b = s1 + (size_t)b*102400;
    const float* xb  = y3 + (size_t)b*30720;
    for (int c=qtr*4; c<qtr*4+4; c++){
      for (int i=t;i<6400;i+=512) sS[i] = s1b[c*6400+i];
      for (int i=t;i<1920;i+=512){
        int f = i % 30;
        sX[i] = sfc[f]*xb[c*1920+i] + sfc[32+f];
      }
      __syncthreads();
      if (act){
        #pragma unroll 2
        for (int n=0;n<64;n++){
          const float* sr = &sS[n*100 + k0];
          const float* xr = &sX[n*30 + d0];
          float s0=sr[0], s1v=sr[1], s2=sr[2], s3=sr[3];
          float x0=xr[0], x1=xr[1], x2=xr[2];
          acc[0][0]+=s0*x0; acc[0][1]+=s0*x1; acc[0][2]+=s0*x2;
          acc[1][0]+=s1v*x0; acc[1][1]+=s1v*x1; acc[1][2]+=s1v*x2;
          acc[2][0]+=s2*x0; acc[2][1]+=s2*x1; acc[2][2]+=s2*x2;
          acc[3][0]+=s3*x0; acc[3][1]+=s3*x1; acc[3][2]+=s3*x2;
        }
      }
      __syncthreads();
    }
    if (act){
      float* pp = partX + (size_t)qtr*192000 + (size_t)b*3000;
      #pragma unroll
      for (int i=0;i<4;i++){
        float* o = pp + (k0+i)*30 + d0;
        #pragma unroll
        for (int j=0;j<3;j++) o[j] = acc[i][j];
      }
    }
  }
}

// blocks 0..63: reduce padj parts in LDS + normalize -> An; 64..813: px reduce
__global__ __launch_bounds__(256) void k_anpx(const float* __restrict__ pA, const float* __restrict__ pX,
                                              float* __restrict__ An, float* __restrict__ px){
  if (blockIdx.x < 64){
    __shared__ float pj[10000];
    __shared__ float dv[100];
    int b = blockIdx.x, t = threadIdx.x;
    size_t base = (size_t)b*10000;
    for (int i=t;i<10000;i+=256)
      pj[i] = pA[base+i] + pA[640000+base+i] + pA[1280000+base+i] + pA[1920000+base+i];
    __syncthreads();
    if (t < 100){
      const float* r = pj + t*100;
      float s = 0.f;
      for (int l=0;l<100;l++){
        float v = r[l];
        if (l==t) v += 1.0f;
        s += v;
      }
      dv[t] = 1.0f/sqrtf(s);
    }
    __syncthreads();
    for (int i=t;i<10000;i+=256){
      int k = i/100, l = i - k*100;
      float a = pj[i] + ((k==l)? 1.0f : 0.0f);
      An[base + i] = (dv[k]*a)*dv[l];
    }
  } else {
    int id = ((int)blockIdx.x - 64)*256 + threadIdx.x;
    if (id < 192000)
      px[id] = pX[id] + pX[192000+id] + pX[384000+id] + pX[576000+id];
  }
}

// ---------------- stage-2 dense GCN ----------------
__global__ __launch_bounds__(256) void k_y2(const float* __restrict__ An, const float* __restrict__ h,
    const float* __restrict__ bias, float* __restrict__ y,
    float* __restrict__ gS, float* __restrict__ gQ){
  __shared__ float binS[30], binQ[30];
  int t = threadIdx.x;
  if (t < 30){ binS[t]=0.f; binQ[t]=0.f; }
  __syncthreads();
  int id = blockIdx.x*256 + t;
  if (id < NBG*100*30){
    int d = id % 30;
    int bk = id / 30;
    int b = bk / 100;
    const float* Ar = An + bk*100;
    const float* hb = h + b*100*30;
    float acc = 0.f;
    for (int l=0;l<100;l++) acc += Ar[l]*hb[l*30+d];
    float val = acc + bias[d];
    y[id] = val;
    atomicAdd(&binS[d], val);
    atomicAdd(&binQ[d], val*val);
  }
  __syncthreads();
  if (t < 30){
    int slot = (blockIdx.x & 63)*30 + t;
    atomicAdd(&gS[slot], binS[t]);
    atomicAdd(&gQ[slot], binQ[t]);
  }
}

// stage-2 pool (big-LDS variant, separate launch)
__global__ __launch_bounds__(256) void k_pool2(const float* __restrict__ A,
    const float* __restrict__ Bv, const float* __restrict__ Cv,
    const float* __restrict__ sfcBase,
    int rows, float* __restrict__ conv, int coff){
  __shared__ float lds[256*31];
  int b = blockIdx.x, a = blockIdx.y, t = threadIdx.x;
  const float* X = (a==0)? A : ((a==1)? Bv : Cv);
  const float* sf = sfcBase + a*64;
  float acc[30];
  #pragma unroll
  for (int f=0;f<30;f++) acc[f] = -FLT_MAX;
  for (int r=t; r<rows; r+=256){
    const float* xr = X + (size_t)(b*rows + r)*30;
    #pragma unroll
    for (int f=0;f<30;f++) acc[f] = fmaxf(acc[f], sf[f]*xr[f] + sf[32+f]);
  }
  #pragma unroll
  for (int f=0;f<30;f++) lds[t*31+f] = acc[f];
  __syncthreads();
  for (int s=128;s>0;s>>=1){
    if (t<s){
      #pragma unroll
      for (int f=0;f<30;f++) lds[t*31+f] = fmaxf(lds[t*31+f], lds[(t+s)*31+f]);
    }
    __syncthreads();
  }
  if (t<30) conv[b*180 + coff + a*30 + t] = lds[t];
}

__global__ __launch_bounds__(64) void k_fc(const float* __restrict__ conv,
    const float* __restrict__ w1, const float* __restrict__ b1,
    const float* __restrict__ w2, const float* __restrict__ b2, float* __restrict__ out){
  __shared__ float row[180];
  __shared__ float hid[50];
  int b = blockIdx.x, t = threadIdx.x;
  for (int i=t;i<180;i+=64) row[i] = conv[b*180+i];
  __syncthreads();
  if (t < 50){
    float a = b1[t];
    for (int i=0;i<180;i++) a += row[i]*w1[i*50+t];
    hid[t] = fmaxf(a, 0.f);
  }
  __syncthreads();
  if (t < 6){
    float a = b2[t];
    for (int i=0;i<50;i++) a += hid[i]*w2[i*6+t];
    out[b*6+t] = a;
  }
  if (b==0 && t==63) out[NBG*6] = 0.0f;
}

// ---------------------------------------------------------------------------
extern "C" void kernel_launch(void* const* d_in, const int* in_sizes, int n_in,
                              void* d_out, int out_size, void* d_ws, size_t ws_size,
                              hipStream_t stream)
{
  (void)in_sizes; (void)n_in; (void)out_size; (void)ws_size;
  const float* x   = (const float*)d_in[0];
  const int*   src = (const int*)d_in[1];
  const int*   dst = src + NEDGE;
  const float* w11=(const float*)d_in[3],  *b11=(const float*)d_in[4],  *g11=(const float*)d_in[5],  *be11=(const float*)d_in[6];
  const float* w12=(const float*)d_in[7],  *b12=(const float*)d_in[8],  *g12=(const float*)d_in[9],  *be12=(const float*)d_in[10];
  const float* w13=(const float*)d_in[11], *b13=(const float*)d_in[12], *g13=(const float*)d_in[13], *be13=(const float*)d_in[14];
  const float* w21=(const float*)d_in[15], *b21=(const float*)d_in[16], *g21=(const float*)d_in[17], *be21=(const float*)d_in[18];
  const float* w22=(const float*)d_in[19], *b22=(const float*)d_in[20], *g22=(const float*)d_in[21], *be22=(const float*)d_in[22];
  const float* w23=(const float*)d_in[23], *b23=(const float*)d_in[24], *g23=(const float*)d_in[25], *be23=(const float*)d_in[26];
  const float* betas=(const float*)d_in[27];
  const float* poolw=(const float*)d_in[28], *poolb=(const float*)d_in[29];
  const float* fc1w=(const float*)d_in[30], *fc1b=(const float*)d_in[31];
  const float* fc2w=(const float*)d_in[32], *fc2b=(const float*)d_in[33];
  float* out = (float*)d_out;

  uint8_t* basep = (uint8_t*)d_ws;
  size_t off = 0;
  auto take = [&](size_t bytes)->void*{
    void* p = basep + off;
    off = (off + bytes + 255) & ~(size_t)255;
    return p;
  };
  int* degi    = (int*)take((size_t)NN*4);
  int* dego    = (int*)take((size_t)NN*4);
  int* cntA    = (int*)take((size_t)NN*4);
  int* cntB    = (int*)take((size_t)NN*4);
  float* gS    = (float*)take(64*30*4);     // BN stat slots (zeroed by memset)
  float* gQ    = (float*)take(64*30*4);
  int* rp_in   = (int*)take((size_t)(NN+1)*4);
  int* rp_out  = (int*)take((size_t)(NN+1)*4);
  int* bsum    = (int*)take(512*4);
  int* col_in  = (int*)take((size_t)NEDGE*4);
  int* col_out = (int*)take((size_t)NEDGE*4);
  float* dinv  = (float*)take((size_t)NN*4);
  float* hbuf  = (float*)take((size_t)NN*30*4);
  float* X1    = (float*)take((size_t)NN*30*4);   // pre-BN y1
  float* X2    = (float*)take((size_t)NN*30*4);   // pre-BN y2
  float* X3    = (float*)take((size_t)NN*30*4);   // pre-BN y3
  float* bufA  = (float*)take((size_t)NN*126*4);
  float* bufB  = (float*)take((size_t)NN*126*4);
  float* logA  = (float*)take((size_t)NN*126*4);
  float* logB  = (float*)take((size_t)NN*126*4);
  float* partCS= (float*)take((size_t)6*256*64*4);
  float* fieldv= (float*)take(384*4);
  float* sfcAll= (float*)take(6*64*4);
  float* wfold = (float*)take(960*4);
  float* cvec  = (float*)take(32*4);
  float* px    = (float*)take(192000*4);
  float* An    = (float*)take(640000*4);
  float* h2    = (float*)take(192000*4);
  float* X21   = (float*)take(192000*4);  // pre-BN
  float* X22   = (float*)take(192000*4);
  float* X23   = (float*)take(192000*4);
  float* conv  = (float*)take(64*180*4);

  // post-BP scratch reuse: catT -> logA; split-K partials -> logB
  float* catT     = logA;
  float* pAdjPart = logB;               // 4*640000 floats
  float* pPxPart  = logB + 2560000;     // 4*192000 floats

  // ---- CSR + stat zero (degi..gQ contiguous -> single memset) ----
  hipMemsetAsync(degi, 0, (size_t)4*NN*4 + 2*64*30*4, stream);
  k_count<<<2048,256,0,stream>>>(src,dst,degi,dego);
  k_scan1<<<dim3(256,2),256,0,stream>>>(degi, dego, rp_in, rp_out, bsum);
  k_scan2<<<2,256,0,stream>>>(bsum);
  k_scan3<<<dim3(256,2),256,0,stream>>>(rp_in, rp_out, bsum);
  k_fill<<<dim3(2048,2),256,0,stream>>>(src, dst, rp_in, rp_out, cntA, cntB, col_in, col_out);
  k_sortrow<<<dim3(256,2),256,0,stream>>>(rp_in, rp_out, col_in, col_out, src, dst, degi, dinv);

  // ---- BP with stage-1 hidden as aux blocks ----
  k_bp_first<<<15872,256,0,stream>>>(bufA, logA, betas, x, w11, hbuf);  // + mm30<3>

  float* cur = bufA;  float* nxt = bufB;
  float* lcur = logA; float* lnxt = logB;
  for (int it=0; it<10; ++it){
    k_colsum_part<<<1536,64,0,stream>>>(cur, partCS);
    // field + optional bnw aux (iters 1,3,5)
    int fold = (it==1||it==3)? 1 : ((it==5)? 0 : -1);
    const float* gg = (it==1)? g11 : ((it==3)? g12 : g13);
    const float* bb = (it==1)? be11: ((it==3)? be12: be13);
    const float* wn = (it==1)? w12 : ((it==3)? w13 : nullptr);
    float* sfc = (it==1)? sfcAll : ((it==3)? sfcAll+64 : sfcAll+128);
    k_field<<<2,384,0,stream>>>(partCS, betas, fieldv, fold, gS, gQ, 65536.f,
                                gg, bb, wn, sfc, wfold, cvec);
    int fin = (it==9);
    int auxType = 0, auxN = 0;
    const float *aA=nullptr, *aB=nullptr, *aC=nullptr; float *aO=nullptr;
    if      (it==0){ auxType=1; auxN=3840; aA=hbuf; aB=b11; aO=X1; }
    else if (it==1){ auxType=2; auxN=7680; aA=X1; aB=wfold; aC=cvec; aO=hbuf; }
    else if (it==2){ auxType=1; auxN=3840; aA=hbuf; aB=b12; aO=X2; }
    else if (it==3){ auxType=2; auxN=7680; aA=X2; aB=wfold; aC=cvec; aO=hbuf; }
    else if (it==4){ auxType=1; auxN=3840; aA=hbuf; aB=b13; aO=X3; }
    else if (it==5){ auxType=3; auxN=192;  aA=X1; aB=X2; aC=X3; }
    k_bp_step<<<8192+auxN,256,0,stream>>>(nxt, lcur, lnxt, rp_in, col_in, fieldv, betas, fin,
        auxType, aA, aB, aC, aO, gS, gQ, dinv, sfcAll, conv);
    float* tp = cur;  cur = nxt;   nxt = tp;
    float* tl = lcur; lcur = lnxt; lnxt = tl;
  }
  // final concatenated psi [NN][126] now in bufA

  // ---- diff-pool ----
  k_catT<<<1024,256,0,stream>>>(bufA, catT);
  k_s1t<<<512,256,0,stream>>>(catT, poolw, poolb, bufB);
  k_T<<<6400,256,0,stream>>>(bufB, rp_out, col_out, bufA);
  k_p1ax<<<512,512,0,stream>>>(bufB, bufA, X3, sfcAll+128, pAdjPart, pPxPart);
  k_anpx<<<814,256,0,stream>>>(pAdjPart, pPxPart, An, px);

  // ---- stage 2: dense GCN x3 with folded BN ----
  k_mm30<30><<<750,256,0,stream>>>(px, w21, h2, NBG*100);
  k_y2<<<750,256,0,stream>>>(An, h2, b21, X21, gS, gQ);
  k_bnw<1><<<1,256,0,stream>>>(gS, gQ, 6400.f, g21, be21, w22, sfcAll+3*64, wfold, cvec);
  k_mm30c<<<750,256,0,stream>>>(X21, wfold, cvec, h2, NBG*100);
  k_y2<<<750,256,0,stream>>>(An, h2, b22, X22, gS, gQ);
  k_bnw<1><<<1,256,0,stream>>>(gS, gQ, 6400.f, g22, be22, w23, sfcAll+4*64, wfold, cvec);
  k_mm30c<<<750,256,0,stream>>>(X22, wfold, cvec, h2, NBG*100);
  k_y2<<<750,256,0,stream>>>(An, h2, b23, X23, gS, gQ);
  k_bnw<0><<<1,256,0,stream>>>(gS, gQ, 6400.f, g23, be23, nullptr, sfcAll+5*64, nullptr, nullptr);
  k_pool2<<<dim3(NBG,3),256,0,stream>>>(X21, X22, X23, sfcAll+3*64, 100, conv, 90);

  // ---- FC head ----
  k_fc<<<64,64,0,stream>>>(conv, fc1w, fc1b, fc2w, fc2b, out);
}